// Round 2
// baseline (6997.378 us; speedup 1.0000x reference)
//
#include <hip/hip_runtime.h>

static constexpr int PB  = 4;
static constexpr int PN  = 4096;
static constexpr int PK  = 20;
static constexpr int PNT = PB*PN*PK;   // 327680
#define NEGF (-3.402823466e38f)

__device__ __forceinline__ float lrelu_f(float x){ return x >= 0.f ? x : 0.2f*x; }

#define FMA4C(accv, av, bv) { accv = fmaf((av).x,(bv).x,accv); accv = fmaf((av).y,(bv).y,accv); \
                              accv = fmaf((av).z,(bv).z,accv); accv = fmaf((av).w,(bv).w,accv); }

// ---------------- xx (squared norms) ----------------
__global__ __launch_bounds__(256) void k_xx3(const float* __restrict__ x, float* __restrict__ xx){
  int i = blockIdx.x*256 + threadIdx.x;
  if(i >= PB*PN) return;
  int b = i >> 12, n = i & 4095;
  const float* xb = x + (size_t)b*3*PN;
  float a0 = xb[n], a1 = xb[PN+n], a2 = xb[2*PN+n];
  float t = a0*a0; t = fmaf(a1,a1,t); t = fmaf(a2,a2,t);
  xx[i] = t;
}

__global__ __launch_bounds__(256) void k_xx64(const float* __restrict__ f, float* __restrict__ xx){
  int i = blockIdx.x*256 + threadIdx.x;
  if(i >= PB*PN) return;
  const float4* p = (const float4*)(f + (size_t)i*64);
  float t = 0.f;
  #pragma unroll
  for(int c=0;c<16;c++){ float4 v = p[c];
    t = fmaf(v.x,v.x,t); t = fmaf(v.y,v.y,t); t = fmaf(v.z,v.z,t); t = fmaf(v.w,v.w,t); }
  xx[i] = t;
}

// ---------------- fused distance-GEMM + top-20 (min-heap) ----------------
__device__ __attribute__((noinline)) void heap_insert(volatile float* hv, volatile int* hi, float d, int j){
  if(!(d > hv[0])) return;               // strict > : lower index wins ties
  int p = 0;
  for(;;){
    int c1 = 2*p+1;
    if(c1 >= PK) break;
    float v1 = hv[c1]; int sel = c1;
    if(c1+1 < PK){ float v2 = hv[c1+1]; if(v2 < v1){ v1 = v2; sel = c1+1; } }
    if(!(v1 < d)) break;
    hv[p] = v1; hi[p] = hi[sel];
    p = sel;
  }
  hv[p] = d; hi[p] = j;
}

template<int C>
__global__ __launch_bounds__(256) void k_knn(const float* __restrict__ X,
                                             const float* __restrict__ xx,
                                             int* __restrict__ idx_out){
  extern __shared__ float sm[];
  const int XiF = (C==64) ? 64*64 : 64*4;
  const int XjF = (C==64) ? 256*64 : 256*4;
  float* Xi  = sm;
  float* Xj  = Xi + XiF;
  float* xxi = Xj + XjF;        // 64
  float* xxj = xxi + 64;        // 256
  float* hv  = xxj + 256;       // 64*PK
  int*   hi  = (int*)(hv + 64*PK);

  const int t    = threadIdx.x;
  const int b    = blockIdx.x >> 6;
  const int i0   = (blockIdx.x & 63) * 64;
  const int lane = t & 63;
  const int rg   = t >> 5;      // 8 row-groups of 8 rows
  const int cg   = t & 31;      // cols = cg + 32*cc

  if(C == 64){
    #pragma unroll
    for(int k=0;k<4;k++){
      int fid = t + k*256; int row = fid>>4, c4 = fid&15;
      float4 v = ((const float4*)(X + ((size_t)(b*PN + i0 + row))*64))[c4];
      ((float4*)Xi)[row*16 + (c4 ^ (row&15))] = v;
    }
    if(t < 64) xxi[t] = xx[b*PN + i0 + t];
  } else {
    if(t < 64){
      int n = i0 + t;
      const float* xb = X + (size_t)b*3*PN;
      Xi[t*4+0] = xb[n]; Xi[t*4+1] = xb[PN+n]; Xi[t*4+2] = xb[2*PN+n]; Xi[t*4+3] = 0.f;
      xxi[t] = xx[b*PN + n];
    }
  }
  for(int k=t; k<64*PK; k+=256){ hv[k] = NEGF; hi[k] = 0; }
  __syncthreads();

  volatile float* hvv = hv;
  volatile int*   hiv = hi;

  for(int jt=0; jt<PN/256; jt++){
    const int j0 = jt*256;
    if(C == 64){
      #pragma unroll
      for(int k=0;k<16;k++){
        int fid = t + k*256; int row = fid>>4, c4 = fid&15;
        float4 v = ((const float4*)(X + ((size_t)(b*PN + j0 + row))*64))[c4];
        ((float4*)Xj)[row*16 + (c4 ^ (row&15))] = v;
      }
      xxj[t] = xx[b*PN + j0 + t];
    } else {
      int n = j0 + t;
      const float* xb = X + (size_t)b*3*PN;
      Xj[t*4+0] = xb[n]; Xj[t*4+1] = xb[PN+n]; Xj[t*4+2] = xb[2*PN+n]; Xj[t*4+3] = 0.f;
      xxj[t] = xx[b*PN + n];
    }
    __syncthreads();

    float acc[8][8];
    #pragma unroll
    for(int rr=0;rr<8;rr++)
      #pragma unroll
      for(int cc=0;cc<8;cc++) acc[rr][cc] = 0.f;

    if(C == 64){
      #pragma unroll 4
      for(int c4=0;c4<16;c4++){
        float4 a[8], bb[8];
        #pragma unroll
        for(int rr=0;rr<8;rr++){ int row = rg*8+rr; a[rr] = ((const float4*)Xi)[row*16 + (c4^(row&15))]; }
        #pragma unroll
        for(int cc=0;cc<8;cc++){ int col = cg + 32*cc; bb[cc] = ((const float4*)Xj)[col*16 + (c4^(col&15))]; }
        #pragma unroll
        for(int rr=0;rr<8;rr++)
          #pragma unroll
          for(int cc=0;cc<8;cc++) FMA4C(acc[rr][cc], a[rr], bb[cc]);
      }
    } else {
      #pragma unroll
      for(int c=0;c<3;c++){
        float a[8], bb[8];
        #pragma unroll
        for(int rr=0;rr<8;rr++) a[rr] = Xi[(rg*8+rr)*4 + c];
        #pragma unroll
        for(int cc=0;cc<8;cc++) bb[cc] = Xj[(cg+32*cc)*4 + c];
        #pragma unroll
        for(int rr=0;rr<8;rr++)
          #pragma unroll
          for(int cc=0;cc<8;cc++) acc[rr][cc] = fmaf(a[rr], bb[cc], acc[rr][cc]);
      }
    }

    // neg_dist = 2*dot - xx_i - xx_j ; drain candidates into per-row heaps
    #pragma unroll
    for(int rr=0;rr<8;rr++){
      const int row = rg*8 + rr;
      const float xi2 = xxi[row];
      #pragma unroll
      for(int cc=0;cc<8;cc++)
        acc[rr][cc] = fmaf(2.f, acc[rr][cc], -xi2) - xxj[cg + 32*cc];
      float mx = acc[rr][0];
      #pragma unroll
      for(int cc=1;cc<8;cc++) mx = fmaxf(mx, acc[rr][cc]);
      unsigned long long am = __ballot(mx > hvv[row*PK]);
      if(am == 0ull) continue;
      #pragma unroll
      for(int cc=0;cc<8;cc++){
        float d = acc[rr][cc];
        unsigned long long mask = __ballot(d > hvv[row*PK]);
        while(mask){
          unsigned long long lo = mask & 0xffffffffull;
          unsigned long long hh = mask >> 32;
          int l0 = lo ? (__ffsll(lo)-1) : 64;
          int l1 = hh ? (__ffsll(hh)+31) : 64;
          if(lane == l0 || lane == l1)
            heap_insert(hvv + row*PK, hiv + row*PK, d, j0 + cg + 32*cc);
          unsigned long long clr = 0ull;
          if(l0 < 64) clr |= (1ull << l0);
          if(l1 < 64) clr |= (1ull << l1);
          mask &= ~clr;
        }
      }
    }
    __syncthreads();
  }
  for(int k=t; k<64*PK; k+=256){
    int row = k/PK, kk = k - row*PK;
    idx_out[((size_t)(b*PN + i0 + row))*PK + kk] = hi[k];
  }
}

// ---------------- conv1: gather(p) + 6->64 ----------------
__global__ __launch_bounds__(256) void k_conv1(const float* __restrict__ x, const int* __restrict__ idx,
                                               const float* __restrict__ w1, float* __restrict__ y){
  __shared__ float e[64][6];
  __shared__ float ww[384];
  int t = threadIdx.x;
  int q0 = blockIdx.x * 64;
  for(int k=t; k<384; k+=256) ww[k] = w1[k];   // FIX: full 384-element load
  if(t < 64){
    int q = q0 + t;
    int b = q / (PN*PK);
    int r = q - b*(PN*PK);
    int n = r / PK;
    int j = idx[q];
    const float* xb = x + (size_t)b*3*PN;
    float c0 = xb[n], c1 = xb[PN+n], c2 = xb[2*PN+n];
    float n0 = xb[j], n1 = xb[PN+j], n2 = xb[2*PN+j];
    e[t][0]=n0-c0; e[t][1]=n1-c1; e[t][2]=n2-c2;
    e[t][3]=c0;    e[t][4]=c1;    e[t][5]=c2;
  }
  __syncthreads();
  int p = t >> 2, oq = t & 3;
  float e0=e[p][0], e1=e[p][1], e2=e[p][2], e3=e[p][3], e4=e[p][4], e5=e[p][5];
  float* yr = y + (size_t)(q0+p)*64 + oq*16;
  #pragma unroll
  for(int m=0;m<16;m++){
    const float* wr = ww + (oq*16+m)*6;
    float s = e0*wr[0];
    s = fmaf(e1,wr[1],s); s = fmaf(e2,wr[2],s); s = fmaf(e3,wr[3],s);
    s = fmaf(e4,wr[4],s); s = fmaf(e5,wr[5],s);
    yr[m] = s;
  }
}

// ---------------- convA: in-place  y := W(64x64) . lrelu(bn(y)) ----------------
__global__ __launch_bounds__(256) void k_convA(const float* __restrict__ wg, const float* __restrict__ sb,
                                               float* __restrict__ y){
  __shared__ float hbuf[128*64];
  __shared__ float wbuf[64*64];
  int t = threadIdx.x;
  size_t q0 = (size_t)blockIdx.x * 128;
  #pragma unroll
  for(int k=0;k<8;k++){
    int fid = t + k*256; int row = fid>>4, c4 = fid&15;
    float4 v  = ((const float4*)(y + (q0+row)*64))[c4];
    float4 sc = ((const float4*)sb)[c4];
    float4 bi = ((const float4*)(sb+1024))[c4];
    v.x = lrelu_f(fmaf(v.x, sc.x, bi.x));
    v.y = lrelu_f(fmaf(v.y, sc.y, bi.y));
    v.z = lrelu_f(fmaf(v.z, sc.z, bi.z));
    v.w = lrelu_f(fmaf(v.w, sc.w, bi.w));
    ((float4*)hbuf)[row*16 + (c4 ^ (row&15))] = v;
  }
  #pragma unroll
  for(int k=0;k<4;k++){
    int fid = t + k*256; int row = fid>>4, c4 = fid&15;
    ((float4*)wbuf)[row*16 + (c4 ^ (row&15))] = ((const float4*)(wg + row*64))[c4];
  }
  __syncthreads();
  int prg = t >> 4, cq = t & 15;
  float acc[8][4];
  #pragma unroll
  for(int pp=0;pp<8;pp++)
    #pragma unroll
    for(int oc=0;oc<4;oc++) acc[pp][oc] = 0.f;
  #pragma unroll 4
  for(int c4=0;c4<16;c4++){
    float4 a[8], b4[4];
    #pragma unroll
    for(int pp=0;pp<8;pp++){ int row = prg*8+pp; a[pp] = ((const float4*)hbuf)[row*16 + (c4^(row&15))]; }
    #pragma unroll
    for(int oc=0;oc<4;oc++){ int och = cq + 16*oc; b4[oc] = ((const float4*)wbuf)[och*16 + (c4^(och&15))]; }
    #pragma unroll
    for(int pp=0;pp<8;pp++)
      #pragma unroll
      for(int oc=0;oc<4;oc++) FMA4C(acc[pp][oc], a[pp], b4[oc]);
  }
  #pragma unroll
  for(int pp=0;pp<8;pp++)
    #pragma unroll
    for(int oc=0;oc<4;oc++)
      y[(q0 + prg*8+pp)*64 + cq + 16*oc] = acc[pp][oc];
}

// ---------------- convG: gather edge-features (128) + W(64x128) ----------------
__global__ __launch_bounds__(256) void k_convG(const float* __restrict__ xf, const int* __restrict__ idx,
                                               const float* __restrict__ wg, float* __restrict__ y){
  extern __shared__ float sm[];
  float* ebuf = sm;             // 128*128
  float* wbuf = sm + 128*128;   // 64*128
  int t = threadIdx.x;
  size_t q0 = (size_t)blockIdx.x * 128;
  #pragma unroll
  for(int k=0;k<16;k++){
    int fid = t + k*256; int pair = fid>>5, c4 = fid&31;
    int q = (int)q0 + pair;
    int b = q / (PN*PK);
    int r = q - b*(PN*PK);
    int n = r / PK;
    float4 v;
    if(c4 < 16){
      int j = idx[q];
      float4 nb = ((const float4*)(xf + ((size_t)(b*PN + j))*64))[c4];
      float4 ct = ((const float4*)(xf + ((size_t)(b*PN + n))*64))[c4];
      v.x = nb.x-ct.x; v.y = nb.y-ct.y; v.z = nb.z-ct.z; v.w = nb.w-ct.w;
    } else {
      v = ((const float4*)(xf + ((size_t)(b*PN + n))*64))[c4-16];
    }
    ((float4*)ebuf)[pair*32 + (c4 ^ (pair&31))] = v;
  }
  #pragma unroll
  for(int k=0;k<8;k++){
    int fid = t + k*256; int row = fid>>5, c4 = fid&31;
    ((float4*)wbuf)[row*32 + (c4 ^ (row&31))] = ((const float4*)(wg + (size_t)row*128))[c4];
  }
  __syncthreads();
  int prg = t >> 4, cq = t & 15;
  float acc[8][4];
  #pragma unroll
  for(int pp=0;pp<8;pp++)
    #pragma unroll
    for(int oc=0;oc<4;oc++) acc[pp][oc] = 0.f;
  #pragma unroll 4
  for(int c4=0;c4<32;c4++){
    float4 a[8], b4[4];
    #pragma unroll
    for(int pp=0;pp<8;pp++){ int row = prg*8+pp; a[pp] = ((const float4*)ebuf)[row*32 + (c4^(row&31))]; }
    #pragma unroll
    for(int oc=0;oc<4;oc++){ int och = cq + 16*oc; b4[oc] = ((const float4*)wbuf)[och*32 + (c4^(och&31))]; }
    #pragma unroll
    for(int pp=0;pp<8;pp++)
      #pragma unroll
      for(int oc=0;oc<4;oc++) FMA4C(acc[pp][oc], a[pp], b4[oc]);
  }
  #pragma unroll
  for(int pp=0;pp<8;pp++)
    #pragma unroll
    for(int oc=0;oc<4;oc++)
      y[(q0 + prg*8+pp)*64 + cq + 16*oc] = acc[pp][oc];
}

// ---------------- BN statistics ----------------
__global__ __launch_bounds__(256) void k_red64(const float* __restrict__ y, float* __restrict__ part){
  __shared__ float ls[512];
  int t = threadIdx.x; int blk = blockIdx.x;
  int ch = t & 63, sub = t >> 6;
  const float* base = y + (size_t)blk*640*64;
  float s = 0.f, q = 0.f;
  for(int r=sub; r<640; r+=4){ float v = base[(size_t)r*64 + ch]; s += v; q = fmaf(v,v,q); }
  ls[t] = s; ls[256+t] = q;
  __syncthreads();
  if(t < 64){
    float S = ls[t]+ls[64+t]+ls[128+t]+ls[192+t];
    float Q = ls[256+t]+ls[320+t]+ls[384+t]+ls[448+t];
    part[(size_t)blk*128 + t] = S; part[(size_t)blk*128 + 64 + t] = Q;
  }
}

__global__ __launch_bounds__(256) void k_red1024(const float* __restrict__ y6, float* __restrict__ part){
  int t = threadIdx.x; int blk = blockIdx.x;   // 128 blocks x 128 rows
  const float4* base = (const float4*)(y6 + (size_t)blk*128*1024);
  float4 s = make_float4(0,0,0,0), q = make_float4(0,0,0,0);
  for(int r=0;r<128;r++){
    float4 v = base[r*256 + t];
    s.x += v.x; s.y += v.y; s.z += v.z; s.w += v.w;
    q.x = fmaf(v.x,v.x,q.x); q.y = fmaf(v.y,v.y,q.y); q.z = fmaf(v.z,v.z,q.z); q.w = fmaf(v.w,v.w,q.w);
  }
  ((float4*)(part + (size_t)blk*2048))[t] = s;
  ((float4*)(part + (size_t)blk*2048 + 1024))[t] = q;
}

__global__ void k_fin(const float* __restrict__ part, int nparts, int chn, float cnt,
                      const float* __restrict__ gamma, const float* __restrict__ beta,
                      float* __restrict__ sb){
  int ch = blockIdx.x*256 + threadIdx.x;
  if(ch >= chn) return;
  float S = 0.f, Q = 0.f;
  for(int p=0;p<nparts;p++){ S += part[(size_t)p*2*chn + ch]; Q += part[(size_t)p*2*chn + chn + ch]; }
  float m  = S/cnt;
  float vr = Q/cnt - m*m;
  float sc = gamma[ch] * rsqrtf(vr + 1e-5f);
  sb[ch] = sc; sb[1024+ch] = beta[ch] - m*sc;
}

// ---------------- finish: x = max_k lrelu(bn(y)) ----------------
__global__ __launch_bounds__(256) void k_finish(const float* __restrict__ y, const float* __restrict__ sb,
                                                float* __restrict__ xo){
  int t = threadIdx.x;
  int pt = blockIdx.x*16 + (t>>4), c4 = t&15;
  const float4* base = (const float4*)(y + (size_t)pt*20*64);
  float4 sc = ((const float4*)sb)[c4];
  float4 bi = ((const float4*)(sb+1024))[c4];
  float4 m = make_float4(NEGF,NEGF,NEGF,NEGF);
  #pragma unroll 4
  for(int k=0;k<20;k++){
    float4 v = base[k*16 + c4];
    v.x = lrelu_f(fmaf(v.x, sc.x, bi.x)); v.y = lrelu_f(fmaf(v.y, sc.y, bi.y));
    v.z = lrelu_f(fmaf(v.z, sc.z, bi.z)); v.w = lrelu_f(fmaf(v.w, sc.w, bi.w));
    m.x = fmaxf(m.x,v.x); m.y = fmaxf(m.y,v.y); m.z = fmaxf(m.z,v.z); m.w = fmaxf(m.w,v.w);
  }
  ((float4*)(xo + (size_t)pt*64))[c4] = m;
}

// ---------------- head GEMM: cat(x1,x2,x3) @ w6^T ----------------
__global__ __launch_bounds__(256) void k_gemm6(const float* __restrict__ x1, const float* __restrict__ x2,
                                               const float* __restrict__ x3, const float* __restrict__ w6,
                                               float* __restrict__ y6){
  __shared__ float cb[128*64];
  __shared__ float wb[64*64];
  int t = threadIdx.x;
  int rb = blockIdx.x >> 4;
  int ob = blockIdx.x & 15;
  size_t r0 = (size_t)rb*128; int o0 = ob*64;
  int prg = t >> 4, cq = t & 15;
  float acc[8][4];
  #pragma unroll
  for(int pp=0;pp<8;pp++)
    #pragma unroll
    for(int oc=0;oc<4;oc++) acc[pp][oc] = 0.f;
  const float* srcs[3] = {x1, x2, x3};
  for(int ph=0; ph<3; ph++){
    __syncthreads();
    const float* src = srcs[ph];
    #pragma unroll
    for(int k=0;k<8;k++){
      int fid = t + k*256; int row = fid>>4, c4 = fid&15;
      ((float4*)cb)[row*16 + (c4^(row&15))] = ((const float4*)(src + (r0+row)*64))[c4];
    }
    #pragma unroll
    for(int k=0;k<4;k++){
      int fid = t + k*256; int row = fid>>4, c4 = fid&15;
      ((float4*)wb)[row*16 + (c4^(row&15))] = ((const float4*)(w6 + (size_t)(o0+row)*192 + ph*64))[c4];
    }
    __syncthreads();
    #pragma unroll 4
    for(int c4=0;c4<16;c4++){
      float4 a[8], b4[4];
      #pragma unroll
      for(int pp=0;pp<8;pp++){ int row = prg*8+pp; a[pp] = ((const float4*)cb)[row*16 + (c4^(row&15))]; }
      #pragma unroll
      for(int oc=0;oc<4;oc++){ int och = cq + 16*oc; b4[oc] = ((const float4*)wb)[och*16 + (c4^(och&15))]; }
      #pragma unroll
      for(int pp=0;pp<8;pp++)
        #pragma unroll
        for(int oc=0;oc<4;oc++) FMA4C(acc[pp][oc], a[pp], b4[oc]);
    }
  }
  #pragma unroll
  for(int pp=0;pp<8;pp++)
    #pragma unroll
    for(int oc=0;oc<4;oc++)
      y6[(r0 + prg*8+pp)*1024 + o0 + cq + 16*oc] = acc[pp][oc];
}

// ---------------- global max over n (bn6+lrelu applied) ----------------
__global__ __launch_bounds__(256) void k_gmax(const float* __restrict__ y6, const float* __restrict__ sb,
                                              float* __restrict__ gpart){
  int t = threadIdx.x; int blk = blockIdx.x;   // 64 blocks x 256 rows
  const float4* base = (const float4*)(y6 + (size_t)blk*256*1024);
  float4 sc = ((const float4*)sb)[t];
  float4 bi = ((const float4*)(sb+1024))[t];
  float4 m = make_float4(NEGF,NEGF,NEGF,NEGF);
  for(int r=0;r<256;r++){
    float4 v = base[r*256 + t];
    v.x = lrelu_f(fmaf(v.x, sc.x, bi.x)); v.y = lrelu_f(fmaf(v.y, sc.y, bi.y));
    v.z = lrelu_f(fmaf(v.z, sc.z, bi.z)); v.w = lrelu_f(fmaf(v.w, sc.w, bi.w));
    m.x = fmaxf(m.x,v.x); m.y = fmaxf(m.y,v.y); m.z = fmaxf(m.z,v.z); m.w = fmaxf(m.w,v.w);
  }
  ((float4*)(gpart + (size_t)blk*1024))[t] = m;
}

__global__ __launch_bounds__(256) void k_gmaxfin(const float* __restrict__ gpart, float* __restrict__ g){
  int b = blockIdx.x, t = threadIdx.x;
  float4 m = make_float4(NEGF,NEGF,NEGF,NEGF);
  for(int c=0;c<16;c++){
    float4 v = ((const float4*)(gpart + ((size_t)b*16 + c)*1024))[t];
    m.x = fmaxf(m.x,v.x); m.y = fmaxf(m.y,v.y); m.z = fmaxf(m.z,v.z); m.w = fmaxf(m.w,v.w);
  }
  ((float4*)(g + (size_t)b*1024))[t] = m;
}

// ---------------- final: bn(g @ wl^T, axis 0) ----------------
__global__ __launch_bounds__(256) void k_final(const float* __restrict__ g, const float* __restrict__ wl,
                                               const float* __restrict__ g7, const float* __restrict__ b7,
                                               float* __restrict__ out){
  int gt = blockIdx.x*256 + threadIdx.x;   // 2048 = 512 o x 4 b
  int o = gt >> 2, b = gt & 3;
  const float4* gb = (const float4*)(g + (size_t)b*1024);
  const float4* wr = (const float4*)(wl + (size_t)o*1024);
  float acc = 0.f;
  #pragma unroll 4
  for(int c=0;c<256;c++){
    float4 a = gb[c], w = wr[c];
    acc = fmaf(a.x,w.x,acc); acc = fmaf(a.y,w.y,acc);
    acc = fmaf(a.z,w.z,acc); acc = fmaf(a.w,w.w,acc);
  }
  float s = acc + __shfl_xor(acc, 1);
  s = s + __shfl_xor(s, 2);
  float m = s * 0.25f;
  float d = acc - m;
  float vv = d*d;
  float v2 = vv + __shfl_xor(vv, 1);
  v2 = v2 + __shfl_xor(v2, 2);
  float var = v2 * 0.25f;
  out[b*512 + o] = d * rsqrtf(var + 1e-5f) * g7[o] + b7[o];
}

// ---------------- launch ----------------
extern "C" void kernel_launch(void* const* d_in, const int* in_sizes, int n_in,
                              void* d_out, int out_size, void* d_ws, size_t ws_size,
                              hipStream_t stream){
  const float* x  = (const float*)d_in[0];
  const float* w1 = (const float*)d_in[1];
  const float* w2 = (const float*)d_in[2];
  const float* w3 = (const float*)d_in[3];
  const float* w4 = (const float*)d_in[4];
  const float* w5 = (const float*)d_in[5];
  const float* w6 = (const float*)d_in[6];
  const float* wl = (const float*)d_in[7];
  const float* g1 = (const float*)d_in[8];  const float* b1 = (const float*)d_in[9];
  const float* g2 = (const float*)d_in[10]; const float* b2 = (const float*)d_in[11];
  const float* g3 = (const float*)d_in[12]; const float* b3 = (const float*)d_in[13];
  const float* g4 = (const float*)d_in[14]; const float* b4 = (const float*)d_in[15];
  const float* g5 = (const float*)d_in[16]; const float* b5 = (const float*)d_in[17];
  const float* g6 = (const float*)d_in[18]; const float* b6 = (const float*)d_in[19];
  const float* g7 = (const float*)d_in[20]; const float* b7 = (const float*)d_in[21];
  float* out = (float*)d_out;

  // workspace layout (floats); total ~99.2 MB
  float* ws    = (float*)d_ws;
  float* xx    = ws;                        // 16384
  int*   idx   = (int*)(ws + 16384);        // 327680
  float* y     = ws + 344064;               // 20971520 (reused y1..y5, y6)
  float* x1    = ws + 21315584;             // 1048576
  float* x2    = x1 + 1048576;
  float* x3    = x2 + 1048576;
  float* part  = x3 + 1048576;              // 262144
  float* sb    = part + 262144;             // 2048
  float* gpart = sb + 2048;                 // 65536
  float* g     = gpart + 65536;             // 4096

  hipFuncSetAttribute(reinterpret_cast<const void*>(&k_knn<64>),
                      hipFuncAttributeMaxDynamicSharedMemorySize, 93440);
  hipFuncSetAttribute(reinterpret_cast<const void*>(&k_convG),
                      hipFuncAttributeMaxDynamicSharedMemorySize, 98304);

  // ---- stage 1 (C=3 graph, conv1 6->64, conv2 64->64, max_k -> x1) ----
  k_xx3<<<64,256,0,stream>>>(x, xx);
  k_knn<3><<<256,256,16640,stream>>>(x, xx, idx);
  k_conv1<<<5120,256,0,stream>>>(x, idx, w1, y);
  k_red64<<<512,256,0,stream>>>(y, part);
  k_fin<<<1,256,0,stream>>>(part, 512, 64, (float)PNT, g1, b1, sb);
  k_convA<<<2560,256,0,stream>>>(w2, sb, y);
  k_red64<<<512,256,0,stream>>>(y, part);
  k_fin<<<1,256,0,stream>>>(part, 512, 64, (float)PNT, g2, b2, sb);
  k_finish<<<1024,256,0,stream>>>(y, sb, x1);

  // ---- stage 2 (C=64 graph on x1, conv3 128->64, conv4 64->64, max_k -> x2) ----
  k_xx64<<<64,256,0,stream>>>(x1, xx);
  k_knn<64><<<256,256,93440,stream>>>(x1, xx, idx);
  k_convG<<<2560,256,98304,stream>>>(x1, idx, w3, y);
  k_red64<<<512,256,0,stream>>>(y, part);
  k_fin<<<1,256,0,stream>>>(part, 512, 64, (float)PNT, g3, b3, sb);
  k_convA<<<2560,256,0,stream>>>(w4, sb, y);
  k_red64<<<512,256,0,stream>>>(y, part);
  k_fin<<<1,256,0,stream>>>(part, 512, 64, (float)PNT, g4, b4, sb);
  k_finish<<<1024,256,0,stream>>>(y, sb, x2);

  // ---- stage 3 (C=64 graph on x2, conv5 128->64, max_k -> x3) ----
  k_xx64<<<64,256,0,stream>>>(x2, xx);
  k_knn<64><<<256,256,93440,stream>>>(x2, xx, idx);
  k_convG<<<2560,256,98304,stream>>>(x2, idx, w5, y);
  k_red64<<<512,256,0,stream>>>(y, part);
  k_fin<<<1,256,0,stream>>>(part, 512, 64, (float)PNT, g5, b5, sb);
  k_finish<<<1024,256,0,stream>>>(y, sb, x3);

  // ---- head ----
  k_gemm6<<<2048,256,0,stream>>>(x1, x2, x3, w6, y);
  k_red1024<<<128,256,0,stream>>>(y, part);
  k_fin<<<4,256,0,stream>>>(part, 128, 1024, 16384.f, g6, b6, sb);
  k_gmax<<<64,256,0,stream>>>(y, sb, gpart);
  k_gmaxfin<<<4,256,0,stream>>>(gpart, g);
  k_final<<<8,256,0,stream>>>(g, wl, g7, b7, out);
}

// Round 3
// 2661.574 us; speedup vs baseline: 2.6290x; 2.6290x over previous
//
#include <hip/hip_runtime.h>

static constexpr int PB  = 4;
static constexpr int PN  = 4096;
static constexpr int PK  = 20;
static constexpr int PNT = PB*PN*PK;   // 327680
#define NEGF (-3.402823466e38f)

__device__ __forceinline__ float lrelu_f(float x){ return x >= 0.f ? x : 0.2f*x; }

#define FMA4C(accv, av, bv) { accv = fmaf((av).x,(bv).x,accv); accv = fmaf((av).y,(bv).y,accv); \
                              accv = fmaf((av).z,(bv).z,accv); accv = fmaf((av).w,(bv).w,accv); }

// ---------------- xx (squared norms) ----------------
__global__ __launch_bounds__(256) void k_xx3(const float* __restrict__ x, float* __restrict__ xx){
  int i = blockIdx.x*256 + threadIdx.x;
  if(i >= PB*PN) return;
  int b = i >> 12, n = i & 4095;
  const float* xb = x + (size_t)b*3*PN;
  float a0 = xb[n], a1 = xb[PN+n], a2 = xb[2*PN+n];
  float t = a0*a0; t = fmaf(a1,a1,t); t = fmaf(a2,a2,t);
  xx[i] = t;
}

__global__ __launch_bounds__(256) void k_xx64(const float* __restrict__ f, float* __restrict__ xx){
  int i = blockIdx.x*256 + threadIdx.x;
  if(i >= PB*PN) return;
  const float4* p = (const float4*)(f + (size_t)i*64);
  float t = 0.f;
  #pragma unroll
  for(int c=0;c<16;c++){ float4 v = p[c];
    t = fmaf(v.x,v.x,t); t = fmaf(v.y,v.y,t); t = fmaf(v.z,v.z,t); t = fmaf(v.w,v.w,t); }
  xx[i] = t;
}

// ---------------- dist: materialize neg_dist for one batch ----------------
// C=3: direct elementwise. 128x128 tile per block, 8x8 per thread.
__global__ __launch_bounds__(256) void k_dist3(const float* __restrict__ xb, const float* __restrict__ xxb,
                                               float* __restrict__ D){
  __shared__ float Pi[3][128], Pj[3][128], xxi[128], xxj[128];
  int t = threadIdx.x;
  int bi = blockIdx.x >> 5, bj = blockIdx.x & 31;
  int i0 = bi*128, j0 = bj*128;
  if(t < 128){
    Pi[0][t]=xb[i0+t]; Pi[1][t]=xb[PN+i0+t]; Pi[2][t]=xb[2*PN+i0+t]; xxi[t]=xxb[i0+t];
  } else {
    int u=t-128;
    Pj[0][u]=xb[j0+u]; Pj[1][u]=xb[PN+j0+u]; Pj[2][u]=xb[2*PN+j0+u]; xxj[u]=xxb[j0+u];
  }
  __syncthreads();
  int prg = t>>4, cq = t&15;
  #pragma unroll
  for(int pp=0;pp<8;pp++){
    int r = prg*8+pp;
    float a0=Pi[0][r], a1=Pi[1][r], a2=Pi[2][r], xi2=xxi[r];
    float* Drow = D + (size_t)(i0+r)*PN + j0;
    #pragma unroll
    for(int oc=0;oc<8;oc++){
      int c = cq + 16*oc;
      float dot = a0*Pj[0][c];
      dot = fmaf(a1, Pj[1][c], dot);
      dot = fmaf(a2, Pj[2][c], dot);
      Drow[c] = fmaf(2.f, dot, -xi2) - xxj[c];
    }
  }
}

// C=64: tiled GEMM. 128x128 tile, K=64, 8x8 acc per thread.
__global__ __launch_bounds__(256) void k_dist64(const float* __restrict__ Xb, const float* __restrict__ xxb,
                                                float* __restrict__ D){
  extern __shared__ float sm[];
  float* Xi  = sm;            // 128*64
  float* Xj  = Xi + 128*64;   // 128*64
  float* xxi = Xj + 128*64;   // 128
  float* xxj = xxi + 128;     // 128
  int t = threadIdx.x;
  int bi = blockIdx.x >> 5, bj = blockIdx.x & 31;
  int i0 = bi*128, j0 = bj*128;
  #pragma unroll
  for(int k=0;k<8;k++){
    int fid = t + k*256; int row = fid>>4, c4 = fid&15;
    ((float4*)Xi)[row*16 + (c4^(row&15))] = ((const float4*)(Xb + (size_t)(i0+row)*64))[c4];
    ((float4*)Xj)[row*16 + (c4^(row&15))] = ((const float4*)(Xb + (size_t)(j0+row)*64))[c4];
  }
  if(t < 128) xxi[t] = xxb[i0+t];
  else        xxj[t-128] = xxb[j0+t-128];
  __syncthreads();
  int prg = t>>4, cq = t&15;
  float acc[8][8];
  #pragma unroll
  for(int pp=0;pp<8;pp++)
    #pragma unroll
    for(int oc=0;oc<8;oc++) acc[pp][oc] = 0.f;
  #pragma unroll 4
  for(int c4=0;c4<16;c4++){
    float4 a[8], bb[8];
    #pragma unroll
    for(int pp=0;pp<8;pp++){ int row = prg*8+pp; a[pp] = ((const float4*)Xi)[row*16 + (c4^(row&15))]; }
    #pragma unroll
    for(int oc=0;oc<8;oc++){ int col = cq+16*oc;  bb[oc] = ((const float4*)Xj)[col*16 + (c4^(col&15))]; }
    #pragma unroll
    for(int pp=0;pp<8;pp++)
      #pragma unroll
      for(int oc=0;oc<8;oc++) FMA4C(acc[pp][oc], a[pp], bb[oc]);
  }
  #pragma unroll
  for(int pp=0;pp<8;pp++){
    int r = prg*8+pp;
    float xi2 = xxi[r];
    float* Drow = D + (size_t)(i0+r)*PN + j0;
    #pragma unroll
    for(int oc=0;oc<8;oc++){
      int c = cq + 16*oc;
      Drow[c] = fmaf(2.f, acc[pp][oc], -xi2) - xxj[c];
    }
  }
}

// ---------------- top-20 per row: one wave per row ----------------
__global__ __launch_bounds__(256) void k_topk(const float* __restrict__ D, int* __restrict__ idxb){
  int t = threadIdx.x, lane = t & 63, w = t >> 6;
  int row = blockIdx.x*4 + w;
  const float4* rp = (const float4*)(D + (size_t)row*PN + lane*64);
  float v[64];
  #pragma unroll
  for(int c=0;c<16;c++){
    float4 q = rp[c];
    v[4*c+0]=q.x; v[4*c+1]=q.y; v[4*c+2]=q.z; v[4*c+3]=q.w;
  }
  float lmax = NEGF; int li = 0;
  #pragma unroll
  for(int e=0;e<64;e++){
    bool better = v[e] > lmax;
    li = better ? e : li; lmax = better ? v[e] : lmax;
  }
  unsigned long long removed = 0ull;
  int myidx = 0;
  for(int k=0;k<PK;k++){
    float g = lmax;
    #pragma unroll
    for(int s=32;s>=1;s>>=1) g = fmaxf(g, __shfl_xor(g, s));
    unsigned long long mask = __ballot(lmax == g);
    int wl = __ffsll((unsigned long long)mask) - 1;
    int rel = __shfl(li, wl);
    if(lane == k) myidx = wl*64 + rel;
    if(lane == wl){
      removed |= (1ull << rel);
      lmax = NEGF; li = 0;
      #pragma unroll
      for(int e=0;e<64;e++){
        bool ok = ((removed >> e) & 1ull) == 0ull;
        bool better = ok && (v[e] > lmax);
        li = better ? e : li; lmax = better ? v[e] : lmax;
      }
    }
  }
  if(lane < PK) idxb[row*PK + lane] = myidx;
}

// ---------------- conv1: gather(p) + 6->64 ----------------
__global__ __launch_bounds__(256) void k_conv1(const float* __restrict__ x, const int* __restrict__ idx,
                                               const float* __restrict__ w1, float* __restrict__ y){
  __shared__ float e[64][6];
  __shared__ float ww[384];
  int t = threadIdx.x;
  int q0 = blockIdx.x * 64;
  for(int k=t; k<384; k+=256) ww[k] = w1[k];
  if(t < 64){
    int q = q0 + t;
    int b = q / (PN*PK);
    int r = q - b*(PN*PK);
    int n = r / PK;
    int j = idx[q];
    const float* xb = x + (size_t)b*3*PN;
    float c0 = xb[n], c1 = xb[PN+n], c2 = xb[2*PN+n];
    float n0 = xb[j], n1 = xb[PN+j], n2 = xb[2*PN+j];
    e[t][0]=n0-c0; e[t][1]=n1-c1; e[t][2]=n2-c2;
    e[t][3]=c0;    e[t][4]=c1;    e[t][5]=c2;
  }
  __syncthreads();
  int p = t >> 2, oq = t & 3;
  float e0=e[p][0], e1=e[p][1], e2=e[p][2], e3=e[p][3], e4=e[p][4], e5=e[p][5];
  float* yr = y + (size_t)(q0+p)*64 + oq*16;
  #pragma unroll
  for(int m=0;m<16;m++){
    const float* wr = ww + (oq*16+m)*6;
    float s = e0*wr[0];
    s = fmaf(e1,wr[1],s); s = fmaf(e2,wr[2],s); s = fmaf(e3,wr[3],s);
    s = fmaf(e4,wr[4],s); s = fmaf(e5,wr[5],s);
    yr[m] = s;
  }
}

// ---------------- convA: in-place  y := W(64x64) . lrelu(bn(y)) ----------------
__global__ __launch_bounds__(256) void k_convA(const float* __restrict__ wg, const float* __restrict__ sb,
                                               float* __restrict__ y){
  __shared__ float hbuf[128*64];
  __shared__ float wbuf[64*64];
  int t = threadIdx.x;
  size_t q0 = (size_t)blockIdx.x * 128;
  #pragma unroll
  for(int k=0;k<8;k++){
    int fid = t + k*256; int row = fid>>4, c4 = fid&15;
    float4 v  = ((const float4*)(y + (q0+row)*64))[c4];
    float4 sc = ((const float4*)sb)[c4];
    float4 bi = ((const float4*)(sb+1024))[c4];
    v.x = lrelu_f(fmaf(v.x, sc.x, bi.x));
    v.y = lrelu_f(fmaf(v.y, sc.y, bi.y));
    v.z = lrelu_f(fmaf(v.z, sc.z, bi.z));
    v.w = lrelu_f(fmaf(v.w, sc.w, bi.w));
    ((float4*)hbuf)[row*16 + (c4 ^ (row&15))] = v;
  }
  #pragma unroll
  for(int k=0;k<4;k++){
    int fid = t + k*256; int row = fid>>4, c4 = fid&15;
    ((float4*)wbuf)[row*16 + (c4 ^ (row&15))] = ((const float4*)(wg + row*64))[c4];
  }
  __syncthreads();
  int prg = t >> 4, cq = t & 15;
  float acc[8][4];
  #pragma unroll
  for(int pp=0;pp<8;pp++)
    #pragma unroll
    for(int oc=0;oc<4;oc++) acc[pp][oc] = 0.f;
  #pragma unroll 4
  for(int c4=0;c4<16;c4++){
    float4 a[8], b4[4];
    #pragma unroll
    for(int pp=0;pp<8;pp++){ int row = prg*8+pp; a[pp] = ((const float4*)hbuf)[row*16 + (c4^(row&15))]; }
    #pragma unroll
    for(int oc=0;oc<4;oc++){ int och = cq + 16*oc; b4[oc] = ((const float4*)wbuf)[och*16 + (c4^(och&15))]; }
    #pragma unroll
    for(int pp=0;pp<8;pp++)
      #pragma unroll
      for(int oc=0;oc<4;oc++) FMA4C(acc[pp][oc], a[pp], b4[oc]);
  }
  #pragma unroll
  for(int pp=0;pp<8;pp++)
    #pragma unroll
    for(int oc=0;oc<4;oc++)
      y[(q0 + prg*8+pp)*64 + cq + 16*oc] = acc[pp][oc];
}

// ---------------- convG: gather edge-features (128) + W(64x128) ----------------
__global__ __launch_bounds__(256) void k_convG(const float* __restrict__ xf, const int* __restrict__ idx,
                                               const float* __restrict__ wg, float* __restrict__ y){
  extern __shared__ float sm[];
  float* ebuf = sm;             // 128*128
  float* wbuf = sm + 128*128;   // 64*128
  int t = threadIdx.x;
  size_t q0 = (size_t)blockIdx.x * 128;
  #pragma unroll
  for(int k=0;k<16;k++){
    int fid = t + k*256; int pair = fid>>5, c4 = fid&31;
    int q = (int)q0 + pair;
    int b = q / (PN*PK);
    int r = q - b*(PN*PK);
    int n = r / PK;
    float4 v;
    if(c4 < 16){
      int j = idx[q];
      float4 nb = ((const float4*)(xf + ((size_t)(b*PN + j))*64))[c4];
      float4 ct = ((const float4*)(xf + ((size_t)(b*PN + n))*64))[c4];
      v.x = nb.x-ct.x; v.y = nb.y-ct.y; v.z = nb.z-ct.z; v.w = nb.w-ct.w;
    } else {
      v = ((const float4*)(xf + ((size_t)(b*PN + n))*64))[c4-16];
    }
    ((float4*)ebuf)[pair*32 + (c4 ^ (pair&31))] = v;
  }
  #pragma unroll
  for(int k=0;k<8;k++){
    int fid = t + k*256; int row = fid>>5, c4 = fid&31;
    ((float4*)wbuf)[row*32 + (c4 ^ (row&31))] = ((const float4*)(wg + (size_t)row*128))[c4];
  }
  __syncthreads();
  int prg = t >> 4, cq = t & 15;
  float acc[8][4];
  #pragma unroll
  for(int pp=0;pp<8;pp++)
    #pragma unroll
    for(int oc=0;oc<4;oc++) acc[pp][oc] = 0.f;
  #pragma unroll 4
  for(int c4=0;c4<32;c4++){
    float4 a[8], b4[4];
    #pragma unroll
    for(int pp=0;pp<8;pp++){ int row = prg*8+pp; a[pp] = ((const float4*)ebuf)[row*32 + (c4^(row&31))]; }
    #pragma unroll
    for(int oc=0;oc<4;oc++){ int och = cq + 16*oc; b4[oc] = ((const float4*)wbuf)[och*32 + (c4^(och&31))]; }
    #pragma unroll
    for(int pp=0;pp<8;pp++)
      #pragma unroll
      for(int oc=0;oc<4;oc++) FMA4C(acc[pp][oc], a[pp], b4[oc]);
  }
  #pragma unroll
  for(int pp=0;pp<8;pp++)
    #pragma unroll
    for(int oc=0;oc<4;oc++)
      y[(q0 + prg*8+pp)*64 + cq + 16*oc] = acc[pp][oc];
}

// ---------------- BN statistics ----------------
__global__ __launch_bounds__(256) void k_red64(const float* __restrict__ y, float* __restrict__ part){
  __shared__ float ls[512];
  int t = threadIdx.x; int blk = blockIdx.x;
  int ch = t & 63, sub = t >> 6;
  const float* base = y + (size_t)blk*640*64;
  float s = 0.f, q = 0.f;
  for(int r=sub; r<640; r+=4){ float v = base[(size_t)r*64 + ch]; s += v; q = fmaf(v,v,q); }
  ls[t] = s; ls[256+t] = q;
  __syncthreads();
  if(t < 64){
    float S = ls[t]+ls[64+t]+ls[128+t]+ls[192+t];
    float Q = ls[256+t]+ls[320+t]+ls[384+t]+ls[448+t];
    part[(size_t)blk*128 + t] = S; part[(size_t)blk*128 + 64 + t] = Q;
  }
}

__global__ __launch_bounds__(256) void k_red1024(const float* __restrict__ y6, float* __restrict__ part){
  int t = threadIdx.x; int blk = blockIdx.x;   // 128 blocks x 128 rows
  const float4* base = (const float4*)(y6 + (size_t)blk*128*1024);
  float4 s = make_float4(0,0,0,0), q = make_float4(0,0,0,0);
  for(int r=0;r<128;r++){
    float4 v = base[r*256 + t];
    s.x += v.x; s.y += v.y; s.z += v.z; s.w += v.w;
    q.x = fmaf(v.x,v.x,q.x); q.y = fmaf(v.y,v.y,q.y); q.z = fmaf(v.z,v.z,q.z); q.w = fmaf(v.w,v.w,q.w);
  }
  ((float4*)(part + (size_t)blk*2048))[t] = s;
  ((float4*)(part + (size_t)blk*2048 + 1024))[t] = q;
}

__global__ void k_fin(const float* __restrict__ part, int nparts, int chn, float cnt,
                      const float* __restrict__ gamma, const float* __restrict__ beta,
                      float* __restrict__ sb){
  int ch = blockIdx.x*256 + threadIdx.x;
  if(ch >= chn) return;
  float S = 0.f, Q = 0.f;
  for(int p=0;p<nparts;p++){ S += part[(size_t)p*2*chn + ch]; Q += part[(size_t)p*2*chn + chn + ch]; }
  float m  = S/cnt;
  float vr = Q/cnt - m*m;
  float sc = gamma[ch] * rsqrtf(vr + 1e-5f);
  sb[ch] = sc; sb[1024+ch] = beta[ch] - m*sc;
}

// ---------------- finish: x = max_k lrelu(bn(y)) ----------------
__global__ __launch_bounds__(256) void k_finish(const float* __restrict__ y, const float* __restrict__ sb,
                                                float* __restrict__ xo){
  int t = threadIdx.x;
  int pt = blockIdx.x*16 + (t>>4), c4 = t&15;
  const float4* base = (const float4*)(y + (size_t)pt*20*64);
  float4 sc = ((const float4*)sb)[c4];
  float4 bi = ((const float4*)(sb+1024))[c4];
  float4 m = make_float4(NEGF,NEGF,NEGF,NEGF);
  #pragma unroll 4
  for(int k=0;k<20;k++){
    float4 v = base[k*16 + c4];
    v.x = lrelu_f(fmaf(v.x, sc.x, bi.x)); v.y = lrelu_f(fmaf(v.y, sc.y, bi.y));
    v.z = lrelu_f(fmaf(v.z, sc.z, bi.z)); v.w = lrelu_f(fmaf(v.w, sc.w, bi.w));
    m.x = fmaxf(m.x,v.x); m.y = fmaxf(m.y,v.y); m.z = fmaxf(m.z,v.z); m.w = fmaxf(m.w,v.w);
  }
  ((float4*)(xo + (size_t)pt*64))[c4] = m;
}

// ---------------- head GEMM: cat(x1,x2,x3) @ w6^T ----------------
__global__ __launch_bounds__(256) void k_gemm6(const float* __restrict__ x1, const float* __restrict__ x2,
                                               const float* __restrict__ x3, const float* __restrict__ w6,
                                               float* __restrict__ y6){
  __shared__ float cb[128*64];
  __shared__ float wb[64*64];
  int t = threadIdx.x;
  int rb = blockIdx.x >> 4;
  int ob = blockIdx.x & 15;
  size_t r0 = (size_t)rb*128; int o0 = ob*64;
  int prg = t >> 4, cq = t & 15;
  float acc[8][4];
  #pragma unroll
  for(int pp=0;pp<8;pp++)
    #pragma unroll
    for(int oc=0;oc<4;oc++) acc[pp][oc] = 0.f;
  const float* srcs[3] = {x1, x2, x3};
  for(int ph=0; ph<3; ph++){
    __syncthreads();
    const float* src = srcs[ph];
    #pragma unroll
    for(int k=0;k<8;k++){
      int fid = t + k*256; int row = fid>>4, c4 = fid&15;
      ((float4*)cb)[row*16 + (c4^(row&15))] = ((const float4*)(src + (r0+row)*64))[c4];
    }
    #pragma unroll
    for(int k=0;k<4;k++){
      int fid = t + k*256; int row = fid>>4, c4 = fid&15;
      ((float4*)wb)[row*16 + (c4^(row&15))] = ((const float4*)(w6 + (size_t)(o0+row)*192 + ph*64))[c4];
    }
    __syncthreads();
    #pragma unroll 4
    for(int c4=0;c4<16;c4++){
      float4 a[8], b4[4];
      #pragma unroll
      for(int pp=0;pp<8;pp++){ int row = prg*8+pp; a[pp] = ((const float4*)cb)[row*16 + (c4^(row&15))]; }
      #pragma unroll
      for(int oc=0;oc<4;oc++){ int och = cq + 16*oc; b4[oc] = ((const float4*)wb)[och*16 + (c4^(och&15))]; }
      #pragma unroll
      for(int pp=0;pp<8;pp++)
        #pragma unroll
        for(int oc=0;oc<4;oc++) FMA4C(acc[pp][oc], a[pp], b4[oc]);
    }
  }
  #pragma unroll
  for(int pp=0;pp<8;pp++)
    #pragma unroll
    for(int oc=0;oc<4;oc++)
      y6[(r0 + prg*8+pp)*1024 + o0 + cq + 16*oc] = acc[pp][oc];
}

// ---------------- global max over n (bn6+lrelu applied) ----------------
__global__ __launch_bounds__(256) void k_gmax(const float* __restrict__ y6, const float* __restrict__ sb,
                                              float* __restrict__ gpart){
  int t = threadIdx.x; int blk = blockIdx.x;   // 64 blocks x 256 rows
  const float4* base = (const float4*)(y6 + (size_t)blk*256*1024);
  float4 sc = ((const float4*)sb)[t];
  float4 bi = ((const float4*)(sb+1024))[t];
  float4 m = make_float4(NEGF,NEGF,NEGF,NEGF);
  for(int r=0;r<256;r++){
    float4 v = base[r*256 + t];
    v.x = lrelu_f(fmaf(v.x, sc.x, bi.x)); v.y = lrelu_f(fmaf(v.y, sc.y, bi.y));
    v.z = lrelu_f(fmaf(v.z, sc.z, bi.z)); v.w = lrelu_f(fmaf(v.w, sc.w, bi.w));
    m.x = fmaxf(m.x,v.x); m.y = fmaxf(m.y,v.y); m.z = fmaxf(m.z,v.z); m.w = fmaxf(m.w,v.w);
  }
  ((float4*)(gpart + (size_t)blk*1024))[t] = m;
}

__global__ __launch_bounds__(256) void k_gmaxfin(const float* __restrict__ gpart, float* __restrict__ g){
  int b = blockIdx.x, t = threadIdx.x;
  float4 m = make_float4(NEGF,NEGF,NEGF,NEGF);
  for(int c=0;c<16;c++){
    float4 v = ((const float4*)(gpart + ((size_t)b*16 + c)*1024))[t];
    m.x = fmaxf(m.x,v.x); m.y = fmaxf(m.y,v.y); m.z = fmaxf(m.z,v.z); m.w = fmaxf(m.w,v.w);
  }
  ((float4*)(g + (size_t)b*1024))[t] = m;
}

// ---------------- final: bn(g @ wl^T, axis 0) ----------------
__global__ __launch_bounds__(256) void k_final(const float* __restrict__ g, const float* __restrict__ wl,
                                               const float* __restrict__ g7, const float* __restrict__ b7,
                                               float* __restrict__ out){
  int gt = blockIdx.x*256 + threadIdx.x;   // 2048 = 512 o x 4 b
  int o = gt >> 2, b = gt & 3;
  const float4* gb = (const float4*)(g + (size_t)b*1024);
  const float4* wr = (const float4*)(wl + (size_t)o*1024);
  float acc = 0.f;
  #pragma unroll 4
  for(int c=0;c<256;c++){
    float4 a = gb[c], w = wr[c];
    acc = fmaf(a.x,w.x,acc); acc = fmaf(a.y,w.y,acc);
    acc = fmaf(a.z,w.z,acc); acc = fmaf(a.w,w.w,acc);
  }
  float s = acc + __shfl_xor(acc, 1);
  s = s + __shfl_xor(s, 2);
  float m = s * 0.25f;
  float d = acc - m;
  float vv = d*d;
  float v2 = vv + __shfl_xor(vv, 1);
  v2 = v2 + __shfl_xor(v2, 2);
  float var = v2 * 0.25f;
  out[b*512 + o] = d * rsqrtf(var + 1e-5f) * g7[o] + b7[o];
}

// ---------------- launch ----------------
extern "C" void kernel_launch(void* const* d_in, const int* in_sizes, int n_in,
                              void* d_out, int out_size, void* d_ws, size_t ws_size,
                              hipStream_t stream){
  const float* x  = (const float*)d_in[0];
  const float* w1 = (const float*)d_in[1];
  const float* w2 = (const float*)d_in[2];
  const float* w3 = (const float*)d_in[3];
  const float* w4 = (const float*)d_in[4];
  const float* w5 = (const float*)d_in[5];
  const float* w6 = (const float*)d_in[6];
  const float* wl = (const float*)d_in[7];
  const float* g1 = (const float*)d_in[8];  const float* b1 = (const float*)d_in[9];
  const float* g2 = (const float*)d_in[10]; const float* b2 = (const float*)d_in[11];
  const float* g3 = (const float*)d_in[12]; const float* b3 = (const float*)d_in[13];
  const float* g4 = (const float*)d_in[14]; const float* b4 = (const float*)d_in[15];
  const float* g5 = (const float*)d_in[16]; const float* b5 = (const float*)d_in[17];
  const float* g6 = (const float*)d_in[18]; const float* b6 = (const float*)d_in[19];
  const float* g7 = (const float*)d_in[20]; const float* b7 = (const float*)d_in[21];
  float* out = (float*)d_out;

  // workspace layout (floats); total ~99.2 MB.  Dbuf (64MB) overlays y (80MB):
  // y is dead during every kNN phase (x1/x2 already extracted, conv writes come after topk).
  float* ws    = (float*)d_ws;
  float* xx    = ws;                        // 16384
  int*   idx   = (int*)(ws + 16384);        // 327680
  float* y     = ws + 344064;               // 20971520 (reused y1..y5, y6)
  float* Dbuf  = y;                         // 16777216 (per-batch 4096x4096 dist)
  float* x1    = ws + 21315584;             // 1048576
  float* x2    = x1 + 1048576;
  float* x3    = x2 + 1048576;
  float* part  = x3 + 1048576;              // 262144
  float* sb    = part + 262144;             // 2048
  float* gpart = sb + 2048;                 // 65536
  float* g     = gpart + 65536;             // 4096

  hipFuncSetAttribute(reinterpret_cast<const void*>(&k_dist64),
                      hipFuncAttributeMaxDynamicSharedMemorySize, 66560);
  hipFuncSetAttribute(reinterpret_cast<const void*>(&k_convG),
                      hipFuncAttributeMaxDynamicSharedMemorySize, 98304);

  // ---- stage 1 (C=3 graph, conv1 6->64, conv2 64->64, max_k -> x1) ----
  k_xx3<<<64,256,0,stream>>>(x, xx);
  for(int b=0;b<PB;b++){
    k_dist3<<<1024,256,0,stream>>>(x + (size_t)b*3*PN, xx + b*PN, Dbuf);
    k_topk<<<1024,256,0,stream>>>(Dbuf, idx + (size_t)b*PN*PK);
  }
  k_conv1<<<5120,256,0,stream>>>(x, idx, w1, y);
  k_red64<<<512,256,0,stream>>>(y, part);
  k_fin<<<1,256,0,stream>>>(part, 512, 64, (float)PNT, g1, b1, sb);
  k_convA<<<2560,256,0,stream>>>(w2, sb, y);
  k_red64<<<512,256,0,stream>>>(y, part);
  k_fin<<<1,256,0,stream>>>(part, 512, 64, (float)PNT, g2, b2, sb);
  k_finish<<<1024,256,0,stream>>>(y, sb, x1);

  // ---- stage 2 (C=64 graph on x1, conv3 128->64, conv4 64->64, max_k -> x2) ----
  k_xx64<<<64,256,0,stream>>>(x1, xx);
  for(int b=0;b<PB;b++){
    k_dist64<<<1024,256,66560,stream>>>(x1 + (size_t)b*PN*64, xx + b*PN, Dbuf);
    k_topk<<<1024,256,0,stream>>>(Dbuf, idx + (size_t)b*PN*PK);
  }
  k_convG<<<2560,256,98304,stream>>>(x1, idx, w3, y);
  k_red64<<<512,256,0,stream>>>(y, part);
  k_fin<<<1,256,0,stream>>>(part, 512, 64, (float)PNT, g3, b3, sb);
  k_convA<<<2560,256,0,stream>>>(w4, sb, y);
  k_red64<<<512,256,0,stream>>>(y, part);
  k_fin<<<1,256,0,stream>>>(part, 512, 64, (float)PNT, g4, b4, sb);
  k_finish<<<1024,256,0,stream>>>(y, sb, x2);

  // ---- stage 3 (C=64 graph on x2, conv5 128->64, max_k -> x3) ----
  k_xx64<<<64,256,0,stream>>>(x2, xx);
  for(int b=0;b<PB;b++){
    k_dist64<<<1024,256,66560,stream>>>(x2 + (size_t)b*PN*64, xx + b*PN, Dbuf);
    k_topk<<<1024,256,0,stream>>>(Dbuf, idx + (size_t)b*PN*PK);
  }
  k_convG<<<2560,256,98304,stream>>>(x2, idx, w5, y);
  k_red64<<<512,256,0,stream>>>(y, part);
  k_fin<<<1,256,0,stream>>>(part, 512, 64, (float)PNT, g5, b5, sb);
  k_finish<<<1024,256,0,stream>>>(y, sb, x3);

  // ---- head ----
  k_gemm6<<<2048,256,0,stream>>>(x1, x2, x3, w6, y);
  k_red1024<<<128,256,0,stream>>>(y, part);
  k_fin<<<4,256,0,stream>>>(part, 128, 1024, 16384.f, g6, b6, sb);
  k_gmax<<<64,256,0,stream>>>(y, sb, gpart);
  k_gmaxfin<<<4,256,0,stream>>>(gpart, g);
  k_final<<<8,256,0,stream>>>(g, wl, g7, b7, out);
}

// Round 4
// 2354.122 us; speedup vs baseline: 2.9724x; 1.1306x over previous
//
#include <hip/hip_runtime.h>

static constexpr int PB  = 4;
static constexpr int PN  = 4096;
static constexpr int PK  = 20;
static constexpr int PNT = PB*PN*PK;   // 327680
#define NEGF (-3.402823466e38f)

__device__ __forceinline__ float lrelu_f(float x){ return x >= 0.f ? x : 0.2f*x; }

#define FMA4C(accv, av, bv) { accv = fmaf((av).x,(bv).x,accv); accv = fmaf((av).y,(bv).y,accv); \
                              accv = fmaf((av).z,(bv).z,accv); accv = fmaf((av).w,(bv).w,accv); }

// ---------------- xx (squared norms) ----------------
__global__ __launch_bounds__(256) void k_xx3(const float* __restrict__ x, float* __restrict__ xx){
  int i = blockIdx.x*256 + threadIdx.x;
  if(i >= PB*PN) return;
  int b = i >> 12, n = i & 4095;
  const float* xb = x + (size_t)b*3*PN;
  float a0 = xb[n], a1 = xb[PN+n], a2 = xb[2*PN+n];
  float t = a0*a0; t = fmaf(a1,a1,t); t = fmaf(a2,a2,t);
  xx[i] = t;
}

__global__ __launch_bounds__(256) void k_xx64(const float* __restrict__ f, float* __restrict__ xx){
  int i = blockIdx.x*256 + threadIdx.x;
  if(i >= PB*PN) return;
  const float4* p = (const float4*)(f + (size_t)i*64);
  float t = 0.f;
  #pragma unroll
  for(int c=0;c<16;c++){ float4 v = p[c];
    t = fmaf(v.x,v.x,t); t = fmaf(v.y,v.y,t); t = fmaf(v.z,v.z,t); t = fmaf(v.w,v.w,t); }
  xx[i] = t;
}

// ---------------- dist: materialize neg_dist for one batch ----------------
__global__ __launch_bounds__(256) void k_dist3(const float* __restrict__ xb, const float* __restrict__ xxb,
                                               float* __restrict__ D){
  __shared__ float Pi[3][128], Pj[3][128], xxi[128], xxj[128];
  int t = threadIdx.x;
  int bi = blockIdx.x >> 5, bj = blockIdx.x & 31;
  int i0 = bi*128, j0 = bj*128;
  if(t < 128){
    Pi[0][t]=xb[i0+t]; Pi[1][t]=xb[PN+i0+t]; Pi[2][t]=xb[2*PN+i0+t]; xxi[t]=xxb[i0+t];
  } else {
    int u=t-128;
    Pj[0][u]=xb[j0+u]; Pj[1][u]=xb[PN+j0+u]; Pj[2][u]=xb[2*PN+j0+u]; xxj[u]=xxb[j0+u];
  }
  __syncthreads();
  int prg = t>>4, cq = t&15;
  #pragma unroll
  for(int pp=0;pp<8;pp++){
    int r = prg*8+pp;
    float a0=Pi[0][r], a1=Pi[1][r], a2=Pi[2][r], xi2=xxi[r];
    float* Drow = D + (size_t)(i0+r)*PN + j0;
    #pragma unroll
    for(int oc=0;oc<8;oc++){
      int c = cq + 16*oc;
      float dot = a0*Pj[0][c];
      dot = fmaf(a1, Pj[1][c], dot);
      dot = fmaf(a2, Pj[2][c], dot);
      Drow[c] = fmaf(2.f, dot, -xi2) - xxj[c];
    }
  }
}

__global__ __launch_bounds__(256) void k_dist64(const float* __restrict__ Xb, const float* __restrict__ xxb,
                                                float* __restrict__ D){
  extern __shared__ float sm[];
  float* Xi  = sm;            // 128*64
  float* Xj  = Xi + 128*64;   // 128*64
  float* xxi = Xj + 128*64;   // 128
  float* xxj = xxi + 128;     // 128
  int t = threadIdx.x;
  int bi = blockIdx.x >> 5, bj = blockIdx.x & 31;
  int i0 = bi*128, j0 = bj*128;
  #pragma unroll
  for(int k=0;k<8;k++){
    int fid = t + k*256; int row = fid>>4, c4 = fid&15;
    ((float4*)Xi)[row*16 + (c4^(row&15))] = ((const float4*)(Xb + (size_t)(i0+row)*64))[c4];
    ((float4*)Xj)[row*16 + (c4^(row&15))] = ((const float4*)(Xb + (size_t)(j0+row)*64))[c4];
  }
  if(t < 128) xxi[t] = xxb[i0+t];
  else        xxj[t-128] = xxb[j0+t-128];
  __syncthreads();
  int prg = t>>4, cq = t&15;
  float acc[8][8];
  #pragma unroll
  for(int pp=0;pp<8;pp++)
    #pragma unroll
    for(int oc=0;oc<8;oc++) acc[pp][oc] = 0.f;
  #pragma unroll 4
  for(int c4=0;c4<16;c4++){
    float4 a[8], bb[8];
    #pragma unroll
    for(int pp=0;pp<8;pp++){ int row = prg*8+pp; a[pp] = ((const float4*)Xi)[row*16 + (c4^(row&15))]; }
    #pragma unroll
    for(int oc=0;oc<8;oc++){ int col = cq+16*oc;  bb[oc] = ((const float4*)Xj)[col*16 + (c4^(col&15))]; }
    #pragma unroll
    for(int pp=0;pp<8;pp++)
      #pragma unroll
      for(int oc=0;oc<8;oc++) FMA4C(acc[pp][oc], a[pp], bb[oc]);
  }
  #pragma unroll
  for(int pp=0;pp<8;pp++){
    int r = prg*8+pp;
    float xi2 = xxi[r];
    float* Drow = D + (size_t)(i0+r)*PN + j0;
    #pragma unroll
    for(int oc=0;oc<8;oc++){
      int c = cq + 16*oc;
      Drow[c] = fmaf(2.f, acc[pp][oc], -xi2) - xxj[c];
    }
  }
}

// ---------------- top-20 per row: one wave per row ----------------
__global__ __launch_bounds__(256) void k_topk(const float* __restrict__ D, int* __restrict__ idxb){
  int t = threadIdx.x, lane = t & 63, w = t >> 6;
  int row = blockIdx.x*4 + w;
  const float4* rp = (const float4*)(D + (size_t)row*PN + lane*64);
  float v[64];
  #pragma unroll
  for(int c=0;c<16;c++){
    float4 q = rp[c];
    v[4*c+0]=q.x; v[4*c+1]=q.y; v[4*c+2]=q.z; v[4*c+3]=q.w;
  }
  float lmax = NEGF; int li = 0;
  #pragma unroll
  for(int e=0;e<64;e++){
    bool better = v[e] > lmax;
    li = better ? e : li; lmax = better ? v[e] : lmax;
  }
  unsigned long long removed = 0ull;
  int myidx = 0;
  for(int k=0;k<PK;k++){
    float g = lmax;
    #pragma unroll
    for(int s=32;s>=1;s>>=1) g = fmaxf(g, __shfl_xor(g, s));
    unsigned long long mask = __ballot(lmax == g);
    int wl = __ffsll((unsigned long long)mask) - 1;
    int rel = __shfl(li, wl);
    if(lane == k) myidx = wl*64 + rel;
    if(lane == wl){
      removed |= (1ull << rel);
      lmax = NEGF; li = 0;
      #pragma unroll
      for(int e=0;e<64;e++){
        bool ok = ((removed >> e) & 1ull) == 0ull;
        bool better = ok && (v[e] > lmax);
        li = better ? e : li; lmax = better ? v[e] : lmax;
      }
    }
  }
  if(lane < PK) idxb[row*PK + lane] = myidx;
}

// ---------------- nodeUV: per-node partial convs ----------------
// conv(e)[o] with e=concat(x_j - x_n, x_n):  y = U[j] + V[n],
// U = X @ W1^T, V = X @ (W2-W1)^T.  (W1 = w[:, :C], W2 = w[:, C:])
__global__ __launch_bounds__(256) void k_nodeUV3(const float* __restrict__ x, const float* __restrict__ w1,
                                                 float* __restrict__ U, float* __restrict__ V){
  __shared__ float ww[384];
  int t = threadIdx.x;
  for(int k=t;k<384;k+=256) ww[k] = w1[k];
  __syncthreads();
  int g = blockIdx.x*256 + t;
  int ng = g >> 6, o = g & 63;
  int b = ng >> 12, n = ng & 4095;
  const float* xb = x + (size_t)b*3*PN;
  float p0 = xb[n], p1 = xb[PN+n], p2 = xb[2*PN+n];
  const float* wr = ww + o*6;
  float u = p0*wr[0]; u = fmaf(p1,wr[1],u); u = fmaf(p2,wr[2],u);
  float vv = p0*(wr[3]-wr[0]); vv = fmaf(p1, wr[4]-wr[1], vv); vv = fmaf(p2, wr[5]-wr[2], vv);
  U[(size_t)ng*64+o] = u;
  V[(size_t)ng*64+o] = vv;
}

// C=64 version: GEMM M=16384, K=64, 128 output cols (U | V)
__global__ __launch_bounds__(256) void k_nodeUV64(const float* __restrict__ xf, const float* __restrict__ w,
                                                  float* __restrict__ U, float* __restrict__ V){
  __shared__ float xbuf[128*64];
  __shared__ float wbuf[128*64];
  int t = threadIdx.x;
  int r0 = blockIdx.x * 128;
  #pragma unroll
  for(int k=0;k<8;k++){
    int fid = t + k*256; int row = fid>>4, c4 = fid&15;
    ((float4*)xbuf)[row*16 + (c4^(row&15))] = ((const float4*)(xf + (size_t)(r0+row)*64))[c4];
    float4 wv;
    if(row < 64){
      wv = ((const float4*)(w + (size_t)row*128))[c4];
    } else {
      float4 w2v = ((const float4*)(w + (size_t)(row-64)*128 + 64))[c4];
      float4 w1v = ((const float4*)(w + (size_t)(row-64)*128))[c4];
      wv.x = w2v.x-w1v.x; wv.y = w2v.y-w1v.y; wv.z = w2v.z-w1v.z; wv.w = w2v.w-w1v.w;
    }
    ((float4*)wbuf)[row*16 + (c4^(row&15))] = wv;
  }
  __syncthreads();
  int rg = t>>4, cq = t&15;
  float acc[8][8];
  #pragma unroll
  for(int pp=0;pp<8;pp++)
    #pragma unroll
    for(int oc=0;oc<8;oc++) acc[pp][oc] = 0.f;
  #pragma unroll 4
  for(int c4=0;c4<16;c4++){
    float4 a[8], bb[8];
    #pragma unroll
    for(int pp=0;pp<8;pp++){ int row = rg*8+pp; a[pp] = ((const float4*)xbuf)[row*16 + (c4^(row&15))]; }
    #pragma unroll
    for(int oc=0;oc<8;oc++){ int col = cq+16*oc;  bb[oc] = ((const float4*)wbuf)[col*16 + (c4^(col&15))]; }
    #pragma unroll
    for(int pp=0;pp<8;pp++)
      #pragma unroll
      for(int oc=0;oc<8;oc++) FMA4C(acc[pp][oc], a[pp], bb[oc]);
  }
  #pragma unroll
  for(int pp=0;pp<8;pp++){
    int r = r0 + rg*8+pp;
    #pragma unroll
    for(int oc=0;oc<8;oc++){
      int col = cq + 16*oc;
      if(col < 64) U[(size_t)r*64 + col] = acc[pp][oc];
      else         V[(size_t)r*64 + col-64] = acc[pp][oc];
    }
  }
}

// ---------------- BN stats over edges of y = U[j]+V[n] ----------------
__global__ __launch_bounds__(256) void k_statUV(const float* __restrict__ U, const float* __restrict__ V,
                                                const int* __restrict__ idx, float* __restrict__ part){
  __shared__ float ls[512];
  int t = threadIdx.x; int blk = blockIdx.x;
  int ch = t & 63, sub = t >> 6;
  int qbase = blk*640;
  float s = 0.f, qq = 0.f;
  for(int r=sub; r<640; r+=4){
    int q = qbase + r;
    int pt = q/PK;
    int b = pt >> 12;
    int j = idx[q];
    float yv = U[(size_t)(b*PN+j)*64 + ch] + V[(size_t)pt*64 + ch];
    s += yv; qq = fmaf(yv,yv,qq);
  }
  ls[t] = s; ls[256+t] = qq;
  __syncthreads();
  if(t < 64){
    float S = ls[t]+ls[64+t]+ls[128+t]+ls[192+t];
    float Q = ls[256+t]+ls[320+t]+ls[384+t]+ls[448+t];
    part[(size_t)blk*128 + t] = S; part[(size_t)blk*128 + 64 + t] = Q;
  }
}

// ---------------- convA fused: y_out := W(64x64) . lrelu(bn(U[j]+V[n])) ----------------
__global__ __launch_bounds__(256) void k_convAF(const float* __restrict__ U, const float* __restrict__ V,
                                                const int* __restrict__ idx, const float* __restrict__ wg,
                                                const float* __restrict__ sb, float* __restrict__ y){
  __shared__ float hbuf[128*64];
  __shared__ float wbuf[64*64];
  int t = threadIdx.x;
  int q0 = blockIdx.x * 128;
  #pragma unroll
  for(int k=0;k<8;k++){
    int fid = t + k*256; int row = fid>>4, c4 = fid&15;
    int q = q0 + row;
    int pt = q/PK; int b = pt>>12; int j = idx[q];
    float4 uu = ((const float4*)(U + (size_t)(b*PN+j)*64))[c4];
    float4 vv = ((const float4*)(V + (size_t)pt*64))[c4];
    float4 sc = ((const float4*)sb)[c4];
    float4 bi = ((const float4*)(sb+1024))[c4];
    float4 h;
    h.x = lrelu_f(fmaf(uu.x+vv.x, sc.x, bi.x));
    h.y = lrelu_f(fmaf(uu.y+vv.y, sc.y, bi.y));
    h.z = lrelu_f(fmaf(uu.z+vv.z, sc.z, bi.z));
    h.w = lrelu_f(fmaf(uu.w+vv.w, sc.w, bi.w));
    ((float4*)hbuf)[row*16 + (c4 ^ (row&15))] = h;
  }
  #pragma unroll
  for(int k=0;k<4;k++){
    int fid = t + k*256; int row = fid>>4, c4 = fid&15;
    ((float4*)wbuf)[row*16 + (c4 ^ (row&15))] = ((const float4*)(wg + row*64))[c4];
  }
  __syncthreads();
  int prg = t >> 4, cq = t & 15;
  float acc[8][4];
  #pragma unroll
  for(int pp=0;pp<8;pp++)
    #pragma unroll
    for(int oc=0;oc<4;oc++) acc[pp][oc] = 0.f;
  #pragma unroll 4
  for(int c4=0;c4<16;c4++){
    float4 a[8], b4[4];
    #pragma unroll
    for(int pp=0;pp<8;pp++){ int row = prg*8+pp; a[pp] = ((const float4*)hbuf)[row*16 + (c4^(row&15))]; }
    #pragma unroll
    for(int oc=0;oc<4;oc++){ int och = cq + 16*oc; b4[oc] = ((const float4*)wbuf)[och*16 + (c4^(och&15))]; }
    #pragma unroll
    for(int pp=0;pp<8;pp++)
      #pragma unroll
      for(int oc=0;oc<4;oc++) FMA4C(acc[pp][oc], a[pp], b4[oc]);
  }
  #pragma unroll
  for(int pp=0;pp<8;pp++)
    #pragma unroll
    for(int oc=0;oc<4;oc++)
      y[(size_t)(q0 + prg*8+pp)*64 + cq + 16*oc] = acc[pp][oc];
}

// ---------------- BN statistics (materialized y) ----------------
__global__ __launch_bounds__(256) void k_red64(const float* __restrict__ y, float* __restrict__ part){
  __shared__ float ls[512];
  int t = threadIdx.x; int blk = blockIdx.x;
  int ch = t & 63, sub = t >> 6;
  const float* base = y + (size_t)blk*640*64;
  float s = 0.f, q = 0.f;
  for(int r=sub; r<640; r+=4){ float v = base[(size_t)r*64 + ch]; s += v; q = fmaf(v,v,q); }
  ls[t] = s; ls[256+t] = q;
  __syncthreads();
  if(t < 64){
    float S = ls[t]+ls[64+t]+ls[128+t]+ls[192+t];
    float Q = ls[256+t]+ls[320+t]+ls[384+t]+ls[448+t];
    part[(size_t)blk*128 + t] = S; part[(size_t)blk*128 + 64 + t] = Q;
  }
}

__global__ __launch_bounds__(256) void k_red1024(const float* __restrict__ y6, float* __restrict__ part){
  int t = threadIdx.x; int blk = blockIdx.x;   // 128 blocks x 128 rows
  const float4* base = (const float4*)(y6 + (size_t)blk*128*1024);
  float4 s = make_float4(0,0,0,0), q = make_float4(0,0,0,0);
  for(int r=0;r<128;r++){
    float4 v = base[r*256 + t];
    s.x += v.x; s.y += v.y; s.z += v.z; s.w += v.w;
    q.x = fmaf(v.x,v.x,q.x); q.y = fmaf(v.y,v.y,q.y); q.z = fmaf(v.z,v.z,q.z); q.w = fmaf(v.w,v.w,q.w);
  }
  ((float4*)(part + (size_t)blk*2048))[t] = s;
  ((float4*)(part + (size_t)blk*2048 + 1024))[t] = q;
}

__global__ void k_fin(const float* __restrict__ part, int nparts, int chn, float cnt,
                      const float* __restrict__ gamma, const float* __restrict__ beta,
                      float* __restrict__ sb){
  int ch = blockIdx.x*256 + threadIdx.x;
  if(ch >= chn) return;
  float S = 0.f, Q = 0.f;
  for(int p=0;p<nparts;p++){ S += part[(size_t)p*2*chn + ch]; Q += part[(size_t)p*2*chn + chn + ch]; }
  float m  = S/cnt;
  float vr = Q/cnt - m*m;
  float sc = gamma[ch] * rsqrtf(vr + 1e-5f);
  sb[ch] = sc; sb[1024+ch] = beta[ch] - m*sc;
}

// ---------------- finish: x = max_k lrelu(bn(y)) ----------------
__global__ __launch_bounds__(256) void k_finish(const float* __restrict__ y, const float* __restrict__ sb,
                                                float* __restrict__ xo){
  int t = threadIdx.x;
  int pt = blockIdx.x*16 + (t>>4), c4 = t&15;
  const float4* base = (const float4*)(y + (size_t)pt*20*64);
  float4 sc = ((const float4*)sb)[c4];
  float4 bi = ((const float4*)(sb+1024))[c4];
  float4 m = make_float4(NEGF,NEGF,NEGF,NEGF);
  #pragma unroll 4
  for(int k=0;k<20;k++){
    float4 v = base[k*16 + c4];
    v.x = lrelu_f(fmaf(v.x, sc.x, bi.x)); v.y = lrelu_f(fmaf(v.y, sc.y, bi.y));
    v.z = lrelu_f(fmaf(v.z, sc.z, bi.z)); v.w = lrelu_f(fmaf(v.w, sc.w, bi.w));
    m.x = fmaxf(m.x,v.x); m.y = fmaxf(m.y,v.y); m.z = fmaxf(m.z,v.z); m.w = fmaxf(m.w,v.w);
  }
  ((float4*)(xo + (size_t)pt*64))[c4] = m;
}

// ---------------- finishUV: x = max_k lrelu(bn(U[j]+V[n])) (no y materialization) ----------------
__global__ __launch_bounds__(256) void k_finishUV(const float* __restrict__ U, const float* __restrict__ V,
                                                  const int* __restrict__ idx, const float* __restrict__ sb,
                                                  float* __restrict__ xo){
  int t = threadIdx.x;
  int pt = blockIdx.x*16 + (t>>4), c4 = t&15;
  int b = pt >> 12;
  float4 sc = ((const float4*)sb)[c4];
  float4 bi = ((const float4*)(sb+1024))[c4];
  float4 vv = ((const float4*)(V + (size_t)pt*64))[c4];
  float4 m = make_float4(NEGF,NEGF,NEGF,NEGF);
  const int* ip = idx + (size_t)pt*PK;
  #pragma unroll 4
  for(int k=0;k<PK;k++){
    int j = ip[k];
    float4 uu = ((const float4*)(U + (size_t)(b*PN+j)*64))[c4];
    float4 v;
    v.x = lrelu_f(fmaf(uu.x+vv.x, sc.x, bi.x)); v.y = lrelu_f(fmaf(uu.y+vv.y, sc.y, bi.y));
    v.z = lrelu_f(fmaf(uu.z+vv.z, sc.z, bi.z)); v.w = lrelu_f(fmaf(uu.w+vv.w, sc.w, bi.w));
    m.x = fmaxf(m.x,v.x); m.y = fmaxf(m.y,v.y); m.z = fmaxf(m.z,v.z); m.w = fmaxf(m.w,v.w);
  }
  ((float4*)(xo + (size_t)pt*64))[c4] = m;
}

// ---------------- head GEMM: cat(x1,x2,x3) @ w6^T ----------------
__global__ __launch_bounds__(256) void k_gemm6(const float* __restrict__ x1, const float* __restrict__ x2,
                                               const float* __restrict__ x3, const float* __restrict__ w6,
                                               float* __restrict__ y6){
  __shared__ float cb[128*64];
  __shared__ float wb[64*64];
  int t = threadIdx.x;
  int rb = blockIdx.x >> 4;
  int ob = blockIdx.x & 15;
  size_t r0 = (size_t)rb*128; int o0 = ob*64;
  int prg = t >> 4, cq = t & 15;
  float acc[8][4];
  #pragma unroll
  for(int pp=0;pp<8;pp++)
    #pragma unroll
    for(int oc=0;oc<4;oc++) acc[pp][oc] = 0.f;
  const float* srcs[3] = {x1, x2, x3};
  for(int ph=0; ph<3; ph++){
    __syncthreads();
    const float* src = srcs[ph];
    #pragma unroll
    for(int k=0;k<8;k++){
      int fid = t + k*256; int row = fid>>4, c4 = fid&15;
      ((float4*)cb)[row*16 + (c4^(row&15))] = ((const float4*)(src + (r0+row)*64))[c4];
    }
    #pragma unroll
    for(int k=0;k<4;k++){
      int fid = t + k*256; int row = fid>>4, c4 = fid&15;
      ((float4*)wb)[row*16 + (c4^(row&15))] = ((const float4*)(w6 + (size_t)(o0+row)*192 + ph*64))[c4];
    }
    __syncthreads();
    #pragma unroll 4
    for(int c4=0;c4<16;c4++){
      float4 a[8], b4[4];
      #pragma unroll
      for(int pp=0;pp<8;pp++){ int row = prg*8+pp; a[pp] = ((const float4*)cb)[row*16 + (c4^(row&15))]; }
      #pragma unroll
      for(int oc=0;oc<4;oc++){ int och = cq + 16*oc; b4[oc] = ((const float4*)wb)[och*16 + (c4^(och&15))]; }
      #pragma unroll
      for(int pp=0;pp<8;pp++)
        #pragma unroll
        for(int oc=0;oc<4;oc++) FMA4C(acc[pp][oc], a[pp], b4[oc]);
    }
  }
  #pragma unroll
  for(int pp=0;pp<8;pp++)
    #pragma unroll
    for(int oc=0;oc<4;oc++)
      y6[(r0 + prg*8+pp)*1024 + o0 + cq + 16*oc] = acc[pp][oc];
}

// ---------------- global max over n (bn6+lrelu applied) ----------------
__global__ __launch_bounds__(256) void k_gmax(const float* __restrict__ y6, const float* __restrict__ sb,
                                              float* __restrict__ gpart){
  int t = threadIdx.x; int blk = blockIdx.x;   // 64 blocks x 256 rows
  const float4* base = (const float4*)(y6 + (size_t)blk*256*1024);
  float4 sc = ((const float4*)sb)[t];
  float4 bi = ((const float4*)(sb+1024))[t];
  float4 m = make_float4(NEGF,NEGF,NEGF,NEGF);
  for(int r=0;r<256;r++){
    float4 v = base[r*256 + t];
    v.x = lrelu_f(fmaf(v.x, sc.x, bi.x)); v.y = lrelu_f(fmaf(v.y, sc.y, bi.y));
    v.z = lrelu_f(fmaf(v.z, sc.z, bi.z)); v.w = lrelu_f(fmaf(v.w, sc.w, bi.w));
    m.x = fmaxf(m.x,v.x); m.y = fmaxf(m.y,v.y); m.z = fmaxf(m.z,v.z); m.w = fmaxf(m.w,v.w);
  }
  ((float4*)(gpart + (size_t)blk*1024))[t] = m;
}

__global__ __launch_bounds__(256) void k_gmaxfin(const float* __restrict__ gpart, float* __restrict__ g){
  int b = blockIdx.x, t = threadIdx.x;
  float4 m = make_float4(NEGF,NEGF,NEGF,NEGF);
  for(int c=0;c<16;c++){
    float4 v = ((const float4*)(gpart + ((size_t)b*16 + c)*1024))[t];
    m.x = fmaxf(m.x,v.x); m.y = fmaxf(m.y,v.y); m.z = fmaxf(m.z,v.z); m.w = fmaxf(m.w,v.w);
  }
  ((float4*)(g + (size_t)b*1024))[t] = m;
}

// ---------------- final: bn(g @ wl^T, axis 0) ----------------
__global__ __launch_bounds__(256) void k_final(const float* __restrict__ g, const float* __restrict__ wl,
                                               const float* __restrict__ g7, const float* __restrict__ b7,
                                               float* __restrict__ out){
  int gt = blockIdx.x*256 + threadIdx.x;   // 2048 = 512 o x 4 b
  int o = gt >> 2, b = gt & 3;
  const float4* gb = (const float4*)(g + (size_t)b*1024);
  const float4* wr = (const float4*)(wl + (size_t)o*1024);
  float acc = 0.f;
  #pragma unroll 4
  for(int c=0;c<256;c++){
    float4 a = gb[c], w = wr[c];
    acc = fmaf(a.x,w.x,acc); acc = fmaf(a.y,w.y,acc);
    acc = fmaf(a.z,w.z,acc); acc = fmaf(a.w,w.w,acc);
  }
  float s = acc + __shfl_xor(acc, 1);
  s = s + __shfl_xor(s, 2);
  float m = s * 0.25f;
  float d = acc - m;
  float vv = d*d;
  float v2 = vv + __shfl_xor(vv, 1);
  v2 = v2 + __shfl_xor(v2, 2);
  float var = v2 * 0.25f;
  out[b*512 + o] = d * rsqrtf(var + 1e-5f) * g7[o] + b7[o];
}

// ---------------- launch ----------------
extern "C" void kernel_launch(void* const* d_in, const int* in_sizes, int n_in,
                              void* d_out, int out_size, void* d_ws, size_t ws_size,
                              hipStream_t stream){
  const float* x  = (const float*)d_in[0];
  const float* w1 = (const float*)d_in[1];
  const float* w2 = (const float*)d_in[2];
  const float* w3 = (const float*)d_in[3];
  const float* w4 = (const float*)d_in[4];
  const float* w5 = (const float*)d_in[5];
  const float* w6 = (const float*)d_in[6];
  const float* wl = (const float*)d_in[7];
  const float* g1 = (const float*)d_in[8];  const float* b1 = (const float*)d_in[9];
  const float* g2 = (const float*)d_in[10]; const float* b2 = (const float*)d_in[11];
  const float* g3 = (const float*)d_in[12]; const float* b3 = (const float*)d_in[13];
  const float* g4 = (const float*)d_in[14]; const float* b4 = (const float*)d_in[15];
  const float* g5 = (const float*)d_in[16]; const float* b5 = (const float*)d_in[17];
  const float* g6 = (const float*)d_in[18]; const float* b6 = (const float*)d_in[19];
  const float* g7 = (const float*)d_in[20]; const float* b7 = (const float*)d_in[21];
  float* out = (float*)d_out;

  // workspace layout (floats); ~107.6 MB total
  float* ws    = (float*)d_ws;
  float* xx    = ws;                        // 16384
  int*   idx   = (int*)(ws + 16384);        // 327680
  float* y     = ws + 344064;               // 20971520 (y2/y4, y6)
  float* Dbuf  = y;                         // 16777216 (per-batch 4096x4096 dist; y dead then)
  float* x1    = ws + 21315584;             // 1048576
  float* x2    = x1 + 1048576;
  float* x3    = x2 + 1048576;
  float* part  = x3 + 1048576;              // 262144
  float* sb    = part + 262144;             // 2048
  float* gpart = sb + 2048;                 // 65536
  float* g     = gpart + 65536;             // 4096
  float* U     = g + 4096;                  // 1048576
  float* V     = U + 1048576;               // 1048576

  hipFuncSetAttribute(reinterpret_cast<const void*>(&k_dist64),
                      hipFuncAttributeMaxDynamicSharedMemorySize, 66560);

  // ---- stage 1 ----
  k_xx3<<<64,256,0,stream>>>(x, xx);
  for(int b=0;b<PB;b++){
    k_dist3<<<1024,256,0,stream>>>(x + (size_t)b*3*PN, xx + b*PN, Dbuf);
    k_topk<<<1024,256,0,stream>>>(Dbuf, idx + (size_t)b*PN*PK);
  }
  k_nodeUV3<<<4096,256,0,stream>>>(x, w1, U, V);
  k_statUV<<<512,256,0,stream>>>(U, V, idx, part);
  k_fin<<<1,256,0,stream>>>(part, 512, 64, (float)PNT, g1, b1, sb);
  k_convAF<<<2560,256,0,stream>>>(U, V, idx, w2, sb, y);
  k_red64<<<512,256,0,stream>>>(y, part);
  k_fin<<<1,256,0,stream>>>(part, 512, 64, (float)PNT, g2, b2, sb);
  k_finish<<<1024,256,0,stream>>>(y, sb, x1);

  // ---- stage 2 ----
  k_xx64<<<64,256,0,stream>>>(x1, xx);
  for(int b=0;b<PB;b++){
    k_dist64<<<1024,256,66560,stream>>>(x1 + (size_t)b*PN*64, xx + b*PN, Dbuf);
    k_topk<<<1024,256,0,stream>>>(Dbuf, idx + (size_t)b*PN*PK);
  }
  k_nodeUV64<<<128,256,0,stream>>>(x1, w3, U, V);
  k_statUV<<<512,256,0,stream>>>(U, V, idx, part);
  k_fin<<<1,256,0,stream>>>(part, 512, 64, (float)PNT, g3, b3, sb);
  k_convAF<<<2560,256,0,stream>>>(U, V, idx, w4, sb, y);
  k_red64<<<512,256,0,stream>>>(y, part);
  k_fin<<<1,256,0,stream>>>(part, 512, 64, (float)PNT, g4, b4, sb);
  k_finish<<<1024,256,0,stream>>>(y, sb, x2);

  // ---- stage 3 ----
  k_xx64<<<64,256,0,stream>>>(x2, xx);
  for(int b=0;b<PB;b++){
    k_dist64<<<1024,256,66560,stream>>>(x2 + (size_t)b*PN*64, xx + b*PN, Dbuf);
    k_topk<<<1024,256,0,stream>>>(Dbuf, idx + (size_t)b*PN*PK);
  }
  k_nodeUV64<<<128,256,0,stream>>>(x2, w5, U, V);
  k_statUV<<<512,256,0,stream>>>(U, V, idx, part);
  k_fin<<<1,256,0,stream>>>(part, 512, 64, (float)PNT, g5, b5, sb);
  k_finishUV<<<1024,256,0,stream>>>(U, V, idx, sb, x3);

  // ---- head ----
  k_gemm6<<<2048,256,0,stream>>>(x1, x2, x3, w6, y);
  k_red1024<<<128,256,0,stream>>>(y, part);
  k_fin<<<4,256,0,stream>>>(part, 128, 1024, 16384.f, g6, b6, sb);
  k_gmax<<<64,256,0,stream>>>(y, sb, gpart);
  k_gmaxfin<<<4,256,0,stream>>>(gpart, g);
  k_final<<<8,256,0,stream>>>(g, wl, g7, b7, out);
}

// Round 5
// 1758.798 us; speedup vs baseline: 3.9785x; 1.3385x over previous
//
#include <hip/hip_runtime.h>

static constexpr int PB  = 4;
static constexpr int PN  = 4096;
static constexpr int PK  = 20;
static constexpr int PNT = PB*PN*PK;   // 327680
#define NEGF (-3.402823466e38f)

__device__ __forceinline__ float lrelu_f(float x){ return x >= 0.f ? x : 0.2f*x; }

#define FMA4C(accv, av, bv) { accv = fmaf((av).x,(bv).x,accv); accv = fmaf((av).y,(bv).y,accv); \
                              accv = fmaf((av).z,(bv).z,accv); accv = fmaf((av).w,(bv).w,accv); }

// ---------------- xx (squared norms) ----------------
__global__ __launch_bounds__(256) void k_xx3(const float* __restrict__ x, float* __restrict__ xx){
  int i = blockIdx.x*256 + threadIdx.x;
  if(i >= PB*PN) return;
  int b = i >> 12, n = i & 4095;
  const float* xb = x + (size_t)b*3*PN;
  float a0 = xb[n], a1 = xb[PN+n], a2 = xb[2*PN+n];
  float t = a0*a0; t = fmaf(a1,a1,t); t = fmaf(a2,a2,t);
  xx[i] = t;
}

__global__ __launch_bounds__(256) void k_xx64(const float* __restrict__ f, float* __restrict__ xx){
  int i = blockIdx.x*256 + threadIdx.x;
  if(i >= PB*PN) return;
  const float4* p = (const float4*)(f + (size_t)i*64);
  float t = 0.f;
  #pragma unroll
  for(int c=0;c<16;c++){ float4 v = p[c];
    t = fmaf(v.x,v.x,t); t = fmaf(v.y,v.y,t); t = fmaf(v.z,v.z,t); t = fmaf(v.w,v.w,t); }
  xx[i] = t;
}

// ---------------- dist: materialize neg_dist for one batch ----------------
__global__ __launch_bounds__(256) void k_dist3(const float* __restrict__ xb, const float* __restrict__ xxb,
                                               float* __restrict__ D){
  __shared__ float Pi[3][128], Pj[3][128], xxi[128], xxj[128];
  int t = threadIdx.x;
  int bi = blockIdx.x >> 5, bj = blockIdx.x & 31;
  int i0 = bi*128, j0 = bj*128;
  if(t < 128){
    Pi[0][t]=xb[i0+t]; Pi[1][t]=xb[PN+i0+t]; Pi[2][t]=xb[2*PN+i0+t]; xxi[t]=xxb[i0+t];
  } else {
    int u=t-128;
    Pj[0][u]=xb[j0+u]; Pj[1][u]=xb[PN+j0+u]; Pj[2][u]=xb[2*PN+j0+u]; xxj[u]=xxb[j0+u];
  }
  __syncthreads();
  int prg = t>>4, cq = t&15;
  #pragma unroll
  for(int pp=0;pp<8;pp++){
    int r = prg*8+pp;
    float a0=Pi[0][r], a1=Pi[1][r], a2=Pi[2][r], xi2=xxi[r];
    float* Drow = D + (size_t)(i0+r)*PN + j0;
    #pragma unroll
    for(int oc=0;oc<8;oc++){
      int c = cq + 16*oc;
      float dot = a0*Pj[0][c];
      dot = fmaf(a1, Pj[1][c], dot);
      dot = fmaf(a2, Pj[2][c], dot);
      Drow[c] = fmaf(2.f, dot, -xi2) - xxj[c];
    }
  }
}

__global__ __launch_bounds__(256) void k_dist64(const float* __restrict__ Xb, const float* __restrict__ xxb,
                                                float* __restrict__ D){
  extern __shared__ float sm[];
  float* Xi  = sm;            // 128*64
  float* Xj  = Xi + 128*64;   // 128*64
  float* xxi = Xj + 128*64;   // 128
  float* xxj = xxi + 128;     // 128
  int t = threadIdx.x;
  int bi = blockIdx.x >> 5, bj = blockIdx.x & 31;
  int i0 = bi*128, j0 = bj*128;
  #pragma unroll
  for(int k=0;k<8;k++){
    int fid = t + k*256; int row = fid>>4, c4 = fid&15;
    ((float4*)Xi)[row*16 + (c4^(row&15))] = ((const float4*)(Xb + (size_t)(i0+row)*64))[c4];
    ((float4*)Xj)[row*16 + (c4^(row&15))] = ((const float4*)(Xb + (size_t)(j0+row)*64))[c4];
  }
  if(t < 128) xxi[t] = xxb[i0+t];
  else        xxj[t-128] = xxb[j0+t-128];
  __syncthreads();
  int prg = t>>4, cq = t&15;
  float acc[8][8];
  #pragma unroll
  for(int pp=0;pp<8;pp++)
    #pragma unroll
    for(int oc=0;oc<8;oc++) acc[pp][oc] = 0.f;
  #pragma unroll 4
  for(int c4=0;c4<16;c4++){
    float4 a[8], bb[8];
    #pragma unroll
    for(int pp=0;pp<8;pp++){ int row = prg*8+pp; a[pp] = ((const float4*)Xi)[row*16 + (c4^(row&15))]; }
    #pragma unroll
    for(int oc=0;oc<8;oc++){ int col = cq+16*oc;  bb[oc] = ((const float4*)Xj)[col*16 + (c4^(col&15))]; }
    #pragma unroll
    for(int pp=0;pp<8;pp++)
      #pragma unroll
      for(int oc=0;oc<8;oc++) FMA4C(acc[pp][oc], a[pp], bb[oc]);
  }
  #pragma unroll
  for(int pp=0;pp<8;pp++){
    int r = prg*8+pp;
    float xi2 = xxi[r];
    float* Drow = D + (size_t)(i0+r)*PN + j0;
    #pragma unroll
    for(int oc=0;oc<8;oc++){
      int c = cq + 16*oc;
      Drow[c] = fmaf(2.f, acc[pp][oc], -xi2) - xxj[c];
    }
  }
}

// ---------------- top-20 per row: one wave per row ----------------
__global__ __launch_bounds__(256) void k_topk(const float* __restrict__ D, int* __restrict__ idxb){
  int t = threadIdx.x, lane = t & 63, w = t >> 6;
  int row = blockIdx.x*4 + w;
  const float4* rp = (const float4*)(D + (size_t)row*PN + lane*64);
  float v[64];
  #pragma unroll
  for(int c=0;c<16;c++){
    float4 q = rp[c];
    v[4*c+0]=q.x; v[4*c+1]=q.y; v[4*c+2]=q.z; v[4*c+3]=q.w;
  }
  float lmax = NEGF; int li = 0;
  #pragma unroll
  for(int e=0;e<64;e++){
    bool better = v[e] > lmax;
    li = better ? e : li; lmax = better ? v[e] : lmax;
  }
  unsigned long long removed = 0ull;
  int myidx = 0;
  for(int k=0;k<PK;k++){
    float g = lmax;
    #pragma unroll
    for(int s=32;s>=1;s>>=1) g = fmaxf(g, __shfl_xor(g, s));
    unsigned long long mask = __ballot(lmax == g);
    int wl = __ffsll((unsigned long long)mask) - 1;
    int rel = __shfl(li, wl);
    if(lane == k) myidx = wl*64 + rel;
    if(lane == wl){
      removed |= (1ull << rel);
      lmax = NEGF; li = 0;
      #pragma unroll
      for(int e=0;e<64;e++){
        bool ok = ((removed >> e) & 1ull) == 0ull;
        bool better = ok && (v[e] > lmax);
        li = better ? e : li; lmax = better ? v[e] : lmax;
      }
    }
  }
  if(lane < PK) idxb[row*PK + lane] = myidx;
}

// ---------------- nodeUV: per-node partial convs ----------------
__global__ __launch_bounds__(256) void k_nodeUV3(const float* __restrict__ x, const float* __restrict__ w1,
                                                 float* __restrict__ U, float* __restrict__ V){
  __shared__ float ww[384];
  int t = threadIdx.x;
  for(int k=t;k<384;k+=256) ww[k] = w1[k];
  __syncthreads();
  int g = blockIdx.x*256 + t;
  int ng = g >> 6, o = g & 63;
  int b = ng >> 12, n = ng & 4095;
  const float* xb = x + (size_t)b*3*PN;
  float p0 = xb[n], p1 = xb[PN+n], p2 = xb[2*PN+n];
  const float* wr = ww + o*6;
  float u = p0*wr[0]; u = fmaf(p1,wr[1],u); u = fmaf(p2,wr[2],u);
  float vv = p0*(wr[3]-wr[0]); vv = fmaf(p1, wr[4]-wr[1], vv); vv = fmaf(p2, wr[5]-wr[2], vv);
  U[(size_t)ng*64+o] = u;
  V[(size_t)ng*64+o] = vv;
}

__global__ __launch_bounds__(256) void k_nodeUV64(const float* __restrict__ xf, const float* __restrict__ w,
                                                  float* __restrict__ U, float* __restrict__ V){
  __shared__ float xbuf[128*64];
  __shared__ float wbuf[128*64];
  int t = threadIdx.x;
  int r0 = blockIdx.x * 128;
  #pragma unroll
  for(int k=0;k<8;k++){
    int fid = t + k*256; int row = fid>>4, c4 = fid&15;
    ((float4*)xbuf)[row*16 + (c4^(row&15))] = ((const float4*)(xf + (size_t)(r0+row)*64))[c4];
    float4 wv;
    if(row < 64){
      wv = ((const float4*)(w + (size_t)row*128))[c4];
    } else {
      float4 w2v = ((const float4*)(w + (size_t)(row-64)*128 + 64))[c4];
      float4 w1v = ((const float4*)(w + (size_t)(row-64)*128))[c4];
      wv.x = w2v.x-w1v.x; wv.y = w2v.y-w1v.y; wv.z = w2v.z-w1v.z; wv.w = w2v.w-w1v.w;
    }
    ((float4*)wbuf)[row*16 + (c4^(row&15))] = wv;
  }
  __syncthreads();
  int rg = t>>4, cq = t&15;
  float acc[8][8];
  #pragma unroll
  for(int pp=0;pp<8;pp++)
    #pragma unroll
    for(int oc=0;oc<8;oc++) acc[pp][oc] = 0.f;
  #pragma unroll 4
  for(int c4=0;c4<16;c4++){
    float4 a[8], bb[8];
    #pragma unroll
    for(int pp=0;pp<8;pp++){ int row = rg*8+pp; a[pp] = ((const float4*)xbuf)[row*16 + (c4^(row&15))]; }
    #pragma unroll
    for(int oc=0;oc<8;oc++){ int col = cq+16*oc;  bb[oc] = ((const float4*)wbuf)[col*16 + (c4^(col&15))]; }
    #pragma unroll
    for(int pp=0;pp<8;pp++)
      #pragma unroll
      for(int oc=0;oc<8;oc++) FMA4C(acc[pp][oc], a[pp], bb[oc]);
  }
  #pragma unroll
  for(int pp=0;pp<8;pp++){
    int r = r0 + rg*8+pp;
    #pragma unroll
    for(int oc=0;oc<8;oc++){
      int col = cq + 16*oc;
      if(col < 64) U[(size_t)r*64 + col] = acc[pp][oc];
      else         V[(size_t)r*64 + col-64] = acc[pp][oc];
    }
  }
}

// ---------------- BN stats over edges of y = U[j]+V[n] ----------------
__global__ __launch_bounds__(256) void k_statUV(const float* __restrict__ U, const float* __restrict__ V,
                                                const int* __restrict__ idx, float* __restrict__ part){
  __shared__ float ls[512];
  int t = threadIdx.x; int blk = blockIdx.x;
  int ch = t & 63, sub = t >> 6;
  int qbase = blk*640;
  float s = 0.f, qq = 0.f;
  for(int r=sub; r<640; r+=4){
    int q = qbase + r;
    int pt = q/PK;
    int b = pt >> 12;
    int j = idx[q];
    float yv = U[(size_t)(b*PN+j)*64 + ch] + V[(size_t)pt*64 + ch];
    s += yv; qq = fmaf(yv,yv,qq);
  }
  ls[t] = s; ls[256+t] = qq;
  __syncthreads();
  if(t < 64){
    float S = ls[t]+ls[64+t]+ls[128+t]+ls[192+t];
    float Q = ls[256+t]+ls[320+t]+ls[384+t]+ls[448+t];
    part[(size_t)blk*128 + t] = S; part[(size_t)blk*128 + 64 + t] = Q;
  }
}

// ---------------- convA fused: y_out := W(64x64) . lrelu(bn(U[j]+V[n])) ----------------
__global__ __launch_bounds__(256) void k_convAF(const float* __restrict__ U, const float* __restrict__ V,
                                                const int* __restrict__ idx, const float* __restrict__ wg,
                                                const float* __restrict__ sb, float* __restrict__ y){
  __shared__ float hbuf[128*64];
  __shared__ float wbuf[64*64];
  int t = threadIdx.x;
  int q0 = blockIdx.x * 128;
  #pragma unroll
  for(int k=0;k<8;k++){
    int fid = t + k*256; int row = fid>>4, c4 = fid&15;
    int q = q0 + row;
    int pt = q/PK; int b = pt>>12; int j = idx[q];
    float4 uu = ((const float4*)(U + (size_t)(b*PN+j)*64))[c4];
    float4 vv = ((const float4*)(V + (size_t)pt*64))[c4];
    float4 sc = ((const float4*)sb)[c4];
    float4 bi = ((const float4*)(sb+1024))[c4];
    float4 h;
    h.x = lrelu_f(fmaf(uu.x+vv.x, sc.x, bi.x));
    h.y = lrelu_f(fmaf(uu.y+vv.y, sc.y, bi.y));
    h.z = lrelu_f(fmaf(uu.z+vv.z, sc.z, bi.z));
    h.w = lrelu_f(fmaf(uu.w+vv.w, sc.w, bi.w));
    ((float4*)hbuf)[row*16 + (c4 ^ (row&15))] = h;
  }
  #pragma unroll
  for(int k=0;k<4;k++){
    int fid = t + k*256; int row = fid>>4, c4 = fid&15;
    ((float4*)wbuf)[row*16 + (c4 ^ (row&15))] = ((const float4*)(wg + row*64))[c4];
  }
  __syncthreads();
  int prg = t >> 4, cq = t & 15;
  float acc[8][4];
  #pragma unroll
  for(int pp=0;pp<8;pp++)
    #pragma unroll
    for(int oc=0;oc<4;oc++) acc[pp][oc] = 0.f;
  #pragma unroll 4
  for(int c4=0;c4<16;c4++){
    float4 a[8], b4[4];
    #pragma unroll
    for(int pp=0;pp<8;pp++){ int row = prg*8+pp; a[pp] = ((const float4*)hbuf)[row*16 + (c4^(row&15))]; }
    #pragma unroll
    for(int oc=0;oc<4;oc++){ int och = cq + 16*oc; b4[oc] = ((const float4*)wbuf)[och*16 + (c4^(och&15))]; }
    #pragma unroll
    for(int pp=0;pp<8;pp++)
      #pragma unroll
      for(int oc=0;oc<4;oc++) FMA4C(acc[pp][oc], a[pp], b4[oc]);
  }
  #pragma unroll
  for(int pp=0;pp<8;pp++)
    #pragma unroll
    for(int oc=0;oc<4;oc++)
      y[(size_t)(q0 + prg*8+pp)*64 + cq + 16*oc] = acc[pp][oc];
}

// ---------------- BN statistics (materialized y) ----------------
__global__ __launch_bounds__(256) void k_red64(const float* __restrict__ y, float* __restrict__ part){
  __shared__ float ls[512];
  int t = threadIdx.x; int blk = blockIdx.x;
  int ch = t & 63, sub = t >> 6;
  const float* base = y + (size_t)blk*640*64;
  float s = 0.f, q = 0.f;
  for(int r=sub; r<640; r+=4){ float v = base[(size_t)r*64 + ch]; s += v; q = fmaf(v,v,q); }
  ls[t] = s; ls[256+t] = q;
  __syncthreads();
  if(t < 64){
    float S = ls[t]+ls[64+t]+ls[128+t]+ls[192+t];
    float Q = ls[256+t]+ls[320+t]+ls[384+t]+ls[448+t];
    part[(size_t)blk*128 + t] = S; part[(size_t)blk*128 + 64 + t] = Q;
  }
}

__global__ __launch_bounds__(256) void k_red1024(const float* __restrict__ y6, float* __restrict__ part){
  int t = threadIdx.x; int blk = blockIdx.x;   // 128 blocks x 128 rows
  const float4* base = (const float4*)(y6 + (size_t)blk*128*1024);
  float4 s = make_float4(0,0,0,0), q = make_float4(0,0,0,0);
  for(int r=0;r<128;r++){
    float4 v = base[r*256 + t];
    s.x += v.x; s.y += v.y; s.z += v.z; s.w += v.w;
    q.x = fmaf(v.x,v.x,q.x); q.y = fmaf(v.y,v.y,q.y); q.z = fmaf(v.z,v.z,q.z); q.w = fmaf(v.w,v.w,q.w);
  }
  ((float4*)(part + (size_t)blk*2048))[t] = s;
  ((float4*)(part + (size_t)blk*2048 + 1024))[t] = q;
}

// ---------------- finalize BN affine: parallel partial-sum reduce ----------------
// grid = chn/16 blocks, 256 threads: thread (sub=t>>4, chl=t&15) strides parts by 16.
__global__ __launch_bounds__(256) void k_fin(const float* __restrict__ part, int nparts, int chn, float cnt,
                                             const float* __restrict__ gamma, const float* __restrict__ beta,
                                             float* __restrict__ sb){
  __shared__ float ls[512];
  int t = threadIdx.x;
  int chl = t & 15, sub = t >> 4;
  int ch = blockIdx.x*16 + chl;
  float S = 0.f, Q = 0.f;
  for(int p=sub; p<nparts; p+=16){
    S += part[(size_t)p*2*chn + ch];
    Q += part[(size_t)p*2*chn + chn + ch];
  }
  ls[t] = S; ls[256+t] = Q;
  __syncthreads();
  if(t < 16){
    float Sa = 0.f, Qa = 0.f;
    #pragma unroll
    for(int s=0;s<16;s++){ Sa += ls[s*16+t]; Qa += ls[256+s*16+t]; }
    int c = blockIdx.x*16 + t;
    float m  = Sa/cnt;
    float vr = Qa/cnt - m*m;
    float sc = gamma[c] * rsqrtf(vr + 1e-5f);
    sb[c] = sc; sb[1024+c] = beta[c] - m*sc;
  }
}

// ---------------- finish: x = max_k lrelu(bn(y)) ----------------
__global__ __launch_bounds__(256) void k_finish(const float* __restrict__ y, const float* __restrict__ sb,
                                                float* __restrict__ xo){
  int t = threadIdx.x;
  int pt = blockIdx.x*16 + (t>>4), c4 = t&15;
  const float4* base = (const float4*)(y + (size_t)pt*20*64);
  float4 sc = ((const float4*)sb)[c4];
  float4 bi = ((const float4*)(sb+1024))[c4];
  float4 m = make_float4(NEGF,NEGF,NEGF,NEGF);
  #pragma unroll 4
  for(int k=0;k<20;k++){
    float4 v = base[k*16 + c4];
    v.x = lrelu_f(fmaf(v.x, sc.x, bi.x)); v.y = lrelu_f(fmaf(v.y, sc.y, bi.y));
    v.z = lrelu_f(fmaf(v.z, sc.z, bi.z)); v.w = lrelu_f(fmaf(v.w, sc.w, bi.w));
    m.x = fmaxf(m.x,v.x); m.y = fmaxf(m.y,v.y); m.z = fmaxf(m.z,v.z); m.w = fmaxf(m.w,v.w);
  }
  ((float4*)(xo + (size_t)pt*64))[c4] = m;
}

// ---------------- finishUV: x = max_k lrelu(bn(U[j]+V[n])) ----------------
__global__ __launch_bounds__(256) void k_finishUV(const float* __restrict__ U, const float* __restrict__ V,
                                                  const int* __restrict__ idx, const float* __restrict__ sb,
                                                  float* __restrict__ xo){
  int t = threadIdx.x;
  int pt = blockIdx.x*16 + (t>>4), c4 = t&15;
  int b = pt >> 12;
  float4 sc = ((const float4*)sb)[c4];
  float4 bi = ((const float4*)(sb+1024))[c4];
  float4 vv = ((const float4*)(V + (size_t)pt*64))[c4];
  float4 m = make_float4(NEGF,NEGF,NEGF,NEGF);
  const int* ip = idx + (size_t)pt*PK;
  #pragma unroll 4
  for(int k=0;k<PK;k++){
    int j = ip[k];
    float4 uu = ((const float4*)(U + (size_t)(b*PN+j)*64))[c4];
    float4 v;
    v.x = lrelu_f(fmaf(uu.x+vv.x, sc.x, bi.x)); v.y = lrelu_f(fmaf(uu.y+vv.y, sc.y, bi.y));
    v.z = lrelu_f(fmaf(uu.z+vv.z, sc.z, bi.z)); v.w = lrelu_f(fmaf(uu.w+vv.w, sc.w, bi.w));
    m.x = fmaxf(m.x,v.x); m.y = fmaxf(m.y,v.y); m.z = fmaxf(m.z,v.z); m.w = fmaxf(m.w,v.w);
  }
  ((float4*)(xo + (size_t)pt*64))[c4] = m;
}

// ---------------- head GEMM: cat(x1,x2,x3) @ w6^T ----------------
__global__ __launch_bounds__(256) void k_gemm6(const float* __restrict__ x1, const float* __restrict__ x2,
                                               const float* __restrict__ x3, const float* __restrict__ w6,
                                               float* __restrict__ y6){
  __shared__ float cb[128*64];
  __shared__ float wb[64*64];
  int t = threadIdx.x;
  int rb = blockIdx.x >> 4;
  int ob = blockIdx.x & 15;
  size_t r0 = (size_t)rb*128; int o0 = ob*64;
  int prg = t >> 4, cq = t & 15;
  float acc[8][4];
  #pragma unroll
  for(int pp=0;pp<8;pp++)
    #pragma unroll
    for(int oc=0;oc<4;oc++) acc[pp][oc] = 0.f;
  const float* srcs[3] = {x1, x2, x3};
  for(int ph=0; ph<3; ph++){
    __syncthreads();
    const float* src = srcs[ph];
    #pragma unroll
    for(int k=0;k<8;k++){
      int fid = t + k*256; int row = fid>>4, c4 = fid&15;
      ((float4*)cb)[row*16 + (c4^(row&15))] = ((const float4*)(src + (r0+row)*64))[c4];
    }
    #pragma unroll
    for(int k=0;k<4;k++){
      int fid = t + k*256; int row = fid>>4, c4 = fid&15;
      ((float4*)wb)[row*16 + (c4^(row&15))] = ((const float4*)(w6 + (size_t)(o0+row)*192 + ph*64))[c4];
    }
    __syncthreads();
    #pragma unroll 4
    for(int c4=0;c4<16;c4++){
      float4 a[8], b4[4];
      #pragma unroll
      for(int pp=0;pp<8;pp++){ int row = prg*8+pp; a[pp] = ((const float4*)cb)[row*16 + (c4^(row&15))]; }
      #pragma unroll
      for(int oc=0;oc<4;oc++){ int och = cq + 16*oc; b4[oc] = ((const float4*)wb)[och*16 + (c4^(och&15))]; }
      #pragma unroll
      for(int pp=0;pp<8;pp++)
        #pragma unroll
        for(int oc=0;oc<4;oc++) FMA4C(acc[pp][oc], a[pp], b4[oc]);
    }
  }
  #pragma unroll
  for(int pp=0;pp<8;pp++)
    #pragma unroll
    for(int oc=0;oc<4;oc++)
      y6[(r0 + prg*8+pp)*1024 + o0 + cq + 16*oc] = acc[pp][oc];
}

// ---------------- global max over n (bn6+lrelu applied) ----------------
__global__ __launch_bounds__(256) void k_gmax(const float* __restrict__ y6, const float* __restrict__ sb,
                                              float* __restrict__ gpart){
  int t = threadIdx.x; int blk = blockIdx.x;   // 64 blocks x 256 rows
  const float4* base = (const float4*)(y6 + (size_t)blk*256*1024);
  float4 sc = ((const float4*)sb)[t];
  float4 bi = ((const float4*)(sb+1024))[t];
  float4 m = make_float4(NEGF,NEGF,NEGF,NEGF);
  for(int r=0;r<256;r++){
    float4 v = base[r*256 + t];
    v.x = lrelu_f(fmaf(v.x, sc.x, bi.x)); v.y = lrelu_f(fmaf(v.y, sc.y, bi.y));
    v.z = lrelu_f(fmaf(v.z, sc.z, bi.z)); v.w = lrelu_f(fmaf(v.w, sc.w, bi.w));
    m.x = fmaxf(m.x,v.x); m.y = fmaxf(m.y,v.y); m.z = fmaxf(m.z,v.z); m.w = fmaxf(m.w,v.w);
  }
  ((float4*)(gpart + (size_t)blk*1024))[t] = m;
}

__global__ __launch_bounds__(256) void k_gmaxfin(const float* __restrict__ gpart, float* __restrict__ g){
  int b = blockIdx.x, t = threadIdx.x;
  float4 m = make_float4(NEGF,NEGF,NEGF,NEGF);
  for(int c=0;c<16;c++){
    float4 v = ((const float4*)(gpart + ((size_t)b*16 + c)*1024))[t];
    m.x = fmaxf(m.x,v.x); m.y = fmaxf(m.y,v.y); m.z = fmaxf(m.z,v.z); m.w = fmaxf(m.w,v.w);
  }
  ((float4*)(g + (size_t)b*1024))[t] = m;
}

// ---------------- final: bn(g @ wl^T, axis 0) ----------------
__global__ __launch_bounds__(256) void k_final(const float* __restrict__ g, const float* __restrict__ wl,
                                               const float* __restrict__ g7, const float* __restrict__ b7,
                                               float* __restrict__ out){
  int gt = blockIdx.x*256 + threadIdx.x;   // 2048 = 512 o x 4 b
  int o = gt >> 2, b = gt & 3;
  const float4* gb = (const float4*)(g + (size_t)b*1024);
  const float4* wr = (const float4*)(wl + (size_t)o*1024);
  float acc = 0.f;
  #pragma unroll 4
  for(int c=0;c<256;c++){
    float4 a = gb[c], w = wr[c];
    acc = fmaf(a.x,w.x,acc); acc = fmaf(a.y,w.y,acc);
    acc = fmaf(a.z,w.z,acc); acc = fmaf(a.w,w.w,acc);
  }
  float s = acc + __shfl_xor(acc, 1);
  s = s + __shfl_xor(s, 2);
  float m = s * 0.25f;
  float d = acc - m;
  float vv = d*d;
  float v2 = vv + __shfl_xor(vv, 1);
  v2 = v2 + __shfl_xor(v2, 2);
  float var = v2 * 0.25f;
  out[b*512 + o] = d * rsqrtf(var + 1e-5f) * g7[o] + b7[o];
}

// ---------------- launch ----------------
extern "C" void kernel_launch(void* const* d_in, const int* in_sizes, int n_in,
                              void* d_out, int out_size, void* d_ws, size_t ws_size,
                              hipStream_t stream){
  const float* x  = (const float*)d_in[0];
  const float* w1 = (const float*)d_in[1];
  const float* w2 = (const float*)d_in[2];
  const float* w3 = (const float*)d_in[3];
  const float* w4 = (const float*)d_in[4];
  const float* w5 = (const float*)d_in[5];
  const float* w6 = (const float*)d_in[6];
  const float* wl = (const float*)d_in[7];
  const float* g1 = (const float*)d_in[8];  const float* b1 = (const float*)d_in[9];
  const float* g2 = (const float*)d_in[10]; const float* b2 = (const float*)d_in[11];
  const float* g3 = (const float*)d_in[12]; const float* b3 = (const float*)d_in[13];
  const float* g4 = (const float*)d_in[14]; const float* b4 = (const float*)d_in[15];
  const float* g5 = (const float*)d_in[16]; const float* b5 = (const float*)d_in[17];
  const float* g6 = (const float*)d_in[18]; const float* b6 = (const float*)d_in[19];
  const float* g7 = (const float*)d_in[20]; const float* b7 = (const float*)d_in[21];
  float* out = (float*)d_out;

  // workspace layout (floats); ~107.6 MB total
  float* ws    = (float*)d_ws;
  float* xx    = ws;                        // 16384
  int*   idx   = (int*)(ws + 16384);        // 327680
  float* y     = ws + 344064;               // 20971520 (y2/y4, y6)
  float* Dbuf  = y;                         // 16777216 (per-batch 4096x4096 dist; y dead then)
  float* x1    = ws + 21315584;             // 1048576
  float* x2    = x1 + 1048576;
  float* x3    = x2 + 1048576;
  float* part  = x3 + 1048576;              // 262144
  float* sb    = part + 262144;             // 2048
  float* gpart = sb + 2048;                 // 65536
  float* g     = gpart + 65536;             // 4096
  float* U     = g + 4096;                  // 1048576
  float* V     = U + 1048576;               // 1048576

  hipFuncSetAttribute(reinterpret_cast<const void*>(&k_dist64),
                      hipFuncAttributeMaxDynamicSharedMemorySize, 66560);

  // ---- stage 1 ----
  k_xx3<<<64,256,0,stream>>>(x, xx);
  for(int b=0;b<PB;b++){
    k_dist3<<<1024,256,0,stream>>>(x + (size_t)b*3*PN, xx + b*PN, Dbuf);
    k_topk<<<1024,256,0,stream>>>(Dbuf, idx + (size_t)b*PN*PK);
  }
  k_nodeUV3<<<4096,256,0,stream>>>(x, w1, U, V);
  k_statUV<<<512,256,0,stream>>>(U, V, idx, part);
  k_fin<<<4,256,0,stream>>>(part, 512, 64, (float)PNT, g1, b1, sb);
  k_convAF<<<2560,256,0,stream>>>(U, V, idx, w2, sb, y);
  k_red64<<<512,256,0,stream>>>(y, part);
  k_fin<<<4,256,0,stream>>>(part, 512, 64, (float)PNT, g2, b2, sb);
  k_finish<<<1024,256,0,stream>>>(y, sb, x1);

  // ---- stage 2 ----
  k_xx64<<<64,256,0,stream>>>(x1, xx);
  for(int b=0;b<PB;b++){
    k_dist64<<<1024,256,66560,stream>>>(x1 + (size_t)b*PN*64, xx + b*PN, Dbuf);
    k_topk<<<1024,256,0,stream>>>(Dbuf, idx + (size_t)b*PN*PK);
  }
  k_nodeUV64<<<128,256,0,stream>>>(x1, w3, U, V);
  k_statUV<<<512,256,0,stream>>>(U, V, idx, part);
  k_fin<<<4,256,0,stream>>>(part, 512, 64, (float)PNT, g3, b3, sb);
  k_convAF<<<2560,256,0,stream>>>(U, V, idx, w4, sb, y);
  k_red64<<<512,256,0,stream>>>(y, part);
  k_fin<<<4,256,0,stream>>>(part, 512, 64, (float)PNT, g4, b4, sb);
  k_finish<<<1024,256,0,stream>>>(y, sb, x2);

  // ---- stage 3 ----
  k_xx64<<<64,256,0,stream>>>(x2, xx);
  for(int b=0;b<PB;b++){
    k_dist64<<<1024,256,66560,stream>>>(x2 + (size_t)b*PN*64, xx + b*PN, Dbuf);
    k_topk<<<1024,256,0,stream>>>(Dbuf, idx + (size_t)b*PN*PK);
  }
  k_nodeUV64<<<128,256,0,stream>>>(x2, w5, U, V);
  k_statUV<<<512,256,0,stream>>>(U, V, idx, part);
  k_fin<<<4,256,0,stream>>>(part, 512, 64, (float)PNT, g5, b5, sb);
  k_finishUV<<<1024,256,0,stream>>>(U, V, idx, sb, x3);

  // ---- head ----
  k_gemm6<<<2048,256,0,stream>>>(x1, x2, x3, w6, y);
  k_red1024<<<128,256,0,stream>>>(y, part);
  k_fin<<<64,256,0,stream>>>(part, 128, 1024, 16384.f, g6, b6, sb);
  k_gmax<<<64,256,0,stream>>>(y, sb, gpart);
  k_gmaxfin<<<4,256,0,stream>>>(gpart, g);
  k_final<<<8,256,0,stream>>>(g, wl, g7, b7, out);
}

// Round 6
// 1341.036 us; speedup vs baseline: 5.2179x; 1.3115x over previous
//
#include <hip/hip_runtime.h>

static constexpr int PB  = 4;
static constexpr int PN  = 4096;
static constexpr int PK  = 20;
static constexpr int PNT = PB*PN*PK;   // 327680
#define NEGF (-3.402823466e38f)

__device__ __forceinline__ float lrelu_f(float x){ return x >= 0.f ? x : 0.2f*x; }

#define FMA4C(accv, av, bv) { accv = fmaf((av).x,(bv).x,accv); accv = fmaf((av).y,(bv).y,accv); \
                              accv = fmaf((av).z,(bv).z,accv); accv = fmaf((av).w,(bv).w,accv); }

// ---------------- xx (squared norms, stages 2/3) ----------------
__global__ __launch_bounds__(256) void k_xx64(const float* __restrict__ f, float* __restrict__ xx){
  int i = blockIdx.x*256 + threadIdx.x;
  if(i >= PB*PN) return;
  const float4* p = (const float4*)(f + (size_t)i*64);
  float t = 0.f;
  #pragma unroll
  for(int c=0;c<16;c++){ float4 v = p[c];
    t = fmaf(v.x,v.x,t); t = fmaf(v.y,v.y,t); t = fmaf(v.z,v.z,t); t = fmaf(v.w,v.w,t); }
  xx[i] = t;
}

// ---------------- fused stage-1 kNN: all points in LDS, register top-k ----------------
// j encoding: j = lane + 64*e.  Composite (value, -j) ordering => lowest index on ties.
__global__ __launch_bounds__(512) void k_knn3(const float* __restrict__ x, int* __restrict__ idxb){
  __shared__ float4 pts[PN];                      // 64 KB: (x, y, z, xx)
  int t = threadIdx.x;
  int b = blockIdx.y;
  const float* xb = x + (size_t)b*3*PN;
  for(int i=t;i<PN;i+=512){
    float a0 = xb[i], a1 = xb[PN+i], a2 = xb[2*PN+i];
    float s = a0*a0; s = fmaf(a1,a1,s); s = fmaf(a2,a2,s);   // same chain as ref xx
    pts[i] = make_float4(a0,a1,a2,s);
  }
  __syncthreads();
  int lane = t & 63, w = t >> 6;
  int row = blockIdx.x*8 + w;
  float4 pi = pts[row];
  unsigned long long removed = 0ull;

#define KDIST(E) ({ float4 pj_ = pts[lane + ((E)<<6)]; \
    float dt_ = pi.x*pj_.x; dt_ = fmaf(pi.y,pj_.y,dt_); dt_ = fmaf(pi.z,pj_.z,dt_); \
    fmaf(2.f,dt_,-pi.w) - pj_.w; })

  float gv0,gv1,gv2,gv3,gv4,gv5,gv6,gv7;
  int   gi0,gi1,gi2,gi3,gi4,gi5,gi6,gi7;
#define KBUILDG(G) { float gm_=NEGF; int ge_=(G)*8; \
    _Pragma("unroll") for(int e_=(G)*8; e_<(G)*8+8; e_++){ \
      bool ok_ = ((removed >> e_) & 1ull) == 0ull; \
      float d_ = KDIST(e_); \
      bool bt_ = ok_ && (d_ > gm_); gm_ = bt_ ? d_ : gm_; ge_ = bt_ ? e_ : ge_; } \
    gv##G = gm_; gi##G = ge_; }
  KBUILDG(0) KBUILDG(1) KBUILDG(2) KBUILDG(3) KBUILDG(4) KBUILDG(5) KBUILDG(6) KBUILDG(7)

  float lmax; int le;
#define KLBEST { lmax = gv0; le = gi0; \
    if(gv1>lmax){lmax=gv1;le=gi1;} if(gv2>lmax){lmax=gv2;le=gi2;} \
    if(gv3>lmax){lmax=gv3;le=gi3;} if(gv4>lmax){lmax=gv4;le=gi4;} \
    if(gv5>lmax){lmax=gv5;le=gi5;} if(gv6>lmax){lmax=gv6;le=gi6;} \
    if(gv7>lmax){lmax=gv7;le=gi7;} }
  KLBEST

  int myidx = 0;
  for(int k=0;k<PK;k++){
    float bg = lmax; int bj = lane + (le<<6);
    #pragma unroll
    for(int s=1;s<64;s<<=1){
      float og = __shfl_xor(bg, s);
      int   oj = __shfl_xor(bj, s);
      if(og > bg || (og == bg && oj < bj)){ bg = og; bj = oj; }
    }
    if(lane == k) myidx = bj;
    if((bj & 63) == lane){
      int e = bj >> 6;
      removed |= (1ull << e);
      int q = e >> 3;
      if(q==0){ KBUILDG(0) } else if(q==1){ KBUILDG(1) }
      else if(q==2){ KBUILDG(2) } else if(q==3){ KBUILDG(3) }
      else if(q==4){ KBUILDG(4) } else if(q==5){ KBUILDG(5) }
      else if(q==6){ KBUILDG(6) } else { KBUILDG(7) }
      KLBEST
    }
  }
  if(lane < PK) idxb[((size_t)b*PN + row)*PK + lane] = myidx;
#undef KDIST
#undef KBUILDG
#undef KLBEST
}

// ---------------- dist64: symmetric tiled GEMM (upper-triangle blocks) ----------------
__global__ __launch_bounds__(256) void k_dist64(const float* __restrict__ Xb, const float* __restrict__ xxb,
                                                float* __restrict__ D){
  extern __shared__ float sm[];
  float* Xi  = sm;            // 128*64
  float* Xj  = Xi + 128*64;   // 128*64
  float* xxi = Xj + 128*64;   // 128
  float* xxj = xxi + 128;     // 128
  int t = threadIdx.x;
  // triangular decode: p -> (bi,bj), bi<=bj, f(bi)=bi*32 - bi*(bi-1)/2
  int p = blockIdx.x;
  int bi = (int)((65.0f - sqrtf(4225.0f - 8.0f*(float)p)) * 0.5f);
  while((bi+1)*32 - ((bi+1)*bi)/2 <= p) bi++;
  while(bi*32 - (bi*(bi-1))/2 > p) bi--;
  int bj = bi + (p - (bi*32 - (bi*(bi-1))/2));
  int i0 = bi*128, j0 = bj*128;
  #pragma unroll
  for(int k=0;k<8;k++){
    int fid = t + k*256; int row = fid>>4, c4 = fid&15;
    ((float4*)Xi)[row*16 + (c4^(row&15))] = ((const float4*)(Xb + (size_t)(i0+row)*64))[c4];
    ((float4*)Xj)[row*16 + (c4^(row&15))] = ((const float4*)(Xb + (size_t)(j0+row)*64))[c4];
  }
  if(t < 128) xxi[t] = xxb[i0+t];
  else        xxj[t-128] = xxb[j0+t-128];
  __syncthreads();
  int prg = t>>4, cq = t&15;
  float acc[8][8];
  #pragma unroll
  for(int pp=0;pp<8;pp++)
    #pragma unroll
    for(int oc=0;oc<8;oc++) acc[pp][oc] = 0.f;
  #pragma unroll 4
  for(int c4=0;c4<16;c4++){
    float4 a[8], bb[8];
    #pragma unroll
    for(int pp=0;pp<8;pp++){ int row = prg*8+pp; a[pp] = ((const float4*)Xi)[row*16 + (c4^(row&15))]; }
    #pragma unroll
    for(int oc=0;oc<8;oc++){ int col = cq+16*oc;  bb[oc] = ((const float4*)Xj)[col*16 + (c4^(col&15))]; }
    #pragma unroll
    for(int pp=0;pp<8;pp++)
      #pragma unroll
      for(int oc=0;oc<8;oc++) FMA4C(acc[pp][oc], a[pp], bb[oc]);
  }
  // normal write: D[i0+r][j0+c]
  #pragma unroll
  for(int pp=0;pp<8;pp++){
    int r = prg*8+pp;
    float xi2 = xxi[r];
    float* Drow = D + (size_t)(i0+r)*PN + j0;
    #pragma unroll
    for(int oc=0;oc<8;oc++){
      int c = cq + 16*oc;
      Drow[c] = fmaf(2.f, acc[pp][oc], -xi2) - xxj[c];
    }
  }
  // mirrored write: D[j0+c][i0+r]  (bit-identical value for the transposed entry)
  if(bi != bj){
    #pragma unroll
    for(int oc=0;oc<8;oc++){
      int c = cq + 16*oc;
      float xj2 = xxj[c];
      float* Dcol = D + (size_t)(j0+c)*PN + i0 + prg*8;
      float4 t0, t1;
      t0.x = fmaf(2.f, acc[0][oc], -xj2) - xxi[prg*8+0];
      t0.y = fmaf(2.f, acc[1][oc], -xj2) - xxi[prg*8+1];
      t0.z = fmaf(2.f, acc[2][oc], -xj2) - xxi[prg*8+2];
      t0.w = fmaf(2.f, acc[3][oc], -xj2) - xxi[prg*8+3];
      t1.x = fmaf(2.f, acc[4][oc], -xj2) - xxi[prg*8+4];
      t1.y = fmaf(2.f, acc[5][oc], -xj2) - xxi[prg*8+5];
      t1.z = fmaf(2.f, acc[6][oc], -xj2) - xxi[prg*8+6];
      t1.w = fmaf(2.f, acc[7][oc], -xj2) - xxi[prg*8+7];
      ((float4*)Dcol)[0] = t0;
      ((float4*)Dcol)[1] = t1;
    }
  }
}

// ---------------- top-20 per row: one wave per row, 2-level rescan ----------------
__global__ __launch_bounds__(256) void k_topk(const float* __restrict__ D, int* __restrict__ idxb){
  int t = threadIdx.x, lane = t & 63, w = t >> 6;
  int row = blockIdx.x*4 + w;
  const float4* rp = (const float4*)(D + (size_t)row*PN + lane*64);
  float v[64];
  #pragma unroll
  for(int c=0;c<16;c++){
    float4 q = rp[c];
    v[4*c+0]=q.x; v[4*c+1]=q.y; v[4*c+2]=q.z; v[4*c+3]=q.w;
  }
  unsigned long long removed = 0ull;
  float gv0,gv1,gv2,gv3,gv4,gv5,gv6,gv7;
  int   gi0,gi1,gi2,gi3,gi4,gi5,gi6,gi7;
#define TBUILDG(G) { float gm_=NEGF; int ge_=(G)*8; \
    _Pragma("unroll") for(int e_=(G)*8; e_<(G)*8+8; e_++){ \
      bool ok_ = ((removed >> e_) & 1ull) == 0ull; \
      bool bt_ = ok_ && (v[e_] > gm_); gm_ = bt_ ? v[e_] : gm_; ge_ = bt_ ? e_ : ge_; } \
    gv##G = gm_; gi##G = ge_; }
  TBUILDG(0) TBUILDG(1) TBUILDG(2) TBUILDG(3) TBUILDG(4) TBUILDG(5) TBUILDG(6) TBUILDG(7)
  float lmax; int li;
#define TLBEST { lmax = gv0; li = gi0; \
    if(gv1>lmax){lmax=gv1;li=gi1;} if(gv2>lmax){lmax=gv2;li=gi2;} \
    if(gv3>lmax){lmax=gv3;li=gi3;} if(gv4>lmax){lmax=gv4;li=gi4;} \
    if(gv5>lmax){lmax=gv5;li=gi5;} if(gv6>lmax){lmax=gv6;li=gi6;} \
    if(gv7>lmax){lmax=gv7;li=gi7;} }
  TLBEST
  int myidx = 0;
  for(int k=0;k<PK;k++){
    float g = lmax;
    #pragma unroll
    for(int s=32;s>=1;s>>=1) g = fmaxf(g, __shfl_xor(g, s));
    unsigned long long mask = __ballot(lmax == g);
    int wl = __ffsll((unsigned long long)mask) - 1;
    int rel = __shfl(li, wl);
    if(lane == k) myidx = wl*64 + rel;
    if(lane == wl){
      removed |= (1ull << rel);
      int q = rel >> 3;
      if(q==0){ TBUILDG(0) } else if(q==1){ TBUILDG(1) }
      else if(q==2){ TBUILDG(2) } else if(q==3){ TBUILDG(3) }
      else if(q==4){ TBUILDG(4) } else if(q==5){ TBUILDG(5) }
      else if(q==6){ TBUILDG(6) } else { TBUILDG(7) }
      TLBEST
    }
  }
  if(lane < PK) idxb[row*PK + lane] = myidx;
#undef TBUILDG
#undef TLBEST
}

// ---------------- nodeUV: per-node partial convs ----------------
__global__ __launch_bounds__(256) void k_nodeUV3(const float* __restrict__ x, const float* __restrict__ w1,
                                                 float* __restrict__ U, float* __restrict__ V){
  __shared__ float ww[384];
  int t = threadIdx.x;
  for(int k=t;k<384;k+=256) ww[k] = w1[k];
  __syncthreads();
  int g = blockIdx.x*256 + t;
  int ng = g >> 6, o = g & 63;
  int b = ng >> 12, n = ng & 4095;
  const float* xb = x + (size_t)b*3*PN;
  float p0 = xb[n], p1 = xb[PN+n], p2 = xb[2*PN+n];
  const float* wr = ww + o*6;
  float u = p0*wr[0]; u = fmaf(p1,wr[1],u); u = fmaf(p2,wr[2],u);
  float vv = p0*(wr[3]-wr[0]); vv = fmaf(p1, wr[4]-wr[1], vv); vv = fmaf(p2, wr[5]-wr[2], vv);
  U[(size_t)ng*64+o] = u;
  V[(size_t)ng*64+o] = vv;
}

__global__ __launch_bounds__(256) void k_nodeUV64(const float* __restrict__ xf, const float* __restrict__ w,
                                                  float* __restrict__ U, float* __restrict__ V){
  __shared__ float xbuf[128*64];
  __shared__ float wbuf[128*64];
  int t = threadIdx.x;
  int r0 = blockIdx.x * 128;
  #pragma unroll
  for(int k=0;k<8;k++){
    int fid = t + k*256; int row = fid>>4, c4 = fid&15;
    ((float4*)xbuf)[row*16 + (c4^(row&15))] = ((const float4*)(xf + (size_t)(r0+row)*64))[c4];
    float4 wv;
    if(row < 64){
      wv = ((const float4*)(w + (size_t)row*128))[c4];
    } else {
      float4 w2v = ((const float4*)(w + (size_t)(row-64)*128 + 64))[c4];
      float4 w1v = ((const float4*)(w + (size_t)(row-64)*128))[c4];
      wv.x = w2v.x-w1v.x; wv.y = w2v.y-w1v.y; wv.z = w2v.z-w1v.z; wv.w = w2v.w-w1v.w;
    }
    ((float4*)wbuf)[row*16 + (c4^(row&15))] = wv;
  }
  __syncthreads();
  int rg = t>>4, cq = t&15;
  float acc[8][8];
  #pragma unroll
  for(int pp=0;pp<8;pp++)
    #pragma unroll
    for(int oc=0;oc<8;oc++) acc[pp][oc] = 0.f;
  #pragma unroll 4
  for(int c4=0;c4<16;c4++){
    float4 a[8], bb[8];
    #pragma unroll
    for(int pp=0;pp<8;pp++){ int row = rg*8+pp; a[pp] = ((const float4*)xbuf)[row*16 + (c4^(row&15))]; }
    #pragma unroll
    for(int oc=0;oc<8;oc++){ int col = cq+16*oc;  bb[oc] = ((const float4*)wbuf)[col*16 + (c4^(col&15))]; }
    #pragma unroll
    for(int pp=0;pp<8;pp++)
      #pragma unroll
      for(int oc=0;oc<8;oc++) FMA4C(acc[pp][oc], a[pp], bb[oc]);
  }
  #pragma unroll
  for(int pp=0;pp<8;pp++){
    int r = r0 + rg*8+pp;
    #pragma unroll
    for(int oc=0;oc<8;oc++){
      int col = cq + 16*oc;
      if(col < 64) U[(size_t)r*64 + col] = acc[pp][oc];
      else         V[(size_t)r*64 + col-64] = acc[pp][oc];
    }
  }
}

// ---------------- BN stats over edges of y = U[j]+V[n] ----------------
__global__ __launch_bounds__(256) void k_statUV(const float* __restrict__ U, const float* __restrict__ V,
                                                const int* __restrict__ idx, float* __restrict__ part){
  __shared__ float ls[512];
  int t = threadIdx.x; int blk = blockIdx.x;
  int ch = t & 63, sub = t >> 6;
  int qbase = blk*640;
  float s = 0.f, qq = 0.f;
  for(int r=sub; r<640; r+=4){
    int q = qbase + r;
    int pt = q/PK;
    int b = pt >> 12;
    int j = idx[q];
    float yv = U[(size_t)(b*PN+j)*64 + ch] + V[(size_t)pt*64 + ch];
    s += yv; qq = fmaf(yv,yv,qq);
  }
  ls[t] = s; ls[256+t] = qq;
  __syncthreads();
  if(t < 64){
    float S = ls[t]+ls[64+t]+ls[128+t]+ls[192+t];
    float Q = ls[256+t]+ls[320+t]+ls[384+t]+ls[448+t];
    part[(size_t)blk*128 + t] = S; part[(size_t)blk*128 + 64 + t] = Q;
  }
}

// ---------------- convA fused: y_out := W(64x64) . lrelu(bn(U[j]+V[n])) ----------------
__global__ __launch_bounds__(256) void k_convAF(const float* __restrict__ U, const float* __restrict__ V,
                                                const int* __restrict__ idx, const float* __restrict__ wg,
                                                const float* __restrict__ sb, float* __restrict__ y){
  __shared__ float hbuf[128*64];
  __shared__ float wbuf[64*64];
  int t = threadIdx.x;
  int q0 = blockIdx.x * 128;
  #pragma unroll
  for(int k=0;k<8;k++){
    int fid = t + k*256; int row = fid>>4, c4 = fid&15;
    int q = q0 + row;
    int pt = q/PK; int b = pt>>12; int j = idx[q];
    float4 uu = ((const float4*)(U + (size_t)(b*PN+j)*64))[c4];
    float4 vv = ((const float4*)(V + (size_t)pt*64))[c4];
    float4 sc = ((const float4*)sb)[c4];
    float4 bi = ((const float4*)(sb+1024))[c4];
    float4 h;
    h.x = lrelu_f(fmaf(uu.x+vv.x, sc.x, bi.x));
    h.y = lrelu_f(fmaf(uu.y+vv.y, sc.y, bi.y));
    h.z = lrelu_f(fmaf(uu.z+vv.z, sc.z, bi.z));
    h.w = lrelu_f(fmaf(uu.w+vv.w, sc.w, bi.w));
    ((float4*)hbuf)[row*16 + (c4 ^ (row&15))] = h;
  }
  #pragma unroll
  for(int k=0;k<4;k++){
    int fid = t + k*256; int row = fid>>4, c4 = fid&15;
    ((float4*)wbuf)[row*16 + (c4 ^ (row&15))] = ((const float4*)(wg + row*64))[c4];
  }
  __syncthreads();
  int prg = t >> 4, cq = t & 15;
  float acc[8][4];
  #pragma unroll
  for(int pp=0;pp<8;pp++)
    #pragma unroll
    for(int oc=0;oc<4;oc++) acc[pp][oc] = 0.f;
  #pragma unroll 4
  for(int c4=0;c4<16;c4++){
    float4 a[8], b4[4];
    #pragma unroll
    for(int pp=0;pp<8;pp++){ int row = prg*8+pp; a[pp] = ((const float4*)hbuf)[row*16 + (c4^(row&15))]; }
    #pragma unroll
    for(int oc=0;oc<4;oc++){ int och = cq + 16*oc; b4[oc] = ((const float4*)wbuf)[och*16 + (c4^(och&15))]; }
    #pragma unroll
    for(int pp=0;pp<8;pp++)
      #pragma unroll
      for(int oc=0;oc<4;oc++) FMA4C(acc[pp][oc], a[pp], b4[oc]);
  }
  #pragma unroll
  for(int pp=0;pp<8;pp++)
    #pragma unroll
    for(int oc=0;oc<4;oc++)
      y[(size_t)(q0 + prg*8+pp)*64 + cq + 16*oc] = acc[pp][oc];
}

// ---------------- BN statistics (materialized y) ----------------
__global__ __launch_bounds__(256) void k_red64(const float* __restrict__ y, float* __restrict__ part){
  __shared__ float ls[512];
  int t = threadIdx.x; int blk = blockIdx.x;
  int ch = t & 63, sub = t >> 6;
  const float* base = y + (size_t)blk*640*64;
  float s = 0.f, q = 0.f;
  for(int r=sub; r<640; r+=4){ float v = base[(size_t)r*64 + ch]; s += v; q = fmaf(v,v,q); }
  ls[t] = s; ls[256+t] = q;
  __syncthreads();
  if(t < 64){
    float S = ls[t]+ls[64+t]+ls[128+t]+ls[192+t];
    float Q = ls[256+t]+ls[320+t]+ls[384+t]+ls[448+t];
    part[(size_t)blk*128 + t] = S; part[(size_t)blk*128 + 64 + t] = Q;
  }
}

__global__ __launch_bounds__(256) void k_red1024(const float* __restrict__ y6, float* __restrict__ part){
  int t = threadIdx.x; int blk = blockIdx.x;   // 128 blocks x 128 rows
  const float4* base = (const float4*)(y6 + (size_t)blk*128*1024);
  float4 s = make_float4(0,0,0,0), q = make_float4(0,0,0,0);
  for(int r=0;r<128;r++){
    float4 v = base[r*256 + t];
    s.x += v.x; s.y += v.y; s.z += v.z; s.w += v.w;
    q.x = fmaf(v.x,v.x,q.x); q.y = fmaf(v.y,v.y,q.y); q.z = fmaf(v.z,v.z,q.z); q.w = fmaf(v.w,v.w,q.w);
  }
  ((float4*)(part + (size_t)blk*2048))[t] = s;
  ((float4*)(part + (size_t)blk*2048 + 1024))[t] = q;
}

// ---------------- finalize BN affine: parallel partial-sum reduce ----------------
__global__ __launch_bounds__(256) void k_fin(const float* __restrict__ part, int nparts, int chn, float cnt,
                                             const float* __restrict__ gamma, const float* __restrict__ beta,
                                             float* __restrict__ sb){
  __shared__ float ls[512];
  int t = threadIdx.x;
  int chl = t & 15, sub = t >> 4;
  int ch = blockIdx.x*16 + chl;
  float S = 0.f, Q = 0.f;
  for(int p=sub; p<nparts; p+=16){
    S += part[(size_t)p*2*chn + ch];
    Q += part[(size_t)p*2*chn + chn + ch];
  }
  ls[t] = S; ls[256+t] = Q;
  __syncthreads();
  if(t < 16){
    float Sa = 0.f, Qa = 0.f;
    #pragma unroll
    for(int s=0;s<16;s++){ Sa += ls[s*16+t]; Qa += ls[256+s*16+t]; }
    int c = blockIdx.x*16 + t;
    float m  = Sa/cnt;
    float vr = Qa/cnt - m*m;
    float sc = gamma[c] * rsqrtf(vr + 1e-5f);
    sb[c] = sc; sb[1024+c] = beta[c] - m*sc;
  }
}

// ---------------- finish: x = max_k lrelu(bn(y)) ----------------
__global__ __launch_bounds__(256) void k_finish(const float* __restrict__ y, const float* __restrict__ sb,
                                                float* __restrict__ xo){
  int t = threadIdx.x;
  int pt = blockIdx.x*16 + (t>>4), c4 = t&15;
  const float4* base = (const float4*)(y + (size_t)pt*20*64);
  float4 sc = ((const float4*)sb)[c4];
  float4 bi = ((const float4*)(sb+1024))[c4];
  float4 m = make_float4(NEGF,NEGF,NEGF,NEGF);
  #pragma unroll 4
  for(int k=0;k<20;k++){
    float4 v = base[k*16 + c4];
    v.x = lrelu_f(fmaf(v.x, sc.x, bi.x)); v.y = lrelu_f(fmaf(v.y, sc.y, bi.y));
    v.z = lrelu_f(fmaf(v.z, sc.z, bi.z)); v.w = lrelu_f(fmaf(v.w, sc.w, bi.w));
    m.x = fmaxf(m.x,v.x); m.y = fmaxf(m.y,v.y); m.z = fmaxf(m.z,v.z); m.w = fmaxf(m.w,v.w);
  }
  ((float4*)(xo + (size_t)pt*64))[c4] = m;
}

// ---------------- finishUV: x = max_k lrelu(bn(U[j]+V[n])) ----------------
__global__ __launch_bounds__(256) void k_finishUV(const float* __restrict__ U, const float* __restrict__ V,
                                                  const int* __restrict__ idx, const float* __restrict__ sb,
                                                  float* __restrict__ xo){
  int t = threadIdx.x;
  int pt = blockIdx.x*16 + (t>>4), c4 = t&15;
  int b = pt >> 12;
  float4 sc = ((const float4*)sb)[c4];
  float4 bi = ((const float4*)(sb+1024))[c4];
  float4 vv = ((const float4*)(V + (size_t)pt*64))[c4];
  float4 m = make_float4(NEGF,NEGF,NEGF,NEGF);
  const int* ip = idx + (size_t)pt*PK;
  #pragma unroll 4
  for(int k=0;k<PK;k++){
    int j = ip[k];
    float4 uu = ((const float4*)(U + (size_t)(b*PN+j)*64))[c4];
    float4 v;
    v.x = lrelu_f(fmaf(uu.x+vv.x, sc.x, bi.x)); v.y = lrelu_f(fmaf(uu.y+vv.y, sc.y, bi.y));
    v.z = lrelu_f(fmaf(uu.z+vv.z, sc.z, bi.z)); v.w = lrelu_f(fmaf(uu.w+vv.w, sc.w, bi.w));
    m.x = fmaxf(m.x,v.x); m.y = fmaxf(m.y,v.y); m.z = fmaxf(m.z,v.z); m.w = fmaxf(m.w,v.w);
  }
  ((float4*)(xo + (size_t)pt*64))[c4] = m;
}

// ---------------- head GEMM: cat(x1,x2,x3) @ w6^T ----------------
__global__ __launch_bounds__(256) void k_gemm6(const float* __restrict__ x1, const float* __restrict__ x2,
                                               const float* __restrict__ x3, const float* __restrict__ w6,
                                               float* __restrict__ y6){
  __shared__ float cb[128*64];
  __shared__ float wb[64*64];
  int t = threadIdx.x;
  int rb = blockIdx.x >> 4;
  int ob = blockIdx.x & 15;
  size_t r0 = (size_t)rb*128; int o0 = ob*64;
  int prg = t >> 4, cq = t & 15;
  float acc[8][4];
  #pragma unroll
  for(int pp=0;pp<8;pp++)
    #pragma unroll
    for(int oc=0;oc<4;oc++) acc[pp][oc] = 0.f;
  const float* srcs[3] = {x1, x2, x3};
  for(int ph=0; ph<3; ph++){
    __syncthreads();
    const float* src = srcs[ph];
    #pragma unroll
    for(int k=0;k<8;k++){
      int fid = t + k*256; int row = fid>>4, c4 = fid&15;
      ((float4*)cb)[row*16 + (c4^(row&15))] = ((const float4*)(src + (r0+row)*64))[c4];
    }
    #pragma unroll
    for(int k=0;k<4;k++){
      int fid = t + k*256; int row = fid>>4, c4 = fid&15;
      ((float4*)wb)[row*16 + (c4^(row&15))] = ((const float4*)(w6 + (size_t)(o0+row)*192 + ph*64))[c4];
    }
    __syncthreads();
    #pragma unroll 4
    for(int c4=0;c4<16;c4++){
      float4 a[8], b4[4];
      #pragma unroll
      for(int pp=0;pp<8;pp++){ int row = prg*8+pp; a[pp] = ((const float4*)cb)[row*16 + (c4^(row&15))]; }
      #pragma unroll
      for(int oc=0;oc<4;oc++){ int och = cq + 16*oc; b4[oc] = ((const float4*)wb)[och*16 + (c4^(och&15))]; }
      #pragma unroll
      for(int pp=0;pp<8;pp++)
        #pragma unroll
        for(int oc=0;oc<4;oc++) FMA4C(acc[pp][oc], a[pp], b4[oc]);
    }
  }
  #pragma unroll
  for(int pp=0;pp<8;pp++)
    #pragma unroll
    for(int oc=0;oc<4;oc++)
      y6[(r0 + prg*8+pp)*1024 + o0 + cq + 16*oc] = acc[pp][oc];
}

// ---------------- global max over n (bn6+lrelu applied) ----------------
__global__ __launch_bounds__(256) void k_gmax(const float* __restrict__ y6, const float* __restrict__ sb,
                                              float* __restrict__ gpart){
  int t = threadIdx.x; int blk = blockIdx.x;   // 64 blocks x 256 rows
  const float4* base = (const float4*)(y6 + (size_t)blk*256*1024);
  float4 sc = ((const float4*)sb)[t];
  float4 bi = ((const float4*)(sb+1024))[t];
  float4 m = make_float4(NEGF,NEGF,NEGF,NEGF);
  for(int r=0;r<256;r++){
    float4 v = base[r*256 + t];
    v.x = lrelu_f(fmaf(v.x, sc.x, bi.x)); v.y = lrelu_f(fmaf(v.y, sc.y, bi.y));
    v.z = lrelu_f(fmaf(v.z, sc.z, bi.z)); v.w = lrelu_f(fmaf(v.w, sc.w, bi.w));
    m.x = fmaxf(m.x,v.x); m.y = fmaxf(m.y,v.y); m.z = fmaxf(m.z,v.z); m.w = fmaxf(m.w,v.w);
  }
  ((float4*)(gpart + (size_t)blk*1024))[t] = m;
}

__global__ __launch_bounds__(256) void k_gmaxfin(const float* __restrict__ gpart, float* __restrict__ g){
  int b = blockIdx.x, t = threadIdx.x;
  float4 m = make_float4(NEGF,NEGF,NEGF,NEGF);
  for(int c=0;c<16;c++){
    float4 v = ((const float4*)(gpart + ((size_t)b*16 + c)*1024))[t];
    m.x = fmaxf(m.x,v.x); m.y = fmaxf(m.y,v.y); m.z = fmaxf(m.z,v.z); m.w = fmaxf(m.w,v.w);
  }
  ((float4*)(g + (size_t)b*1024))[t] = m;
}

// ---------------- final: bn(g @ wl^T, axis 0) ----------------
__global__ __launch_bounds__(256) void k_final(const float* __restrict__ g, const float* __restrict__ wl,
                                               const float* __restrict__ g7, const float* __restrict__ b7,
                                               float* __restrict__ out){
  int gt = blockIdx.x*256 + threadIdx.x;   // 2048 = 512 o x 4 b
  int o = gt >> 2, b = gt & 3;
  const float4* gb = (const float4*)(g + (size_t)b*1024);
  const float4* wr = (const float4*)(wl + (size_t)o*1024);
  float acc = 0.f;
  #pragma unroll 4
  for(int c=0;c<256;c++){
    float4 a = gb[c], w = wr[c];
    acc = fmaf(a.x,w.x,acc); acc = fmaf(a.y,w.y,acc);
    acc = fmaf(a.z,w.z,acc); acc = fmaf(a.w,w.w,acc);
  }
  float s = acc + __shfl_xor(acc, 1);
  s = s + __shfl_xor(s, 2);
  float m = s * 0.25f;
  float d = acc - m;
  float vv = d*d;
  float v2 = vv + __shfl_xor(vv, 1);
  v2 = v2 + __shfl_xor(v2, 2);
  float var = v2 * 0.25f;
  out[b*512 + o] = d * rsqrtf(var + 1e-5f) * g7[o] + b7[o];
}

// ---------------- launch ----------------
extern "C" void kernel_launch(void* const* d_in, const int* in_sizes, int n_in,
                              void* d_out, int out_size, void* d_ws, size_t ws_size,
                              hipStream_t stream){
  const float* x  = (const float*)d_in[0];
  const float* w1 = (const float*)d_in[1];
  const float* w2 = (const float*)d_in[2];
  const float* w3 = (const float*)d_in[3];
  const float* w4 = (const float*)d_in[4];
  const float* w5 = (const float*)d_in[5];
  const float* w6 = (const float*)d_in[6];
  const float* wl = (const float*)d_in[7];
  const float* g1 = (const float*)d_in[8];  const float* b1 = (const float*)d_in[9];
  const float* g2 = (const float*)d_in[10]; const float* b2 = (const float*)d_in[11];
  const float* g3 = (const float*)d_in[12]; const float* b3 = (const float*)d_in[13];
  const float* g4 = (const float*)d_in[14]; const float* b4 = (const float*)d_in[15];
  const float* g5 = (const float*)d_in[16]; const float* b5 = (const float*)d_in[17];
  const float* g6 = (const float*)d_in[18]; const float* b6 = (const float*)d_in[19];
  const float* g7 = (const float*)d_in[20]; const float* b7 = (const float*)d_in[21];
  float* out = (float*)d_out;

  // workspace layout (floats); ~107.6 MB total
  float* ws    = (float*)d_ws;
  float* xx    = ws;                        // 16384
  int*   idx   = (int*)(ws + 16384);        // 327680
  float* y     = ws + 344064;               // 20971520 (y2/y4, y6)
  float* Dbuf  = y;                         // 16777216 (per-batch 4096x4096 dist; y dead then)
  float* x1    = ws + 21315584;             // 1048576
  float* x2    = x1 + 1048576;
  float* x3    = x2 + 1048576;
  float* part  = x3 + 1048576;              // 262144
  float* sb    = part + 262144;             // 2048
  float* gpart = sb + 2048;                 // 65536
  float* g     = gpart + 65536;             // 4096
  float* U     = g + 4096;                  // 1048576
  float* V     = U + 1048576;               // 1048576

  hipFuncSetAttribute(reinterpret_cast<const void*>(&k_dist64),
                      hipFuncAttributeMaxDynamicSharedMemorySize, 66560);

  // ---- stage 1 ----
  k_knn3<<<dim3(512,4),512,0,stream>>>(x, idx);
  k_nodeUV3<<<4096,256,0,stream>>>(x, w1, U, V);
  k_statUV<<<512,256,0,stream>>>(U, V, idx, part);
  k_fin<<<4,256,0,stream>>>(part, 512, 64, (float)PNT, g1, b1, sb);
  k_convAF<<<2560,256,0,stream>>>(U, V, idx, w2, sb, y);
  k_red64<<<512,256,0,stream>>>(y, part);
  k_fin<<<4,256,0,stream>>>(part, 512, 64, (float)PNT, g2, b2, sb);
  k_finish<<<1024,256,0,stream>>>(y, sb, x1);

  // ---- stage 2 ----
  k_xx64<<<64,256,0,stream>>>(x1, xx);
  for(int b=0;b<PB;b++){
    k_dist64<<<528,256,66560,stream>>>(x1 + (size_t)b*PN*64, xx + b*PN, Dbuf);
    k_topk<<<1024,256,0,stream>>>(Dbuf, idx + (size_t)b*PN*PK);
  }
  k_nodeUV64<<<128,256,0,stream>>>(x1, w3, U, V);
  k_statUV<<<512,256,0,stream>>>(U, V, idx, part);
  k_fin<<<4,256,0,stream>>>(part, 512, 64, (float)PNT, g3, b3, sb);
  k_convAF<<<2560,256,0,stream>>>(U, V, idx, w4, sb, y);
  k_red64<<<512,256,0,stream>>>(y, part);
  k_fin<<<4,256,0,stream>>>(part, 512, 64, (float)PNT, g4, b4, sb);
  k_finish<<<1024,256,0,stream>>>(y, sb, x2);

  // ---- stage 3 ----
  k_xx64<<<64,256,0,stream>>>(x2, xx);
  for(int b=0;b<PB;b++){
    k_dist64<<<528,256,66560,stream>>>(x2 + (size_t)b*PN*64, xx + b*PN, Dbuf);
    k_topk<<<1024,256,0,stream>>>(Dbuf, idx + (size_t)b*PN*PK);
  }
  k_nodeUV64<<<128,256,0,stream>>>(x2, w5, U, V);
  k_statUV<<<512,256,0,stream>>>(U, V, idx, part);
  k_fin<<<4,256,0,stream>>>(part, 512, 64, (float)PNT, g5, b5, sb);
  k_finishUV<<<1024,256,0,stream>>>(U, V, idx, sb, x3);

  // ---- head ----
  k_gemm6<<<2048,256,0,stream>>>(x1, x2, x3, w6, y);
  k_red1024<<<128,256,0,stream>>>(y, part);
  k_fin<<<64,256,0,stream>>>(part, 128, 1024, 16384.f, g6, b6, sb);
  k_gmax<<<64,256,0,stream>>>(y, sb, gpart);
  k_gmaxfin<<<4,256,0,stream>>>(gpart, g);
  k_final<<<8,256,0,stream>>>(g, wl, g7, b7, out);
}

// Round 7
// 1253.923 us; speedup vs baseline: 5.5804x; 1.0695x over previous
//
#include <hip/hip_runtime.h>

static constexpr int PB  = 4;
static constexpr int PN  = 4096;
static constexpr int PK  = 20;
static constexpr int PNT = PB*PN*PK;   // 327680
#define NEGF (-3.402823466e38f)

__device__ __forceinline__ float lrelu_f(float x){ return x >= 0.f ? x : 0.2f*x; }

__device__ __forceinline__ unsigned int ordf(float v){
  unsigned int u = __float_as_uint(v);
  unsigned int mask = ((unsigned int)(((int)u) >> 31)) | 0x80000000u;
  return u ^ mask;
}

#define FMA4C(accv, av, bv) { accv = fmaf((av).x,(bv).x,accv); accv = fmaf((av).y,(bv).y,accv); \
                              accv = fmaf((av).z,(bv).z,accv); accv = fmaf((av).w,(bv).w,accv); }

// ---------------- fused stage-1 kNN: all points in LDS, register top-k ----------------
// j encoding: j = lane + 64*e.  Packed key (value, ~j): max => highest value, lowest j.
__global__ __launch_bounds__(512) void k_knn3(const float* __restrict__ x, int* __restrict__ idxb){
  __shared__ float4 pts[PN];                      // 64 KB: (x, y, z, xx)
  int t = threadIdx.x;
  int b = blockIdx.y;
  const float* xb = x + (size_t)b*3*PN;
  for(int i=t;i<PN;i+=512){
    float a0 = xb[i], a1 = xb[PN+i], a2 = xb[2*PN+i];
    float s = a0*a0; s = fmaf(a1,a1,s); s = fmaf(a2,a2,s);
    pts[i] = make_float4(a0,a1,a2,s);
  }
  __syncthreads();
  int lane = t & 63, w = t >> 6;
  int row = blockIdx.x*8 + w;
  float4 pi = pts[row];
  unsigned long long removed = 0ull;

#define KDIST(E) ({ float4 pj_ = pts[lane + ((E)<<6)]; \
    float dt_ = pi.x*pj_.x; dt_ = fmaf(pi.y,pj_.y,dt_); dt_ = fmaf(pi.z,pj_.z,dt_); \
    fmaf(2.f,dt_,-pi.w) - pj_.w; })

  float gv0,gv1,gv2,gv3,gv4,gv5,gv6,gv7;
  int   gi0,gi1,gi2,gi3,gi4,gi5,gi6,gi7;
#define KBUILDG(G) { float gm_=NEGF; int ge_=(G)*8; \
    _Pragma("unroll") for(int e_=(G)*8; e_<(G)*8+8; e_++){ \
      bool ok_ = ((removed >> e_) & 1ull) == 0ull; \
      float d_ = KDIST(e_); \
      bool bt_ = ok_ && (d_ > gm_); gm_ = bt_ ? d_ : gm_; ge_ = bt_ ? e_ : ge_; } \
    gv##G = gm_; gi##G = ge_; }
  KBUILDG(0) KBUILDG(1) KBUILDG(2) KBUILDG(3) KBUILDG(4) KBUILDG(5) KBUILDG(6) KBUILDG(7)

  float lmax; int le;
#define KLBEST { lmax = gv0; le = gi0; \
    if(gv1>lmax){lmax=gv1;le=gi1;} if(gv2>lmax){lmax=gv2;le=gi2;} \
    if(gv3>lmax){lmax=gv3;le=gi3;} if(gv4>lmax){lmax=gv4;le=gi4;} \
    if(gv5>lmax){lmax=gv5;le=gi5;} if(gv6>lmax){lmax=gv6;le=gi6;} \
    if(gv7>lmax){lmax=gv7;le=gi7;} }
  KLBEST

  int myidx = 0;
  for(int k=0;k<PK;k++){
    unsigned long long key = ((unsigned long long)ordf(lmax) << 32) |
                             (unsigned int)(~(lane + (le<<6)));
    #pragma unroll
    for(int s=1;s<64;s<<=1){
      unsigned long long o = __shfl_xor(key, s);
      if(o > key) key = o;
    }
    int jw = (int)(~((unsigned int)key));       // global j of winner
    if(lane == k) myidx = jw;
    if((jw & 63) == lane){
      int e = jw >> 6;
      removed |= (1ull << e);
      int q = e >> 3;
      if(q==0){ KBUILDG(0) } else if(q==1){ KBUILDG(1) }
      else if(q==2){ KBUILDG(2) } else if(q==3){ KBUILDG(3) }
      else if(q==4){ KBUILDG(4) } else if(q==5){ KBUILDG(5) }
      else if(q==6){ KBUILDG(6) } else { KBUILDG(7) }
      KLBEST
    }
  }
  if(lane < PK) idxb[((size_t)b*PN + row)*PK + lane] = myidx;
#undef KDIST
#undef KBUILDG
#undef KLBEST
}

// ---------------- dist64: symmetric tiled GEMM, K split in 2 (33 KB LDS, 4 blocks/CU) ----------------
__global__ __launch_bounds__(256) void k_dist64(const float* __restrict__ Xb, const float* __restrict__ xxb,
                                                float* __restrict__ D){
  __shared__ float Xi[128*32];
  __shared__ float Xj[128*32];
  __shared__ float xxi[128], xxj[128];
  int t = threadIdx.x;
  // triangular decode: p -> (bi,bj), bi<=bj
  int p = blockIdx.x;
  int bi = (int)((65.0f - sqrtf(4225.0f - 8.0f*(float)p)) * 0.5f);
  while((bi+1)*32 - ((bi+1)*bi)/2 <= p) bi++;
  while(bi*32 - (bi*(bi-1))/2 > p) bi--;
  int bj = bi + (p - (bi*32 - (bi*(bi-1))/2));
  int i0 = bi*128, j0 = bj*128;
  int prg = t>>4, cq = t&15;
  float acc[8][8];
  #pragma unroll
  for(int pp=0;pp<8;pp++)
    #pragma unroll
    for(int oc=0;oc<8;oc++) acc[pp][oc] = 0.f;

  for(int h=0;h<2;h++){
    if(h) __syncthreads();
    #pragma unroll
    for(int k=0;k<4;k++){
      int fid = t + k*256; int row = fid>>3, c4 = fid&7;
      ((float4*)Xi)[row*8 + (c4^(row&7))] = ((const float4*)(Xb + (size_t)(i0+row)*64 + h*32))[c4];
      ((float4*)Xj)[row*8 + (c4^(row&7))] = ((const float4*)(Xb + (size_t)(j0+row)*64 + h*32))[c4];
    }
    if(h==0){
      if(t < 128) xxi[t] = xxb[i0+t];
      else        xxj[t-128] = xxb[j0+t-128];
    }
    __syncthreads();
    #pragma unroll 4
    for(int c4=0;c4<8;c4++){
      float4 a[8], bb[8];
      #pragma unroll
      for(int pp=0;pp<8;pp++){ int row = prg*8+pp; a[pp] = ((const float4*)Xi)[row*8 + (c4^(row&7))]; }
      #pragma unroll
      for(int oc=0;oc<8;oc++){ int col = cq+16*oc;  bb[oc] = ((const float4*)Xj)[col*8 + (c4^(col&7))]; }
      #pragma unroll
      for(int pp=0;pp<8;pp++)
        #pragma unroll
        for(int oc=0;oc<8;oc++) FMA4C(acc[pp][oc], a[pp], bb[oc]);
    }
  }
  #pragma unroll
  for(int pp=0;pp<8;pp++){
    int r = prg*8+pp;
    float xi2 = xxi[r];
    float* Drow = D + (size_t)(i0+r)*PN + j0;
    #pragma unroll
    for(int oc=0;oc<8;oc++){
      int c = cq + 16*oc;
      Drow[c] = fmaf(2.f, acc[pp][oc], -xi2) - xxj[c];
    }
  }
  if(bi != bj){
    #pragma unroll
    for(int oc=0;oc<8;oc++){
      int c = cq + 16*oc;
      float xj2 = xxj[c];
      float* Dcol = D + (size_t)(j0+c)*PN + i0 + prg*8;
      float4 t0, t1;
      t0.x = fmaf(2.f, acc[0][oc], -xj2) - xxi[prg*8+0];
      t0.y = fmaf(2.f, acc[1][oc], -xj2) - xxi[prg*8+1];
      t0.z = fmaf(2.f, acc[2][oc], -xj2) - xxi[prg*8+2];
      t0.w = fmaf(2.f, acc[3][oc], -xj2) - xxi[prg*8+3];
      t1.x = fmaf(2.f, acc[4][oc], -xj2) - xxi[prg*8+4];
      t1.y = fmaf(2.f, acc[5][oc], -xj2) - xxi[prg*8+5];
      t1.z = fmaf(2.f, acc[6][oc], -xj2) - xxi[prg*8+6];
      t1.w = fmaf(2.f, acc[7][oc], -xj2) - xxi[prg*8+7];
      ((float4*)Dcol)[0] = t0;
      ((float4*)Dcol)[1] = t1;
    }
  }
}

// ---------------- top-20 per row: one wave per row, poison rebuild ----------------
__global__ __launch_bounds__(256) void k_topk(const float* __restrict__ D, int* __restrict__ idxb){
  int t = threadIdx.x, lane = t & 63, w = t >> 6;
  int row = blockIdx.x*4 + w;
  const float4* rp = (const float4*)(D + (size_t)row*PN + lane*64);
  float v[64];
  #pragma unroll
  for(int c=0;c<16;c++){
    float4 q = rp[c];
    v[4*c+0]=q.x; v[4*c+1]=q.y; v[4*c+2]=q.z; v[4*c+3]=q.w;
  }
  float gv0,gv1,gv2,gv3,gv4,gv5,gv6,gv7;
  int   gi0,gi1,gi2,gi3,gi4,gi5,gi6,gi7;
#define TBUILDG(G) { float gm_=NEGF; int ge_=(G)*8; \
    _Pragma("unroll") for(int e_=(G)*8; e_<(G)*8+8; e_++){ \
      bool bt_ = v[e_] > gm_; gm_ = bt_ ? v[e_] : gm_; ge_ = bt_ ? e_ : ge_; } \
    gv##G = gm_; gi##G = ge_; }
#define TPOIS(G) { _Pragma("unroll") for(int e_=(G)*8; e_<(G)*8+8; e_++){ \
      if(e_ == rel) v[e_] = NEGF; } }
  TBUILDG(0) TBUILDG(1) TBUILDG(2) TBUILDG(3) TBUILDG(4) TBUILDG(5) TBUILDG(6) TBUILDG(7)
  float lmax; int li;
#define TLBEST { lmax = gv0; li = gi0; \
    if(gv1>lmax){lmax=gv1;li=gi1;} if(gv2>lmax){lmax=gv2;li=gi2;} \
    if(gv3>lmax){lmax=gv3;li=gi3;} if(gv4>lmax){lmax=gv4;li=gi4;} \
    if(gv5>lmax){lmax=gv5;li=gi5;} if(gv6>lmax){lmax=gv6;li=gi6;} \
    if(gv7>lmax){lmax=gv7;li=gi7;} }
  TLBEST
  int myidx = 0;
  for(int k=0;k<PK;k++){
    float g = lmax;
    #pragma unroll
    for(int s=32;s>=1;s>>=1) g = fmaxf(g, __shfl_xor(g, s));
    unsigned long long mask = __ballot(lmax == g);
    int wl = __ffsll((unsigned long long)mask) - 1;
    int rel = __shfl(li, wl);
    if(lane == k) myidx = wl*64 + rel;
    if(lane == wl){
      int q = rel >> 3;
      if(q==0){ TPOIS(0) TBUILDG(0) } else if(q==1){ TPOIS(1) TBUILDG(1) }
      else if(q==2){ TPOIS(2) TBUILDG(2) } else if(q==3){ TPOIS(3) TBUILDG(3) }
      else if(q==4){ TPOIS(4) TBUILDG(4) } else if(q==5){ TPOIS(5) TBUILDG(5) }
      else if(q==6){ TPOIS(6) TBUILDG(6) } else { TPOIS(7) TBUILDG(7) }
      TLBEST
    }
  }
  if(lane < PK) idxb[row*PK + lane] = myidx;
#undef TBUILDG
#undef TPOIS
#undef TLBEST
}

// ---------------- nodeUV: per-node partial convs ----------------
__global__ __launch_bounds__(256) void k_nodeUV3(const float* __restrict__ x, const float* __restrict__ w1,
                                                 float* __restrict__ U, float* __restrict__ V){
  __shared__ float ww[384];
  int t = threadIdx.x;
  for(int k=t;k<384;k+=256) ww[k] = w1[k];
  __syncthreads();
  int g = blockIdx.x*256 + t;
  int ng = g >> 6, o = g & 63;
  int b = ng >> 12, n = ng & 4095;
  const float* xb = x + (size_t)b*3*PN;
  float p0 = xb[n], p1 = xb[PN+n], p2 = xb[2*PN+n];
  const float* wr = ww + o*6;
  float u = p0*wr[0]; u = fmaf(p1,wr[1],u); u = fmaf(p2,wr[2],u);
  float vv = p0*(wr[3]-wr[0]); vv = fmaf(p1, wr[4]-wr[1], vv); vv = fmaf(p2, wr[5]-wr[2], vv);
  U[(size_t)ng*64+o] = u;
  V[(size_t)ng*64+o] = vv;
}

__global__ __launch_bounds__(256) void k_nodeUV64(const float* __restrict__ xf, const float* __restrict__ w,
                                                  float* __restrict__ U, float* __restrict__ V){
  __shared__ float xbuf[128*64];
  __shared__ float wbuf[128*64];
  int t = threadIdx.x;
  int r0 = blockIdx.x * 128;
  #pragma unroll
  for(int k=0;k<8;k++){
    int fid = t + k*256; int row = fid>>4, c4 = fid&15;
    ((float4*)xbuf)[row*16 + (c4^(row&15))] = ((const float4*)(xf + (size_t)(r0+row)*64))[c4];
    float4 wv;
    if(row < 64){
      wv = ((const float4*)(w + (size_t)row*128))[c4];
    } else {
      float4 w2v = ((const float4*)(w + (size_t)(row-64)*128 + 64))[c4];
      float4 w1v = ((const float4*)(w + (size_t)(row-64)*128))[c4];
      wv.x = w2v.x-w1v.x; wv.y = w2v.y-w1v.y; wv.z = w2v.z-w1v.z; wv.w = w2v.w-w1v.w;
    }
    ((float4*)wbuf)[row*16 + (c4^(row&15))] = wv;
  }
  __syncthreads();
  int rg = t>>4, cq = t&15;
  float acc[8][8];
  #pragma unroll
  for(int pp=0;pp<8;pp++)
    #pragma unroll
    for(int oc=0;oc<8;oc++) acc[pp][oc] = 0.f;
  #pragma unroll 4
  for(int c4=0;c4<16;c4++){
    float4 a[8], bb[8];
    #pragma unroll
    for(int pp=0;pp<8;pp++){ int row = rg*8+pp; a[pp] = ((const float4*)xbuf)[row*16 + (c4^(row&15))]; }
    #pragma unroll
    for(int oc=0;oc<8;oc++){ int col = cq+16*oc;  bb[oc] = ((const float4*)wbuf)[col*16 + (c4^(col&15))]; }
    #pragma unroll
    for(int pp=0;pp<8;pp++)
      #pragma unroll
      for(int oc=0;oc<8;oc++) FMA4C(acc[pp][oc], a[pp], bb[oc]);
  }
  #pragma unroll
  for(int pp=0;pp<8;pp++){
    int r = r0 + rg*8+pp;
    #pragma unroll
    for(int oc=0;oc<8;oc++){
      int col = cq + 16*oc;
      if(col < 64) U[(size_t)r*64 + col] = acc[pp][oc];
      else         V[(size_t)r*64 + col-64] = acc[pp][oc];
    }
  }
}

// ---------------- BN stats over edges of y = U[j]+V[n]  (float4 channels) ----------------
__global__ __launch_bounds__(256) void k_statUV(const float* __restrict__ U, const float* __restrict__ V,
                                                const int* __restrict__ idx, float* __restrict__ part){
  __shared__ float4 sArr[256];
  __shared__ float4 qArr[256];
  int t = threadIdx.x; int blk = blockIdx.x;
  int ch4 = t & 15, sub = t >> 4;
  int qbase = blk*640;
  float4 s = make_float4(0,0,0,0), qq = make_float4(0,0,0,0);
  for(int r=sub; r<640; r+=16){
    int q = qbase + r;
    int pt = q/PK;
    int b = pt >> 12;
    int j = idx[q];
    float4 u4 = ((const float4*)(U + (size_t)(b*PN+j)*64))[ch4];
    float4 v4 = ((const float4*)(V + (size_t)pt*64))[ch4];
    float4 y4;
    y4.x = u4.x+v4.x; y4.y = u4.y+v4.y; y4.z = u4.z+v4.z; y4.w = u4.w+v4.w;
    s.x += y4.x; s.y += y4.y; s.z += y4.z; s.w += y4.w;
    qq.x = fmaf(y4.x,y4.x,qq.x); qq.y = fmaf(y4.y,y4.y,qq.y);
    qq.z = fmaf(y4.z,y4.z,qq.z); qq.w = fmaf(y4.w,y4.w,qq.w);
  }
  sArr[t] = s; qArr[t] = qq;
  __syncthreads();
  if(t < 16){
    float4 S = make_float4(0,0,0,0), Q = make_float4(0,0,0,0);
    #pragma unroll
    for(int g=0;g<16;g++){
      float4 a = sArr[g*16 + t], b = qArr[g*16 + t];
      S.x+=a.x; S.y+=a.y; S.z+=a.z; S.w+=a.w;
      Q.x+=b.x; Q.y+=b.y; Q.z+=b.z; Q.w+=b.w;
    }
    ((float4*)(part + (size_t)blk*128))[t] = S;
    ((float4*)(part + (size_t)blk*128 + 64))[t] = Q;
  }
}

// ---------------- convA fused: y := W(64x64).lrelu(bn(U[j]+V[n])), + fused BN stats of y ----------------
__global__ __launch_bounds__(256) void k_convAF(const float* __restrict__ U, const float* __restrict__ V,
                                                const int* __restrict__ idx, const float* __restrict__ wg,
                                                const float* __restrict__ sb, float* __restrict__ y,
                                                float* __restrict__ part){
  __shared__ float hbuf[128*64];
  __shared__ float wbuf[64*64];
  int t = threadIdx.x;
  int q0 = blockIdx.x * 128;
  #pragma unroll
  for(int k=0;k<8;k++){
    int fid = t + k*256; int row = fid>>4, c4 = fid&15;
    int q = q0 + row;
    int pt = q/PK; int b = pt>>12; int j = idx[q];
    float4 uu = ((const float4*)(U + (size_t)(b*PN+j)*64))[c4];
    float4 vv = ((const float4*)(V + (size_t)pt*64))[c4];
    float4 sc = ((const float4*)sb)[c4];
    float4 bi = ((const float4*)(sb+1024))[c4];
    float4 h;
    h.x = lrelu_f(fmaf(uu.x+vv.x, sc.x, bi.x));
    h.y = lrelu_f(fmaf(uu.y+vv.y, sc.y, bi.y));
    h.z = lrelu_f(fmaf(uu.z+vv.z, sc.z, bi.z));
    h.w = lrelu_f(fmaf(uu.w+vv.w, sc.w, bi.w));
    ((float4*)hbuf)[row*16 + (c4 ^ (row&15))] = h;
  }
  #pragma unroll
  for(int k=0;k<4;k++){
    int fid = t + k*256; int row = fid>>4, c4 = fid&15;
    ((float4*)wbuf)[row*16 + (c4 ^ (row&15))] = ((const float4*)(wg + row*64))[c4];
  }
  __syncthreads();
  int prg = t >> 4, cq = t & 15;
  float acc[8][4];
  #pragma unroll
  for(int pp=0;pp<8;pp++)
    #pragma unroll
    for(int oc=0;oc<4;oc++) acc[pp][oc] = 0.f;
  #pragma unroll 4
  for(int c4=0;c4<16;c4++){
    float4 a[8], b4[4];
    #pragma unroll
    for(int pp=0;pp<8;pp++){ int row = prg*8+pp; a[pp] = ((const float4*)hbuf)[row*16 + (c4^(row&15))]; }
    #pragma unroll
    for(int oc=0;oc<4;oc++){ int och = cq + 16*oc; b4[oc] = ((const float4*)wbuf)[och*16 + (c4^(och&15))]; }
    #pragma unroll
    for(int pp=0;pp<8;pp++)
      #pragma unroll
      for(int oc=0;oc<4;oc++) FMA4C(acc[pp][oc], a[pp], b4[oc]);
  }
  #pragma unroll
  for(int pp=0;pp<8;pp++)
    #pragma unroll
    for(int oc=0;oc<4;oc++)
      y[(size_t)(q0 + prg*8+pp)*64 + cq + 16*oc] = acc[pp][oc];

  // fused BN statistics over this block's 128 rows
  float s_[4], q_[4];
  #pragma unroll
  for(int oc=0;oc<4;oc++){
    float s = 0.f, q = 0.f;
    #pragma unroll
    for(int pp=0;pp<8;pp++){ s += acc[pp][oc]; q = fmaf(acc[pp][oc], acc[pp][oc], q); }
    s_[oc] = s; q_[oc] = q;
  }
  __syncthreads();                       // wbuf reads done; reuse as scratch
  float* ls = wbuf;                      // 4096 floats
  #pragma unroll
  for(int oc=0;oc<4;oc++){
    ls[(cq + 16*oc)*16 + prg]        = s_[oc];
    ls[2048 + (cq + 16*oc)*16 + prg] = q_[oc];
  }
  __syncthreads();
  if(t < 64){
    float S = 0.f, Q = 0.f;
    #pragma unroll
    for(int g=0;g<16;g++){ S += ls[t*16+g]; Q += ls[2048 + t*16+g]; }
    part[(size_t)blockIdx.x*128 + t] = S;
    part[(size_t)blockIdx.x*128 + 64 + t] = Q;
  }
}

__global__ __launch_bounds__(256) void k_red1024(const float* __restrict__ y6, float* __restrict__ part){
  int t = threadIdx.x; int blk = blockIdx.x;   // 128 blocks x 128 rows
  const float4* base = (const float4*)(y6 + (size_t)blk*128*1024);
  float4 s = make_float4(0,0,0,0), q = make_float4(0,0,0,0);
  for(int r=0;r<128;r++){
    float4 v = base[r*256 + t];
    s.x += v.x; s.y += v.y; s.z += v.z; s.w += v.w;
    q.x = fmaf(v.x,v.x,q.x); q.y = fmaf(v.y,v.y,q.y); q.z = fmaf(v.z,v.z,q.z); q.w = fmaf(v.w,v.w,q.w);
  }
  ((float4*)(part + (size_t)blk*2048))[t] = s;
  ((float4*)(part + (size_t)blk*2048 + 1024))[t] = q;
}

// ---------------- finalize BN affine ----------------
__global__ __launch_bounds__(256) void k_fin(const float* __restrict__ part, int nparts, int chn, float cnt,
                                             const float* __restrict__ gamma, const float* __restrict__ beta,
                                             float* __restrict__ sb){
  __shared__ float ls[512];
  int t = threadIdx.x;
  int chl = t & 15, sub = t >> 4;
  int ch = blockIdx.x*16 + chl;
  float S = 0.f, Q = 0.f;
  for(int p=sub; p<nparts; p+=16){
    S += part[(size_t)p*2*chn + ch];
    Q += part[(size_t)p*2*chn + chn + ch];
  }
  ls[t] = S; ls[256+t] = Q;
  __syncthreads();
  if(t < 16){
    float Sa = 0.f, Qa = 0.f;
    #pragma unroll
    for(int s=0;s<16;s++){ Sa += ls[s*16+t]; Qa += ls[256+s*16+t]; }
    int c = blockIdx.x*16 + t;
    float m  = Sa/cnt;
    float vr = Qa/cnt - m*m;
    float sc = gamma[c] * rsqrtf(vr + 1e-5f);
    sb[c] = sc; sb[1024+c] = beta[c] - m*sc;
  }
}

// ---------------- finish: x = max_k lrelu(bn(y)), + fused xx for next stage ----------------
__global__ __launch_bounds__(256) void k_finish(const float* __restrict__ y, const float* __restrict__ sb,
                                                float* __restrict__ xo, float* __restrict__ xxo){
  __shared__ float ls[256];
  int t = threadIdx.x;
  int pt = blockIdx.x*16 + (t>>4), c4 = t&15;
  const float4* base = (const float4*)(y + (size_t)pt*20*64);
  float4 sc = ((const float4*)sb)[c4];
  float4 bi = ((const float4*)(sb+1024))[c4];
  float4 m = make_float4(NEGF,NEGF,NEGF,NEGF);
  #pragma unroll 4
  for(int k=0;k<20;k++){
    float4 v = base[k*16 + c4];
    v.x = lrelu_f(fmaf(v.x, sc.x, bi.x)); v.y = lrelu_f(fmaf(v.y, sc.y, bi.y));
    v.z = lrelu_f(fmaf(v.z, sc.z, bi.z)); v.w = lrelu_f(fmaf(v.w, sc.w, bi.w));
    m.x = fmaxf(m.x,v.x); m.y = fmaxf(m.y,v.y); m.z = fmaxf(m.z,v.z); m.w = fmaxf(m.w,v.w);
  }
  ((float4*)(xo + (size_t)pt*64))[c4] = m;
  float ss = m.x*m.x; ss = fmaf(m.y,m.y,ss); ss = fmaf(m.z,m.z,ss); ss = fmaf(m.w,m.w,ss);
  ls[t] = ss;
  __syncthreads();
  if(c4 == 0){
    float S = 0.f;
    #pragma unroll
    for(int c=0;c<16;c++) S += ls[(t & 0xF0) + c];
    xxo[pt] = S;
  }
}

// ---------------- finishUV: x = max_k lrelu(bn(U[j]+V[n])) ----------------
__global__ __launch_bounds__(256) void k_finishUV(const float* __restrict__ U, const float* __restrict__ V,
                                                  const int* __restrict__ idx, const float* __restrict__ sb,
                                                  float* __restrict__ xo){
  int t = threadIdx.x;
  int pt = blockIdx.x*16 + (t>>4), c4 = t&15;
  int b = pt >> 12;
  float4 sc = ((const float4*)sb)[c4];
  float4 bi = ((const float4*)(sb+1024))[c4];
  float4 vv = ((const float4*)(V + (size_t)pt*64))[c4];
  float4 m = make_float4(NEGF,NEGF,NEGF,NEGF);
  const int* ip = idx + (size_t)pt*PK;
  #pragma unroll 4
  for(int k=0;k<PK;k++){
    int j = ip[k];
    float4 uu = ((const float4*)(U + (size_t)(b*PN+j)*64))[c4];
    float4 v;
    v.x = lrelu_f(fmaf(uu.x+vv.x, sc.x, bi.x)); v.y = lrelu_f(fmaf(uu.y+vv.y, sc.y, bi.y));
    v.z = lrelu_f(fmaf(uu.z+vv.z, sc.z, bi.z)); v.w = lrelu_f(fmaf(uu.w+vv.w, sc.w, bi.w));
    m.x = fmaxf(m.x,v.x); m.y = fmaxf(m.y,v.y); m.z = fmaxf(m.z,v.z); m.w = fmaxf(m.w,v.w);
  }
  ((float4*)(xo + (size_t)pt*64))[c4] = m;
}

// ---------------- head GEMM: cat(x1,x2,x3) @ w6^T ----------------
__global__ __launch_bounds__(256) void k_gemm6(const float* __restrict__ x1, const float* __restrict__ x2,
                                               const float* __restrict__ x3, const float* __restrict__ w6,
                                               float* __restrict__ y6){
  __shared__ float cb[128*64];
  __shared__ float wb[64*64];
  int t = threadIdx.x;
  int rb = blockIdx.x >> 4;
  int ob = blockIdx.x & 15;
  size_t r0 = (size_t)rb*128; int o0 = ob*64;
  int prg = t >> 4, cq = t & 15;
  float acc[8][4];
  #pragma unroll
  for(int pp=0;pp<8;pp++)
    #pragma unroll
    for(int oc=0;oc<4;oc++) acc[pp][oc] = 0.f;
  const float* srcs[3] = {x1, x2, x3};
  for(int ph=0; ph<3; ph++){
    __syncthreads();
    const float* src = srcs[ph];
    #pragma unroll
    for(int k=0;k<8;k++){
      int fid = t + k*256; int row = fid>>4, c4 = fid&15;
      ((float4*)cb)[row*16 + (c4^(row&15))] = ((const float4*)(src + (r0+row)*64))[c4];
    }
    #pragma unroll
    for(int k=0;k<4;k++){
      int fid = t + k*256; int row = fid>>4, c4 = fid&15;
      ((float4*)wb)[row*16 + (c4^(row&15))] = ((const float4*)(w6 + (size_t)(o0+row)*192 + ph*64))[c4];
    }
    __syncthreads();
    #pragma unroll 4
    for(int c4=0;c4<16;c4++){
      float4 a[8], b4[4];
      #pragma unroll
      for(int pp=0;pp<8;pp++){ int row = prg*8+pp; a[pp] = ((const float4*)cb)[row*16 + (c4^(row&15))]; }
      #pragma unroll
      for(int oc=0;oc<4;oc++){ int och = cq + 16*oc; b4[oc] = ((const float4*)wb)[och*16 + (c4^(och&15))]; }
      #pragma unroll
      for(int pp=0;pp<8;pp++)
        #pragma unroll
        for(int oc=0;oc<4;oc++) FMA4C(acc[pp][oc], a[pp], b4[oc]);
    }
  }
  #pragma unroll
  for(int pp=0;pp<8;pp++)
    #pragma unroll
    for(int oc=0;oc<4;oc++)
      y6[(r0 + prg*8+pp)*1024 + o0 + cq + 16*oc] = acc[pp][oc];
}

// ---------------- global max over n (bn6+lrelu applied) ----------------
__global__ __launch_bounds__(256) void k_gmax(const float* __restrict__ y6, const float* __restrict__ sb,
                                              float* __restrict__ gpart){
  int t = threadIdx.x; int blk = blockIdx.x;   // 64 blocks x 256 rows
  const float4* base = (const float4*)(y6 + (size_t)blk*256*1024);
  float4 sc = ((const float4*)sb)[t];
  float4 bi = ((const float4*)(sb+1024))[t];
  float4 m = make_float4(NEGF,NEGF,NEGF,NEGF);
  for(int r=0;r<256;r++){
    float4 v = base[r*256 + t];
    v.x = lrelu_f(fmaf(v.x, sc.x, bi.x)); v.y = lrelu_f(fmaf(v.y, sc.y, bi.y));
    v.z = lrelu_f(fmaf(v.z, sc.z, bi.z)); v.w = lrelu_f(fmaf(v.w, sc.w, bi.w));
    m.x = fmaxf(m.x,v.x); m.y = fmaxf(m.y,v.y); m.z = fmaxf(m.z,v.z); m.w = fmaxf(m.w,v.w);
  }
  ((float4*)(gpart + (size_t)blk*1024))[t] = m;
}

__global__ __launch_bounds__(256) void k_gmaxfin(const float* __restrict__ gpart, float* __restrict__ g){
  int b = blockIdx.x, t = threadIdx.x;
  float4 m = make_float4(NEGF,NEGF,NEGF,NEGF);
  for(int c=0;c<16;c++){
    float4 v = ((const float4*)(gpart + ((size_t)b*16 + c)*1024))[t];
    m.x = fmaxf(m.x,v.x); m.y = fmaxf(m.y,v.y); m.z = fmaxf(m.z,v.z); m.w = fmaxf(m.w,v.w);
  }
  ((float4*)(g + (size_t)b*1024))[t] = m;
}

// ---------------- final: bn(g @ wl^T, axis 0) ----------------
__global__ __launch_bounds__(256) void k_final(const float* __restrict__ g, const float* __restrict__ wl,
                                               const float* __restrict__ g7, const float* __restrict__ b7,
                                               float* __restrict__ out){
  int gt = blockIdx.x*256 + threadIdx.x;   // 2048 = 512 o x 4 b
  int o = gt >> 2, b = gt & 3;
  const float4* gb = (const float4*)(g + (size_t)b*1024);
  const float4* wr = (const float4*)(wl + (size_t)o*1024);
  float acc = 0.f;
  #pragma unroll 4
  for(int c=0;c<256;c++){
    float4 a = gb[c], w = wr[c];
    acc = fmaf(a.x,w.x,acc); acc = fmaf(a.y,w.y,acc);
    acc = fmaf(a.z,w.z,acc); acc = fmaf(a.w,w.w,acc);
  }
  float s = acc + __shfl_xor(acc, 1);
  s = s + __shfl_xor(s, 2);
  float m = s * 0.25f;
  float d = acc - m;
  float vv = d*d;
  float v2 = vv + __shfl_xor(vv, 1);
  v2 = v2 + __shfl_xor(v2, 2);
  float var = v2 * 0.25f;
  out[b*512 + o] = d * rsqrtf(var + 1e-5f) * g7[o] + b7[o];
}

// ---------------- launch ----------------
extern "C" void kernel_launch(void* const* d_in, const int* in_sizes, int n_in,
                              void* d_out, int out_size, void* d_ws, size_t ws_size,
                              hipStream_t stream){
  const float* x  = (const float*)d_in[0];
  const float* w1 = (const float*)d_in[1];
  const float* w2 = (const float*)d_in[2];
  const float* w3 = (const float*)d_in[3];
  const float* w4 = (const float*)d_in[4];
  const float* w5 = (const float*)d_in[5];
  const float* w6 = (const float*)d_in[6];
  const float* wl = (const float*)d_in[7];
  const float* g1 = (const float*)d_in[8];  const float* b1 = (const float*)d_in[9];
  const float* g2 = (const float*)d_in[10]; const float* b2 = (const float*)d_in[11];
  const float* g3 = (const float*)d_in[12]; const float* b3 = (const float*)d_in[13];
  const float* g4 = (const float*)d_in[14]; const float* b4 = (const float*)d_in[15];
  const float* g5 = (const float*)d_in[16]; const float* b5 = (const float*)d_in[17];
  const float* g6 = (const float*)d_in[18]; const float* b6 = (const float*)d_in[19];
  const float* g7 = (const float*)d_in[20]; const float* b7 = (const float*)d_in[21];
  float* out = (float*)d_out;

  // workspace layout (floats); ~107.9 MB total
  float* ws    = (float*)d_ws;
  float* xx    = ws;                        // 16384
  int*   idx   = (int*)(ws + 16384);        // 327680
  float* y     = ws + 344064;               // 20971520 (y2/y4, y6)
  float* Dbuf  = y;                         // 16777216 (per-batch dist; y dead then)
  float* x1    = ws + 21315584;             // 1048576
  float* x2    = x1 + 1048576;
  float* x3    = x2 + 1048576;
  float* part  = x3 + 1048576;              // 327680 (max: convAF 2560 blocks x 128)
  float* sb    = part + 327680;             // 2048
  float* gpart = sb + 2048;                 // 65536
  float* g     = gpart + 65536;             // 4096
  float* U     = g + 4096;                  // 1048576
  float* V     = U + 1048576;               // 1048576

  // ---- stage 1 ----
  k_knn3<<<dim3(512,4),512,0,stream>>>(x, idx);
  k_nodeUV3<<<4096,256,0,stream>>>(x, w1, U, V);
  k_statUV<<<512,256,0,stream>>>(U, V, idx, part);
  k_fin<<<4,256,0,stream>>>(part, 512, 64, (float)PNT, g1, b1, sb);
  k_convAF<<<2560,256,0,stream>>>(U, V, idx, w2, sb, y, part);
  k_fin<<<4,256,0,stream>>>(part, 2560, 64, (float)PNT, g2, b2, sb);
  k_finish<<<1024,256,0,stream>>>(y, sb, x1, xx);

  // ---- stage 2 ----
  for(int b=0;b<PB;b++){
    k_dist64<<<528,256,0,stream>>>(x1 + (size_t)b*PN*64, xx + b*PN, Dbuf);
    k_topk<<<1024,256,0,stream>>>(Dbuf, idx + (size_t)b*PN*PK);
  }
  k_nodeUV64<<<128,256,0,stream>>>(x1, w3, U, V);
  k_statUV<<<512,256,0,stream>>>(U, V, idx, part);
  k_fin<<<4,256,0,stream>>>(part, 512, 64, (float)PNT, g3, b3, sb);
  k_convAF<<<2560,256,0,stream>>>(U, V, idx, w4, sb, y, part);
  k_fin<<<4,256,0,stream>>>(part, 2560, 64, (float)PNT, g4, b4, sb);
  k_finish<<<1024,256,0,stream>>>(y, sb, x2, xx);

  // ---- stage 3 ----
  for(int b=0;b<PB;b++){
    k_dist64<<<528,256,0,stream>>>(x2 + (size_t)b*PN*64, xx + b*PN, Dbuf);
    k_topk<<<1024,256,0,stream>>>(Dbuf, idx + (size_t)b*PN*PK);
  }
  k_nodeUV64<<<128,256,0,stream>>>(x2, w5, U, V);
  k_statUV<<<512,256,0,stream>>>(U, V, idx, part);
  k_fin<<<4,256,0,stream>>>(part, 512, 64, (float)PNT, g5, b5, sb);
  k_finishUV<<<1024,256,0,stream>>>(U, V, idx, sb, x3);

  // ---- head ----
  k_gemm6<<<2048,256,0,stream>>>(x1, x2, x3, w6, y);
  k_red1024<<<128,256,0,stream>>>(y, part);
  k_fin<<<64,256,0,stream>>>(part, 128, 1024, 16384.f, g6, b6, sb);
  k_gmax<<<64,256,0,stream>>>(y, sb, gpart);
  k_gmaxfin<<<4,256,0,stream>>>(gpart, g);
  k_final<<<8,256,0,stream>>>(g, wl, g7, b7, out);
}

// Round 8
// 1244.926 us; speedup vs baseline: 5.6207x; 1.0072x over previous
//
#include <hip/hip_runtime.h>

static constexpr int PB  = 4;
static constexpr int PN  = 4096;
static constexpr int PK  = 20;
static constexpr int PNT = PB*PN*PK;   // 327680
#define NEGF (-3.402823466e38f)

__device__ __forceinline__ float lrelu_f(float x){ return x >= 0.f ? x : 0.2f*x; }

#define FMA4C(accv, av, bv) { accv = fmaf((av).x,(bv).x,accv); accv = fmaf((av).y,(bv).y,accv); \
                              accv = fmaf((av).z,(bv).z,accv); accv = fmaf((av).w,(bv).w,accv); }

// ---------------- fused stage-1 kNN: all points in LDS, register top-k ----------------
// j encoding: j = lane + 64*e.  Float max-reduce + ballot; exact lowest-j via rare-path min-reduce.
__global__ __launch_bounds__(512) void k_knn3(const float* __restrict__ x, int* __restrict__ idxb){
  __shared__ float4 pts[PN];                      // 64 KB: (x, y, z, xx)
  int t = threadIdx.x;
  int b = blockIdx.y;
  const float* xb = x + (size_t)b*3*PN;
  for(int i=t;i<PN;i+=512){
    float a0 = xb[i], a1 = xb[PN+i], a2 = xb[2*PN+i];
    float s = a0*a0; s = fmaf(a1,a1,s); s = fmaf(a2,a2,s);
    pts[i] = make_float4(a0,a1,a2,s);
  }
  __syncthreads();
  int lane = t & 63, w = t >> 6;
  int row = blockIdx.x*8 + w;
  float4 pi = pts[row];
  unsigned long long removed = 0ull;

#define KDIST(E) ({ float4 pj_ = pts[lane + ((E)<<6)]; \
    float dt_ = pi.x*pj_.x; dt_ = fmaf(pi.y,pj_.y,dt_); dt_ = fmaf(pi.z,pj_.z,dt_); \
    fmaf(2.f,dt_,-pi.w) - pj_.w; })

  float gv0,gv1,gv2,gv3,gv4,gv5,gv6,gv7;
  int   gi0,gi1,gi2,gi3,gi4,gi5,gi6,gi7;
#define KBUILDG(G) { float gm_=NEGF; int ge_=(G)*8; \
    _Pragma("unroll") for(int e_=(G)*8; e_<(G)*8+8; e_++){ \
      bool ok_ = ((removed >> e_) & 1ull) == 0ull; \
      float d_ = KDIST(e_); \
      bool bt_ = ok_ && (d_ > gm_); gm_ = bt_ ? d_ : gm_; ge_ = bt_ ? e_ : ge_; } \
    gv##G = gm_; gi##G = ge_; }
  KBUILDG(0) KBUILDG(1) KBUILDG(2) KBUILDG(3) KBUILDG(4) KBUILDG(5) KBUILDG(6) KBUILDG(7)

  float lmax; int le;
#define KLBEST { lmax = gv0; le = gi0; \
    if(gv1>lmax){lmax=gv1;le=gi1;} if(gv2>lmax){lmax=gv2;le=gi2;} \
    if(gv3>lmax){lmax=gv3;le=gi3;} if(gv4>lmax){lmax=gv4;le=gi4;} \
    if(gv5>lmax){lmax=gv5;le=gi5;} if(gv6>lmax){lmax=gv6;le=gi6;} \
    if(gv7>lmax){lmax=gv7;le=gi7;} }
  KLBEST

  int myidx = 0;
  for(int k=0;k<PK;k++){
    float g = lmax;
    #pragma unroll
    for(int s=32;s>=1;s>>=1) g = fmaxf(g, __shfl_xor(g, s));
    unsigned long long cand = __ballot(lmax == g);
    int jw;
    if(__popcll(cand) == 1){
      int wl = __ffsll(cand) - 1;
      int e  = __shfl(le, wl);
      jw = wl + (e<<6);
    } else {
      // exact lowest global j among equal-valued candidates
      unsigned jj = (lmax == g) ? (unsigned)(lane + (le<<6)) : 0xFFFFFFFFu;
      #pragma unroll
      for(int s=32;s>=1;s>>=1){ unsigned o = __shfl_xor(jj, s); jj = (o < jj) ? o : jj; }
      jw = (int)jj;
    }
    if(lane == k) myidx = jw;
    if((jw & 63) == lane){
      int e = jw >> 6;
      removed |= (1ull << e);
      int q = e >> 3;
      if(q==0){ KBUILDG(0) } else if(q==1){ KBUILDG(1) }
      else if(q==2){ KBUILDG(2) } else if(q==3){ KBUILDG(3) }
      else if(q==4){ KBUILDG(4) } else if(q==5){ KBUILDG(5) }
      else if(q==6){ KBUILDG(6) } else { KBUILDG(7) }
      KLBEST
    }
  }
  if(lane < PK) idxb[((size_t)b*PN + row)*PK + lane] = myidx;
#undef KDIST
#undef KBUILDG
#undef KLBEST
}

// ---------------- dist64: symmetric tiled GEMM, K split in 2 (33 KB LDS, 4 blocks/CU) ----------------
__global__ __launch_bounds__(256) void k_dist64(const float* __restrict__ Xb, const float* __restrict__ xxb,
                                                float* __restrict__ D){
  __shared__ float Xi[128*32];
  __shared__ float Xj[128*32];
  __shared__ float xxi[128], xxj[128];
  int t = threadIdx.x;
  // triangular decode: p -> (bi,bj), bi<=bj
  int p = blockIdx.x;
  int bi = (int)((65.0f - sqrtf(4225.0f - 8.0f*(float)p)) * 0.5f);
  while((bi+1)*32 - ((bi+1)*bi)/2 <= p) bi++;
  while(bi*32 - (bi*(bi-1))/2 > p) bi--;
  int bj = bi + (p - (bi*32 - (bi*(bi-1))/2));
  int i0 = bi*128, j0 = bj*128;
  int prg = t>>4, cq = t&15;
  float acc[8][8];
  #pragma unroll
  for(int pp=0;pp<8;pp++)
    #pragma unroll
    for(int oc=0;oc<8;oc++) acc[pp][oc] = 0.f;

  for(int h=0;h<2;h++){
    if(h) __syncthreads();
    #pragma unroll
    for(int k=0;k<4;k++){
      int fid = t + k*256; int row = fid>>3, c4 = fid&7;
      ((float4*)Xi)[row*8 + (c4^(row&7))] = ((const float4*)(Xb + (size_t)(i0+row)*64 + h*32))[c4];
      ((float4*)Xj)[row*8 + (c4^(row&7))] = ((const float4*)(Xb + (size_t)(j0+row)*64 + h*32))[c4];
    }
    if(h==0){
      if(t < 128) xxi[t] = xxb[i0+t];
      else        xxj[t-128] = xxb[j0+t-128];
    }
    __syncthreads();
    #pragma unroll 4
    for(int c4=0;c4<8;c4++){
      float4 a[8], bb[8];
      #pragma unroll
      for(int pp=0;pp<8;pp++){ int row = prg*8+pp; a[pp] = ((const float4*)Xi)[row*8 + (c4^(row&7))]; }
      #pragma unroll
      for(int oc=0;oc<8;oc++){ int col = cq+16*oc;  bb[oc] = ((const float4*)Xj)[col*8 + (c4^(col&7))]; }
      #pragma unroll
      for(int pp=0;pp<8;pp++)
        #pragma unroll
        for(int oc=0;oc<8;oc++) FMA4C(acc[pp][oc], a[pp], bb[oc]);
    }
  }
  #pragma unroll
  for(int pp=0;pp<8;pp++){
    int r = prg*8+pp;
    float xi2 = xxi[r];
    float* Drow = D + (size_t)(i0+r)*PN + j0;
    #pragma unroll
    for(int oc=0;oc<8;oc++){
      int c = cq + 16*oc;
      Drow[c] = fmaf(2.f, acc[pp][oc], -xi2) - xxj[c];
    }
  }
  if(bi != bj){
    #pragma unroll
    for(int oc=0;oc<8;oc++){
      int c = cq + 16*oc;
      float xj2 = xxj[c];
      float* Dcol = D + (size_t)(j0+c)*PN + i0 + prg*8;
      float4 t0, t1;
      t0.x = fmaf(2.f, acc[0][oc], -xj2) - xxi[prg*8+0];
      t0.y = fmaf(2.f, acc[1][oc], -xj2) - xxi[prg*8+1];
      t0.z = fmaf(2.f, acc[2][oc], -xj2) - xxi[prg*8+2];
      t0.w = fmaf(2.f, acc[3][oc], -xj2) - xxi[prg*8+3];
      t1.x = fmaf(2.f, acc[4][oc], -xj2) - xxi[prg*8+4];
      t1.y = fmaf(2.f, acc[5][oc], -xj2) - xxi[prg*8+5];
      t1.z = fmaf(2.f, acc[6][oc], -xj2) - xxi[prg*8+6];
      t1.w = fmaf(2.f, acc[7][oc], -xj2) - xxi[prg*8+7];
      ((float4*)Dcol)[0] = t0;
      ((float4*)Dcol)[1] = t1;
    }
  }
}

// ---------------- top-20 per row: one wave per row, poison rebuild ----------------
__global__ __launch_bounds__(256) void k_topk(const float* __restrict__ D, int* __restrict__ idxb){
  int t = threadIdx.x, lane = t & 63, w = t >> 6;
  int row = blockIdx.x*4 + w;
  const float4* rp = (const float4*)(D + (size_t)row*PN + lane*64);
  float v[64];
  #pragma unroll
  for(int c=0;c<16;c++){
    float4 q = rp[c];
    v[4*c+0]=q.x; v[4*c+1]=q.y; v[4*c+2]=q.z; v[4*c+3]=q.w;
  }
  float gv0,gv1,gv2,gv3,gv4,gv5,gv6,gv7;
  int   gi0,gi1,gi2,gi3,gi4,gi5,gi6,gi7;
#define TBUILDG(G) { float gm_=NEGF; int ge_=(G)*8; \
    _Pragma("unroll") for(int e_=(G)*8; e_<(G)*8+8; e_++){ \
      bool bt_ = v[e_] > gm_; gm_ = bt_ ? v[e_] : gm_; ge_ = bt_ ? e_ : ge_; } \
    gv##G = gm_; gi##G = ge_; }
#define TPOIS(G) { _Pragma("unroll") for(int e_=(G)*8; e_<(G)*8+8; e_++){ \
      if(e_ == rel) v[e_] = NEGF; } }
  TBUILDG(0) TBUILDG(1) TBUILDG(2) TBUILDG(3) TBUILDG(4) TBUILDG(5) TBUILDG(6) TBUILDG(7)
  float lmax; int li;
#define TLBEST { lmax = gv0; li = gi0; \
    if(gv1>lmax){lmax=gv1;li=gi1;} if(gv2>lmax){lmax=gv2;li=gi2;} \
    if(gv3>lmax){lmax=gv3;li=gi3;} if(gv4>lmax){lmax=gv4;li=gi4;} \
    if(gv5>lmax){lmax=gv5;li=gi5;} if(gv6>lmax){lmax=gv6;li=gi6;} \
    if(gv7>lmax){lmax=gv7;li=gi7;} }
  TLBEST
  int myidx = 0;
  for(int k=0;k<PK;k++){
    float g = lmax;
    #pragma unroll
    for(int s=32;s>=1;s>>=1) g = fmaxf(g, __shfl_xor(g, s));
    unsigned long long mask = __ballot(lmax == g);
    int wl = __ffsll((unsigned long long)mask) - 1;
    int rel = __shfl(li, wl);
    if(lane == k) myidx = wl*64 + rel;
    if(lane == wl){
      int q = rel >> 3;
      if(q==0){ TPOIS(0) TBUILDG(0) } else if(q==1){ TPOIS(1) TBUILDG(1) }
      else if(q==2){ TPOIS(2) TBUILDG(2) } else if(q==3){ TPOIS(3) TBUILDG(3) }
      else if(q==4){ TPOIS(4) TBUILDG(4) } else if(q==5){ TPOIS(5) TBUILDG(5) }
      else if(q==6){ TPOIS(6) TBUILDG(6) } else { TPOIS(7) TBUILDG(7) }
      TLBEST
    }
  }
  if(lane < PK) idxb[row*PK + lane] = myidx;
#undef TBUILDG
#undef TPOIS
#undef TLBEST
}

// ---------------- nodeUV: per-node partial convs ----------------
__global__ __launch_bounds__(256) void k_nodeUV3(const float* __restrict__ x, const float* __restrict__ w1,
                                                 float* __restrict__ U, float* __restrict__ V){
  __shared__ float ww[384];
  int t = threadIdx.x;
  for(int k=t;k<384;k+=256) ww[k] = w1[k];
  __syncthreads();
  int g = blockIdx.x*256 + t;
  int ng = g >> 6, o = g & 63;
  int b = ng >> 12, n = ng & 4095;
  const float* xb = x + (size_t)b*3*PN;
  float p0 = xb[n], p1 = xb[PN+n], p2 = xb[2*PN+n];
  const float* wr = ww + o*6;
  float u = p0*wr[0]; u = fmaf(p1,wr[1],u); u = fmaf(p2,wr[2],u);
  float vv = p0*(wr[3]-wr[0]); vv = fmaf(p1, wr[4]-wr[1], vv); vv = fmaf(p2, wr[5]-wr[2], vv);
  U[(size_t)ng*64+o] = u;
  V[(size_t)ng*64+o] = vv;
}

__global__ __launch_bounds__(256) void k_nodeUV64(const float* __restrict__ xf, const float* __restrict__ w,
                                                  float* __restrict__ U, float* __restrict__ V){
  __shared__ float xbuf[128*64];
  __shared__ float wbuf[128*64];
  int t = threadIdx.x;
  int r0 = blockIdx.x * 128;
  #pragma unroll
  for(int k=0;k<8;k++){
    int fid = t + k*256; int row = fid>>4, c4 = fid&15;
    ((float4*)xbuf)[row*16 + (c4^(row&15))] = ((const float4*)(xf + (size_t)(r0+row)*64))[c4];
    float4 wv;
    if(row < 64){
      wv = ((const float4*)(w + (size_t)row*128))[c4];
    } else {
      float4 w2v = ((const float4*)(w + (size_t)(row-64)*128 + 64))[c4];
      float4 w1v = ((const float4*)(w + (size_t)(row-64)*128))[c4];
      wv.x = w2v.x-w1v.x; wv.y = w2v.y-w1v.y; wv.z = w2v.z-w1v.z; wv.w = w2v.w-w1v.w;
    }
    ((float4*)wbuf)[row*16 + (c4^(row&15))] = wv;
  }
  __syncthreads();
  int rg = t>>4, cq = t&15;
  float acc[8][8];
  #pragma unroll
  for(int pp=0;pp<8;pp++)
    #pragma unroll
    for(int oc=0;oc<8;oc++) acc[pp][oc] = 0.f;
  #pragma unroll 4
  for(int c4=0;c4<16;c4++){
    float4 a[8], bb[8];
    #pragma unroll
    for(int pp=0;pp<8;pp++){ int row = rg*8+pp; a[pp] = ((const float4*)xbuf)[row*16 + (c4^(row&15))]; }
    #pragma unroll
    for(int oc=0;oc<8;oc++){ int col = cq+16*oc;  bb[oc] = ((const float4*)wbuf)[col*16 + (c4^(col&15))]; }
    #pragma unroll
    for(int pp=0;pp<8;pp++)
      #pragma unroll
      for(int oc=0;oc<8;oc++) FMA4C(acc[pp][oc], a[pp], bb[oc]);
  }
  #pragma unroll
  for(int pp=0;pp<8;pp++){
    int r = r0 + rg*8+pp;
    #pragma unroll
    for(int oc=0;oc<8;oc++){
      int col = cq + 16*oc;
      if(col < 64) U[(size_t)r*64 + col] = acc[pp][oc];
      else         V[(size_t)r*64 + col-64] = acc[pp][oc];
    }
  }
}

// ---------------- BN stats over edges of y = U[j]+V[n]  (float4 channels) ----------------
__global__ __launch_bounds__(256) void k_statUV(const float* __restrict__ U, const float* __restrict__ V,
                                                const int* __restrict__ idx, float* __restrict__ part){
  __shared__ float4 sArr[256];
  __shared__ float4 qArr[256];
  int t = threadIdx.x; int blk = blockIdx.x;
  int ch4 = t & 15, sub = t >> 4;
  int qbase = blk*640;
  float4 s = make_float4(0,0,0,0), qq = make_float4(0,0,0,0);
  for(int r=sub; r<640; r+=16){
    int q = qbase + r;
    int pt = q/PK;
    int b = pt >> 12;
    int j = idx[q];
    float4 u4 = ((const float4*)(U + (size_t)(b*PN+j)*64))[ch4];
    float4 v4 = ((const float4*)(V + (size_t)pt*64))[ch4];
    float4 y4;
    y4.x = u4.x+v4.x; y4.y = u4.y+v4.y; y4.z = u4.z+v4.z; y4.w = u4.w+v4.w;
    s.x += y4.x; s.y += y4.y; s.z += y4.z; s.w += y4.w;
    qq.x = fmaf(y4.x,y4.x,qq.x); qq.y = fmaf(y4.y,y4.y,qq.y);
    qq.z = fmaf(y4.z,y4.z,qq.z); qq.w = fmaf(y4.w,y4.w,qq.w);
  }
  sArr[t] = s; qArr[t] = qq;
  __syncthreads();
  if(t < 16){
    float4 S = make_float4(0,0,0,0), Q = make_float4(0,0,0,0);
    #pragma unroll
    for(int g=0;g<16;g++){
      float4 a = sArr[g*16 + t], b = qArr[g*16 + t];
      S.x+=a.x; S.y+=a.y; S.z+=a.z; S.w+=a.w;
      Q.x+=b.x; Q.y+=b.y; Q.z+=b.z; Q.w+=b.w;
    }
    ((float4*)(part + (size_t)blk*128))[t] = S;
    ((float4*)(part + (size_t)blk*128 + 64))[t] = Q;
  }
}

// ---------------- convA fused: y := W(64x64).lrelu(bn(U[j]+V[n])), + fused BN stats of y ----------------
__global__ __launch_bounds__(256) void k_convAF(const float* __restrict__ U, const float* __restrict__ V,
                                                const int* __restrict__ idx, const float* __restrict__ wg,
                                                const float* __restrict__ sb, float* __restrict__ y,
                                                float* __restrict__ part){
  __shared__ float hbuf[128*64];
  __shared__ float wbuf[64*64];
  int t = threadIdx.x;
  int q0 = blockIdx.x * 128;
  #pragma unroll
  for(int k=0;k<8;k++){
    int fid = t + k*256; int row = fid>>4, c4 = fid&15;
    int q = q0 + row;
    int pt = q/PK; int b = pt>>12; int j = idx[q];
    float4 uu = ((const float4*)(U + (size_t)(b*PN+j)*64))[c4];
    float4 vv = ((const float4*)(V + (size_t)pt*64))[c4];
    float4 sc = ((const float4*)sb)[c4];
    float4 bi = ((const float4*)(sb+1024))[c4];
    float4 h;
    h.x = lrelu_f(fmaf(uu.x+vv.x, sc.x, bi.x));
    h.y = lrelu_f(fmaf(uu.y+vv.y, sc.y, bi.y));
    h.z = lrelu_f(fmaf(uu.z+vv.z, sc.z, bi.z));
    h.w = lrelu_f(fmaf(uu.w+vv.w, sc.w, bi.w));
    ((float4*)hbuf)[row*16 + (c4 ^ (row&15))] = h;
  }
  #pragma unroll
  for(int k=0;k<4;k++){
    int fid = t + k*256; int row = fid>>4, c4 = fid&15;
    ((float4*)wbuf)[row*16 + (c4 ^ (row&15))] = ((const float4*)(wg + row*64))[c4];
  }
  __syncthreads();
  int prg = t >> 4, cq = t & 15;
  float acc[8][4];
  #pragma unroll
  for(int pp=0;pp<8;pp++)
    #pragma unroll
    for(int oc=0;oc<4;oc++) acc[pp][oc] = 0.f;
  #pragma unroll 4
  for(int c4=0;c4<16;c4++){
    float4 a[8], b4[4];
    #pragma unroll
    for(int pp=0;pp<8;pp++){ int row = prg*8+pp; a[pp] = ((const float4*)hbuf)[row*16 + (c4^(row&15))]; }
    #pragma unroll
    for(int oc=0;oc<4;oc++){ int och = cq + 16*oc; b4[oc] = ((const float4*)wbuf)[och*16 + (c4^(och&15))]; }
    #pragma unroll
    for(int pp=0;pp<8;pp++)
      #pragma unroll
      for(int oc=0;oc<4;oc++) FMA4C(acc[pp][oc], a[pp], b4[oc]);
  }
  #pragma unroll
  for(int pp=0;pp<8;pp++)
    #pragma unroll
    for(int oc=0;oc<4;oc++)
      y[(size_t)(q0 + prg*8+pp)*64 + cq + 16*oc] = acc[pp][oc];

  // fused BN statistics over this block's 128 rows
  float s_[4], q_[4];
  #pragma unroll
  for(int oc=0;oc<4;oc++){
    float s = 0.f, q = 0.f;
    #pragma unroll
    for(int pp=0;pp<8;pp++){ s += acc[pp][oc]; q = fmaf(acc[pp][oc], acc[pp][oc], q); }
    s_[oc] = s; q_[oc] = q;
  }
  __syncthreads();                       // wbuf reads done; reuse as scratch
  float* ls = wbuf;                      // 4096 floats
  #pragma unroll
  for(int oc=0;oc<4;oc++){
    ls[(cq + 16*oc)*16 + prg]        = s_[oc];
    ls[2048 + (cq + 16*oc)*16 + prg] = q_[oc];
  }
  __syncthreads();
  if(t < 64){
    float S = 0.f, Q = 0.f;
    #pragma unroll
    for(int g=0;g<16;g++){ S += ls[t*16+g]; Q += ls[2048 + t*16+g]; }
    part[(size_t)blockIdx.x*128 + t] = S;
    part[(size_t)blockIdx.x*128 + 64 + t] = Q;
  }
}

__global__ __launch_bounds__(256) void k_red1024(const float* __restrict__ y6, float* __restrict__ part){
  int t = threadIdx.x; int blk = blockIdx.x;   // 128 blocks x 128 rows
  const float4* base = (const float4*)(y6 + (size_t)blk*128*1024);
  float4 s = make_float4(0,0,0,0), q = make_float4(0,0,0,0);
  for(int r=0;r<128;r++){
    float4 v = base[r*256 + t];
    s.x += v.x; s.y += v.y; s.z += v.z; s.w += v.w;
    q.x = fmaf(v.x,v.x,q.x); q.y = fmaf(v.y,v.y,q.y); q.z = fmaf(v.z,v.z,q.z); q.w = fmaf(v.w,v.w,q.w);
  }
  ((float4*)(part + (size_t)blk*2048))[t] = s;
  ((float4*)(part + (size_t)blk*2048 + 1024))[t] = q;
}

// ---------------- finalize BN affine ----------------
__global__ __launch_bounds__(256) void k_fin(const float* __restrict__ part, int nparts, int chn, float cnt,
                                             const float* __restrict__ gamma, const float* __restrict__ beta,
                                             float* __restrict__ sb){
  __shared__ float ls[512];
  int t = threadIdx.x;
  int chl = t & 15, sub = t >> 4;
  int ch = blockIdx.x*16 + chl;
  float S = 0.f, Q = 0.f;
  for(int p=sub; p<nparts; p+=16){
    S += part[(size_t)p*2*chn + ch];
    Q += part[(size_t)p*2*chn + chn + ch];
  }
  ls[t] = S; ls[256+t] = Q;
  __syncthreads();
  if(t < 16){
    float Sa = 0.f, Qa = 0.f;
    #pragma unroll
    for(int s=0;s<16;s++){ Sa += ls[s*16+t]; Qa += ls[256+s*16+t]; }
    int c = blockIdx.x*16 + t;
    float m  = Sa/cnt;
    float vr = Qa/cnt - m*m;
    float sc = gamma[c] * rsqrtf(vr + 1e-5f);
    sb[c] = sc; sb[1024+c] = beta[c] - m*sc;
  }
}

// ---------------- finish: x = max_k lrelu(bn(y)), + fused xx for next stage ----------------
__global__ __launch_bounds__(256) void k_finish(const float* __restrict__ y, const float* __restrict__ sb,
                                                float* __restrict__ xo, float* __restrict__ xxo){
  __shared__ float ls[256];
  int t = threadIdx.x;
  int pt = blockIdx.x*16 + (t>>4), c4 = t&15;
  const float4* base = (const float4*)(y + (size_t)pt*20*64);
  float4 sc = ((const float4*)sb)[c4];
  float4 bi = ((const float4*)(sb+1024))[c4];
  float4 m = make_float4(NEGF,NEGF,NEGF,NEGF);
  #pragma unroll 4
  for(int k=0;k<20;k++){
    float4 v = base[k*16 + c4];
    v.x = lrelu_f(fmaf(v.x, sc.x, bi.x)); v.y = lrelu_f(fmaf(v.y, sc.y, bi.y));
    v.z = lrelu_f(fmaf(v.z, sc.z, bi.z)); v.w = lrelu_f(fmaf(v.w, sc.w, bi.w));
    m.x = fmaxf(m.x,v.x); m.y = fmaxf(m.y,v.y); m.z = fmaxf(m.z,v.z); m.w = fmaxf(m.w,v.w);
  }
  ((float4*)(xo + (size_t)pt*64))[c4] = m;
  float ss = m.x*m.x; ss = fmaf(m.y,m.y,ss); ss = fmaf(m.z,m.z,ss); ss = fmaf(m.w,m.w,ss);
  ls[t] = ss;
  __syncthreads();
  if(c4 == 0){
    float S = 0.f;
    #pragma unroll
    for(int c=0;c<16;c++) S += ls[(t & 0xF0) + c];
    xxo[pt] = S;
  }
}

// ---------------- finishUV: x = max_k lrelu(bn(U[j]+V[n])) ----------------
__global__ __launch_bounds__(256) void k_finishUV(const float* __restrict__ U, const float* __restrict__ V,
                                                  const int* __restrict__ idx, const float* __restrict__ sb,
                                                  float* __restrict__ xo){
  int t = threadIdx.x;
  int pt = blockIdx.x*16 + (t>>4), c4 = t&15;
  int b = pt >> 12;
  float4 sc = ((const float4*)sb)[c4];
  float4 bi = ((const float4*)(sb+1024))[c4];
  float4 vv = ((const float4*)(V + (size_t)pt*64))[c4];
  float4 m = make_float4(NEGF,NEGF,NEGF,NEGF);
  const int* ip = idx + (size_t)pt*PK;
  #pragma unroll 4
  for(int k=0;k<PK;k++){
    int j = ip[k];
    float4 uu = ((const float4*)(U + (size_t)(b*PN+j)*64))[c4];
    float4 v;
    v.x = lrelu_f(fmaf(uu.x+vv.x, sc.x, bi.x)); v.y = lrelu_f(fmaf(uu.y+vv.y, sc.y, bi.y));
    v.z = lrelu_f(fmaf(uu.z+vv.z, sc.z, bi.z)); v.w = lrelu_f(fmaf(uu.w+vv.w, sc.w, bi.w));
    m.x = fmaxf(m.x,v.x); m.y = fmaxf(m.y,v.y); m.z = fmaxf(m.z,v.z); m.w = fmaxf(m.w,v.w);
  }
  ((float4*)(xo + (size_t)pt*64))[c4] = m;
}

// ---------------- head GEMM: 128x128 tile, 8x8 acc ----------------
__global__ __launch_bounds__(256) void k_gemm6(const float* __restrict__ x1, const float* __restrict__ x2,
                                               const float* __restrict__ x3, const float* __restrict__ w6,
                                               float* __restrict__ y6){
  __shared__ float cb[128*64];
  __shared__ float wb[128*64];
  int t = threadIdx.x;
  int rb = blockIdx.x >> 3;
  int ob = blockIdx.x & 7;
  size_t r0 = (size_t)rb*128; int o0 = ob*128;
  int prg = t >> 4, cq = t & 15;
  float acc[8][8];
  #pragma unroll
  for(int pp=0;pp<8;pp++)
    #pragma unroll
    for(int oc=0;oc<8;oc++) acc[pp][oc] = 0.f;
  const float* srcs[3] = {x1, x2, x3};
  for(int ph=0; ph<3; ph++){
    __syncthreads();
    const float* src = srcs[ph];
    #pragma unroll
    for(int k=0;k<8;k++){
      int fid = t + k*256; int row = fid>>4, c4 = fid&15;
      ((float4*)cb)[row*16 + (c4^(row&15))] = ((const float4*)(src + (r0+row)*64))[c4];
      ((float4*)wb)[row*16 + (c4^(row&15))] = ((const float4*)(w6 + (size_t)(o0+row)*192 + ph*64))[c4];
    }
    __syncthreads();
    #pragma unroll 4
    for(int c4=0;c4<16;c4++){
      float4 a[8], b8[8];
      #pragma unroll
      for(int pp=0;pp<8;pp++){ int row = prg*8+pp; a[pp] = ((const float4*)cb)[row*16 + (c4^(row&15))]; }
      #pragma unroll
      for(int oc=0;oc<8;oc++){ int och = cq + 16*oc; b8[oc] = ((const float4*)wb)[och*16 + (c4^(och&15))]; }
      #pragma unroll
      for(int pp=0;pp<8;pp++)
        #pragma unroll
        for(int oc=0;oc<8;oc++) FMA4C(acc[pp][oc], a[pp], b8[oc]);
    }
  }
  #pragma unroll
  for(int pp=0;pp<8;pp++)
    #pragma unroll
    for(int oc=0;oc<8;oc++)
      y6[(r0 + prg*8+pp)*1024 + o0 + cq + 16*oc] = acc[pp][oc];
}

// ---------------- global max over n (bn6+lrelu applied) ----------------
__global__ __launch_bounds__(256) void k_gmax(const float* __restrict__ y6, const float* __restrict__ sb,
                                              float* __restrict__ gpart){
  int t = threadIdx.x; int blk = blockIdx.x;   // 64 blocks x 256 rows
  const float4* base = (const float4*)(y6 + (size_t)blk*256*1024);
  float4 sc = ((const float4*)sb)[t];
  float4 bi = ((const float4*)(sb+1024))[t];
  float4 m = make_float4(NEGF,NEGF,NEGF,NEGF);
  for(int r=0;r<256;r++){
    float4 v = base[r*256 + t];
    v.x = lrelu_f(fmaf(v.x, sc.x, bi.x)); v.y = lrelu_f(fmaf(v.y, sc.y, bi.y));
    v.z = lrelu_f(fmaf(v.z, sc.z, bi.z)); v.w = lrelu_f(fmaf(v.w, sc.w, bi.w));
    m.x = fmaxf(m.x,v.x); m.y = fmaxf(m.y,v.y); m.z = fmaxf(m.z,v.z); m.w = fmaxf(m.w,v.w);
  }
  ((float4*)(gpart + (size_t)blk*1024))[t] = m;
}

__global__ __launch_bounds__(256) void k_gmaxfin(const float* __restrict__ gpart, float* __restrict__ g){
  int b = blockIdx.x, t = threadIdx.x;
  float4 m = make_float4(NEGF,NEGF,NEGF,NEGF);
  for(int c=0;c<16;c++){
    float4 v = ((const float4*)(gpart + ((size_t)b*16 + c)*1024))[t];
    m.x = fmaxf(m.x,v.x); m.y = fmaxf(m.y,v.y); m.z = fmaxf(m.z,v.z); m.w = fmaxf(m.w,v.w);
  }
  ((float4*)(g + (size_t)b*1024))[t] = m;
}

// ---------------- final: bn(g @ wl^T, axis 0) ----------------
__global__ __launch_bounds__(256) void k_final(const float* __restrict__ g, const float* __restrict__ wl,
                                               const float* __restrict__ g7, const float* __restrict__ b7,
                                               float* __restrict__ out){
  int gt = blockIdx.x*256 + threadIdx.x;   // 2048 = 512 o x 4 b
  int o = gt >> 2, b = gt & 3;
  const float4* gb = (const float4*)(g + (size_t)b*1024);
  const float4* wr = (const float4*)(wl + (size_t)o*1024);
  float acc = 0.f;
  #pragma unroll 4
  for(int c=0;c<256;c++){
    float4 a = gb[c], w = wr[c];
    acc = fmaf(a.x,w.x,acc); acc = fmaf(a.y,w.y,acc);
    acc = fmaf(a.z,w.z,acc); acc = fmaf(a.w,w.w,acc);
  }
  float s = acc + __shfl_xor(acc, 1);
  s = s + __shfl_xor(s, 2);
  float m = s * 0.25f;
  float d = acc - m;
  float vv = d*d;
  float v2 = vv + __shfl_xor(vv, 1);
  v2 = v2 + __shfl_xor(v2, 2);
  float var = v2 * 0.25f;
  out[b*512 + o] = d * rsqrtf(var + 1e-5f) * g7[o] + b7[o];
}

// ---------------- launch ----------------
extern "C" void kernel_launch(void* const* d_in, const int* in_sizes, int n_in,
                              void* d_out, int out_size, void* d_ws, size_t ws_size,
                              hipStream_t stream){
  const float* x  = (const float*)d_in[0];
  const float* w1 = (const float*)d_in[1];
  const float* w2 = (const float*)d_in[2];
  const float* w3 = (const float*)d_in[3];
  const float* w4 = (const float*)d_in[4];
  const float* w5 = (const float*)d_in[5];
  const float* w6 = (const float*)d_in[6];
  const float* wl = (const float*)d_in[7];
  const float* g1 = (const float*)d_in[8];  const float* b1 = (const float*)d_in[9];
  const float* g2 = (const float*)d_in[10]; const float* b2 = (const float*)d_in[11];
  const float* g3 = (const float*)d_in[12]; const float* b3 = (const float*)d_in[13];
  const float* g4 = (const float*)d_in[14]; const float* b4 = (const float*)d_in[15];
  const float* g5 = (const float*)d_in[16]; const float* b5 = (const float*)d_in[17];
  const float* g6 = (const float*)d_in[18]; const float* b6 = (const float*)d_in[19];
  const float* g7 = (const float*)d_in[20]; const float* b7 = (const float*)d_in[21];
  float* out = (float*)d_out;

  // workspace layout (floats); ~107.9 MB total
  float* ws    = (float*)d_ws;
  float* xx    = ws;                        // 16384
  int*   idx   = (int*)(ws + 16384);        // 327680
  float* y     = ws + 344064;               // 20971520 (y2/y4, y6)
  float* Dbuf  = y;                         // 16777216 (per-batch dist; y dead then)
  float* x1    = ws + 21315584;             // 1048576
  float* x2    = x1 + 1048576;
  float* x3    = x2 + 1048576;
  float* part  = x3 + 1048576;              // 327680 (max: convAF 2560 blocks x 128)
  float* sb    = part + 327680;             // 2048
  float* gpart = sb + 2048;                 // 65536
  float* g     = gpart + 65536;             // 4096
  float* U     = g + 4096;                  // 1048576
  float* V     = U + 1048576;               // 1048576

  // ---- stage 1 ----
  k_knn3<<<dim3(512,4),512,0,stream>>>(x, idx);
  k_nodeUV3<<<4096,256,0,stream>>>(x, w1, U, V);
  k_statUV<<<512,256,0,stream>>>(U, V, idx, part);
  k_fin<<<4,256,0,stream>>>(part, 512, 64, (float)PNT, g1, b1, sb);
  k_convAF<<<2560,256,0,stream>>>(U, V, idx, w2, sb, y, part);
  k_fin<<<4,256,0,stream>>>(part, 2560, 64, (float)PNT, g2, b2, sb);
  k_finish<<<1024,256,0,stream>>>(y, sb, x1, xx);

  // ---- stage 2 ----
  for(int b=0;b<PB;b++){
    k_dist64<<<528,256,0,stream>>>(x1 + (size_t)b*PN*64, xx + b*PN, Dbuf);
    k_topk<<<1024,256,0,stream>>>(Dbuf, idx + (size_t)b*PN*PK);
  }
  k_nodeUV64<<<128,256,0,stream>>>(x1, w3, U, V);
  k_statUV<<<512,256,0,stream>>>(U, V, idx, part);
  k_fin<<<4,256,0,stream>>>(part, 512, 64, (float)PNT, g3, b3, sb);
  k_convAF<<<2560,256,0,stream>>>(U, V, idx, w4, sb, y, part);
  k_fin<<<4,256,0,stream>>>(part, 2560, 64, (float)PNT, g4, b4, sb);
  k_finish<<<1024,256,0,stream>>>(y, sb, x2, xx);

  // ---- stage 3 ----
  for(int b=0;b<PB;b++){
    k_dist64<<<528,256,0,stream>>>(x2 + (size_t)b*PN*64, xx + b*PN, Dbuf);
    k_topk<<<1024,256,0,stream>>>(Dbuf, idx + (size_t)b*PN*PK);
  }
  k_nodeUV64<<<128,256,0,stream>>>(x2, w5, U, V);
  k_statUV<<<512,256,0,stream>>>(U, V, idx, part);
  k_fin<<<4,256,0,stream>>>(part, 512, 64, (float)PNT, g5, b5, sb);
  k_finishUV<<<1024,256,0,stream>>>(U, V, idx, sb, x3);

  // ---- head ----
  k_gemm6<<<1024,256,0,stream>>>(x1, x2, x3, w6, y);
  k_red1024<<<128,256,0,stream>>>(y, part);
  k_fin<<<64,256,0,stream>>>(part, 128, 1024, 16384.f, g6, b6, sb);
  k_gmax<<<64,256,0,stream>>>(y, sb, gpart);
  k_gmaxfin<<<4,256,0,stream>>>(gpart, g);
  k_final<<<8,256,0,stream>>>(g, wl, g7, b7, out);
}

// Round 9
// 1198.601 us; speedup vs baseline: 5.8380x; 1.0386x over previous
//
#include <hip/hip_runtime.h>

static constexpr int PB  = 4;
static constexpr int PN  = 4096;
static constexpr int PK  = 20;
static constexpr int PNT = PB*PN*PK;   // 327680
#define NEGF (-3.402823466e38f)

__device__ __forceinline__ float lrelu_f(float x){ return x >= 0.f ? x : 0.2f*x; }

typedef __attribute__((ext_vector_type(8))) short short8v;
typedef __attribute__((ext_vector_type(4))) float f32x4;

__device__ __forceinline__ unsigned short f2bf(float f){
  unsigned u = __float_as_uint(f);
  unsigned r = u + 0x7FFFu + ((u>>16)&1u);
  return (unsigned short)(r>>16);
}
__device__ __forceinline__ float bf2f(unsigned short s){ return __uint_as_float(((unsigned)s)<<16); }

#define FMA4C(accv, av, bv) { accv = fmaf((av).x,(bv).x,accv); accv = fmaf((av).y,(bv).y,accv); \
                              accv = fmaf((av).z,(bv).z,accv); accv = fmaf((av).w,(bv).w,accv); }

// ---------------- fused stage-1 kNN: all points in LDS, register top-k ----------------
__global__ __launch_bounds__(512) void k_knn3(const float* __restrict__ x, int* __restrict__ idxb){
  __shared__ float4 pts[PN];                      // 64 KB: (x, y, z, xx)
  int t = threadIdx.x;
  int b = blockIdx.y;
  const float* xb = x + (size_t)b*3*PN;
  for(int i=t;i<PN;i+=512){
    float a0 = xb[i], a1 = xb[PN+i], a2 = xb[2*PN+i];
    float s = a0*a0; s = fmaf(a1,a1,s); s = fmaf(a2,a2,s);
    pts[i] = make_float4(a0,a1,a2,s);
  }
  __syncthreads();
  int lane = t & 63, w = t >> 6;
  int row = blockIdx.x*8 + w;
  float4 pi = pts[row];
  unsigned long long removed = 0ull;

#define KDIST(E) ({ float4 pj_ = pts[lane + ((E)<<6)]; \
    float dt_ = pi.x*pj_.x; dt_ = fmaf(pi.y,pj_.y,dt_); dt_ = fmaf(pi.z,pj_.z,dt_); \
    fmaf(2.f,dt_,-pi.w) - pj_.w; })

  float gv0,gv1,gv2,gv3,gv4,gv5,gv6,gv7;
  int   gi0,gi1,gi2,gi3,gi4,gi5,gi6,gi7;
#define KBUILDG(G) { float gm_=NEGF; int ge_=(G)*8; \
    _Pragma("unroll") for(int e_=(G)*8; e_<(G)*8+8; e_++){ \
      bool ok_ = ((removed >> e_) & 1ull) == 0ull; \
      float d_ = KDIST(e_); \
      bool bt_ = ok_ && (d_ > gm_); gm_ = bt_ ? d_ : gm_; ge_ = bt_ ? e_ : ge_; } \
    gv##G = gm_; gi##G = ge_; }
  KBUILDG(0) KBUILDG(1) KBUILDG(2) KBUILDG(3) KBUILDG(4) KBUILDG(5) KBUILDG(6) KBUILDG(7)

  float lmax; int le;
#define KLBEST { lmax = gv0; le = gi0; \
    if(gv1>lmax){lmax=gv1;le=gi1;} if(gv2>lmax){lmax=gv2;le=gi2;} \
    if(gv3>lmax){lmax=gv3;le=gi3;} if(gv4>lmax){lmax=gv4;le=gi4;} \
    if(gv5>lmax){lmax=gv5;le=gi5;} if(gv6>lmax){lmax=gv6;le=gi6;} \
    if(gv7>lmax){lmax=gv7;le=gi7;} }
  KLBEST

  int myidx = 0;
  for(int k=0;k<PK;k++){
    float g = lmax;
    #pragma unroll
    for(int s=32;s>=1;s>>=1) g = fmaxf(g, __shfl_xor(g, s));
    unsigned long long cand = __ballot(lmax == g);
    int jw;
    if(__popcll(cand) == 1){
      int wl = __ffsll(cand) - 1;
      int e  = __shfl(le, wl);
      jw = wl + (e<<6);
    } else {
      unsigned jj = (lmax == g) ? (unsigned)(lane + (le<<6)) : 0xFFFFFFFFu;
      #pragma unroll
      for(int s=32;s>=1;s>>=1){ unsigned o = __shfl_xor(jj, s); jj = (o < jj) ? o : jj; }
      jw = (int)jj;
    }
    if(lane == k) myidx = jw;
    if((jw & 63) == lane){
      int e = jw >> 6;
      removed |= (1ull << e);
      int q = e >> 3;
      if(q==0){ KBUILDG(0) } else if(q==1){ KBUILDG(1) }
      else if(q==2){ KBUILDG(2) } else if(q==3){ KBUILDG(3) }
      else if(q==4){ KBUILDG(4) } else if(q==5){ KBUILDG(5) }
      else if(q==6){ KBUILDG(6) } else { KBUILDG(7) }
      KLBEST
    }
  }
  if(lane < PK) idxb[((size_t)b*PN + row)*PK + lane] = myidx;
#undef KDIST
#undef KBUILDG
#undef KLBEST
}

// ---------------- dist64: symmetric tiled GEMM, K split in 2 (33 KB LDS, 4 blocks/CU) ----------------
__global__ __launch_bounds__(256) void k_dist64(const float* __restrict__ Xb, const float* __restrict__ xxb,
                                                float* __restrict__ D){
  __shared__ float Xi[128*32];
  __shared__ float Xj[128*32];
  __shared__ float xxi[128], xxj[128];
  int t = threadIdx.x;
  int p = blockIdx.x;
  int bi = (int)((65.0f - sqrtf(4225.0f - 8.0f*(float)p)) * 0.5f);
  while((bi+1)*32 - ((bi+1)*bi)/2 <= p) bi++;
  while(bi*32 - (bi*(bi-1))/2 > p) bi--;
  int bj = bi + (p - (bi*32 - (bi*(bi-1))/2));
  int i0 = bi*128, j0 = bj*128;
  int prg = t>>4, cq = t&15;
  float acc[8][8];
  #pragma unroll
  for(int pp=0;pp<8;pp++)
    #pragma unroll
    for(int oc=0;oc<8;oc++) acc[pp][oc] = 0.f;

  for(int h=0;h<2;h++){
    if(h) __syncthreads();
    #pragma unroll
    for(int k=0;k<4;k++){
      int fid = t + k*256; int row = fid>>3, c4 = fid&7;
      ((float4*)Xi)[row*8 + (c4^(row&7))] = ((const float4*)(Xb + (size_t)(i0+row)*64 + h*32))[c4];
      ((float4*)Xj)[row*8 + (c4^(row&7))] = ((const float4*)(Xb + (size_t)(j0+row)*64 + h*32))[c4];
    }
    if(h==0){
      if(t < 128) xxi[t] = xxb[i0+t];
      else        xxj[t-128] = xxb[j0+t-128];
    }
    __syncthreads();
    #pragma unroll 4
    for(int c4=0;c4<8;c4++){
      float4 a[8], bb[8];
      #pragma unroll
      for(int pp=0;pp<8;pp++){ int row = prg*8+pp; a[pp] = ((const float4*)Xi)[row*8 + (c4^(row&7))]; }
      #pragma unroll
      for(int oc=0;oc<8;oc++){ int col = cq+16*oc;  bb[oc] = ((const float4*)Xj)[col*8 + (c4^(col&7))]; }
      #pragma unroll
      for(int pp=0;pp<8;pp++)
        #pragma unroll
        for(int oc=0;oc<8;oc++) FMA4C(acc[pp][oc], a[pp], bb[oc]);
    }
  }
  #pragma unroll
  for(int pp=0;pp<8;pp++){
    int r = prg*8+pp;
    float xi2 = xxi[r];
    float* Drow = D + (size_t)(i0+r)*PN + j0;
    #pragma unroll
    for(int oc=0;oc<8;oc++){
      int c = cq + 16*oc;
      Drow[c] = fmaf(2.f, acc[pp][oc], -xi2) - xxj[c];
    }
  }
  if(bi != bj){
    #pragma unroll
    for(int oc=0;oc<8;oc++){
      int c = cq + 16*oc;
      float xj2 = xxj[c];
      float* Dcol = D + (size_t)(j0+c)*PN + i0 + prg*8;
      float4 t0, t1;
      t0.x = fmaf(2.f, acc[0][oc], -xj2) - xxi[prg*8+0];
      t0.y = fmaf(2.f, acc[1][oc], -xj2) - xxi[prg*8+1];
      t0.z = fmaf(2.f, acc[2][oc], -xj2) - xxi[prg*8+2];
      t0.w = fmaf(2.f, acc[3][oc], -xj2) - xxi[prg*8+3];
      t1.x = fmaf(2.f, acc[4][oc], -xj2) - xxi[prg*8+4];
      t1.y = fmaf(2.f, acc[5][oc], -xj2) - xxi[prg*8+5];
      t1.z = fmaf(2.f, acc[6][oc], -xj2) - xxi[prg*8+6];
      t1.w = fmaf(2.f, acc[7][oc], -xj2) - xxi[prg*8+7];
      ((float4*)Dcol)[0] = t0;
      ((float4*)Dcol)[1] = t1;
    }
  }
}

// ---------------- top-20 per row: one wave per row, poison rebuild ----------------
__global__ __launch_bounds__(256) void k_topk(const float* __restrict__ D, int* __restrict__ idxb){
  int t = threadIdx.x, lane = t & 63, w = t >> 6;
  int row = blockIdx.x*4 + w;
  const float4* rp = (const float4*)(D + (size_t)row*PN + lane*64);
  float v[64];
  #pragma unroll
  for(int c=0;c<16;c++){
    float4 q = rp[c];
    v[4*c+0]=q.x; v[4*c+1]=q.y; v[4*c+2]=q.z; v[4*c+3]=q.w;
  }
  float gv0,gv1,gv2,gv3,gv4,gv5,gv6,gv7;
  int   gi0,gi1,gi2,gi3,gi4,gi5,gi6,gi7;
#define TBUILDG(G) { float gm_=NEGF; int ge_=(G)*8; \
    _Pragma("unroll") for(int e_=(G)*8; e_<(G)*8+8; e_++){ \
      bool bt_ = v[e_] > gm_; gm_ = bt_ ? v[e_] : gm_; ge_ = bt_ ? e_ : ge_; } \
    gv##G = gm_; gi##G = ge_; }
#define TPOIS(G) { _Pragma("unroll") for(int e_=(G)*8; e_<(G)*8+8; e_++){ \
      if(e_ == rel) v[e_] = NEGF; } }
  TBUILDG(0) TBUILDG(1) TBUILDG(2) TBUILDG(3) TBUILDG(4) TBUILDG(5) TBUILDG(6) TBUILDG(7)
  float lmax; int li;
#define TLBEST { lmax = gv0; li = gi0; \
    if(gv1>lmax){lmax=gv1;li=gi1;} if(gv2>lmax){lmax=gv2;li=gi2;} \
    if(gv3>lmax){lmax=gv3;li=gi3;} if(gv4>lmax){lmax=gv4;li=gi4;} \
    if(gv5>lmax){lmax=gv5;li=gi5;} if(gv6>lmax){lmax=gv6;li=gi6;} \
    if(gv7>lmax){lmax=gv7;li=gi7;} }
  TLBEST
  int myidx = 0;
  for(int k=0;k<PK;k++){
    float g = lmax;
    #pragma unroll
    for(int s=32;s>=1;s>>=1) g = fmaxf(g, __shfl_xor(g, s));
    unsigned long long mask = __ballot(lmax == g);
    int wl = __ffsll((unsigned long long)mask) - 1;
    int rel = __shfl(li, wl);
    if(lane == k) myidx = wl*64 + rel;
    if(lane == wl){
      int q = rel >> 3;
      if(q==0){ TPOIS(0) TBUILDG(0) } else if(q==1){ TPOIS(1) TBUILDG(1) }
      else if(q==2){ TPOIS(2) TBUILDG(2) } else if(q==3){ TPOIS(3) TBUILDG(3) }
      else if(q==4){ TPOIS(4) TBUILDG(4) } else if(q==5){ TPOIS(5) TBUILDG(5) }
      else if(q==6){ TPOIS(6) TBUILDG(6) } else { TPOIS(7) TBUILDG(7) }
      TLBEST
    }
  }
  if(lane < PK) idxb[row*PK + lane] = myidx;
#undef TBUILDG
#undef TPOIS
#undef TLBEST
}

// ---------------- nodeUV: per-node partial convs ----------------
__global__ __launch_bounds__(256) void k_nodeUV3(const float* __restrict__ x, const float* __restrict__ w1,
                                                 float* __restrict__ U, float* __restrict__ V){
  __shared__ float ww[384];
  int t = threadIdx.x;
  for(int k=t;k<384;k+=256) ww[k] = w1[k];
  __syncthreads();
  int g = blockIdx.x*256 + t;
  int ng = g >> 6, o = g & 63;
  int b = ng >> 12, n = ng & 4095;
  const float* xb = x + (size_t)b*3*PN;
  float p0 = xb[n], p1 = xb[PN+n], p2 = xb[2*PN+n];
  const float* wr = ww + o*6;
  float u = p0*wr[0]; u = fmaf(p1,wr[1],u); u = fmaf(p2,wr[2],u);
  float vv = p0*(wr[3]-wr[0]); vv = fmaf(p1, wr[4]-wr[1], vv); vv = fmaf(p2, wr[5]-wr[2], vv);
  U[(size_t)ng*64+o] = u;
  V[(size_t)ng*64+o] = vv;
}

__global__ __launch_bounds__(256) void k_nodeUV64(const float* __restrict__ xf, const float* __restrict__ w,
                                                  float* __restrict__ U, float* __restrict__ V){
  __shared__ float xbuf[128*64];
  __shared__ float wbuf[128*64];
  int t = threadIdx.x;
  int r0 = blockIdx.x * 128;
  #pragma unroll
  for(int k=0;k<8;k++){
    int fid = t + k*256; int row = fid>>4, c4 = fid&15;
    ((float4*)xbuf)[row*16 + (c4^(row&15))] = ((const float4*)(xf + (size_t)(r0+row)*64))[c4];
    float4 wv;
    if(row < 64){
      wv = ((const float4*)(w + (size_t)row*128))[c4];
    } else {
      float4 w2v = ((const float4*)(w + (size_t)(row-64)*128 + 64))[c4];
      float4 w1v = ((const float4*)(w + (size_t)(row-64)*128))[c4];
      wv.x = w2v.x-w1v.x; wv.y = w2v.y-w1v.y; wv.z = w2v.z-w1v.z; wv.w = w2v.w-w1v.w;
    }
    ((float4*)wbuf)[row*16 + (c4^(row&15))] = wv;
  }
  __syncthreads();
  int rg = t>>4, cq = t&15;
  float acc[8][8];
  #pragma unroll
  for(int pp=0;pp<8;pp++)
    #pragma unroll
    for(int oc=0;oc<8;oc++) acc[pp][oc] = 0.f;
  #pragma unroll 4
  for(int c4=0;c4<16;c4++){
    float4 a[8], bb[8];
    #pragma unroll
    for(int pp=0;pp<8;pp++){ int row = rg*8+pp; a[pp] = ((const float4*)xbuf)[row*16 + (c4^(row&15))]; }
    #pragma unroll
    for(int oc=0;oc<8;oc++){ int col = cq+16*oc;  bb[oc] = ((const float4*)wbuf)[col*16 + (c4^(col&15))]; }
    #pragma unroll
    for(int pp=0;pp<8;pp++)
      #pragma unroll
      for(int oc=0;oc<8;oc++) FMA4C(acc[pp][oc], a[pp], bb[oc]);
  }
  #pragma unroll
  for(int pp=0;pp<8;pp++){
    int r = r0 + rg*8+pp;
    #pragma unroll
    for(int oc=0;oc<8;oc++){
      int col = cq + 16*oc;
      if(col < 64) U[(size_t)r*64 + col] = acc[pp][oc];
      else         V[(size_t)r*64 + col-64] = acc[pp][oc];
    }
  }
}

// ---------------- BN stats over edges of y = U[j]+V[n]  (float4 channels) ----------------
__global__ __launch_bounds__(256) void k_statUV(const float* __restrict__ U, const float* __restrict__ V,
                                                const int* __restrict__ idx, float* __restrict__ part){
  __shared__ float4 sArr[256];
  __shared__ float4 qArr[256];
  int t = threadIdx.x; int blk = blockIdx.x;
  int ch4 = t & 15, sub = t >> 4;
  int qbase = blk*640;
  float4 s = make_float4(0,0,0,0), qq = make_float4(0,0,0,0);
  for(int r=sub; r<640; r+=16){
    int q = qbase + r;
    int pt = q/PK;
    int b = pt >> 12;
    int j = idx[q];
    float4 u4 = ((const float4*)(U + (size_t)(b*PN+j)*64))[ch4];
    float4 v4 = ((const float4*)(V + (size_t)pt*64))[ch4];
    float4 y4;
    y4.x = u4.x+v4.x; y4.y = u4.y+v4.y; y4.z = u4.z+v4.z; y4.w = u4.w+v4.w;
    s.x += y4.x; s.y += y4.y; s.z += y4.z; s.w += y4.w;
    qq.x = fmaf(y4.x,y4.x,qq.x); qq.y = fmaf(y4.y,y4.y,qq.y);
    qq.z = fmaf(y4.z,y4.z,qq.z); qq.w = fmaf(y4.w,y4.w,qq.w);
  }
  sArr[t] = s; qArr[t] = qq;
  __syncthreads();
  if(t < 16){
    float4 S = make_float4(0,0,0,0), Q = make_float4(0,0,0,0);
    #pragma unroll
    for(int g=0;g<16;g++){
      float4 a = sArr[g*16 + t], b = qArr[g*16 + t];
      S.x+=a.x; S.y+=a.y; S.z+=a.z; S.w+=a.w;
      Q.x+=b.x; Q.y+=b.y; Q.z+=b.z; Q.w+=b.w;
    }
    ((float4*)(part + (size_t)blk*128))[t] = S;
    ((float4*)(part + (size_t)blk*128 + 64))[t] = Q;
  }
}

// ---------------- convA fused (MFMA split-bf16): y := W.lrelu(bn(U[j]+V[n])), + BN stats ----------------
// A: h[128 rows][64 k] hi/lo bf16; B: W[64 out][64 k] hi/lo bf16 (W row-major = Wt for MFMA B).
// mfma_f32_16x16x32_bf16: A row=lane&15, k=(lane>>4)*8+i;  B n=lane&15, k=(lane>>4)*8+i;
// D col=lane&15, row=(lane>>4)*4+reg   [m89-verified].
__global__ __launch_bounds__(256) void k_convAF(const float* __restrict__ U, const float* __restrict__ V,
                                                const int* __restrict__ idx, const float* __restrict__ wg,
                                                const float* __restrict__ sb, float* __restrict__ y,
                                                float* __restrict__ part){
  __shared__ short hb[2*128*64];   // 32 KB (hi @0, lo @8192)
  __shared__ short wb[2*64*64];    // 16 KB (hi @0, lo @4096)
  int t = threadIdx.x;
  int q0 = blockIdx.x * 128;
  #pragma unroll
  for(int k=0;k<8;k++){
    int fid = t + k*256; int row = fid>>4, c4 = fid&15;
    int q = q0 + row;
    int pt = q/PK; int b = pt>>12; int j = idx[q];
    float4 uu = ((const float4*)(U + (size_t)(b*PN+j)*64))[c4];
    float4 vv = ((const float4*)(V + (size_t)pt*64))[c4];
    float4 sc = ((const float4*)sb)[c4];
    float4 bi = ((const float4*)(sb+1024))[c4];
    float4 h;
    h.x = lrelu_f(fmaf(uu.x+vv.x, sc.x, bi.x));
    h.y = lrelu_f(fmaf(uu.y+vv.y, sc.y, bi.y));
    h.z = lrelu_f(fmaf(uu.z+vv.z, sc.z, bi.z));
    h.w = lrelu_f(fmaf(uu.w+vv.w, sc.w, bi.w));
    int base = row*64 + ((((c4>>1) ^ (row&7)))<<3) + ((c4&1)<<2);
    short4 hi4, lo4;
    hi4.x = (short)f2bf(h.x); lo4.x = (short)f2bf(h.x - bf2f((unsigned short)hi4.x));
    hi4.y = (short)f2bf(h.y); lo4.y = (short)f2bf(h.y - bf2f((unsigned short)hi4.y));
    hi4.z = (short)f2bf(h.z); lo4.z = (short)f2bf(h.z - bf2f((unsigned short)hi4.z));
    hi4.w = (short)f2bf(h.w); lo4.w = (short)f2bf(h.w - bf2f((unsigned short)hi4.w));
    *(short4*)(hb + base) = hi4;
    *(short4*)(hb + 8192 + base) = lo4;
  }
  #pragma unroll
  for(int k=0;k<4;k++){
    int fid = t + k*256; int row = fid>>4, c4 = fid&15;
    float4 wv = ((const float4*)(wg + (size_t)row*64))[c4];
    int base = row*64 + ((((c4>>1) ^ (row&7)))<<3) + ((c4&1)<<2);
    short4 hi4, lo4;
    hi4.x = (short)f2bf(wv.x); lo4.x = (short)f2bf(wv.x - bf2f((unsigned short)hi4.x));
    hi4.y = (short)f2bf(wv.y); lo4.y = (short)f2bf(wv.y - bf2f((unsigned short)hi4.y));
    hi4.z = (short)f2bf(wv.z); lo4.z = (short)f2bf(wv.z - bf2f((unsigned short)hi4.z));
    hi4.w = (short)f2bf(wv.w); lo4.w = (short)f2bf(wv.w - bf2f((unsigned short)hi4.w));
    *(short4*)(wb + base) = hi4;
    *(short4*)(wb + 4096 + base) = lo4;
  }
  __syncthreads();

  int lane = t & 63, w = t >> 6;
  int r0w = w*32;
  short8v ah[2][2], al[2][2];
  #pragma unroll
  for(int rt=0;rt<2;rt++)
    #pragma unroll
    for(int kc=0;kc<2;kc++){
      int row = r0w + rt*16 + (lane&15);
      int kb  = kc*4 + (lane>>4);
      int off = row*64 + ((kb ^ (row&7))<<3);
      ah[rt][kc] = *(const short8v*)(hb + off);
      al[rt][kc] = *(const short8v*)(hb + 8192 + off);
    }
  short8v bh[4][2], bl[4][2];
  #pragma unroll
  for(int ct=0;ct<4;ct++)
    #pragma unroll
    for(int kc=0;kc<2;kc++){
      int o   = ct*16 + (lane&15);
      int kb  = kc*4 + (lane>>4);
      int off = o*64 + ((kb ^ (o&7))<<3);
      bh[ct][kc] = *(const short8v*)(wb + off);
      bl[ct][kc] = *(const short8v*)(wb + 4096 + off);
    }

  f32x4 acc[2][4];
  #pragma unroll
  for(int rt=0;rt<2;rt++)
    #pragma unroll
    for(int ct=0;ct<4;ct++)
      acc[rt][ct] = (f32x4){0.f,0.f,0.f,0.f};

  #pragma unroll
  for(int rt=0;rt<2;rt++)
    #pragma unroll
    for(int ct=0;ct<4;ct++)
      #pragma unroll
      for(int kc=0;kc<2;kc++){
        acc[rt][ct] = __builtin_amdgcn_mfma_f32_16x16x32_bf16(ah[rt][kc], bh[ct][kc], acc[rt][ct], 0,0,0);
        acc[rt][ct] = __builtin_amdgcn_mfma_f32_16x16x32_bf16(ah[rt][kc], bl[ct][kc], acc[rt][ct], 0,0,0);
        acc[rt][ct] = __builtin_amdgcn_mfma_f32_16x16x32_bf16(al[rt][kc], bh[ct][kc], acc[rt][ct], 0,0,0);
      }

  float s_[4] = {0.f,0.f,0.f,0.f}, q_[4] = {0.f,0.f,0.f,0.f};
  #pragma unroll
  for(int rt=0;rt<2;rt++)
    #pragma unroll
    for(int ct=0;ct<4;ct++){
      int colg = ct*16 + (lane&15);
      #pragma unroll
      for(int reg=0;reg<4;reg++){
        int row = r0w + rt*16 + (lane>>4)*4 + reg;
        float val = acc[rt][ct][reg];
        y[(size_t)(q0 + row)*64 + colg] = val;
        s_[ct] += val; q_[ct] = fmaf(val, val, q_[ct]);
      }
    }

  __syncthreads();                       // frag reads done; reuse wb as scratch (4096 floats)
  float* ls = (float*)wb;
  #pragma unroll
  for(int ct=0;ct<4;ct++){
    int colg = ct*16 + (lane&15);
    ls[colg*16 + (w*4 + (lane>>4))]        = s_[ct];
    ls[2048 + colg*16 + (w*4 + (lane>>4))] = q_[ct];
  }
  __syncthreads();
  if(t < 64){
    float S = 0.f, Q = 0.f;
    #pragma unroll
    for(int g=0;g<16;g++){ S += ls[t*16+g]; Q += ls[2048 + t*16+g]; }
    part[(size_t)blockIdx.x*128 + t] = S;
    part[(size_t)blockIdx.x*128 + 64 + t] = Q;
  }
}

__global__ __launch_bounds__(256) void k_red1024(const float* __restrict__ y6, float* __restrict__ part){
  int t = threadIdx.x; int blk = blockIdx.x;   // 128 blocks x 128 rows
  const float4* base = (const float4*)(y6 + (size_t)blk*128*1024);
  float4 s = make_float4(0,0,0,0), q = make_float4(0,0,0,0);
  for(int r=0;r<128;r++){
    float4 v = base[r*256 + t];
    s.x += v.x; s.y += v.y; s.z += v.z; s.w += v.w;
    q.x = fmaf(v.x,v.x,q.x); q.y = fmaf(v.y,v.y,q.y); q.z = fmaf(v.z,v.z,q.z); q.w = fmaf(v.w,v.w,q.w);
  }
  ((float4*)(part + (size_t)blk*2048))[t] = s;
  ((float4*)(part + (size_t)blk*2048 + 1024))[t] = q;
}

// ---------------- finalize BN affine ----------------
__global__ __launch_bounds__(256) void k_fin(const float* __restrict__ part, int nparts, int chn, float cnt,
                                             const float* __restrict__ gamma, const float* __restrict__ beta,
                                             float* __restrict__ sb){
  __shared__ float ls[512];
  int t = threadIdx.x;
  int chl = t & 15, sub = t >> 4;
  int ch = blockIdx.x*16 + chl;
  float S = 0.f, Q = 0.f;
  for(int p=sub; p<nparts; p+=16){
    S += part[(size_t)p*2*chn + ch];
    Q += part[(size_t)p*2*chn + chn + ch];
  }
  ls[t] = S; ls[256+t] = Q;
  __syncthreads();
  if(t < 16){
    float Sa = 0.f, Qa = 0.f;
    #pragma unroll
    for(int s=0;s<16;s++){ Sa += ls[s*16+t]; Qa += ls[256+s*16+t]; }
    int c = blockIdx.x*16 + t;
    float m  = Sa/cnt;
    float vr = Qa/cnt - m*m;
    float sc = gamma[c] * rsqrtf(vr + 1e-5f);
    sb[c] = sc; sb[1024+c] = beta[c] - m*sc;
  }
}

// ---------------- finish: x = max_k lrelu(bn(y)), + fused xx for next stage ----------------
__global__ __launch_bounds__(256) void k_finish(const float* __restrict__ y, const float* __restrict__ sb,
                                                float* __restrict__ xo, float* __restrict__ xxo){
  __shared__ float ls[256];
  int t = threadIdx.x;
  int pt = blockIdx.x*16 + (t>>4), c4 = t&15;
  const float4* base = (const float4*)(y + (size_t)pt*20*64);
  float4 sc = ((const float4*)sb)[c4];
  float4 bi = ((const float4*)(sb+1024))[c4];
  float4 m = make_float4(NEGF,NEGF,NEGF,NEGF);
  #pragma unroll 4
  for(int k=0;k<20;k++){
    float4 v = base[k*16 + c4];
    v.x = lrelu_f(fmaf(v.x, sc.x, bi.x)); v.y = lrelu_f(fmaf(v.y, sc.y, bi.y));
    v.z = lrelu_f(fmaf(v.z, sc.z, bi.z)); v.w = lrelu_f(fmaf(v.w, sc.w, bi.w));
    m.x = fmaxf(m.x,v.x); m.y = fmaxf(m.y,v.y); m.z = fmaxf(m.z,v.z); m.w = fmaxf(m.w,v.w);
  }
  ((float4*)(xo + (size_t)pt*64))[c4] = m;
  float ss = m.x*m.x; ss = fmaf(m.y,m.y,ss); ss = fmaf(m.z,m.z,ss); ss = fmaf(m.w,m.w,ss);
  ls[t] = ss;
  __syncthreads();
  if(c4 == 0){
    float S = 0.f;
    #pragma unroll
    for(int c=0;c<16;c++) S += ls[(t & 0xF0) + c];
    xxo[pt] = S;
  }
}

// ---------------- finishUV: x = max_k lrelu(bn(U[j]+V[n])) ----------------
__global__ __launch_bounds__(256) void k_finishUV(const float* __restrict__ U, const float* __restrict__ V,
                                                  const int* __restrict__ idx, const float* __restrict__ sb,
                                                  float* __restrict__ xo){
  int t = threadIdx.x;
  int pt = blockIdx.x*16 + (t>>4), c4 = t&15;
  int b = pt >> 12;
  float4 sc = ((const float4*)sb)[c4];
  float4 bi = ((const float4*)(sb+1024))[c4];
  float4 vv = ((const float4*)(V + (size_t)pt*64))[c4];
  float4 m = make_float4(NEGF,NEGF,NEGF,NEGF);
  const int* ip = idx + (size_t)pt*PK;
  #pragma unroll 4
  for(int k=0;k<PK;k++){
    int j = ip[k];
    float4 uu = ((const float4*)(U + (size_t)(b*PN+j)*64))[c4];
    float4 v;
    v.x = lrelu_f(fmaf(uu.x+vv.x, sc.x, bi.x)); v.y = lrelu_f(fmaf(uu.y+vv.y, sc.y, bi.y));
    v.z = lrelu_f(fmaf(uu.z+vv.z, sc.z, bi.z)); v.w = lrelu_f(fmaf(uu.w+vv.w, sc.w, bi.w));
    m.x = fmaxf(m.x,v.x); m.y = fmaxf(m.y,v.y); m.z = fmaxf(m.z,v.z); m.w = fmaxf(m.w,v.w);
  }
  ((float4*)(xo + (size_t)pt*64))[c4] = m;
}

// ---------------- head GEMM: 128x128 tile, 8x8 acc ----------------
__global__ __launch_bounds__(256) void k_gemm6(const float* __restrict__ x1, const float* __restrict__ x2,
                                               const float* __restrict__ x3, const float* __restrict__ w6,
                                               float* __restrict__ y6){
  __shared__ float cb[128*64];
  __shared__ float wb2[128*64];
  int t = threadIdx.x;
  int rb = blockIdx.x >> 3;
  int ob = blockIdx.x & 7;
  size_t r0 = (size_t)rb*128; int o0 = ob*128;
  int prg = t >> 4, cq = t & 15;
  float acc[8][8];
  #pragma unroll
  for(int pp=0;pp<8;pp++)
    #pragma unroll
    for(int oc=0;oc<8;oc++) acc[pp][oc] = 0.f;
  const float* srcs[3] = {x1, x2, x3};
  for(int ph=0; ph<3; ph++){
    __syncthreads();
    const float* src = srcs[ph];
    #pragma unroll
    for(int k=0;k<8;k++){
      int fid = t + k*256; int row = fid>>4, c4 = fid&15;
      ((float4*)cb)[row*16 + (c4^(row&15))] = ((const float4*)(src + (r0+row)*64))[c4];
      ((float4*)wb2)[row*16 + (c4^(row&15))] = ((const float4*)(w6 + (size_t)(o0+row)*192 + ph*64))[c4];
    }
    __syncthreads();
    #pragma unroll 4
    for(int c4=0;c4<16;c4++){
      float4 a[8], b8[8];
      #pragma unroll
      for(int pp=0;pp<8;pp++){ int row = prg*8+pp; a[pp] = ((const float4*)cb)[row*16 + (c4^(row&15))]; }
      #pragma unroll
      for(int oc=0;oc<8;oc++){ int och = cq + 16*oc; b8[oc] = ((const float4*)wb2)[och*16 + (c4^(och&15))]; }
      #pragma unroll
      for(int pp=0;pp<8;pp++)
        #pragma unroll
        for(int oc=0;oc<8;oc++) FMA4C(acc[pp][oc], a[pp], b8[oc]);
    }
  }
  #pragma unroll
  for(int pp=0;pp<8;pp++)
    #pragma unroll
    for(int oc=0;oc<8;oc++)
      y6[(r0 + prg*8+pp)*1024 + o0 + cq + 16*oc] = acc[pp][oc];
}

// ---------------- global max over n (bn6+lrelu applied) ----------------
__global__ __launch_bounds__(256) void k_gmax(const float* __restrict__ y6, const float* __restrict__ sb,
                                              float* __restrict__ gpart){
  int t = threadIdx.x; int blk = blockIdx.x;   // 64 blocks x 256 rows
  const float4* base = (const float4*)(y6 + (size_t)blk*256*1024);
  float4 sc = ((const float4*)sb)[t];
  float4 bi = ((const float4*)(sb+1024))[t];
  float4 m = make_float4(NEGF,NEGF,NEGF,NEGF);
  for(int r=0;r<256;r++){
    float4 v = base[r*256 + t];
    v.x = lrelu_f(fmaf(v.x, sc.x, bi.x)); v.y = lrelu_f(fmaf(v.y, sc.y, bi.y));
    v.z = lrelu_f(fmaf(v.z, sc.z, bi.z)); v.w = lrelu_f(fmaf(v.w, sc.w, bi.w));
    m.x = fmaxf(m.x,v.x); m.y = fmaxf(m.y,v.y); m.z = fmaxf(m.z,v.z); m.w = fmaxf(m.w,v.w);
  }
  ((float4*)(gpart + (size_t)blk*1024))[t] = m;
}

__global__ __launch_bounds__(256) void k_gmaxfin(const float* __restrict__ gpart, float* __restrict__ g){
  int b = blockIdx.x, t = threadIdx.x;
  float4 m = make_float4(NEGF,NEGF,NEGF,NEGF);
  for(int c=0;c<16;c++){
    float4 v = ((const float4*)(gpart + ((size_t)b*16 + c)*1024))[t];
    m.x = fmaxf(m.x,v.x); m.y = fmaxf(m.y,v.y); m.z = fmaxf(m.z,v.z); m.w = fmaxf(m.w,v.w);
  }
  ((float4*)(g + (size_t)b*1024))[t] = m;
}

// ---------------- final: bn(g @ wl^T, axis 0) ----------------
__global__ __launch_bounds__(256) void k_final(const float* __restrict__ g, const float* __restrict__ wl,
                                               const float* __restrict__ g7, const float* __restrict__ b7,
                                               float* __restrict__ out){
  int gt = blockIdx.x*256 + threadIdx.x;   // 2048 = 512 o x 4 b
  int o = gt >> 2, b = gt & 3;
  const float4* gb = (const float4*)(g + (size_t)b*1024);
  const float4* wr = (const float4*)(wl + (size_t)o*1024);
  float acc = 0.f;
  #pragma unroll 4
  for(int c=0;c<256;c++){
    float4 a = gb[c], w = wr[c];
    acc = fmaf(a.x,w.x,acc); acc = fmaf(a.y,w.y,acc);
    acc = fmaf(a.z,w.z,acc); acc = fmaf(a.w,w.w,acc);
  }
  float s = acc + __shfl_xor(acc, 1);
  s = s + __shfl_xor(s, 2);
  float m = s * 0.25f;
  float d = acc - m;
  float vv = d*d;
  float v2 = vv + __shfl_xor(vv, 1);
  v2 = v2 + __shfl_xor(v2, 2);
  float var = v2 * 0.25f;
  out[b*512 + o] = d * rsqrtf(var + 1e-5f) * g7[o] + b7[o];
}

// ---------------- launch ----------------
extern "C" void kernel_launch(void* const* d_in, const int* in_sizes, int n_in,
                              void* d_out, int out_size, void* d_ws, size_t ws_size,
                              hipStream_t stream){
  const float* x  = (const float*)d_in[0];
  const float* w1 = (const float*)d_in[1];
  const float* w2 = (const float*)d_in[2];
  const float* w3 = (const float*)d_in[3];
  const float* w4 = (const float*)d_in[4];
  const float* w5 = (const float*)d_in[5];
  const float* w6 = (const float*)d_in[6];
  const float* wl = (const float*)d_in[7];
  const float* g1 = (const float*)d_in[8];  const float* b1 = (const float*)d_in[9];
  const float* g2 = (const float*)d_in[10]; const float* b2 = (const float*)d_in[11];
  const float* g3 = (const float*)d_in[12]; const float* b3 = (const float*)d_in[13];
  const float* g4 = (const float*)d_in[14]; const float* b4 = (const float*)d_in[15];
  const float* g5 = (const float*)d_in[16]; const float* b5 = (const float*)d_in[17];
  const float* g6 = (const float*)d_in[18]; const float* b6 = (const float*)d_in[19];
  const float* g7 = (const float*)d_in[20]; const float* b7 = (const float*)d_in[21];
  float* out = (float*)d_out;

  // workspace layout (floats); ~107.9 MB total
  float* ws    = (float*)d_ws;
  float* xx    = ws;                        // 16384
  int*   idx   = (int*)(ws + 16384);        // 327680
  float* y     = ws + 344064;               // 20971520 (y2/y4, y6)
  float* Dbuf  = y;                         // 16777216 (per-batch dist; y dead then)
  float* x1    = ws + 21315584;             // 1048576
  float* x2    = x1 + 1048576;
  float* x3    = x2 + 1048576;
  float* part  = x3 + 1048576;              // 327680 (max: convAF 2560 blocks x 128)
  float* sb    = part + 327680;             // 2048
  float* gpart = sb + 2048;                 // 65536
  float* g     = gpart + 65536;             // 4096
  float* U     = g + 4096;                  // 1048576
  float* V     = U + 1048576;               // 1048576

  // ---- stage 1 ----
  k_knn3<<<dim3(512,4),512,0,stream>>>(x, idx);
  k_nodeUV3<<<4096,256,0,stream>>>(x, w1, U, V);
  k_statUV<<<512,256,0,stream>>>(U, V, idx, part);
  k_fin<<<4,256,0,stream>>>(part, 512, 64, (float)PNT, g1, b1, sb);
  k_convAF<<<2560,256,0,stream>>>(U, V, idx, w2, sb, y, part);
  k_fin<<<4,256,0,stream>>>(part, 2560, 64, (float)PNT, g2, b2, sb);
  k_finish<<<1024,256,0,stream>>>(y, sb, x1, xx);

  // ---- stage 2 ----
  for(int b=0;b<PB;b++){
    k_dist64<<<528,256,0,stream>>>(x1 + (size_t)b*PN*64, xx + b*PN, Dbuf);
    k_topk<<<1024,256,0,stream>>>(Dbuf, idx + (size_t)b*PN*PK);
  }
  k_nodeUV64<<<128,256,0,stream>>>(x1, w3, U, V);
  k_statUV<<<512,256,0,stream>>>(U, V, idx, part);
  k_fin<<<4,256,0,stream>>>(part, 512, 64, (float)PNT, g3, b3, sb);
  k_convAF<<<2560,256,0,stream>>>(U, V, idx, w4, sb, y, part);
  k_fin<<<4,256,0,stream>>>(part, 2560, 64, (float)PNT, g4, b4, sb);
  k_finish<<<1024,256,0,stream>>>(y, sb, x2, xx);

  // ---- stage 3 ----
  for(int b=0;b<PB;b++){
    k_dist64<<<528,256,0,stream>>>(x2 + (size_t)b*PN*64, xx + b*PN, Dbuf);
    k_topk<<<1024,256,0,stream>>>(Dbuf, idx + (size_t)b*PN*PK);
  }
  k_nodeUV64<<<128,256,0,stream>>>(x2, w5, U, V);
  k_statUV<<<512,256,0,stream>>>(U, V, idx, part);
  k_fin<<<4,256,0,stream>>>(part, 512, 64, (float)PNT, g5, b5, sb);
  k_finishUV<<<1024,256,0,stream>>>(U, V, idx, sb, x3);

  // ---- head ----
  k_gemm6<<<1024,256,0,stream>>>(x1, x2, x3, w6, y);
  k_red1024<<<128,256,0,stream>>>(y, part);
  k_fin<<<64,256,0,stream>>>(part, 128, 1024, 16384.f, g6, b6, sb);
  k_gmax<<<64,256,0,stream>>>(y, sb, gpart);
  k_gmaxfin<<<4,256,0,stream>>>(gpart, g);
  k_final<<<8,256,0,stream>>>(g, wl, g7, b7, out);
}

// Round 10
// 1178.754 us; speedup vs baseline: 5.9363x; 1.0168x over previous
//
#include <hip/hip_runtime.h>

static constexpr int PB  = 4;
static constexpr int PN  = 4096;
static constexpr int PK  = 20;
static constexpr int PNT = PB*PN*PK;   // 327680
#define NEGF (-3.402823466e38f)

__device__ __forceinline__ float lrelu_f(float x){ return x >= 0.f ? x : 0.2f*x; }

typedef __attribute__((ext_vector_type(8))) short short8v;
typedef __attribute__((ext_vector_type(4))) float f32x4;

__device__ __forceinline__ unsigned short f2bf(float f){
  unsigned u = __float_as_uint(f);
  unsigned r = u + 0x7FFFu + ((u>>16)&1u);
  return (unsigned short)(r>>16);
}
__device__ __forceinline__ float bf2f(unsigned short s){ return __uint_as_float(((unsigned)s)<<16); }

#define FMA4C(accv, av, bv) { accv = fmaf((av).x,(bv).x,accv); accv = fmaf((av).y,(bv).y,accv); \
                              accv = fmaf((av).z,(bv).z,accv); accv = fmaf((av).w,(bv).w,accv); }

// ---------------- fused stage-1 kNN: all points in LDS, register-resident dists ----------------
__global__ __launch_bounds__(512) void k_knn3(const float* __restrict__ x, int* __restrict__ idxb){
  __shared__ float4 pts[PN];                      // 64 KB: (x, y, z, xx)
  int t = threadIdx.x;
  int b = blockIdx.y;
  const float* xb = x + (size_t)b*3*PN;
  for(int i=t;i<PN;i+=512){
    float a0 = xb[i], a1 = xb[PN+i], a2 = xb[2*PN+i];
    float s = a0*a0; s = fmaf(a1,a1,s); s = fmaf(a2,a2,s);
    pts[i] = make_float4(a0,a1,a2,s);
  }
  __syncthreads();
  int lane = t & 63, w = t >> 6;
  int row = blockIdx.x*8 + w;
  float4 pi = pts[row];

  float v[64];
  #pragma unroll
  for(int e=0;e<64;e++){
    float4 pj = pts[lane + (e<<6)];
    float dt = pi.x*pj.x; dt = fmaf(pi.y,pj.y,dt); dt = fmaf(pi.z,pj.z,dt);
    v[e] = fmaf(2.f,dt,-pi.w) - pj.w;
  }

  float gv0,gv1,gv2,gv3,gv4,gv5,gv6,gv7;
  int   gi0,gi1,gi2,gi3,gi4,gi5,gi6,gi7;
#define KBUILDG(G) { float gm_=NEGF; int ge_=(G)*8; \
    _Pragma("unroll") for(int e_=(G)*8; e_<(G)*8+8; e_++){ \
      bool bt_ = v[e_] > gm_; gm_ = bt_ ? v[e_] : gm_; ge_ = bt_ ? e_ : ge_; } \
    gv##G = gm_; gi##G = ge_; }
#define KPOIS(G) { _Pragma("unroll") for(int e_=(G)*8; e_<(G)*8+8; e_++){ \
      if(e_ == e) v[e_] = NEGF; } }
  KBUILDG(0) KBUILDG(1) KBUILDG(2) KBUILDG(3) KBUILDG(4) KBUILDG(5) KBUILDG(6) KBUILDG(7)

  float lmax; int le;
#define KLBEST { lmax = gv0; le = gi0; \
    if(gv1>lmax){lmax=gv1;le=gi1;} if(gv2>lmax){lmax=gv2;le=gi2;} \
    if(gv3>lmax){lmax=gv3;le=gi3;} if(gv4>lmax){lmax=gv4;le=gi4;} \
    if(gv5>lmax){lmax=gv5;le=gi5;} if(gv6>lmax){lmax=gv6;le=gi6;} \
    if(gv7>lmax){lmax=gv7;le=gi7;} }
  KLBEST

  int myidx = 0;
  for(int k=0;k<PK;k++){
    float g = lmax;
    #pragma unroll
    for(int s=32;s>=1;s>>=1) g = fmaxf(g, __shfl_xor(g, s));
    unsigned long long cand = __ballot(lmax == g);
    int jw;
    if(__popcll(cand) == 1){
      int wl = __ffsll(cand) - 1;
      int e  = __shfl(le, wl);
      jw = wl + (e<<6);
    } else {
      unsigned jj = (lmax == g) ? (unsigned)(lane + (le<<6)) : 0xFFFFFFFFu;
      #pragma unroll
      for(int s=32;s>=1;s>>=1){ unsigned o = __shfl_xor(jj, s); jj = (o < jj) ? o : jj; }
      jw = (int)jj;
    }
    if(lane == k) myidx = jw;
    if((jw & 63) == lane){
      int e = jw >> 6;
      int q = e >> 3;
      if(q==0){ KPOIS(0) KBUILDG(0) } else if(q==1){ KPOIS(1) KBUILDG(1) }
      else if(q==2){ KPOIS(2) KBUILDG(2) } else if(q==3){ KPOIS(3) KBUILDG(3) }
      else if(q==4){ KPOIS(4) KBUILDG(4) } else if(q==5){ KPOIS(5) KBUILDG(5) }
      else if(q==6){ KPOIS(6) KBUILDG(6) } else { KPOIS(7) KBUILDG(7) }
      KLBEST
    }
  }
  if(lane < PK) idxb[((size_t)b*PN + row)*PK + lane] = myidx;
#undef KBUILDG
#undef KPOIS
#undef KLBEST
}

// ---------------- dist64: symmetric tiled GEMM, K split in 2 (33 KB LDS, 4 blocks/CU) ----------------
__global__ __launch_bounds__(256) void k_dist64(const float* __restrict__ Xb, const float* __restrict__ xxb,
                                                float* __restrict__ D){
  __shared__ float Xi[128*32];
  __shared__ float Xj[128*32];
  __shared__ float xxi[128], xxj[128];
  int t = threadIdx.x;
  int p = blockIdx.x;
  int bi = (int)((65.0f - sqrtf(4225.0f - 8.0f*(float)p)) * 0.5f);
  while((bi+1)*32 - ((bi+1)*bi)/2 <= p) bi++;
  while(bi*32 - (bi*(bi-1))/2 > p) bi--;
  int bj = bi + (p - (bi*32 - (bi*(bi-1))/2));
  int i0 = bi*128, j0 = bj*128;
  int prg = t>>4, cq = t&15;
  float acc[8][8];
  #pragma unroll
  for(int pp=0;pp<8;pp++)
    #pragma unroll
    for(int oc=0;oc<8;oc++) acc[pp][oc] = 0.f;

  for(int h=0;h<2;h++){
    if(h) __syncthreads();
    #pragma unroll
    for(int k=0;k<4;k++){
      int fid = t + k*256; int row = fid>>3, c4 = fid&7;
      ((float4*)Xi)[row*8 + (c4^(row&7))] = ((const float4*)(Xb + (size_t)(i0+row)*64 + h*32))[c4];
      ((float4*)Xj)[row*8 + (c4^(row&7))] = ((const float4*)(Xb + (size_t)(j0+row)*64 + h*32))[c4];
    }
    if(h==0){
      if(t < 128) xxi[t] = xxb[i0+t];
      else        xxj[t-128] = xxb[j0+t-128];
    }
    __syncthreads();
    #pragma unroll 4
    for(int c4=0;c4<8;c4++){
      float4 a[8], bb[8];
      #pragma unroll
      for(int pp=0;pp<8;pp++){ int row = prg*8+pp; a[pp] = ((const float4*)Xi)[row*8 + (c4^(row&7))]; }
      #pragma unroll
      for(int oc=0;oc<8;oc++){ int col = cq+16*oc;  bb[oc] = ((const float4*)Xj)[col*8 + (c4^(col&7))]; }
      #pragma unroll
      for(int pp=0;pp<8;pp++)
        #pragma unroll
        for(int oc=0;oc<8;oc++) FMA4C(acc[pp][oc], a[pp], bb[oc]);
    }
  }
  #pragma unroll
  for(int pp=0;pp<8;pp++){
    int r = prg*8+pp;
    float xi2 = xxi[r];
    float* Drow = D + (size_t)(i0+r)*PN + j0;
    #pragma unroll
    for(int oc=0;oc<8;oc++){
      int c = cq + 16*oc;
      Drow[c] = fmaf(2.f, acc[pp][oc], -xi2) - xxj[c];
    }
  }
  if(bi != bj){
    #pragma unroll
    for(int oc=0;oc<8;oc++){
      int c = cq + 16*oc;
      float xj2 = xxj[c];
      float* Dcol = D + (size_t)(j0+c)*PN + i0 + prg*8;
      float4 t0, t1;
      t0.x = fmaf(2.f, acc[0][oc], -xj2) - xxi[prg*8+0];
      t0.y = fmaf(2.f, acc[1][oc], -xj2) - xxi[prg*8+1];
      t0.z = fmaf(2.f, acc[2][oc], -xj2) - xxi[prg*8+2];
      t0.w = fmaf(2.f, acc[3][oc], -xj2) - xxi[prg*8+3];
      t1.x = fmaf(2.f, acc[4][oc], -xj2) - xxi[prg*8+4];
      t1.y = fmaf(2.f, acc[5][oc], -xj2) - xxi[prg*8+5];
      t1.z = fmaf(2.f, acc[6][oc], -xj2) - xxi[prg*8+6];
      t1.w = fmaf(2.f, acc[7][oc], -xj2) - xxi[prg*8+7];
      ((float4*)Dcol)[0] = t0;
      ((float4*)Dcol)[1] = t1;
    }
  }
}

// ---------------- top-20 per row: one wave per row, poison rebuild ----------------
__global__ __launch_bounds__(256) void k_topk(const float* __restrict__ D, int* __restrict__ idxb){
  int t = threadIdx.x, lane = t & 63, w = t >> 6;
  int row = blockIdx.x*4 + w;
  const float4* rp = (const float4*)(D + (size_t)row*PN + lane*64);
  float v[64];
  #pragma unroll
  for(int c=0;c<16;c++){
    float4 q = rp[c];
    v[4*c+0]=q.x; v[4*c+1]=q.y; v[4*c+2]=q.z; v[4*c+3]=q.w;
  }
  float gv0,gv1,gv2,gv3,gv4,gv5,gv6,gv7;
  int   gi0,gi1,gi2,gi3,gi4,gi5,gi6,gi7;
#define TBUILDG(G) { float gm_=NEGF; int ge_=(G)*8; \
    _Pragma("unroll") for(int e_=(G)*8; e_<(G)*8+8; e_++){ \
      bool bt_ = v[e_] > gm_; gm_ = bt_ ? v[e_] : gm_; ge_ = bt_ ? e_ : ge_; } \
    gv##G = gm_; gi##G = ge_; }
#define TPOIS(G) { _Pragma("unroll") for(int e_=(G)*8; e_<(G)*8+8; e_++){ \
      if(e_ == rel) v[e_] = NEGF; } }
  TBUILDG(0) TBUILDG(1) TBUILDG(2) TBUILDG(3) TBUILDG(4) TBUILDG(5) TBUILDG(6) TBUILDG(7)
  float lmax; int li;
#define TLBEST { lmax = gv0; li = gi0; \
    if(gv1>lmax){lmax=gv1;li=gi1;} if(gv2>lmax){lmax=gv2;li=gi2;} \
    if(gv3>lmax){lmax=gv3;li=gi3;} if(gv4>lmax){lmax=gv4;li=gi4;} \
    if(gv5>lmax){lmax=gv5;li=gi5;} if(gv6>lmax){lmax=gv6;li=gi6;} \
    if(gv7>lmax){lmax=gv7;li=gi7;} }
  TLBEST
  int myidx = 0;
  for(int k=0;k<PK;k++){
    float g = lmax;
    #pragma unroll
    for(int s=32;s>=1;s>>=1) g = fmaxf(g, __shfl_xor(g, s));
    unsigned long long mask = __ballot(lmax == g);
    int wl = __ffsll((unsigned long long)mask) - 1;
    int rel = __shfl(li, wl);
    if(lane == k) myidx = wl*64 + rel;
    if(lane == wl){
      int q = rel >> 3;
      if(q==0){ TPOIS(0) TBUILDG(0) } else if(q==1){ TPOIS(1) TBUILDG(1) }
      else if(q==2){ TPOIS(2) TBUILDG(2) } else if(q==3){ TPOIS(3) TBUILDG(3) }
      else if(q==4){ TPOIS(4) TBUILDG(4) } else if(q==5){ TPOIS(5) TBUILDG(5) }
      else if(q==6){ TPOIS(6) TBUILDG(6) } else { TPOIS(7) TBUILDG(7) }
      TLBEST
    }
  }
  if(lane < PK) idxb[row*PK + lane] = myidx;
#undef TBUILDG
#undef TPOIS
#undef TLBEST
}

// ---------------- nodeUV: per-node partial convs ----------------
__global__ __launch_bounds__(256) void k_nodeUV3(const float* __restrict__ x, const float* __restrict__ w1,
                                                 float* __restrict__ U, float* __restrict__ V){
  __shared__ float ww[384];
  int t = threadIdx.x;
  for(int k=t;k<384;k+=256) ww[k] = w1[k];
  __syncthreads();
  int g = blockIdx.x*256 + t;
  int ng = g >> 6, o = g & 63;
  int b = ng >> 12, n = ng & 4095;
  const float* xb = x + (size_t)b*3*PN;
  float p0 = xb[n], p1 = xb[PN+n], p2 = xb[2*PN+n];
  const float* wr = ww + o*6;
  float u = p0*wr[0]; u = fmaf(p1,wr[1],u); u = fmaf(p2,wr[2],u);
  float vv = p0*(wr[3]-wr[0]); vv = fmaf(p1, wr[4]-wr[1], vv); vv = fmaf(p2, wr[5]-wr[2], vv);
  U[(size_t)ng*64+o] = u;
  V[(size_t)ng*64+o] = vv;
}

__global__ __launch_bounds__(256) void k_nodeUV64(const float* __restrict__ xf, const float* __restrict__ w,
                                                  float* __restrict__ U, float* __restrict__ V){
  __shared__ float xbuf[128*64];
  __shared__ float wbuf[128*64];
  int t = threadIdx.x;
  int r0 = blockIdx.x * 128;
  #pragma unroll
  for(int k=0;k<8;k++){
    int fid = t + k*256; int row = fid>>4, c4 = fid&15;
    ((float4*)xbuf)[row*16 + (c4^(row&15))] = ((const float4*)(xf + (size_t)(r0+row)*64))[c4];
    float4 wv;
    if(row < 64){
      wv = ((const float4*)(w + (size_t)row*128))[c4];
    } else {
      float4 w2v = ((const float4*)(w + (size_t)(row-64)*128 + 64))[c4];
      float4 w1v = ((const float4*)(w + (size_t)(row-64)*128))[c4];
      wv.x = w2v.x-w1v.x; wv.y = w2v.y-w1v.y; wv.z = w2v.z-w1v.z; wv.w = w2v.w-w1v.w;
    }
    ((float4*)wbuf)[row*16 + (c4^(row&15))] = wv;
  }
  __syncthreads();
  int rg = t>>4, cq = t&15;
  float acc[8][8];
  #pragma unroll
  for(int pp=0;pp<8;pp++)
    #pragma unroll
    for(int oc=0;oc<8;oc++) acc[pp][oc] = 0.f;
  #pragma unroll 4
  for(int c4=0;c4<16;c4++){
    float4 a[8], bb[8];
    #pragma unroll
    for(int pp=0;pp<8;pp++){ int row = rg*8+pp; a[pp] = ((const float4*)xbuf)[row*16 + (c4^(row&15))]; }
    #pragma unroll
    for(int oc=0;oc<8;oc++){ int col = cq+16*oc;  bb[oc] = ((const float4*)wbuf)[col*16 + (c4^(col&15))]; }
    #pragma unroll
    for(int pp=0;pp<8;pp++)
      #pragma unroll
      for(int oc=0;oc<8;oc++) FMA4C(acc[pp][oc], a[pp], bb[oc]);
  }
  #pragma unroll
  for(int pp=0;pp<8;pp++){
    int r = r0 + rg*8+pp;
    #pragma unroll
    for(int oc=0;oc<8;oc++){
      int col = cq + 16*oc;
      if(col < 64) U[(size_t)r*64 + col] = acc[pp][oc];
      else         V[(size_t)r*64 + col-64] = acc[pp][oc];
    }
  }
}

// ---------------- BN stats over edges of y = U[j]+V[n]  (float4 channels) ----------------
__global__ __launch_bounds__(256) void k_statUV(const float* __restrict__ U, const float* __restrict__ V,
                                                const int* __restrict__ idx, float* __restrict__ part){
  __shared__ float4 sArr[256];
  __shared__ float4 qArr[256];
  int t = threadIdx.x; int blk = blockIdx.x;
  int ch4 = t & 15, sub = t >> 4;
  int qbase = blk*640;
  float4 s = make_float4(0,0,0,0), qq = make_float4(0,0,0,0);
  for(int r=sub; r<640; r+=16){
    int q = qbase + r;
    int pt = q/PK;
    int b = pt >> 12;
    int j = idx[q];
    float4 u4 = ((const float4*)(U + (size_t)(b*PN+j)*64))[ch4];
    float4 v4 = ((const float4*)(V + (size_t)pt*64))[ch4];
    float4 y4;
    y4.x = u4.x+v4.x; y4.y = u4.y+v4.y; y4.z = u4.z+v4.z; y4.w = u4.w+v4.w;
    s.x += y4.x; s.y += y4.y; s.z += y4.z; s.w += y4.w;
    qq.x = fmaf(y4.x,y4.x,qq.x); qq.y = fmaf(y4.y,y4.y,qq.y);
    qq.z = fmaf(y4.z,y4.z,qq.z); qq.w = fmaf(y4.w,y4.w,qq.w);
  }
  sArr[t] = s; qArr[t] = qq;
  __syncthreads();
  if(t < 16){
    float4 S = make_float4(0,0,0,0), Q = make_float4(0,0,0,0);
    #pragma unroll
    for(int g=0;g<16;g++){
      float4 a = sArr[g*16 + t], b = qArr[g*16 + t];
      S.x+=a.x; S.y+=a.y; S.z+=a.z; S.w+=a.w;
      Q.x+=b.x; Q.y+=b.y; Q.z+=b.z; Q.w+=b.w;
    }
    ((float4*)(part + (size_t)blk*128))[t] = S;
    ((float4*)(part + (size_t)blk*128 + 64))[t] = Q;
  }
}

// ---------------- convA fused (MFMA split-bf16): y := W.lrelu(bn(U[j]+V[n])), + BN stats ----------------
__global__ __launch_bounds__(256) void k_convAF(const float* __restrict__ U, const float* __restrict__ V,
                                                const int* __restrict__ idx, const float* __restrict__ wg,
                                                const float* __restrict__ sb, float* __restrict__ y,
                                                float* __restrict__ part){
  __shared__ short hb[2*128*64];   // 32 KB (hi @0, lo @8192)
  __shared__ short wb[2*64*64];    // 16 KB (hi @0, lo @4096)
  int t = threadIdx.x;
  int q0 = blockIdx.x * 128;
  #pragma unroll
  for(int k=0;k<8;k++){
    int fid = t + k*256; int row = fid>>4, c4 = fid&15;
    int q = q0 + row;
    int pt = q/PK; int b = pt>>12; int j = idx[q];
    float4 uu = ((const float4*)(U + (size_t)(b*PN+j)*64))[c4];
    float4 vv = ((const float4*)(V + (size_t)pt*64))[c4];
    float4 sc = ((const float4*)sb)[c4];
    float4 bi = ((const float4*)(sb+1024))[c4];
    float4 h;
    h.x = lrelu_f(fmaf(uu.x+vv.x, sc.x, bi.x));
    h.y = lrelu_f(fmaf(uu.y+vv.y, sc.y, bi.y));
    h.z = lrelu_f(fmaf(uu.z+vv.z, sc.z, bi.z));
    h.w = lrelu_f(fmaf(uu.w+vv.w, sc.w, bi.w));
    int base = row*64 + ((((c4>>1) ^ (row&7)))<<3) + ((c4&1)<<2);
    short4 hi4, lo4;
    hi4.x = (short)f2bf(h.x); lo4.x = (short)f2bf(h.x - bf2f((unsigned short)hi4.x));
    hi4.y = (short)f2bf(h.y); lo4.y = (short)f2bf(h.y - bf2f((unsigned short)hi4.y));
    hi4.z = (short)f2bf(h.z); lo4.z = (short)f2bf(h.z - bf2f((unsigned short)hi4.z));
    hi4.w = (short)f2bf(h.w); lo4.w = (short)f2bf(h.w - bf2f((unsigned short)hi4.w));
    *(short4*)(hb + base) = hi4;
    *(short4*)(hb + 8192 + base) = lo4;
  }
  #pragma unroll
  for(int k=0;k<4;k++){
    int fid = t + k*256; int row = fid>>4, c4 = fid&15;
    float4 wv = ((const float4*)(wg + (size_t)row*64))[c4];
    int base = row*64 + ((((c4>>1) ^ (row&7)))<<3) + ((c4&1)<<2);
    short4 hi4, lo4;
    hi4.x = (short)f2bf(wv.x); lo4.x = (short)f2bf(wv.x - bf2f((unsigned short)hi4.x));
    hi4.y = (short)f2bf(wv.y); lo4.y = (short)f2bf(wv.y - bf2f((unsigned short)hi4.y));
    hi4.z = (short)f2bf(wv.z); lo4.z = (short)f2bf(wv.z - bf2f((unsigned short)hi4.z));
    hi4.w = (short)f2bf(wv.w); lo4.w = (short)f2bf(wv.w - bf2f((unsigned short)hi4.w));
    *(short4*)(wb + base) = hi4;
    *(short4*)(wb + 4096 + base) = lo4;
  }
  __syncthreads();

  int lane = t & 63, w = t >> 6;
  int r0w = w*32;
  short8v ah[2][2], al[2][2];
  #pragma unroll
  for(int rt=0;rt<2;rt++)
    #pragma unroll
    for(int kc=0;kc<2;kc++){
      int row = r0w + rt*16 + (lane&15);
      int kb  = kc*4 + (lane>>4);
      int off = row*64 + ((kb ^ (row&7))<<3);
      ah[rt][kc] = *(const short8v*)(hb + off);
      al[rt][kc] = *(const short8v*)(hb + 8192 + off);
    }
  short8v bh[4][2], bl[4][2];
  #pragma unroll
  for(int ct=0;ct<4;ct++)
    #pragma unroll
    for(int kc=0;kc<2;kc++){
      int o   = ct*16 + (lane&15);
      int kb  = kc*4 + (lane>>4);
      int off = o*64 + ((kb ^ (o&7))<<3);
      bh[ct][kc] = *(const short8v*)(wb + off);
      bl[ct][kc] = *(const short8v*)(wb + 4096 + off);
    }

  f32x4 acc[2][4];
  #pragma unroll
  for(int rt=0;rt<2;rt++)
    #pragma unroll
    for(int ct=0;ct<4;ct++)
      acc[rt][ct] = (f32x4){0.f,0.f,0.f,0.f};

  #pragma unroll
  for(int rt=0;rt<2;rt++)
    #pragma unroll
    for(int ct=0;ct<4;ct++)
      #pragma unroll
      for(int kc=0;kc<2;kc++){
        acc[rt][ct] = __builtin_amdgcn_mfma_f32_16x16x32_bf16(ah[rt][kc], bh[ct][kc], acc[rt][ct], 0,0,0);
        acc[rt][ct] = __builtin_amdgcn_mfma_f32_16x16x32_bf16(ah[rt][kc], bl[ct][kc], acc[rt][ct], 0,0,0);
        acc[rt][ct] = __builtin_amdgcn_mfma_f32_16x16x32_bf16(al[rt][kc], bh[ct][kc], acc[rt][ct], 0,0,0);
      }

  float s_[4] = {0.f,0.f,0.f,0.f}, q_[4] = {0.f,0.f,0.f,0.f};
  #pragma unroll
  for(int rt=0;rt<2;rt++)
    #pragma unroll
    for(int ct=0;ct<4;ct++){
      int colg = ct*16 + (lane&15);
      #pragma unroll
      for(int reg=0;reg<4;reg++){
        int row = r0w + rt*16 + (lane>>4)*4 + reg;
        float val = acc[rt][ct][reg];
        y[(size_t)(q0 + row)*64 + colg] = val;
        s_[ct] += val; q_[ct] = fmaf(val, val, q_[ct]);
      }
    }

  __syncthreads();                       // frag reads done; reuse wb as scratch (4096 floats)
  float* ls = (float*)wb;
  #pragma unroll
  for(int ct=0;ct<4;ct++){
    int colg = ct*16 + (lane&15);
    ls[colg*16 + (w*4 + (lane>>4))]        = s_[ct];
    ls[2048 + colg*16 + (w*4 + (lane>>4))] = q_[ct];
  }
  __syncthreads();
  if(t < 64){
    float S = 0.f, Q = 0.f;
    #pragma unroll
    for(int g=0;g<16;g++){ S += ls[t*16+g]; Q += ls[2048 + t*16+g]; }
    part[(size_t)blockIdx.x*128 + t] = S;
    part[(size_t)blockIdx.x*128 + 64 + t] = Q;
  }
}

// ---------------- finalize BN affine ----------------
__global__ __launch_bounds__(256) void k_fin(const float* __restrict__ part, int nparts, int chn, float cnt,
                                             const float* __restrict__ gamma, const float* __restrict__ beta,
                                             float* __restrict__ sb){
  __shared__ float ls[512];
  int t = threadIdx.x;
  int chl = t & 15, sub = t >> 4;
  int ch = blockIdx.x*16 + chl;
  float S = 0.f, Q = 0.f;
  for(int p=sub; p<nparts; p+=16){
    S += part[(size_t)p*2*chn + ch];
    Q += part[(size_t)p*2*chn + chn + ch];
  }
  ls[t] = S; ls[256+t] = Q;
  __syncthreads();
  if(t < 16){
    float Sa = 0.f, Qa = 0.f;
    #pragma unroll
    for(int s=0;s<16;s++){ Sa += ls[s*16+t]; Qa += ls[256+s*16+t]; }
    int c = blockIdx.x*16 + t;
    float m  = Sa/cnt;
    float vr = Qa/cnt - m*m;
    float sc = gamma[c] * rsqrtf(vr + 1e-5f);
    sb[c] = sc; sb[1024+c] = beta[c] - m*sc;
  }
}

// ---------------- finish: x = max_k lrelu(bn(y)), + fused xx for next stage ----------------
__global__ __launch_bounds__(256) void k_finish(const float* __restrict__ y, const float* __restrict__ sb,
                                                float* __restrict__ xo, float* __restrict__ xxo){
  __shared__ float ls[256];
  int t = threadIdx.x;
  int pt = blockIdx.x*16 + (t>>4), c4 = t&15;
  const float4* base = (const float4*)(y + (size_t)pt*20*64);
  float4 sc = ((const float4*)sb)[c4];
  float4 bi = ((const float4*)(sb+1024))[c4];
  float4 m = make_float4(NEGF,NEGF,NEGF,NEGF);
  #pragma unroll 4
  for(int k=0;k<20;k++){
    float4 v = base[k*16 + c4];
    v.x = lrelu_f(fmaf(v.x, sc.x, bi.x)); v.y = lrelu_f(fmaf(v.y, sc.y, bi.y));
    v.z = lrelu_f(fmaf(v.z, sc.z, bi.z)); v.w = lrelu_f(fmaf(v.w, sc.w, bi.w));
    m.x = fmaxf(m.x,v.x); m.y = fmaxf(m.y,v.y); m.z = fmaxf(m.z,v.z); m.w = fmaxf(m.w,v.w);
  }
  ((float4*)(xo + (size_t)pt*64))[c4] = m;
  float ss = m.x*m.x; ss = fmaf(m.y,m.y,ss); ss = fmaf(m.z,m.z,ss); ss = fmaf(m.w,m.w,ss);
  ls[t] = ss;
  __syncthreads();
  if(c4 == 0){
    float S = 0.f;
    #pragma unroll
    for(int c=0;c<16;c++) S += ls[(t & 0xF0) + c];
    xxo[pt] = S;
  }
}

// ---------------- finishUV: x = max_k lrelu(bn(U[j]+V[n])) ----------------
__global__ __launch_bounds__(256) void k_finishUV(const float* __restrict__ U, const float* __restrict__ V,
                                                  const int* __restrict__ idx, const float* __restrict__ sb,
                                                  float* __restrict__ xo){
  int t = threadIdx.x;
  int pt = blockIdx.x*16 + (t>>4), c4 = t&15;
  int b = pt >> 12;
  float4 sc = ((const float4*)sb)[c4];
  float4 bi = ((const float4*)(sb+1024))[c4];
  float4 vv = ((const float4*)(V + (size_t)pt*64))[c4];
  float4 m = make_float4(NEGF,NEGF,NEGF,NEGF);
  const int* ip = idx + (size_t)pt*PK;
  #pragma unroll 4
  for(int k=0;k<PK;k++){
    int j = ip[k];
    float4 uu = ((const float4*)(U + (size_t)(b*PN+j)*64))[c4];
    float4 v;
    v.x = lrelu_f(fmaf(uu.x+vv.x, sc.x, bi.x)); v.y = lrelu_f(fmaf(uu.y+vv.y, sc.y, bi.y));
    v.z = lrelu_f(fmaf(uu.z+vv.z, sc.z, bi.z)); v.w = lrelu_f(fmaf(uu.w+vv.w, sc.w, bi.w));
    m.x = fmaxf(m.x,v.x); m.y = fmaxf(m.y,v.y); m.z = fmaxf(m.z,v.z); m.w = fmaxf(m.w,v.w);
  }
  ((float4*)(xo + (size_t)pt*64))[c4] = m;
}

// ---------------- head GEMM (MFMA split-bf16): y6 = cat(x1,x2,x3) @ w6^T, + fused BN stats ----------------
__global__ __launch_bounds__(256) void k_gemm6(const float* __restrict__ x1, const float* __restrict__ x2,
                                               const float* __restrict__ x3, const float* __restrict__ w6,
                                               float* __restrict__ y6, float* __restrict__ part){
  __shared__ short cb[2*128*64];   // 32 KB hi@0 lo@8192
  __shared__ short wb[2*128*64];   // 32 KB hi@0 lo@8192
  int t = threadIdx.x;
  int rb = blockIdx.x >> 3, ob = blockIdx.x & 7;
  size_t r0 = (size_t)rb*128; int o0 = ob*128;
  int lane = t & 63, w = t >> 6;
  int r0w = w*32;
  f32x4 acc[2][8];
  #pragma unroll
  for(int rt=0;rt<2;rt++)
    #pragma unroll
    for(int ct=0;ct<8;ct++)
      acc[rt][ct] = (f32x4){0.f,0.f,0.f,0.f};
  const float* srcs[3] = {x1, x2, x3};
  for(int ph=0; ph<3; ph++){
    __syncthreads();
    const float* src = srcs[ph];
    #pragma unroll
    for(int k=0;k<8;k++){
      int fid = t + k*256; int row = fid>>4, c4 = fid&15;
      float4 av = ((const float4*)(src + (r0+row)*64))[c4];
      float4 wv = *(const float4*)(w6 + (size_t)(o0+row)*192 + ph*64 + c4*4);
      int base = row*64 + ((((c4>>1) ^ (row&7)))<<3) + ((c4&1)<<2);
      short4 hi4, lo4;
      hi4.x = (short)f2bf(av.x); lo4.x = (short)f2bf(av.x - bf2f((unsigned short)hi4.x));
      hi4.y = (short)f2bf(av.y); lo4.y = (short)f2bf(av.y - bf2f((unsigned short)hi4.y));
      hi4.z = (short)f2bf(av.z); lo4.z = (short)f2bf(av.z - bf2f((unsigned short)hi4.z));
      hi4.w = (short)f2bf(av.w); lo4.w = (short)f2bf(av.w - bf2f((unsigned short)hi4.w));
      *(short4*)(cb + base) = hi4;
      *(short4*)(cb + 8192 + base) = lo4;
      hi4.x = (short)f2bf(wv.x); lo4.x = (short)f2bf(wv.x - bf2f((unsigned short)hi4.x));
      hi4.y = (short)f2bf(wv.y); lo4.y = (short)f2bf(wv.y - bf2f((unsigned short)hi4.y));
      hi4.z = (short)f2bf(wv.z); lo4.z = (short)f2bf(wv.z - bf2f((unsigned short)hi4.z));
      hi4.w = (short)f2bf(wv.w); lo4.w = (short)f2bf(wv.w - bf2f((unsigned short)hi4.w));
      *(short4*)(wb + base) = hi4;
      *(short4*)(wb + 8192 + base) = lo4;
    }
    __syncthreads();
    short8v ah[2][2], al[2][2];
    #pragma unroll
    for(int rt=0;rt<2;rt++)
      #pragma unroll
      for(int kc=0;kc<2;kc++){
        int row = r0w + rt*16 + (lane&15);
        int kb  = kc*4 + (lane>>4);
        int off = row*64 + ((kb ^ (row&7))<<3);
        ah[rt][kc] = *(const short8v*)(cb + off);
        al[rt][kc] = *(const short8v*)(cb + 8192 + off);
      }
    #pragma unroll
    for(int ct=0;ct<8;ct++){
      short8v bh[2], bl[2];
      #pragma unroll
      for(int kc=0;kc<2;kc++){
        int o   = ct*16 + (lane&15);
        int kb  = kc*4 + (lane>>4);
        int off = o*64 + ((kb ^ (o&7))<<3);
        bh[kc] = *(const short8v*)(wb + off);
        bl[kc] = *(const short8v*)(wb + 8192 + off);
      }
      #pragma unroll
      for(int rt=0;rt<2;rt++)
        #pragma unroll
        for(int kc=0;kc<2;kc++){
          acc[rt][ct] = __builtin_amdgcn_mfma_f32_16x16x32_bf16(ah[rt][kc], bh[kc], acc[rt][ct], 0,0,0);
          acc[rt][ct] = __builtin_amdgcn_mfma_f32_16x16x32_bf16(ah[rt][kc], bl[kc], acc[rt][ct], 0,0,0);
          acc[rt][ct] = __builtin_amdgcn_mfma_f32_16x16x32_bf16(al[rt][kc], bh[kc], acc[rt][ct], 0,0,0);
        }
    }
  }
  float s_[8] = {0,0,0,0,0,0,0,0}, q_[8] = {0,0,0,0,0,0,0,0};
  #pragma unroll
  for(int rt=0;rt<2;rt++)
    #pragma unroll
    for(int ct=0;ct<8;ct++){
      int colg = ct*16 + (lane&15);
      #pragma unroll
      for(int reg=0;reg<4;reg++){
        int row = r0w + rt*16 + (lane>>4)*4 + reg;
        float val = acc[rt][ct][reg];
        y6[(r0 + row)*1024 + o0 + colg] = val;
        s_[ct] += val; q_[ct] = fmaf(val, val, q_[ct]);
      }
    }
  __syncthreads();
  float* ls = (float*)wb;                 // 4096 floats scratch
  #pragma unroll
  for(int ct=0;ct<8;ct++){
    int colg = ct*16 + (lane&15);
    ls[colg*16 + (w*4 + (lane>>4))]        = s_[ct];
    ls[2048 + colg*16 + (w*4 + (lane>>4))] = q_[ct];
  }
  __syncthreads();
  if(t < 128){
    float S = 0.f, Q = 0.f;
    #pragma unroll
    for(int g=0;g<16;g++){ S += ls[t*16+g]; Q += ls[2048 + t*16+g]; }
    part[(size_t)rb*2048 + ob*128 + t] = S;
    part[(size_t)rb*2048 + 1024 + ob*128 + t] = Q;
  }
}

// ---------------- global max over n (bn6+lrelu applied) ----------------
__global__ __launch_bounds__(256) void k_gmax(const float* __restrict__ y6, const float* __restrict__ sb,
                                              float* __restrict__ gpart){
  int t = threadIdx.x; int blk = blockIdx.x;   // 64 blocks x 256 rows
  const float4* base = (const float4*)(y6 + (size_t)blk*256*1024);
  float4 sc = ((const float4*)sb)[t];
  float4 bi = ((const float4*)(sb+1024))[t];
  float4 m = make_float4(NEGF,NEGF,NEGF,NEGF);
  for(int r=0;r<256;r++){
    float4 v = base[r*256 + t];
    v.x = lrelu_f(fmaf(v.x, sc.x, bi.x)); v.y = lrelu_f(fmaf(v.y, sc.y, bi.y));
    v.z = lrelu_f(fmaf(v.z, sc.z, bi.z)); v.w = lrelu_f(fmaf(v.w, sc.w, bi.w));
    m.x = fmaxf(m.x,v.x); m.y = fmaxf(m.y,v.y); m.z = fmaxf(m.z,v.z); m.w = fmaxf(m.w,v.w);
  }
  ((float4*)(gpart + (size_t)blk*1024))[t] = m;
}

__global__ __launch_bounds__(256) void k_gmaxfin(const float* __restrict__ gpart, float* __restrict__ g){
  int b = blockIdx.x, t = threadIdx.x;
  float4 m = make_float4(NEGF,NEGF,NEGF,NEGF);
  for(int c=0;c<16;c++){
    float4 v = ((const float4*)(gpart + ((size_t)b*16 + c)*1024))[t];
    m.x = fmaxf(m.x,v.x); m.y = fmaxf(m.y,v.y); m.z = fmaxf(m.z,v.z); m.w = fmaxf(m.w,v.w);
  }
  ((float4*)(g + (size_t)b*1024))[t] = m;
}

// ---------------- final: bn(g @ wl^T, axis 0) ----------------
__global__ __launch_bounds__(256) void k_final(const float* __restrict__ g, const float* __restrict__ wl,
                                               const float* __restrict__ g7, const float* __restrict__ b7,
                                               float* __restrict__ out){
  int gt = blockIdx.x*256 + threadIdx.x;   // 2048 = 512 o x 4 b
  int o = gt >> 2, b = gt & 3;
  const float4* gb = (const float4*)(g + (size_t)b*1024);
  const float4* wr = (const float4*)(wl + (size_t)o*1024);
  float acc = 0.f;
  #pragma unroll 4
  for(int c=0;c<256;c++){
    float4 a = gb[c], w = wr[c];
    acc = fmaf(a.x,w.x,acc); acc = fmaf(a.y,w.y,acc);
    acc = fmaf(a.z,w.z,acc); acc = fmaf(a.w,w.w,acc);
  }
  float s = acc + __shfl_xor(acc, 1);
  s = s + __shfl_xor(s, 2);
  float m = s * 0.25f;
  float d = acc - m;
  float vv = d*d;
  float v2 = vv + __shfl_xor(vv, 1);
  v2 = v2 + __shfl_xor(v2, 2);
  float var = v2 * 0.25f;
  out[b*512 + o] = d * rsqrtf(var + 1e-5f) * g7[o] + b7[o];
}

// ---------------- launch ----------------
extern "C" void kernel_launch(void* const* d_in, const int* in_sizes, int n_in,
                              void* d_out, int out_size, void* d_ws, size_t ws_size,
                              hipStream_t stream){
  const float* x  = (const float*)d_in[0];
  const float* w1 = (const float*)d_in[1];
  const float* w2 = (const float*)d_in[2];
  const float* w3 = (const float*)d_in[3];
  const float* w4 = (const float*)d_in[4];
  const float* w5 = (const float*)d_in[5];
  const float* w6 = (const float*)d_in[6];
  const float* wl = (const float*)d_in[7];
  const float* g1 = (const float*)d_in[8];  const float* b1 = (const float*)d_in[9];
  const float* g2 = (const float*)d_in[10]; const float* b2 = (const float*)d_in[11];
  const float* g3 = (const float*)d_in[12]; const float* b3 = (const float*)d_in[13];
  const float* g4 = (const float*)d_in[14]; const float* b4 = (const float*)d_in[15];
  const float* g5 = (const float*)d_in[16]; const float* b5 = (const float*)d_in[17];
  const float* g6 = (const float*)d_in[18]; const float* b6 = (const float*)d_in[19];
  const float* g7 = (const float*)d_in[20]; const float* b7 = (const float*)d_in[21];
  float* out = (float*)d_out;

  // workspace layout (floats); ~107.9 MB total
  float* ws    = (float*)d_ws;
  float* xx    = ws;                        // 16384
  int*   idx   = (int*)(ws + 16384);        // 327680
  float* y     = ws + 344064;               // 20971520 (y2/y4, y6)
  float* Dbuf  = y;                         // 16777216 (per-batch dist; y dead then)
  float* x1    = ws + 21315584;             // 1048576
  float* x2    = x1 + 1048576;
  float* x3    = x2 + 1048576;
  float* part  = x3 + 1048576;              // 327680 (max: convAF 2560 blocks x 128)
  float* sb    = part + 327680;             // 2048
  float* gpart = sb + 2048;                 // 65536
  float* g     = gpart + 65536;             // 4096
  float* U     = g + 4096;                  // 1048576
  float* V     = U + 1048576;               // 1048576

  // ---- stage 1 ----
  k_knn3<<<dim3(512,4),512,0,stream>>>(x, idx);
  k_nodeUV3<<<4096,256,0,stream>>>(x, w1, U, V);
  k_statUV<<<512,256,0,stream>>>(U, V, idx, part);
  k_fin<<<4,256,0,stream>>>(part, 512, 64, (float)PNT, g1, b1, sb);
  k_convAF<<<2560,256,0,stream>>>(U, V, idx, w2, sb, y, part);
  k_fin<<<4,256,0,stream>>>(part, 2560, 64, (float)PNT, g2, b2, sb);
  k_finish<<<1024,256,0,stream>>>(y, sb, x1, xx);

  // ---- stage 2 ----
  for(int b=0;b<PB;b++){
    k_dist64<<<528,256,0,stream>>>(x1 + (size_t)b*PN*64, xx + b*PN, Dbuf);
    k_topk<<<1024,256,0,stream>>>(Dbuf, idx + (size_t)b*PN*PK);
  }
  k_nodeUV64<<<128,256,0,stream>>>(x1, w3, U, V);
  k_statUV<<<512,256,0,stream>>>(U, V, idx, part);
  k_fin<<<4,256,0,stream>>>(part, 512, 64, (float)PNT, g3, b3, sb);
  k_convAF<<<2560,256,0,stream>>>(U, V, idx, w4, sb, y, part);
  k_fin<<<4,256,0,stream>>>(part, 2560, 64, (float)PNT, g4, b4, sb);
  k_finish<<<1024,256,0,stream>>>(y, sb, x2, xx);

  // ---- stage 3 ----
  for(int b=0;b<PB;b++){
    k_dist64<<<528,256,0,stream>>>(x2 + (size_t)b*PN*64, xx + b*PN, Dbuf);
    k_topk<<<1024,256,0,stream>>>(Dbuf, idx + (size_t)b*PN*PK);
  }
  k_nodeUV64<<<128,256,0,stream>>>(x2, w5, U, V);
  k_statUV<<<512,256,0,stream>>>(U, V, idx, part);
  k_fin<<<4,256,0,stream>>>(part, 512, 64, (float)PNT, g5, b5, sb);
  k_finishUV<<<1024,256,0,stream>>>(U, V, idx, sb, x3);

  // ---- head ----
  k_gemm6<<<1024,256,0,stream>>>(x1, x2, x3, w6, y, part);
  k_fin<<<64,256,0,stream>>>(part, 128, 1024, 16384.f, g6, b6, sb);
  k_gmax<<<64,256,0,stream>>>(y, sb, gpart);
  k_gmaxfin<<<4,256,0,stream>>>(gpart, g);
  k_final<<<8,256,0,stream>>>(g, wl, g7, b7, out);
}

// Round 11
// 1118.093 us; speedup vs baseline: 6.2583x; 1.0543x over previous
//
#include <hip/hip_runtime.h>

static constexpr int PB  = 4;
static constexpr int PN  = 4096;
static constexpr int PK  = 20;
static constexpr int PNT = PB*PN*PK;   // 327680
#define NEGF (-3.402823466e38f)

__device__ __forceinline__ float lrelu_f(float x){ return x >= 0.f ? x : 0.2f*x; }

typedef __attribute__((ext_vector_type(8))) short short8v;
typedef __attribute__((ext_vector_type(4))) float f32x4;

__device__ __forceinline__ unsigned short f2bf(float f){
  unsigned u = __float_as_uint(f);
  unsigned r = u + 0x7FFFu + ((u>>16)&1u);
  return (unsigned short)(r>>16);
}
__device__ __forceinline__ float bf2f(unsigned short s){ return __uint_as_float(((unsigned)s)<<16); }

#define FMA4C(accv, av, bv) { accv = fmaf((av).x,(bv).x,accv); accv = fmaf((av).y,(bv).y,accv); \
                              accv = fmaf((av).z,(bv).z,accv); accv = fmaf((av).w,(bv).w,accv); }

// ---------------- fused stage-1 kNN (R9 version: LDS recompute, 52 VGPR) ----------------
__global__ __launch_bounds__(512) void k_knn3(const float* __restrict__ x, int* __restrict__ idxb){
  __shared__ float4 pts[PN];                      // 64 KB: (x, y, z, xx)
  int t = threadIdx.x;
  int b = blockIdx.y;
  const float* xb = x + (size_t)b*3*PN;
  for(int i=t;i<PN;i+=512){
    float a0 = xb[i], a1 = xb[PN+i], a2 = xb[2*PN+i];
    float s = a0*a0; s = fmaf(a1,a1,s); s = fmaf(a2,a2,s);
    pts[i] = make_float4(a0,a1,a2,s);
  }
  __syncthreads();
  int lane = t & 63, w = t >> 6;
  int row = blockIdx.x*8 + w;
  float4 pi = pts[row];
  unsigned long long removed = 0ull;

#define KDIST(E) ({ float4 pj_ = pts[lane + ((E)<<6)]; \
    float dt_ = pi.x*pj_.x; dt_ = fmaf(pi.y,pj_.y,dt_); dt_ = fmaf(pi.z,pj_.z,dt_); \
    fmaf(2.f,dt_,-pi.w) - pj_.w; })

  float gv0,gv1,gv2,gv3,gv4,gv5,gv6,gv7;
  int   gi0,gi1,gi2,gi3,gi4,gi5,gi6,gi7;
#define KBUILDG(G) { float gm_=NEGF; int ge_=(G)*8; \
    _Pragma("unroll") for(int e_=(G)*8; e_<(G)*8+8; e_++){ \
      bool ok_ = ((removed >> e_) & 1ull) == 0ull; \
      float d_ = KDIST(e_); \
      bool bt_ = ok_ && (d_ > gm_); gm_ = bt_ ? d_ : gm_; ge_ = bt_ ? e_ : ge_; } \
    gv##G = gm_; gi##G = ge_; }
  KBUILDG(0) KBUILDG(1) KBUILDG(2) KBUILDG(3) KBUILDG(4) KBUILDG(5) KBUILDG(6) KBUILDG(7)

  float lmax; int le;
#define KLBEST { lmax = gv0; le = gi0; \
    if(gv1>lmax){lmax=gv1;le=gi1;} if(gv2>lmax){lmax=gv2;le=gi2;} \
    if(gv3>lmax){lmax=gv3;le=gi3;} if(gv4>lmax){lmax=gv4;le=gi4;} \
    if(gv5>lmax){lmax=gv5;le=gi5;} if(gv6>lmax){lmax=gv6;le=gi6;} \
    if(gv7>lmax){lmax=gv7;le=gi7;} }
  KLBEST

  int myidx = 0;
  for(int k=0;k<PK;k++){
    float g = lmax;
    #pragma unroll
    for(int s=32;s>=1;s>>=1) g = fmaxf(g, __shfl_xor(g, s));
    unsigned long long cand = __ballot(lmax == g);
    int jw;
    if(__popcll(cand) == 1){
      int wl = __ffsll(cand) - 1;
      int e  = __shfl(le, wl);
      jw = wl + (e<<6);
    } else {
      unsigned jj = (lmax == g) ? (unsigned)(lane + (le<<6)) : 0xFFFFFFFFu;
      #pragma unroll
      for(int s=32;s>=1;s>>=1){ unsigned o = __shfl_xor(jj, s); jj = (o < jj) ? o : jj; }
      jw = (int)jj;
    }
    if(lane == k) myidx = jw;
    if((jw & 63) == lane){
      int e = jw >> 6;
      removed |= (1ull << e);
      int q = e >> 3;
      if(q==0){ KBUILDG(0) } else if(q==1){ KBUILDG(1) }
      else if(q==2){ KBUILDG(2) } else if(q==3){ KBUILDG(3) }
      else if(q==4){ KBUILDG(4) } else if(q==5){ KBUILDG(5) }
      else if(q==6){ KBUILDG(6) } else { KBUILDG(7) }
      KLBEST
    }
  }
  if(lane < PK) idxb[((size_t)b*PN + row)*PK + lane] = myidx;
#undef KDIST
#undef KBUILDG
#undef KLBEST
}

// ---------------- dist64: symmetric tiled GEMM, K split in 2 (33 KB LDS, 4 blocks/CU) ----------------
__global__ __launch_bounds__(256) void k_dist64(const float* __restrict__ Xb, const float* __restrict__ xxb,
                                                float* __restrict__ D){
  __shared__ float Xi[128*32];
  __shared__ float Xj[128*32];
  __shared__ float xxi[128], xxj[128];
  int t = threadIdx.x;
  int p = blockIdx.x;
  int bi = (int)((65.0f - sqrtf(4225.0f - 8.0f*(float)p)) * 0.5f);
  while((bi+1)*32 - ((bi+1)*bi)/2 <= p) bi++;
  while(bi*32 - (bi*(bi-1))/2 > p) bi--;
  int bj = bi + (p - (bi*32 - (bi*(bi-1))/2));
  int i0 = bi*128, j0 = bj*128;
  int prg = t>>4, cq = t&15;
  float acc[8][8];
  #pragma unroll
  for(int pp=0;pp<8;pp++)
    #pragma unroll
    for(int oc=0;oc<8;oc++) acc[pp][oc] = 0.f;

  for(int h=0;h<2;h++){
    if(h) __syncthreads();
    #pragma unroll
    for(int k=0;k<4;k++){
      int fid = t + k*256; int row = fid>>3, c4 = fid&7;
      ((float4*)Xi)[row*8 + (c4^(row&7))] = ((const float4*)(Xb + (size_t)(i0+row)*64 + h*32))[c4];
      ((float4*)Xj)[row*8 + (c4^(row&7))] = ((const float4*)(Xb + (size_t)(j0+row)*64 + h*32))[c4];
    }
    if(h==0){
      if(t < 128) xxi[t] = xxb[i0+t];
      else        xxj[t-128] = xxb[j0+t-128];
    }
    __syncthreads();
    #pragma unroll 4
    for(int c4=0;c4<8;c4++){
      float4 a[8], bb[8];
      #pragma unroll
      for(int pp=0;pp<8;pp++){ int row = prg*8+pp; a[pp] = ((const float4*)Xi)[row*8 + (c4^(row&7))]; }
      #pragma unroll
      for(int oc=0;oc<8;oc++){ int col = cq+16*oc;  bb[oc] = ((const float4*)Xj)[col*8 + (c4^(col&7))]; }
      #pragma unroll
      for(int pp=0;pp<8;pp++)
        #pragma unroll
        for(int oc=0;oc<8;oc++) FMA4C(acc[pp][oc], a[pp], bb[oc]);
    }
  }
  #pragma unroll
  for(int pp=0;pp<8;pp++){
    int r = prg*8+pp;
    float xi2 = xxi[r];
    float* Drow = D + (size_t)(i0+r)*PN + j0;
    #pragma unroll
    for(int oc=0;oc<8;oc++){
      int c = cq + 16*oc;
      Drow[c] = fmaf(2.f, acc[pp][oc], -xi2) - xxj[c];
    }
  }
  if(bi != bj){
    #pragma unroll
    for(int oc=0;oc<8;oc++){
      int c = cq + 16*oc;
      float xj2 = xxj[c];
      float* Dcol = D + (size_t)(j0+c)*PN + i0 + prg*8;
      float4 t0, t1;
      t0.x = fmaf(2.f, acc[0][oc], -xj2) - xxi[prg*8+0];
      t0.y = fmaf(2.f, acc[1][oc], -xj2) - xxi[prg*8+1];
      t0.z = fmaf(2.f, acc[2][oc], -xj2) - xxi[prg*8+2];
      t0.w = fmaf(2.f, acc[3][oc], -xj2) - xxi[prg*8+3];
      t1.x = fmaf(2.f, acc[4][oc], -xj2) - xxi[prg*8+4];
      t1.y = fmaf(2.f, acc[5][oc], -xj2) - xxi[prg*8+5];
      t1.z = fmaf(2.f, acc[6][oc], -xj2) - xxi[prg*8+6];
      t1.w = fmaf(2.f, acc[7][oc], -xj2) - xxi[prg*8+7];
      ((float4*)Dcol)[0] = t0;
      ((float4*)Dcol)[1] = t1;
    }
  }
}

// ---------------- top-20 per row: one wave per row, poison rebuild ----------------
__global__ __launch_bounds__(256) void k_topk(const float* __restrict__ D, int* __restrict__ idxb){
  int t = threadIdx.x, lane = t & 63, w = t >> 6;
  int row = blockIdx.x*4 + w;
  const float4* rp = (const float4*)(D + (size_t)row*PN + lane*64);
  float v[64];
  #pragma unroll
  for(int c=0;c<16;c++){
    float4 q = rp[c];
    v[4*c+0]=q.x; v[4*c+1]=q.y; v[4*c+2]=q.z; v[4*c+3]=q.w;
  }
  float gv0,gv1,gv2,gv3,gv4,gv5,gv6,gv7;
  int   gi0,gi1,gi2,gi3,gi4,gi5,gi6,gi7;
#define TBUILDG(G) { float gm_=NEGF; int ge_=(G)*8; \
    _Pragma("unroll") for(int e_=(G)*8; e_<(G)*8+8; e_++){ \
      bool bt_ = v[e_] > gm_; gm_ = bt_ ? v[e_] : gm_; ge_ = bt_ ? e_ : ge_; } \
    gv##G = gm_; gi##G = ge_; }
#define TPOIS(G) { _Pragma("unroll") for(int e_=(G)*8; e_<(G)*8+8; e_++){ \
      if(e_ == rel) v[e_] = NEGF; } }
  TBUILDG(0) TBUILDG(1) TBUILDG(2) TBUILDG(3) TBUILDG(4) TBUILDG(5) TBUILDG(6) TBUILDG(7)
  float lmax; int li;
#define TLBEST { lmax = gv0; li = gi0; \
    if(gv1>lmax){lmax=gv1;li=gi1;} if(gv2>lmax){lmax=gv2;li=gi2;} \
    if(gv3>lmax){lmax=gv3;li=gi3;} if(gv4>lmax){lmax=gv4;li=gi4;} \
    if(gv5>lmax){lmax=gv5;li=gi5;} if(gv6>lmax){lmax=gv6;li=gi6;} \
    if(gv7>lmax){lmax=gv7;li=gi7;} }
  TLBEST
  int myidx = 0;
  for(int k=0;k<PK;k++){
    float g = lmax;
    #pragma unroll
    for(int s=32;s>=1;s>>=1) g = fmaxf(g, __shfl_xor(g, s));
    unsigned long long mask = __ballot(lmax == g);
    int wl = __ffsll((unsigned long long)mask) - 1;
    int rel = __shfl(li, wl);
    if(lane == k) myidx = wl*64 + rel;
    if(lane == wl){
      int q = rel >> 3;
      if(q==0){ TPOIS(0) TBUILDG(0) } else if(q==1){ TPOIS(1) TBUILDG(1) }
      else if(q==2){ TPOIS(2) TBUILDG(2) } else if(q==3){ TPOIS(3) TBUILDG(3) }
      else if(q==4){ TPOIS(4) TBUILDG(4) } else if(q==5){ TPOIS(5) TBUILDG(5) }
      else if(q==6){ TPOIS(6) TBUILDG(6) } else { TPOIS(7) TBUILDG(7) }
      TLBEST
    }
  }
  if(lane < PK) idxb[row*PK + lane] = myidx;
#undef TBUILDG
#undef TPOIS
#undef TLBEST
}

// ---------------- nodeUV: per-node partial convs ----------------
__global__ __launch_bounds__(256) void k_nodeUV3(const float* __restrict__ x, const float* __restrict__ w1,
                                                 float* __restrict__ U, float* __restrict__ V){
  __shared__ float ww[384];
  int t = threadIdx.x;
  for(int k=t;k<384;k+=256) ww[k] = w1[k];
  __syncthreads();
  int g = blockIdx.x*256 + t;
  int ng = g >> 6, o = g & 63;
  int b = ng >> 12, n = ng & 4095;
  const float* xb = x + (size_t)b*3*PN;
  float p0 = xb[n], p1 = xb[PN+n], p2 = xb[2*PN+n];
  const float* wr = ww + o*6;
  float u = p0*wr[0]; u = fmaf(p1,wr[1],u); u = fmaf(p2,wr[2],u);
  float vv = p0*(wr[3]-wr[0]); vv = fmaf(p1, wr[4]-wr[1], vv); vv = fmaf(p2, wr[5]-wr[2], vv);
  U[(size_t)ng*64+o] = u;
  V[(size_t)ng*64+o] = vv;
}

__global__ __launch_bounds__(256) void k_nodeUV64(const float* __restrict__ xf, const float* __restrict__ w,
                                                  float* __restrict__ U, float* __restrict__ V){
  __shared__ float xbuf[128*64];
  __shared__ float wbuf[128*64];
  int t = threadIdx.x;
  int r0 = blockIdx.x * 128;
  #pragma unroll
  for(int k=0;k<8;k++){
    int fid = t + k*256; int row = fid>>4, c4 = fid&15;
    ((float4*)xbuf)[row*16 + (c4^(row&15))] = ((const float4*)(xf + (size_t)(r0+row)*64))[c4];
    float4 wv;
    if(row < 64){
      wv = ((const float4*)(w + (size_t)row*128))[c4];
    } else {
      float4 w2v = ((const float4*)(w + (size_t)(row-64)*128 + 64))[c4];
      float4 w1v = ((const float4*)(w + (size_t)(row-64)*128))[c4];
      wv.x = w2v.x-w1v.x; wv.y = w2v.y-w1v.y; wv.z = w2v.z-w1v.z; wv.w = w2v.w-w1v.w;
    }
    ((float4*)wbuf)[row*16 + (c4^(row&15))] = wv;
  }
  __syncthreads();
  int rg = t>>4, cq = t&15;
  float acc[8][8];
  #pragma unroll
  for(int pp=0;pp<8;pp++)
    #pragma unroll
    for(int oc=0;oc<8;oc++) acc[pp][oc] = 0.f;
  #pragma unroll 4
  for(int c4=0;c4<16;c4++){
    float4 a[8], bb[8];
    #pragma unroll
    for(int pp=0;pp<8;pp++){ int row = rg*8+pp; a[pp] = ((const float4*)xbuf)[row*16 + (c4^(row&15))]; }
    #pragma unroll
    for(int oc=0;oc<8;oc++){ int col = cq+16*oc;  bb[oc] = ((const float4*)wbuf)[col*16 + (c4^(col&15))]; }
    #pragma unroll
    for(int pp=0;pp<8;pp++)
      #pragma unroll
      for(int oc=0;oc<8;oc++) FMA4C(acc[pp][oc], a[pp], bb[oc]);
  }
  #pragma unroll
  for(int pp=0;pp<8;pp++){
    int r = r0 + rg*8+pp;
    #pragma unroll
    for(int oc=0;oc<8;oc++){
      int col = cq + 16*oc;
      if(col < 64) U[(size_t)r*64 + col] = acc[pp][oc];
      else         V[(size_t)r*64 + col-64] = acc[pp][oc];
    }
  }
}

// ---------------- BN stats over edges of y = U[j]+V[n]  (float4 channels) ----------------
__global__ __launch_bounds__(256) void k_statUV(const float* __restrict__ U, const float* __restrict__ V,
                                                const int* __restrict__ idx, float* __restrict__ part){
  __shared__ float4 sArr[256];
  __shared__ float4 qArr[256];
  int t = threadIdx.x; int blk = blockIdx.x;
  int ch4 = t & 15, sub = t >> 4;
  int qbase = blk*640;
  float4 s = make_float4(0,0,0,0), qq = make_float4(0,0,0,0);
  for(int r=sub; r<640; r+=16){
    int q = qbase + r;
    int pt = q/PK;
    int b = pt >> 12;
    int j = idx[q];
    float4 u4 = ((const float4*)(U + (size_t)(b*PN+j)*64))[ch4];
    float4 v4 = ((const float4*)(V + (size_t)pt*64))[ch4];
    float4 y4;
    y4.x = u4.x+v4.x; y4.y = u4.y+v4.y; y4.z = u4.z+v4.z; y4.w = u4.w+v4.w;
    s.x += y4.x; s.y += y4.y; s.z += y4.z; s.w += y4.w;
    qq.x = fmaf(y4.x,y4.x,qq.x); qq.y = fmaf(y4.y,y4.y,qq.y);
    qq.z = fmaf(y4.z,y4.z,qq.z); qq.w = fmaf(y4.w,y4.w,qq.w);
  }
  sArr[t] = s; qArr[t] = qq;
  __syncthreads();
  if(t < 16){
    float4 S = make_float4(0,0,0,0), Q = make_float4(0,0,0,0);
    #pragma unroll
    for(int g=0;g<16;g++){
      float4 a = sArr[g*16 + t], b = qArr[g*16 + t];
      S.x+=a.x; S.y+=a.y; S.z+=a.z; S.w+=a.w;
      Q.x+=b.x; Q.y+=b.y; Q.z+=b.z; Q.w+=b.w;
    }
    ((float4*)(part + (size_t)blk*128))[t] = S;
    ((float4*)(part + (size_t)blk*128 + 64))[t] = Q;
  }
}

// ---------------- convA fused (MFMA split-bf16): y := W.lrelu(bn(U[j]+V[n])), + BN stats ----------------
__global__ __launch_bounds__(256) void k_convAF(const float* __restrict__ U, const float* __restrict__ V,
                                                const int* __restrict__ idx, const float* __restrict__ wg,
                                                const float* __restrict__ sb, float* __restrict__ y,
                                                float* __restrict__ part){
  __shared__ short hb[2*128*64];   // 32 KB (hi @0, lo @8192)
  __shared__ short wb[2*64*64];    // 16 KB (hi @0, lo @4096)
  int t = threadIdx.x;
  int q0 = blockIdx.x * 128;
  #pragma unroll
  for(int k=0;k<8;k++){
    int fid = t + k*256; int row = fid>>4, c4 = fid&15;
    int q = q0 + row;
    int pt = q/PK; int b = pt>>12; int j = idx[q];
    float4 uu = ((const float4*)(U + (size_t)(b*PN+j)*64))[c4];
    float4 vv = ((const float4*)(V + (size_t)pt*64))[c4];
    float4 sc = ((const float4*)sb)[c4];
    float4 bi = ((const float4*)(sb+1024))[c4];
    float4 h;
    h.x = lrelu_f(fmaf(uu.x+vv.x, sc.x, bi.x));
    h.y = lrelu_f(fmaf(uu.y+vv.y, sc.y, bi.y));
    h.z = lrelu_f(fmaf(uu.z+vv.z, sc.z, bi.z));
    h.w = lrelu_f(fmaf(uu.w+vv.w, sc.w, bi.w));
    int base = row*64 + ((((c4>>1) ^ (row&7)))<<3) + ((c4&1)<<2);
    short4 hi4, lo4;
    hi4.x = (short)f2bf(h.x); lo4.x = (short)f2bf(h.x - bf2f((unsigned short)hi4.x));
    hi4.y = (short)f2bf(h.y); lo4.y = (short)f2bf(h.y - bf2f((unsigned short)hi4.y));
    hi4.z = (short)f2bf(h.z); lo4.z = (short)f2bf(h.z - bf2f((unsigned short)hi4.z));
    hi4.w = (short)f2bf(h.w); lo4.w = (short)f2bf(h.w - bf2f((unsigned short)hi4.w));
    *(short4*)(hb + base) = hi4;
    *(short4*)(hb + 8192 + base) = lo4;
  }
  #pragma unroll
  for(int k=0;k<4;k++){
    int fid = t + k*256; int row = fid>>4, c4 = fid&15;
    float4 wv = ((const float4*)(wg + (size_t)row*64))[c4];
    int base = row*64 + ((((c4>>1) ^ (row&7)))<<3) + ((c4&1)<<2);
    short4 hi4, lo4;
    hi4.x = (short)f2bf(wv.x); lo4.x = (short)f2bf(wv.x - bf2f((unsigned short)hi4.x));
    hi4.y = (short)f2bf(wv.y); lo4.y = (short)f2bf(wv.y - bf2f((unsigned short)hi4.y));
    hi4.z = (short)f2bf(wv.z); lo4.z = (short)f2bf(wv.z - bf2f((unsigned short)hi4.z));
    hi4.w = (short)f2bf(wv.w); lo4.w = (short)f2bf(wv.w - bf2f((unsigned short)hi4.w));
    *(short4*)(wb + base) = hi4;
    *(short4*)(wb + 4096 + base) = lo4;
  }
  __syncthreads();

  int lane = t & 63, w = t >> 6;
  int r0w = w*32;
  short8v ah[2][2], al[2][2];
  #pragma unroll
  for(int rt=0;rt<2;rt++)
    #pragma unroll
    for(int kc=0;kc<2;kc++){
      int row = r0w + rt*16 + (lane&15);
      int kb  = kc*4 + (lane>>4);
      int off = row*64 + ((kb ^ (row&7))<<3);
      ah[rt][kc] = *(const short8v*)(hb + off);
      al[rt][kc] = *(const short8v*)(hb + 8192 + off);
    }
  short8v bh[4][2], bl[4][2];
  #pragma unroll
  for(int ct=0;ct<4;ct++)
    #pragma unroll
    for(int kc=0;kc<2;kc++){
      int o   = ct*16 + (lane&15);
      int kb  = kc*4 + (lane>>4);
      int off = o*64 + ((kb ^ (o&7))<<3);
      bh[ct][kc] = *(const short8v*)(wb + off);
      bl[ct][kc] = *(const short8v*)(wb + 4096 + off);
    }

  f32x4 acc[2][4];
  #pragma unroll
  for(int rt=0;rt<2;rt++)
    #pragma unroll
    for(int ct=0;ct<4;ct++)
      acc[rt][ct] = (f32x4){0.f,0.f,0.f,0.f};

  #pragma unroll
  for(int rt=0;rt<2;rt++)
    #pragma unroll
    for(int ct=0;ct<4;ct++)
      #pragma unroll
      for(int kc=0;kc<2;kc++){
        acc[rt][ct] = __builtin_amdgcn_mfma_f32_16x16x32_bf16(ah[rt][kc], bh[ct][kc], acc[rt][ct], 0,0,0);
        acc[rt][ct] = __builtin_amdgcn_mfma_f32_16x16x32_bf16(ah[rt][kc], bl[ct][kc], acc[rt][ct], 0,0,0);
        acc[rt][ct] = __builtin_amdgcn_mfma_f32_16x16x32_bf16(al[rt][kc], bh[ct][kc], acc[rt][ct], 0,0,0);
      }

  float s_[4] = {0.f,0.f,0.f,0.f}, q_[4] = {0.f,0.f,0.f,0.f};
  #pragma unroll
  for(int rt=0;rt<2;rt++)
    #pragma unroll
    for(int ct=0;ct<4;ct++){
      int colg = ct*16 + (lane&15);
      #pragma unroll
      for(int reg=0;reg<4;reg++){
        int row = r0w + rt*16 + (lane>>4)*4 + reg;
        float val = acc[rt][ct][reg];
        y[(size_t)(q0 + row)*64 + colg] = val;
        s_[ct] += val; q_[ct] = fmaf(val, val, q_[ct]);
      }
    }

  __syncthreads();                       // frag reads done; reuse wb as scratch (4096 floats)
  float* ls = (float*)wb;
  #pragma unroll
  for(int ct=0;ct<4;ct++){
    int colg = ct*16 + (lane&15);
    ls[colg*16 + (w*4 + (lane>>4))]        = s_[ct];
    ls[2048 + colg*16 + (w*4 + (lane>>4))] = q_[ct];
  }
  __syncthreads();
  if(t < 64){
    float S = 0.f, Q = 0.f;
    #pragma unroll
    for(int g=0;g<16;g++){ S += ls[t*16+g]; Q += ls[2048 + t*16+g]; }
    part[(size_t)blockIdx.x*128 + t] = S;
    part[(size_t)blockIdx.x*128 + 64 + t] = Q;
  }
}

// ---------------- finalize BN affine ----------------
__global__ __launch_bounds__(256) void k_fin(const float* __restrict__ part, int nparts, int chn, float cnt,
                                             const float* __restrict__ gamma, const float* __restrict__ beta,
                                             float* __restrict__ sb){
  __shared__ float ls[512];
  int t = threadIdx.x;
  int chl = t & 15, sub = t >> 4;
  int ch = blockIdx.x*16 + chl;
  float S = 0.f, Q = 0.f;
  for(int p=sub; p<nparts; p+=16){
    S += part[(size_t)p*2*chn + ch];
    Q += part[(size_t)p*2*chn + chn + ch];
  }
  ls[t] = S; ls[256+t] = Q;
  __syncthreads();
  if(t < 16){
    float Sa = 0.f, Qa = 0.f;
    #pragma unroll
    for(int s=0;s<16;s++){ Sa += ls[s*16+t]; Qa += ls[256+s*16+t]; }
    int c = blockIdx.x*16 + t;
    float m  = Sa/cnt;
    float vr = Qa/cnt - m*m;
    float sc = gamma[c] * rsqrtf(vr + 1e-5f);
    sb[c] = sc; sb[1024+c] = beta[c] - m*sc;
  }
}

// ---------------- finish: x = max_k lrelu(bn(y)), + fused xx for next stage ----------------
__global__ __launch_bounds__(256) void k_finish(const float* __restrict__ y, const float* __restrict__ sb,
                                                float* __restrict__ xo, float* __restrict__ xxo){
  __shared__ float ls[256];
  int t = threadIdx.x;
  int pt = blockIdx.x*16 + (t>>4), c4 = t&15;
  const float4* base = (const float4*)(y + (size_t)pt*20*64);
  float4 sc = ((const float4*)sb)[c4];
  float4 bi = ((const float4*)(sb+1024))[c4];
  float4 m = make_float4(NEGF,NEGF,NEGF,NEGF);
  #pragma unroll 4
  for(int k=0;k<20;k++){
    float4 v = base[k*16 + c4];
    v.x = lrelu_f(fmaf(v.x, sc.x, bi.x)); v.y = lrelu_f(fmaf(v.y, sc.y, bi.y));
    v.z = lrelu_f(fmaf(v.z, sc.z, bi.z)); v.w = lrelu_f(fmaf(v.w, sc.w, bi.w));
    m.x = fmaxf(m.x,v.x); m.y = fmaxf(m.y,v.y); m.z = fmaxf(m.z,v.z); m.w = fmaxf(m.w,v.w);
  }
  ((float4*)(xo + (size_t)pt*64))[c4] = m;
  float ss = m.x*m.x; ss = fmaf(m.y,m.y,ss); ss = fmaf(m.z,m.z,ss); ss = fmaf(m.w,m.w,ss);
  ls[t] = ss;
  __syncthreads();
  if(c4 == 0){
    float S = 0.f;
    #pragma unroll
    for(int c=0;c<16;c++) S += ls[(t & 0xF0) + c];
    xxo[pt] = S;
  }
}

// ---------------- finishUV: x = max_k lrelu(bn(U[j]+V[n])) ----------------
__global__ __launch_bounds__(256) void k_finishUV(const float* __restrict__ U, const float* __restrict__ V,
                                                  const int* __restrict__ idx, const float* __restrict__ sb,
                                                  float* __restrict__ xo){
  int t = threadIdx.x;
  int pt = blockIdx.x*16 + (t>>4), c4 = t&15;
  int b = pt >> 12;
  float4 sc = ((const float4*)sb)[c4];
  float4 bi = ((const float4*)(sb+1024))[c4];
  float4 vv = ((const float4*)(V + (size_t)pt*64))[c4];
  float4 m = make_float4(NEGF,NEGF,NEGF,NEGF);
  const int* ip = idx + (size_t)pt*PK;
  #pragma unroll 4
  for(int k=0;k<PK;k++){
    int j = ip[k];
    float4 uu = ((const float4*)(U + (size_t)(b*PN+j)*64))[c4];
    float4 v;
    v.x = lrelu_f(fmaf(uu.x+vv.x, sc.x, bi.x)); v.y = lrelu_f(fmaf(uu.y+vv.y, sc.y, bi.y));
    v.z = lrelu_f(fmaf(uu.z+vv.z, sc.z, bi.z)); v.w = lrelu_f(fmaf(uu.w+vv.w, sc.w, bi.w));
    m.x = fmaxf(m.x,v.x); m.y = fmaxf(m.y,v.y); m.z = fmaxf(m.z,v.z); m.w = fmaxf(m.w,v.w);
  }
  ((float4*)(xo + (size_t)pt*64))[c4] = m;
}

// ---------------- head GEMM (MFMA split-bf16): y6 = cat(x1,x2,x3) @ w6^T, + fused BN stats ----------------
__global__ __launch_bounds__(256) void k_gemm6(const float* __restrict__ x1, const float* __restrict__ x2,
                                               const float* __restrict__ x3, const float* __restrict__ w6,
                                               float* __restrict__ y6, float* __restrict__ part){
  __shared__ short cb[2*128*64];   // 32 KB hi@0 lo@8192
  __shared__ short wb[2*128*64];   // 32 KB hi@0 lo@8192
  int t = threadIdx.x;
  int rb = blockIdx.x >> 3, ob = blockIdx.x & 7;
  size_t r0 = (size_t)rb*128; int o0 = ob*128;
  int lane = t & 63, w = t >> 6;
  int r0w = w*32;
  f32x4 acc[2][8];
  #pragma unroll
  for(int rt=0;rt<2;rt++)
    #pragma unroll
    for(int ct=0;ct<8;ct++)
      acc[rt][ct] = (f32x4){0.f,0.f,0.f,0.f};
  const float* srcs[3] = {x1, x2, x3};
  for(int ph=0; ph<3; ph++){
    __syncthreads();
    const float* src = srcs[ph];
    #pragma unroll
    for(int k=0;k<8;k++){
      int fid = t + k*256; int row = fid>>4, c4 = fid&15;
      float4 av = ((const float4*)(src + (r0+row)*64))[c4];
      float4 wv = *(const float4*)(w6 + (size_t)(o0+row)*192 + ph*64 + c4*4);
      int base = row*64 + ((((c4>>1) ^ (row&7)))<<3) + ((c4&1)<<2);
      short4 hi4, lo4;
      hi4.x = (short)f2bf(av.x); lo4.x = (short)f2bf(av.x - bf2f((unsigned short)hi4.x));
      hi4.y = (short)f2bf(av.y); lo4.y = (short)f2bf(av.y - bf2f((unsigned short)hi4.y));
      hi4.z = (short)f2bf(av.z); lo4.z = (short)f2bf(av.z - bf2f((unsigned short)hi4.z));
      hi4.w = (short)f2bf(av.w); lo4.w = (short)f2bf(av.w - bf2f((unsigned short)hi4.w));
      *(short4*)(cb + base) = hi4;
      *(short4*)(cb + 8192 + base) = lo4;
      hi4.x = (short)f2bf(wv.x); lo4.x = (short)f2bf(wv.x - bf2f((unsigned short)hi4.x));
      hi4.y = (short)f2bf(wv.y); lo4.y = (short)f2bf(wv.y - bf2f((unsigned short)hi4.y));
      hi4.z = (short)f2bf(wv.z); lo4.z = (short)f2bf(wv.z - bf2f((unsigned short)hi4.z));
      hi4.w = (short)f2bf(wv.w); lo4.w = (short)f2bf(wv.w - bf2f((unsigned short)hi4.w));
      *(short4*)(wb + base) = hi4;
      *(short4*)(wb + 8192 + base) = lo4;
    }
    __syncthreads();
    short8v ah[2][2], al[2][2];
    #pragma unroll
    for(int rt=0;rt<2;rt++)
      #pragma unroll
      for(int kc=0;kc<2;kc++){
        int row = r0w + rt*16 + (lane&15);
        int kb  = kc*4 + (lane>>4);
        int off = row*64 + ((kb ^ (row&7))<<3);
        ah[rt][kc] = *(const short8v*)(cb + off);
        al[rt][kc] = *(const short8v*)(cb + 8192 + off);
      }
    #pragma unroll
    for(int ct=0;ct<8;ct++){
      short8v bh[2], bl[2];
      #pragma unroll
      for(int kc=0;kc<2;kc++){
        int o   = ct*16 + (lane&15);
        int kb  = kc*4 + (lane>>4);
        int off = o*64 + ((kb ^ (o&7))<<3);
        bh[kc] = *(const short8v*)(wb + off);
        bl[kc] = *(const short8v*)(wb + 8192 + off);
      }
      #pragma unroll
      for(int rt=0;rt<2;rt++)
        #pragma unroll
        for(int kc=0;kc<2;kc++){
          acc[rt][ct] = __builtin_amdgcn_mfma_f32_16x16x32_bf16(ah[rt][kc], bh[kc], acc[rt][ct], 0,0,0);
          acc[rt][ct] = __builtin_amdgcn_mfma_f32_16x16x32_bf16(ah[rt][kc], bl[kc], acc[rt][ct], 0,0,0);
          acc[rt][ct] = __builtin_amdgcn_mfma_f32_16x16x32_bf16(al[rt][kc], bh[kc], acc[rt][ct], 0,0,0);
        }
    }
  }
  float s_[8] = {0,0,0,0,0,0,0,0}, q_[8] = {0,0,0,0,0,0,0,0};
  #pragma unroll
  for(int rt=0;rt<2;rt++)
    #pragma unroll
    for(int ct=0;ct<8;ct++){
      int colg = ct*16 + (lane&15);
      #pragma unroll
      for(int reg=0;reg<4;reg++){
        int row = r0w + rt*16 + (lane>>4)*4 + reg;
        float val = acc[rt][ct][reg];
        y6[(r0 + row)*1024 + o0 + colg] = val;
        s_[ct] += val; q_[ct] = fmaf(val, val, q_[ct]);
      }
    }
  __syncthreads();
  float* ls = (float*)wb;                 // 4096 floats scratch
  #pragma unroll
  for(int ct=0;ct<8;ct++){
    int colg = ct*16 + (lane&15);
    ls[colg*16 + (w*4 + (lane>>4))]        = s_[ct];
    ls[2048 + colg*16 + (w*4 + (lane>>4))] = q_[ct];
  }
  __syncthreads();
  if(t < 128){
    float S = 0.f, Q = 0.f;
    #pragma unroll
    for(int g=0;g<16;g++){ S += ls[t*16+g]; Q += ls[2048 + t*16+g]; }
    part[(size_t)rb*2048 + ob*128 + t] = S;
    part[(size_t)rb*2048 + 1024 + ob*128 + t] = Q;
  }
}

// ---------------- global max over n (bn6+lrelu applied), 256 blocks x 64 rows ----------------
__global__ __launch_bounds__(256) void k_gmax(const float* __restrict__ y6, const float* __restrict__ sb,
                                              float* __restrict__ gpart){
  int t = threadIdx.x; int blk = blockIdx.x;   // 256 blocks x 64 rows
  const float4* base = (const float4*)(y6 + (size_t)blk*64*1024);
  float4 sc = ((const float4*)sb)[t];
  float4 bi = ((const float4*)(sb+1024))[t];
  float4 m = make_float4(NEGF,NEGF,NEGF,NEGF);
  for(int r=0;r<64;r++){
    float4 v = base[r*256 + t];
    v.x = lrelu_f(fmaf(v.x, sc.x, bi.x)); v.y = lrelu_f(fmaf(v.y, sc.y, bi.y));
    v.z = lrelu_f(fmaf(v.z, sc.z, bi.z)); v.w = lrelu_f(fmaf(v.w, sc.w, bi.w));
    m.x = fmaxf(m.x,v.x); m.y = fmaxf(m.y,v.y); m.z = fmaxf(m.z,v.z); m.w = fmaxf(m.w,v.w);
  }
  ((float4*)(gpart + (size_t)blk*1024))[t] = m;
}

__global__ __launch_bounds__(256) void k_gmaxfin(const float* __restrict__ gpart, float* __restrict__ g){
  int b = blockIdx.x, t = threadIdx.x;
  float4 m = make_float4(NEGF,NEGF,NEGF,NEGF);
  for(int c=0;c<64;c++){
    float4 v = ((const float4*)(gpart + ((size_t)b*64 + c)*1024))[t];
    m.x = fmaxf(m.x,v.x); m.y = fmaxf(m.y,v.y); m.z = fmaxf(m.z,v.z); m.w = fmaxf(m.w,v.w);
  }
  ((float4*)(g + (size_t)b*1024))[t] = m;
}

// ---------------- final: bn(g @ wl^T, axis 0) ----------------
__global__ __launch_bounds__(256) void k_final(const float* __restrict__ g, const float* __restrict__ wl,
                                               const float* __restrict__ g7, const float* __restrict__ b7,
                                               float* __restrict__ out){
  int gt = blockIdx.x*256 + threadIdx.x;   // 2048 = 512 o x 4 b
  int o = gt >> 2, b = gt & 3;
  const float4* gb = (const float4*)(g + (size_t)b*1024);
  const float4* wr = (const float4*)(wl + (size_t)o*1024);
  float acc = 0.f;
  #pragma unroll 4
  for(int c=0;c<256;c++){
    float4 a = gb[c], w = wr[c];
    acc = fmaf(a.x,w.x,acc); acc = fmaf(a.y,w.y,acc);
    acc = fmaf(a.z,w.z,acc); acc = fmaf(a.w,w.w,acc);
  }
  float s = acc + __shfl_xor(acc, 1);
  s = s + __shfl_xor(s, 2);
  float m = s * 0.25f;
  float d = acc - m;
  float vv = d*d;
  float v2 = vv + __shfl_xor(vv, 1);
  v2 = v2 + __shfl_xor(v2, 2);
  float var = v2 * 0.25f;
  out[b*512 + o] = d * rsqrtf(var + 1e-5f) * g7[o] + b7[o];
}

// ---------------- launch ----------------
extern "C" void kernel_launch(void* const* d_in, const int* in_sizes, int n_in,
                              void* d_out, int out_size, void* d_ws, size_t ws_size,
                              hipStream_t stream){
  const float* x  = (const float*)d_in[0];
  const float* w1 = (const float*)d_in[1];
  const float* w2 = (const float*)d_in[2];
  const float* w3 = (const float*)d_in[3];
  const float* w4 = (const float*)d_in[4];
  const float* w5 = (const float*)d_in[5];
  const float* w6 = (const float*)d_in[6];
  const float* wl = (const float*)d_in[7];
  const float* g1 = (const float*)d_in[8];  const float* b1 = (const float*)d_in[9];
  const float* g2 = (const float*)d_in[10]; const float* b2 = (const float*)d_in[11];
  const float* g3 = (const float*)d_in[12]; const float* b3 = (const float*)d_in[13];
  const float* g4 = (const float*)d_in[14]; const float* b4 = (const float*)d_in[15];
  const float* g5 = (const float*)d_in[16]; const float* b5 = (const float*)d_in[17];
  const float* g6 = (const float*)d_in[18]; const float* b6 = (const float*)d_in[19];
  const float* g7 = (const float*)d_in[20]; const float* b7 = (const float*)d_in[21];
  float* out = (float*)d_out;

  // workspace layout (floats); ~108.7 MB total
  float* ws    = (float*)d_ws;
  float* xx    = ws;                        // 16384
  int*   idx   = (int*)(ws + 16384);        // 327680
  float* y     = ws + 344064;               // 20971520 (y2/y4, y6)
  float* Dbuf  = y;                         // 16777216 (per-batch dist; y dead then)
  float* x1    = ws + 21315584;             // 1048576
  float* x2    = x1 + 1048576;
  float* x3    = x2 + 1048576;
  float* part  = x3 + 1048576;              // 327680 (max: convAF 2560 blocks x 128)
  float* sb    = part + 327680;             // 2048
  float* gpart = sb + 2048;                 // 262144 (256 blocks x 1024)
  float* g     = gpart + 262144;            // 4096
  float* U     = g + 4096;                  // 1048576
  float* V     = U + 1048576;               // 1048576

  // ---- stage 1 ----
  k_knn3<<<dim3(512,4),512,0,stream>>>(x, idx);
  k_nodeUV3<<<4096,256,0,stream>>>(x, w1, U, V);
  k_statUV<<<512,256,0,stream>>>(U, V, idx, part);
  k_fin<<<4,256,0,stream>>>(part, 512, 64, (float)PNT, g1, b1, sb);
  k_convAF<<<2560,256,0,stream>>>(U, V, idx, w2, sb, y, part);
  k_fin<<<4,256,0,stream>>>(part, 2560, 64, (float)PNT, g2, b2, sb);
  k_finish<<<1024,256,0,stream>>>(y, sb, x1, xx);

  // ---- stage 2 ----
  for(int b=0;b<PB;b++){
    k_dist64<<<528,256,0,stream>>>(x1 + (size_t)b*PN*64, xx + b*PN, Dbuf);
    k_topk<<<1024,256,0,stream>>>(Dbuf, idx + (size_t)b*PN*PK);
  }
  k_nodeUV64<<<128,256,0,stream>>>(x1, w3, U, V);
  k_statUV<<<512,256,0,stream>>>(U, V, idx, part);
  k_fin<<<4,256,0,stream>>>(part, 512, 64, (float)PNT, g3, b3, sb);
  k_convAF<<<2560,256,0,stream>>>(U, V, idx, w4, sb, y, part);
  k_fin<<<4,256,0,stream>>>(part, 2560, 64, (float)PNT, g4, b4, sb);
  k_finish<<<1024,256,0,stream>>>(y, sb, x2, xx);

  // ---- stage 3 ----
  for(int b=0;b<PB;b++){
    k_dist64<<<528,256,0,stream>>>(x2 + (size_t)b*PN*64, xx + b*PN, Dbuf);
    k_topk<<<1024,256,0,stream>>>(Dbuf, idx + (size_t)b*PN*PK);
  }
  k_nodeUV64<<<128,256,0,stream>>>(x2, w5, U, V);
  k_statUV<<<512,256,0,stream>>>(U, V, idx, part);
  k_fin<<<4,256,0,stream>>>(part, 512, 64, (float)PNT, g5, b5, sb);
  k_finishUV<<<1024,256,0,stream>>>(U, V, idx, sb, x3);

  // ---- head ----
  k_gemm6<<<1024,256,0,stream>>>(x1, x2, x3, w6, y, part);
  k_fin<<<64,256,0,stream>>>(part, 128, 1024, 16384.f, g6, b6, sb);
  k_gmax<<<256,256,0,stream>>>(y, sb, gpart);
  k_gmaxfin<<<4,256,0,stream>>>(gpart, g);
  k_final<<<8,256,0,stream>>>(g, wl, g7, b7, out);
}

// Round 12
// 1078.655 us; speedup vs baseline: 6.4871x; 1.0366x over previous
//
#include <hip/hip_runtime.h>

static constexpr int PB  = 4;
static constexpr int PN  = 4096;
static constexpr int PK  = 20;
static constexpr int PNT = PB*PN*PK;   // 327680
#define NEGF (-3.402823466e38f)

__device__ __forceinline__ float lrelu_f(float x){ return x >= 0.f ? x : 0.2f*x; }

typedef __attribute__((ext_vector_type(8))) short short8v;
typedef __attribute__((ext_vector_type(4))) float f32x4;

__device__ __forceinline__ unsigned short f2bf(float f){
  unsigned u = __float_as_uint(f);
  unsigned r = u + 0x7FFFu + ((u>>16)&1u);
  return (unsigned short)(r>>16);
}
__device__ __forceinline__ float bf2f(unsigned short s){ return __uint_as_float(((unsigned)s)<<16); }

#define FMA4C(accv, av, bv) { accv = fmaf((av).x,(bv).x,accv); accv = fmaf((av).y,(bv).y,accv); \
                              accv = fmaf((av).z,(bv).z,accv); accv = fmaf((av).w,(bv).w,accv); }

// ---------------- fused stage-1 kNN: LDS points, cooperative group rebuild ----------------
__global__ __launch_bounds__(512) void k_knn3(const float* __restrict__ x, int* __restrict__ idxb){
  __shared__ float4 pts[PN];                      // 64 KB: (x, y, z, xx)
  int t = threadIdx.x;
  int b = blockIdx.y;
  const float* xb = x + (size_t)b*3*PN;
  for(int i=t;i<PN;i+=512){
    float a0 = xb[i], a1 = xb[PN+i], a2 = xb[2*PN+i];
    float s = a0*a0; s = fmaf(a1,a1,s); s = fmaf(a2,a2,s);
    pts[i] = make_float4(a0,a1,a2,s);
  }
  __syncthreads();
  int lane = t & 63, w = t >> 6;
  int row = blockIdx.x*8 + w;
  float4 pi = pts[row];
  unsigned long long removed = 0ull;

#define KDIST(E) ({ float4 pj_ = pts[lane + ((E)<<6)]; \
    float dt_ = pi.x*pj_.x; dt_ = fmaf(pi.y,pj_.y,dt_); dt_ = fmaf(pi.z,pj_.z,dt_); \
    fmaf(2.f,dt_,-pi.w) - pj_.w; })

  float gv0,gv1,gv2,gv3,gv4,gv5,gv6,gv7;
  int   gi0,gi1,gi2,gi3,gi4,gi5,gi6,gi7;
#define KBUILDG(G) { float gm_=NEGF; int ge_=(G)*8; \
    _Pragma("unroll") for(int e_=(G)*8; e_<(G)*8+8; e_++){ \
      bool ok_ = ((removed >> e_) & 1ull) == 0ull; \
      float d_ = KDIST(e_); \
      bool bt_ = ok_ && (d_ > gm_); gm_ = bt_ ? d_ : gm_; ge_ = bt_ ? e_ : ge_; } \
    gv##G = gm_; gi##G = ge_; }
  KBUILDG(0) KBUILDG(1) KBUILDG(2) KBUILDG(3) KBUILDG(4) KBUILDG(5) KBUILDG(6) KBUILDG(7)

  float lmax; int le;
#define KLBEST { lmax = gv0; le = gi0; \
    if(gv1>lmax){lmax=gv1;le=gi1;} if(gv2>lmax){lmax=gv2;le=gi2;} \
    if(gv3>lmax){lmax=gv3;le=gi3;} if(gv4>lmax){lmax=gv4;le=gi4;} \
    if(gv5>lmax){lmax=gv5;le=gi5;} if(gv6>lmax){lmax=gv6;le=gi6;} \
    if(gv7>lmax){lmax=gv7;le=gi7;} }
  KLBEST

  int myidx = 0;
  for(int k=0;k<PK;k++){
    float g = lmax;
    #pragma unroll
    for(int s=32;s>=1;s>>=1) g = fmaxf(g, __shfl_xor(g, s));
    unsigned long long cand = __ballot(lmax == g);
    int jw;
    if(__popcll(cand) == 1){
      int wl = __ffsll(cand) - 1;
      int e  = __shfl(le, wl);
      jw = wl + (e<<6);
    } else {
      unsigned jj = (lmax == g) ? (unsigned)(lane + (le<<6)) : 0xFFFFFFFFu;
      #pragma unroll
      for(int s=32;s>=1;s>>=1){ unsigned o = __shfl_xor(jj, s); jj = (o < jj) ? o : jj; }
      jw = (int)jj;
    }
    if(lane == k) myidx = jw;
    int WL = jw & 63, eW = jw >> 6, gW = eW >> 3;
    unsigned long long remW = __shfl(removed, WL) | (1ull << eW);
    if(lane == WL) removed = remW;
    // cooperative rescan of winner's group (8-lane octets, replicated)
    int e_ = (gW<<3) + (lane & 7);
    float4 pj = pts[WL + (e_<<6)];
    float dt = pi.x*pj.x; dt = fmaf(pi.y,pj.y,dt); dt = fmaf(pi.z,pj.z,dt);
    float d_ = fmaf(2.f,dt,-pi.w) - pj.w;
    bool ok = ((remW >> e_) & 1ull) == 0ull;
    float dd = ok ? d_ : NEGF;
    int   de = e_;
    #pragma unroll
    for(int s=1;s<8;s<<=1){
      float od = __shfl_xor(dd, s); int oe = __shfl_xor(de, s);
      if(od > dd || (od == dd && oe < de)){ dd = od; de = oe; }
    }
    if(lane == WL){
      int q = gW;
      if(q==0){ gv0=dd; gi0=de; } else if(q==1){ gv1=dd; gi1=de; }
      else if(q==2){ gv2=dd; gi2=de; } else if(q==3){ gv3=dd; gi3=de; }
      else if(q==4){ gv4=dd; gi4=de; } else if(q==5){ gv5=dd; gi5=de; }
      else if(q==6){ gv6=dd; gi6=de; } else { gv7=dd; gi7=de; }
      KLBEST
    }
  }
  if(lane < PK) idxb[((size_t)b*PN + row)*PK + lane] = myidx;
#undef KDIST
#undef KBUILDG
#undef KLBEST
}

// ---------------- dist64: symmetric tiled GEMM, K split in 2 (33 KB LDS, 4 blocks/CU) ----------------
__global__ __launch_bounds__(256) void k_dist64(const float* __restrict__ Xb, const float* __restrict__ xxb,
                                                float* __restrict__ D){
  __shared__ float Xi[128*32];
  __shared__ float Xj[128*32];
  __shared__ float xxi[128], xxj[128];
  int t = threadIdx.x;
  int p = blockIdx.x;
  int bi = (int)((65.0f - sqrtf(4225.0f - 8.0f*(float)p)) * 0.5f);
  while((bi+1)*32 - ((bi+1)*bi)/2 <= p) bi++;
  while(bi*32 - (bi*(bi-1))/2 > p) bi--;
  int bj = bi + (p - (bi*32 - (bi*(bi-1))/2));
  int i0 = bi*128, j0 = bj*128;
  int prg = t>>4, cq = t&15;
  float acc[8][8];
  #pragma unroll
  for(int pp=0;pp<8;pp++)
    #pragma unroll
    for(int oc=0;oc<8;oc++) acc[pp][oc] = 0.f;

  for(int h=0;h<2;h++){
    if(h) __syncthreads();
    #pragma unroll
    for(int k=0;k<4;k++){
      int fid = t + k*256; int row = fid>>3, c4 = fid&7;
      ((float4*)Xi)[row*8 + (c4^(row&7))] = ((const float4*)(Xb + (size_t)(i0+row)*64 + h*32))[c4];
      ((float4*)Xj)[row*8 + (c4^(row&7))] = ((const float4*)(Xb + (size_t)(j0+row)*64 + h*32))[c4];
    }
    if(h==0){
      if(t < 128) xxi[t] = xxb[i0+t];
      else        xxj[t-128] = xxb[j0+t-128];
    }
    __syncthreads();
    #pragma unroll 4
    for(int c4=0;c4<8;c4++){
      float4 a[8], bb[8];
      #pragma unroll
      for(int pp=0;pp<8;pp++){ int row = prg*8+pp; a[pp] = ((const float4*)Xi)[row*8 + (c4^(row&7))]; }
      #pragma unroll
      for(int oc=0;oc<8;oc++){ int col = cq+16*oc;  bb[oc] = ((const float4*)Xj)[col*8 + (c4^(col&7))]; }
      #pragma unroll
      for(int pp=0;pp<8;pp++)
        #pragma unroll
        for(int oc=0;oc<8;oc++) FMA4C(acc[pp][oc], a[pp], bb[oc]);
    }
  }
  #pragma unroll
  for(int pp=0;pp<8;pp++){
    int r = prg*8+pp;
    float xi2 = xxi[r];
    float* Drow = D + (size_t)(i0+r)*PN + j0;
    #pragma unroll
    for(int oc=0;oc<8;oc++){
      int c = cq + 16*oc;
      Drow[c] = fmaf(2.f, acc[pp][oc], -xi2) - xxj[c];
    }
  }
  if(bi != bj){
    #pragma unroll
    for(int oc=0;oc<8;oc++){
      int c = cq + 16*oc;
      float xj2 = xxj[c];
      float* Dcol = D + (size_t)(j0+c)*PN + i0 + prg*8;
      float4 t0, t1;
      t0.x = fmaf(2.f, acc[0][oc], -xj2) - xxi[prg*8+0];
      t0.y = fmaf(2.f, acc[1][oc], -xj2) - xxi[prg*8+1];
      t0.z = fmaf(2.f, acc[2][oc], -xj2) - xxi[prg*8+2];
      t0.w = fmaf(2.f, acc[3][oc], -xj2) - xxi[prg*8+3];
      t1.x = fmaf(2.f, acc[4][oc], -xj2) - xxi[prg*8+4];
      t1.y = fmaf(2.f, acc[5][oc], -xj2) - xxi[prg*8+5];
      t1.z = fmaf(2.f, acc[6][oc], -xj2) - xxi[prg*8+6];
      t1.w = fmaf(2.f, acc[7][oc], -xj2) - xxi[prg*8+7];
      ((float4*)Dcol)[0] = t0;
      ((float4*)Dcol)[1] = t1;
    }
  }
}

// ---------------- top-20 per row: one wave per row, poison rebuild ----------------
__global__ __launch_bounds__(256) void k_topk(const float* __restrict__ D, int* __restrict__ idxb){
  int t = threadIdx.x, lane = t & 63, w = t >> 6;
  int row = blockIdx.x*4 + w;
  const float4* rp = (const float4*)(D + (size_t)row*PN + lane*64);
  float v[64];
  #pragma unroll
  for(int c=0;c<16;c++){
    float4 q = rp[c];
    v[4*c+0]=q.x; v[4*c+1]=q.y; v[4*c+2]=q.z; v[4*c+3]=q.w;
  }
  float gv0,gv1,gv2,gv3,gv4,gv5,gv6,gv7;
  int   gi0,gi1,gi2,gi3,gi4,gi5,gi6,gi7;
#define TBUILDG(G) { float gm_=NEGF; int ge_=(G)*8; \
    _Pragma("unroll") for(int e_=(G)*8; e_<(G)*8+8; e_++){ \
      bool bt_ = v[e_] > gm_; gm_ = bt_ ? v[e_] : gm_; ge_ = bt_ ? e_ : ge_; } \
    gv##G = gm_; gi##G = ge_; }
#define TPOIS(G) { _Pragma("unroll") for(int e_=(G)*8; e_<(G)*8+8; e_++){ \
      if(e_ == rel) v[e_] = NEGF; } }
  TBUILDG(0) TBUILDG(1) TBUILDG(2) TBUILDG(3) TBUILDG(4) TBUILDG(5) TBUILDG(6) TBUILDG(7)
  float lmax; int li;
#define TLBEST { lmax = gv0; li = gi0; \
    if(gv1>lmax){lmax=gv1;li=gi1;} if(gv2>lmax){lmax=gv2;li=gi2;} \
    if(gv3>lmax){lmax=gv3;li=gi3;} if(gv4>lmax){lmax=gv4;li=gi4;} \
    if(gv5>lmax){lmax=gv5;li=gi5;} if(gv6>lmax){lmax=gv6;li=gi6;} \
    if(gv7>lmax){lmax=gv7;li=gi7;} }
  TLBEST
  int myidx = 0;
  for(int k=0;k<PK;k++){
    float g = lmax;
    #pragma unroll
    for(int s=32;s>=1;s>>=1) g = fmaxf(g, __shfl_xor(g, s));
    unsigned long long mask = __ballot(lmax == g);
    int wl = __ffsll((unsigned long long)mask) - 1;
    int rel = __shfl(li, wl);
    if(lane == k) myidx = wl*64 + rel;
    if(lane == wl){
      int q = rel >> 3;
      if(q==0){ TPOIS(0) TBUILDG(0) } else if(q==1){ TPOIS(1) TBUILDG(1) }
      else if(q==2){ TPOIS(2) TBUILDG(2) } else if(q==3){ TPOIS(3) TBUILDG(3) }
      else if(q==4){ TPOIS(4) TBUILDG(4) } else if(q==5){ TPOIS(5) TBUILDG(5) }
      else if(q==6){ TPOIS(6) TBUILDG(6) } else { TPOIS(7) TBUILDG(7) }
      TLBEST
    }
  }
  if(lane < PK) idxb[row*PK + lane] = myidx;
#undef TBUILDG
#undef TPOIS
#undef TLBEST
}

// ---------------- nodeUV: per-node partial convs ----------------
__global__ __launch_bounds__(256) void k_nodeUV3(const float* __restrict__ x, const float* __restrict__ w1,
                                                 float* __restrict__ U, float* __restrict__ V){
  __shared__ float ww[384];
  int t = threadIdx.x;
  for(int k=t;k<384;k+=256) ww[k] = w1[k];
  __syncthreads();
  int g = blockIdx.x*256 + t;
  int ng = g >> 6, o = g & 63;
  int b = ng >> 12, n = ng & 4095;
  const float* xb = x + (size_t)b*3*PN;
  float p0 = xb[n], p1 = xb[PN+n], p2 = xb[2*PN+n];
  const float* wr = ww + o*6;
  float u = p0*wr[0]; u = fmaf(p1,wr[1],u); u = fmaf(p2,wr[2],u);
  float vv = p0*(wr[3]-wr[0]); vv = fmaf(p1, wr[4]-wr[1], vv); vv = fmaf(p2, wr[5]-wr[2], vv);
  U[(size_t)ng*64+o] = u;
  V[(size_t)ng*64+o] = vv;
}

__global__ __launch_bounds__(256) void k_nodeUV64(const float* __restrict__ xf, const float* __restrict__ w,
                                                  float* __restrict__ U, float* __restrict__ V){
  __shared__ float xbuf[128*64];
  __shared__ float wbuf[128*64];
  int t = threadIdx.x;
  int r0 = blockIdx.x * 128;
  #pragma unroll
  for(int k=0;k<8;k++){
    int fid = t + k*256; int row = fid>>4, c4 = fid&15;
    ((float4*)xbuf)[row*16 + (c4^(row&15))] = ((const float4*)(xf + (size_t)(r0+row)*64))[c4];
    float4 wv;
    if(row < 64){
      wv = ((const float4*)(w + (size_t)row*128))[c4];
    } else {
      float4 w2v = ((const float4*)(w + (size_t)(row-64)*128 + 64))[c4];
      float4 w1v = ((const float4*)(w + (size_t)(row-64)*128))[c4];
      wv.x = w2v.x-w1v.x; wv.y = w2v.y-w1v.y; wv.z = w2v.z-w1v.z; wv.w = w2v.w-w1v.w;
    }
    ((float4*)wbuf)[row*16 + (c4^(row&15))] = wv;
  }
  __syncthreads();
  int rg = t>>4, cq = t&15;
  float acc[8][8];
  #pragma unroll
  for(int pp=0;pp<8;pp++)
    #pragma unroll
    for(int oc=0;oc<8;oc++) acc[pp][oc] = 0.f;
  #pragma unroll 4
  for(int c4=0;c4<16;c4++){
    float4 a[8], bb[8];
    #pragma unroll
    for(int pp=0;pp<8;pp++){ int row = rg*8+pp; a[pp] = ((const float4*)xbuf)[row*16 + (c4^(row&15))]; }
    #pragma unroll
    for(int oc=0;oc<8;oc++){ int col = cq+16*oc;  bb[oc] = ((const float4*)wbuf)[col*16 + (c4^(col&15))]; }
    #pragma unroll
    for(int pp=0;pp<8;pp++)
      #pragma unroll
      for(int oc=0;oc<8;oc++) FMA4C(acc[pp][oc], a[pp], bb[oc]);
  }
  #pragma unroll
  for(int pp=0;pp<8;pp++){
    int r = r0 + rg*8+pp;
    #pragma unroll
    for(int oc=0;oc<8;oc++){
      int col = cq + 16*oc;
      if(col < 64) U[(size_t)r*64 + col] = acc[pp][oc];
      else         V[(size_t)r*64 + col-64] = acc[pp][oc];
    }
  }
}

// ---------------- BN stats over edges, point-major (V row read once per point) ----------------
__global__ __launch_bounds__(256) void k_statUV(const float* __restrict__ U, const float* __restrict__ V,
                                                const int* __restrict__ idx, float* __restrict__ part){
  __shared__ float4 sArr[256];
  __shared__ float4 qArr[256];
  int t = threadIdx.x; int blk = blockIdx.x;
  int ch4 = t & 15, sub = t >> 4;
  int p0 = blk*32;                               // 32 points = 640 edges, same range as before
  float4 s = make_float4(0,0,0,0), qq = make_float4(0,0,0,0);
  for(int pp=sub; pp<32; pp+=16){
    int p = p0 + pp;
    int b = p >> 12;
    float4 v4 = ((const float4*)(V + (size_t)p*64))[ch4];
    const int* ip = idx + (size_t)p*PK;
    #pragma unroll 4
    for(int k=0;k<PK;k++){
      int j = ip[k];
      float4 u4 = ((const float4*)(U + (size_t)(b*PN+j)*64))[ch4];
      float4 y4;
      y4.x = u4.x+v4.x; y4.y = u4.y+v4.y; y4.z = u4.z+v4.z; y4.w = u4.w+v4.w;
      s.x += y4.x; s.y += y4.y; s.z += y4.z; s.w += y4.w;
      qq.x = fmaf(y4.x,y4.x,qq.x); qq.y = fmaf(y4.y,y4.y,qq.y);
      qq.z = fmaf(y4.z,y4.z,qq.z); qq.w = fmaf(y4.w,y4.w,qq.w);
    }
  }
  sArr[t] = s; qArr[t] = qq;
  __syncthreads();
  if(t < 16){
    float4 S = make_float4(0,0,0,0), Q = make_float4(0,0,0,0);
    #pragma unroll
    for(int g=0;g<16;g++){
      float4 a = sArr[g*16 + t], b = qArr[g*16 + t];
      S.x+=a.x; S.y+=a.y; S.z+=a.z; S.w+=a.w;
      Q.x+=b.x; Q.y+=b.y; Q.z+=b.z; Q.w+=b.w;
    }
    ((float4*)(part + (size_t)blk*128))[t] = S;
    ((float4*)(part + (size_t)blk*128 + 64))[t] = Q;
  }
}

// ---------------- convA fused (MFMA split-bf16): y := W.lrelu(bn(U[j]+V[n])), + BN stats ----------------
__global__ __launch_bounds__(256) void k_convAF(const float* __restrict__ U, const float* __restrict__ V,
                                                const int* __restrict__ idx, const float* __restrict__ wg,
                                                const float* __restrict__ sb, float* __restrict__ y,
                                                float* __restrict__ part){
  __shared__ short hb[2*128*64];   // 32 KB (hi @0, lo @8192)
  __shared__ short wb[2*64*64];    // 16 KB (hi @0, lo @4096)
  int t = threadIdx.x;
  int q0 = blockIdx.x * 128;
  #pragma unroll
  for(int k=0;k<8;k++){
    int fid = t + k*256; int row = fid>>4, c4 = fid&15;
    int q = q0 + row;
    int pt = q/PK; int b = pt>>12; int j = idx[q];
    float4 uu = ((const float4*)(U + (size_t)(b*PN+j)*64))[c4];
    float4 vv = ((const float4*)(V + (size_t)pt*64))[c4];
    float4 sc = ((const float4*)sb)[c4];
    float4 bi = ((const float4*)(sb+1024))[c4];
    float4 h;
    h.x = lrelu_f(fmaf(uu.x+vv.x, sc.x, bi.x));
    h.y = lrelu_f(fmaf(uu.y+vv.y, sc.y, bi.y));
    h.z = lrelu_f(fmaf(uu.z+vv.z, sc.z, bi.z));
    h.w = lrelu_f(fmaf(uu.w+vv.w, sc.w, bi.w));
    int base = row*64 + ((((c4>>1) ^ (row&7)))<<3) + ((c4&1)<<2);
    short4 hi4, lo4;
    hi4.x = (short)f2bf(h.x); lo4.x = (short)f2bf(h.x - bf2f((unsigned short)hi4.x));
    hi4.y = (short)f2bf(h.y); lo4.y = (short)f2bf(h.y - bf2f((unsigned short)hi4.y));
    hi4.z = (short)f2bf(h.z); lo4.z = (short)f2bf(h.z - bf2f((unsigned short)hi4.z));
    hi4.w = (short)f2bf(h.w); lo4.w = (short)f2bf(h.w - bf2f((unsigned short)hi4.w));
    *(short4*)(hb + base) = hi4;
    *(short4*)(hb + 8192 + base) = lo4;
  }
  #pragma unroll
  for(int k=0;k<4;k++){
    int fid = t + k*256; int row = fid>>4, c4 = fid&15;
    float4 wv = ((const float4*)(wg + (size_t)row*64))[c4];
    int base = row*64 + ((((c4>>1) ^ (row&7)))<<3) + ((c4&1)<<2);
    short4 hi4, lo4;
    hi4.x = (short)f2bf(wv.x); lo4.x = (short)f2bf(wv.x - bf2f((unsigned short)hi4.x));
    hi4.y = (short)f2bf(wv.y); lo4.y = (short)f2bf(wv.y - bf2f((unsigned short)hi4.y));
    hi4.z = (short)f2bf(wv.z); lo4.z = (short)f2bf(wv.z - bf2f((unsigned short)hi4.z));
    hi4.w = (short)f2bf(wv.w); lo4.w = (short)f2bf(wv.w - bf2f((unsigned short)hi4.w));
    *(short4*)(wb + base) = hi4;
    *(short4*)(wb + 4096 + base) = lo4;
  }
  __syncthreads();

  int lane = t & 63, w = t >> 6;
  int r0w = w*32;
  short8v ah[2][2], al[2][2];
  #pragma unroll
  for(int rt=0;rt<2;rt++)
    #pragma unroll
    for(int kc=0;kc<2;kc++){
      int row = r0w + rt*16 + (lane&15);
      int kb  = kc*4 + (lane>>4);
      int off = row*64 + ((kb ^ (row&7))<<3);
      ah[rt][kc] = *(const short8v*)(hb + off);
      al[rt][kc] = *(const short8v*)(hb + 8192 + off);
    }
  short8v bh[4][2], bl[4][2];
  #pragma unroll
  for(int ct=0;ct<4;ct++)
    #pragma unroll
    for(int kc=0;kc<2;kc++){
      int o   = ct*16 + (lane&15);
      int kb  = kc*4 + (lane>>4);
      int off = o*64 + ((kb ^ (o&7))<<3);
      bh[ct][kc] = *(const short8v*)(wb + off);
      bl[ct][kc] = *(const short8v*)(wb + 4096 + off);
    }

  f32x4 acc[2][4];
  #pragma unroll
  for(int rt=0;rt<2;rt++)
    #pragma unroll
    for(int ct=0;ct<4;ct++)
      acc[rt][ct] = (f32x4){0.f,0.f,0.f,0.f};

  #pragma unroll
  for(int rt=0;rt<2;rt++)
    #pragma unroll
    for(int ct=0;ct<4;ct++)
      #pragma unroll
      for(int kc=0;kc<2;kc++){
        acc[rt][ct] = __builtin_amdgcn_mfma_f32_16x16x32_bf16(ah[rt][kc], bh[ct][kc], acc[rt][ct], 0,0,0);
        acc[rt][ct] = __builtin_amdgcn_mfma_f32_16x16x32_bf16(ah[rt][kc], bl[ct][kc], acc[rt][ct], 0,0,0);
        acc[rt][ct] = __builtin_amdgcn_mfma_f32_16x16x32_bf16(al[rt][kc], bh[ct][kc], acc[rt][ct], 0,0,0);
      }

  float s_[4] = {0.f,0.f,0.f,0.f}, q_[4] = {0.f,0.f,0.f,0.f};
  #pragma unroll
  for(int rt=0;rt<2;rt++)
    #pragma unroll
    for(int ct=0;ct<4;ct++){
      int colg = ct*16 + (lane&15);
      #pragma unroll
      for(int reg=0;reg<4;reg++){
        int row = r0w + rt*16 + (lane>>4)*4 + reg;
        float val = acc[rt][ct][reg];
        y[(size_t)(q0 + row)*64 + colg] = val;
        s_[ct] += val; q_[ct] = fmaf(val, val, q_[ct]);
      }
    }

  __syncthreads();                       // frag reads done; reuse wb as scratch (4096 floats)
  float* ls = (float*)wb;
  #pragma unroll
  for(int ct=0;ct<4;ct++){
    int colg = ct*16 + (lane&15);
    ls[colg*16 + (w*4 + (lane>>4))]        = s_[ct];
    ls[2048 + colg*16 + (w*4 + (lane>>4))] = q_[ct];
  }
  __syncthreads();
  if(t < 64){
    float S = 0.f, Q = 0.f;
    #pragma unroll
    for(int g=0;g<16;g++){ S += ls[t*16+g]; Q += ls[2048 + t*16+g]; }
    part[(size_t)blockIdx.x*128 + t] = S;
    part[(size_t)blockIdx.x*128 + 64 + t] = Q;
  }
}

// ---------------- finalize BN affine ----------------
__global__ __launch_bounds__(256) void k_fin(const float* __restrict__ part, int nparts, int chn, float cnt,
                                             const float* __restrict__ gamma, const float* __restrict__ beta,
                                             float* __restrict__ sb){
  __shared__ float ls[512];
  int t = threadIdx.x;
  int chl = t & 15, sub = t >> 4;
  int ch = blockIdx.x*16 + chl;
  float S = 0.f, Q = 0.f;
  for(int p=sub; p<nparts; p+=16){
    S += part[(size_t)p*2*chn + ch];
    Q += part[(size_t)p*2*chn + chn + ch];
  }
  ls[t] = S; ls[256+t] = Q;
  __syncthreads();
  if(t < 16){
    float Sa = 0.f, Qa = 0.f;
    #pragma unroll
    for(int s=0;s<16;s++){ Sa += ls[s*16+t]; Qa += ls[256+s*16+t]; }
    int c = blockIdx.x*16 + t;
    float m  = Sa/cnt;
    float vr = Qa/cnt - m*m;
    float sc = gamma[c] * rsqrtf(vr + 1e-5f);
    sb[c] = sc; sb[1024+c] = beta[c] - m*sc;
  }
}

// ---------------- finish: x = max_k lrelu(bn(y)), + fused xx for next stage ----------------
__global__ __launch_bounds__(256) void k_finish(const float* __restrict__ y, const float* __restrict__ sb,
                                                float* __restrict__ xo, float* __restrict__ xxo){
  __shared__ float ls[256];
  int t = threadIdx.x;
  int pt = blockIdx.x*16 + (t>>4), c4 = t&15;
  const float4* base = (const float4*)(y + (size_t)pt*20*64);
  float4 sc = ((const float4*)sb)[c4];
  float4 bi = ((const float4*)(sb+1024))[c4];
  float4 m = make_float4(NEGF,NEGF,NEGF,NEGF);
  #pragma unroll 4
  for(int k=0;k<20;k++){
    float4 v = base[k*16 + c4];
    v.x = lrelu_f(fmaf(v.x, sc.x, bi.x)); v.y = lrelu_f(fmaf(v.y, sc.y, bi.y));
    v.z = lrelu_f(fmaf(v.z, sc.z, bi.z)); v.w = lrelu_f(fmaf(v.w, sc.w, bi.w));
    m.x = fmaxf(m.x,v.x); m.y = fmaxf(m.y,v.y); m.z = fmaxf(m.z,v.z); m.w = fmaxf(m.w,v.w);
  }
  ((float4*)(xo + (size_t)pt*64))[c4] = m;
  float ss = m.x*m.x; ss = fmaf(m.y,m.y,ss); ss = fmaf(m.z,m.z,ss); ss = fmaf(m.w,m.w,ss);
  ls[t] = ss;
  __syncthreads();
  if(c4 == 0){
    float S = 0.f;
    #pragma unroll
    for(int c=0;c<16;c++) S += ls[(t & 0xF0) + c];
    xxo[pt] = S;
  }
}

// ---------------- finishUV: x = max_k lrelu(bn(U[j]+V[n])) ----------------
__global__ __launch_bounds__(256) void k_finishUV(const float* __restrict__ U, const float* __restrict__ V,
                                                  const int* __restrict__ idx, const float* __restrict__ sb,
                                                  float* __restrict__ xo){
  int t = threadIdx.x;
  int pt = blockIdx.x*16 + (t>>4), c4 = t&15;
  int b = pt >> 12;
  float4 sc = ((const float4*)sb)[c4];
  float4 bi = ((const float4*)(sb+1024))[c4];
  float4 vv = ((const float4*)(V + (size_t)pt*64))[c4];
  float4 m = make_float4(NEGF,NEGF,NEGF,NEGF);
  const int* ip = idx + (size_t)pt*PK;
  #pragma unroll 4
  for(int k=0;k<PK;k++){
    int j = ip[k];
    float4 uu = ((const float4*)(U + (size_t)(b*PN+j)*64))[c4];
    float4 v;
    v.x = lrelu_f(fmaf(uu.x+vv.x, sc.x, bi.x)); v.y = lrelu_f(fmaf(uu.y+vv.y, sc.y, bi.y));
    v.z = lrelu_f(fmaf(uu.z+vv.z, sc.z, bi.z)); v.w = lrelu_f(fmaf(uu.w+vv.w, sc.w, bi.w));
    m.x = fmaxf(m.x,v.x); m.y = fmaxf(m.y,v.y); m.z = fmaxf(m.z,v.z); m.w = fmaxf(m.w,v.w);
  }
  ((float4*)(xo + (size_t)pt*64))[c4] = m;
}

// ---------------- head GEMM (MFMA split-bf16): y6 = cat(x1,x2,x3) @ w6^T, + fused BN stats ----------------
__global__ __launch_bounds__(256) void k_gemm6(const float* __restrict__ x1, const float* __restrict__ x2,
                                               const float* __restrict__ x3, const float* __restrict__ w6,
                                               float* __restrict__ y6, float* __restrict__ part){
  __shared__ short cb[2*128*64];   // 32 KB hi@0 lo@8192
  __shared__ short wb[2*128*64];   // 32 KB hi@0 lo@8192
  int t = threadIdx.x;
  int rb = blockIdx.x >> 3, ob = blockIdx.x & 7;
  size_t r0 = (size_t)rb*128; int o0 = ob*128;
  int lane = t & 63, w = t >> 6;
  int r0w = w*32;
  f32x4 acc[2][8];
  #pragma unroll
  for(int rt=0;rt<2;rt++)
    #pragma unroll
    for(int ct=0;ct<8;ct++)
      acc[rt][ct] = (f32x4){0.f,0.f,0.f,0.f};
  const float* srcs[3] = {x1, x2, x3};
  for(int ph=0; ph<3; ph++){
    __syncthreads();
    const float* src = srcs[ph];
    #pragma unroll
    for(int k=0;k<8;k++){
      int fid = t + k*256; int row = fid>>4, c4 = fid&15;
      float4 av = ((const float4*)(src + (r0+row)*64))[c4];
      float4 wv = *(const float4*)(w6 + (size_t)(o0+row)*192 + ph*64 + c4*4);
      int base = row*64 + ((((c4>>1) ^ (row&7)))<<3) + ((c4&1)<<2);
      short4 hi4, lo4;
      hi4.x = (short)f2bf(av.x); lo4.x = (short)f2bf(av.x - bf2f((unsigned short)hi4.x));
      hi4.y = (short)f2bf(av.y); lo4.y = (short)f2bf(av.y - bf2f((unsigned short)hi4.y));
      hi4.z = (short)f2bf(av.z); lo4.z = (short)f2bf(av.z - bf2f((unsigned short)hi4.z));
      hi4.w = (short)f2bf(av.w); lo4.w = (short)f2bf(av.w - bf2f((unsigned short)hi4.w));
      *(short4*)(cb + base) = hi4;
      *(short4*)(cb + 8192 + base) = lo4;
      hi4.x = (short)f2bf(wv.x); lo4.x = (short)f2bf(wv.x - bf2f((unsigned short)hi4.x));
      hi4.y = (short)f2bf(wv.y); lo4.y = (short)f2bf(wv.y - bf2f((unsigned short)hi4.y));
      hi4.z = (short)f2bf(wv.z); lo4.z = (short)f2bf(wv.z - bf2f((unsigned short)hi4.z));
      hi4.w = (short)f2bf(wv.w); lo4.w = (short)f2bf(wv.w - bf2f((unsigned short)hi4.w));
      *(short4*)(wb + base) = hi4;
      *(short4*)(wb + 8192 + base) = lo4;
    }
    __syncthreads();
    short8v ah[2][2], al[2][2];
    #pragma unroll
    for(int rt=0;rt<2;rt++)
      #pragma unroll
      for(int kc=0;kc<2;kc++){
        int row = r0w + rt*16 + (lane&15);
        int kb  = kc*4 + (lane>>4);
        int off = row*64 + ((kb ^ (row&7))<<3);
        ah[rt][kc] = *(const short8v*)(cb + off);
        al[rt][kc] = *(const short8v*)(cb + 8192 + off);
      }
    #pragma unroll
    for(int ct=0;ct<8;ct++){
      short8v bh[2], bl[2];
      #pragma unroll
      for(int kc=0;kc<2;kc++){
        int o   = ct*16 + (lane&15);
        int kb  = kc*4 + (lane>>4);
        int off = o*64 + ((kb ^ (o&7))<<3);
        bh[kc] = *(const short8v*)(wb + off);
        bl[kc] = *(const short8v*)(wb + 8192 + off);
      }
      #pragma unroll
      for(int rt=0;rt<2;rt++)
        #pragma unroll
        for(int kc=0;kc<2;kc++){
          acc[rt][ct] = __builtin_amdgcn_mfma_f32_16x16x32_bf16(ah[rt][kc], bh[kc], acc[rt][ct], 0,0,0);
          acc[rt][ct] = __builtin_amdgcn_mfma_f32_16x16x32_bf16(ah[rt][kc], bl[kc], acc[rt][ct], 0,0,0);
          acc[rt][ct] = __builtin_amdgcn_mfma_f32_16x16x32_bf16(al[rt][kc], bh[kc], acc[rt][ct], 0,0,0);
        }
    }
  }
  float s_[8] = {0,0,0,0,0,0,0,0}, q_[8] = {0,0,0,0,0,0,0,0};
  #pragma unroll
  for(int rt=0;rt<2;rt++)
    #pragma unroll
    for(int ct=0;ct<8;ct++){
      int colg = ct*16 + (lane&15);
      #pragma unroll
      for(int reg=0;reg<4;reg++){
        int row = r0w + rt*16 + (lane>>4)*4 + reg;
        float val = acc[rt][ct][reg];
        y6[(r0 + row)*1024 + o0 + colg] = val;
        s_[ct] += val; q_[ct] = fmaf(val, val, q_[ct]);
      }
    }
  __syncthreads();
  float* ls = (float*)wb;                 // 4096 floats scratch
  #pragma unroll
  for(int ct=0;ct<8;ct++){
    int colg = ct*16 + (lane&15);
    ls[colg*16 + (w*4 + (lane>>4))]        = s_[ct];
    ls[2048 + colg*16 + (w*4 + (lane>>4))] = q_[ct];
  }
  __syncthreads();
  if(t < 128){
    float S = 0.f, Q = 0.f;
    #pragma unroll
    for(int g=0;g<16;g++){ S += ls[t*16+g]; Q += ls[2048 + t*16+g]; }
    part[(size_t)rb*2048 + ob*128 + t] = S;
    part[(size_t)rb*2048 + 1024 + ob*128 + t] = Q;
  }
}

// ---------------- global max over n (bn6+lrelu applied), 256 blocks x 64 rows ----------------
__global__ __launch_bounds__(256) void k_gmax(const float* __restrict__ y6, const float* __restrict__ sb,
                                              float* __restrict__ gpart){
  int t = threadIdx.x; int blk = blockIdx.x;   // 256 blocks x 64 rows
  const float4* base = (const float4*)(y6 + (size_t)blk*64*1024);
  float4 sc = ((const float4*)sb)[t];
  float4 bi = ((const float4*)(sb+1024))[t];
  float4 m = make_float4(NEGF,NEGF,NEGF,NEGF);
  for(int r=0;r<64;r++){
    float4 v = base[r*256 + t];
    v.x = lrelu_f(fmaf(v.x, sc.x, bi.x)); v.y = lrelu_f(fmaf(v.y, sc.y, bi.y));
    v.z = lrelu_f(fmaf(v.z, sc.z, bi.z)); v.w = lrelu_f(fmaf(v.w, sc.w, bi.w));
    m.x = fmaxf(m.x,v.x); m.y = fmaxf(m.y,v.y); m.z = fmaxf(m.z,v.z); m.w = fmaxf(m.w,v.w);
  }
  ((float4*)(gpart + (size_t)blk*1024))[t] = m;
}

__global__ __launch_bounds__(256) void k_gmaxfin(const float* __restrict__ gpart, float* __restrict__ g){
  int b = blockIdx.x, t = threadIdx.x;
  float4 m = make_float4(NEGF,NEGF,NEGF,NEGF);
  for(int c=0;c<64;c++){
    float4 v = ((const float4*)(gpart + ((size_t)b*64 + c)*1024))[t];
    m.x = fmaxf(m.x,v.x); m.y = fmaxf(m.y,v.y); m.z = fmaxf(m.z,v.z); m.w = fmaxf(m.w,v.w);
  }
  ((float4*)(g + (size_t)b*1024))[t] = m;
}

// ---------------- final: bn(g @ wl^T, axis 0) ----------------
__global__ __launch_bounds__(256) void k_final(const float* __restrict__ g, const float* __restrict__ wl,
                                               const float* __restrict__ g7, const float* __restrict__ b7,
                                               float* __restrict__ out){
  int gt = blockIdx.x*256 + threadIdx.x;   // 2048 = 512 o x 4 b
  int o = gt >> 2, b = gt & 3;
  const float4* gb = (const float4*)(g + (size_t)b*1024);
  const float4* wr = (const float4*)(wl + (size_t)o*1024);
  float acc = 0.f;
  #pragma unroll 4
  for(int c=0;c<256;c++){
    float4 a = gb[c], w = wr[c];
    acc = fmaf(a.x,w.x,acc); acc = fmaf(a.y,w.y,acc);
    acc = fmaf(a.z,w.z,acc); acc = fmaf(a.w,w.w,acc);
  }
  float s = acc + __shfl_xor(acc, 1);
  s = s + __shfl_xor(s, 2);
  float m = s * 0.25f;
  float d = acc - m;
  float vv = d*d;
  float v2 = vv + __shfl_xor(vv, 1);
  v2 = v2 + __shfl_xor(v2, 2);
  float var = v2 * 0.25f;
  out[b*512 + o] = d * rsqrtf(var + 1e-5f) * g7[o] + b7[o];
}

// ---------------- launch ----------------
extern "C" void kernel_launch(void* const* d_in, const int* in_sizes, int n_in,
                              void* d_out, int out_size, void* d_ws, size_t ws_size,
                              hipStream_t stream){
  const float* x  = (const float*)d_in[0];
  const float* w1 = (const float*)d_in[1];
  const float* w2 = (const float*)d_in[2];
  const float* w3 = (const float*)d_in[3];
  const float* w4 = (const float*)d_in[4];
  const float* w5 = (const float*)d_in[5];
  const float* w6 = (const float*)d_in[6];
  const float* wl = (const float*)d_in[7];
  const float* g1 = (const float*)d_in[8];  const float* b1 = (const float*)d_in[9];
  const float* g2 = (const float*)d_in[10]; const float* b2 = (const float*)d_in[11];
  const float* g3 = (const float*)d_in[12]; const float* b3 = (const float*)d_in[13];
  const float* g4 = (const float*)d_in[14]; const float* b4 = (const float*)d_in[15];
  const float* g5 = (const float*)d_in[16]; const float* b5 = (const float*)d_in[17];
  const float* g6 = (const float*)d_in[18]; const float* b6 = (const float*)d_in[19];
  const float* g7 = (const float*)d_in[20]; const float* b7 = (const float*)d_in[21];
  float* out = (float*)d_out;

  // workspace layout (floats); ~108.7 MB total
  float* ws    = (float*)d_ws;
  float* xx    = ws;                        // 16384
  int*   idx   = (int*)(ws + 16384);        // 327680
  float* y     = ws + 344064;               // 20971520 (y2/y4, y6)
  float* Dbuf  = y;                         // 16777216 (per-batch dist; y dead then)
  float* x1    = ws + 21315584;             // 1048576
  float* x2    = x1 + 1048576;
  float* x3    = x2 + 1048576;
  float* part  = x3 + 1048576;              // 327680 (max: convAF 2560 blocks x 128)
  float* sb    = part + 327680;             // 2048
  float* gpart = sb + 2048;                 // 262144 (256 blocks x 1024)
  float* g     = gpart + 262144;            // 4096
  float* U     = g + 4096;                  // 1048576
  float* V     = U + 1048576;               // 1048576

  // ---- stage 1 ----
  k_knn3<<<dim3(512,4),512,0,stream>>>(x, idx);
  k_nodeUV3<<<4096,256,0,stream>>>(x, w1, U, V);
  k_statUV<<<512,256,0,stream>>>(U, V, idx, part);
  k_fin<<<4,256,0,stream>>>(part, 512, 64, (float)PNT, g1, b1, sb);
  k_convAF<<<2560,256,0,stream>>>(U, V, idx, w2, sb, y, part);
  k_fin<<<4,256,0,stream>>>(part, 2560, 64, (float)PNT, g2, b2, sb);
  k_finish<<<1024,256,0,stream>>>(y, sb, x1, xx);

  // ---- stage 2 ----
  for(int b=0;b<PB;b++){
    k_dist64<<<528,256,0,stream>>>(x1 + (size_t)b*PN*64, xx + b*PN, Dbuf);
    k_topk<<<1024,256,0,stream>>>(Dbuf, idx + (size_t)b*PN*PK);
  }
  k_nodeUV64<<<128,256,0,stream>>>(x1, w3, U, V);
  k_statUV<<<512,256,0,stream>>>(U, V, idx, part);
  k_fin<<<4,256,0,stream>>>(part, 512, 64, (float)PNT, g3, b3, sb);
  k_convAF<<<2560,256,0,stream>>>(U, V, idx, w4, sb, y, part);
  k_fin<<<4,256,0,stream>>>(part, 2560, 64, (float)PNT, g4, b4, sb);
  k_finish<<<1024,256,0,stream>>>(y, sb, x2, xx);

  // ---- stage 3 ----
  for(int b=0;b<PB;b++){
    k_dist64<<<528,256,0,stream>>>(x2 + (size_t)b*PN*64, xx + b*PN, Dbuf);
    k_topk<<<1024,256,0,stream>>>(Dbuf, idx + (size_t)b*PN*PK);
  }
  k_nodeUV64<<<128,256,0,stream>>>(x2, w5, U, V);
  k_statUV<<<512,256,0,stream>>>(U, V, idx, part);
  k_fin<<<4,256,0,stream>>>(part, 512, 64, (float)PNT, g5, b5, sb);
  k_finishUV<<<1024,256,0,stream>>>(U, V, idx, sb, x3);

  // ---- head ----
  k_gemm6<<<1024,256,0,stream>>>(x1, x2, x3, w6, y, part);
  k_fin<<<64,256,0,stream>>>(part, 128, 1024, 16384.f, g6, b6, sb);
  k_gmax<<<256,256,0,stream>>>(y, sb, gpart);
  k_gmaxfin<<<4,256,0,stream>>>(gpart, g);
  k_final<<<8,256,0,stream>>>(g, wl, g7, b7, out);
}

// Round 13
// 1074.847 us; speedup vs baseline: 6.5101x; 1.0035x over previous
//
#include <hip/hip_runtime.h>

static constexpr int PB  = 4;
static constexpr int PN  = 4096;
static constexpr int PK  = 20;
static constexpr int PNT = PB*PN*PK;   // 327680
#define NEGF (-3.402823466e38f)

__device__ __forceinline__ float lrelu_f(float x){ return x >= 0.f ? x : 0.2f*x; }

typedef __attribute__((ext_vector_type(8))) short short8v;
typedef __attribute__((ext_vector_type(4))) float f32x4;

__device__ __forceinline__ unsigned short f2bf(float f){
  unsigned u = __float_as_uint(f);
  unsigned r = u + 0x7FFFu + ((u>>16)&1u);
  return (unsigned short)(r>>16);
}
__device__ __forceinline__ float bf2f(unsigned short s){ return __uint_as_float(((unsigned)s)<<16); }

#define FMA4C(accv, av, bv) { accv = fmaf((av).x,(bv).x,accv); accv = fmaf((av).y,(bv).y,accv); \
                              accv = fmaf((av).z,(bv).z,accv); accv = fmaf((av).w,(bv).w,accv); }

// ---------------- fused stage-1 kNN: padded LDS (stride 65), cooperative group rebuild ----------------
__global__ __launch_bounds__(512) void k_knn3(const float* __restrict__ x, int* __restrict__ idxb){
  extern __shared__ float4 pts[];                 // 4160 float4 = 66560 B; phys(i) = i + (i>>6)
  int t = threadIdx.x;
  int b = blockIdx.y;
  const float* xb = x + (size_t)b*3*PN;
  for(int i=t;i<PN;i+=512){
    float a0 = xb[i], a1 = xb[PN+i], a2 = xb[2*PN+i];
    float s = a0*a0; s = fmaf(a1,a1,s); s = fmaf(a2,a2,s);
    pts[i + (i>>6)] = make_float4(a0,a1,a2,s);
  }
  __syncthreads();
  int lane = t & 63, w = t >> 6;
  int row = blockIdx.x*8 + w;
  float4 pi = pts[row + (row>>6)];
  unsigned long long removed = 0ull;

#define KDIST(E) ({ float4 pj_ = pts[lane + 65*(E)]; \
    float dt_ = pi.x*pj_.x; dt_ = fmaf(pi.y,pj_.y,dt_); dt_ = fmaf(pi.z,pj_.z,dt_); \
    fmaf(2.f,dt_,-pi.w) - pj_.w; })

  float gv0,gv1,gv2,gv3,gv4,gv5,gv6,gv7;
  int   gi0,gi1,gi2,gi3,gi4,gi5,gi6,gi7;
#define KBUILDG(G) { float gm_=NEGF; int ge_=(G)*8; \
    _Pragma("unroll") for(int e_=(G)*8; e_<(G)*8+8; e_++){ \
      bool ok_ = ((removed >> e_) & 1ull) == 0ull; \
      float d_ = KDIST(e_); \
      bool bt_ = ok_ && (d_ > gm_); gm_ = bt_ ? d_ : gm_; ge_ = bt_ ? e_ : ge_; } \
    gv##G = gm_; gi##G = ge_; }
  KBUILDG(0) KBUILDG(1) KBUILDG(2) KBUILDG(3) KBUILDG(4) KBUILDG(5) KBUILDG(6) KBUILDG(7)

  float lmax; int le;
#define KLBEST { lmax = gv0; le = gi0; \
    if(gv1>lmax){lmax=gv1;le=gi1;} if(gv2>lmax){lmax=gv2;le=gi2;} \
    if(gv3>lmax){lmax=gv3;le=gi3;} if(gv4>lmax){lmax=gv4;le=gi4;} \
    if(gv5>lmax){lmax=gv5;le=gi5;} if(gv6>lmax){lmax=gv6;le=gi6;} \
    if(gv7>lmax){lmax=gv7;le=gi7;} }
  KLBEST

  int myidx = 0;
  for(int k=0;k<PK;k++){
    float g = lmax;
    #pragma unroll
    for(int s=32;s>=1;s>>=1) g = fmaxf(g, __shfl_xor(g, s));
    unsigned long long cand = __ballot(lmax == g);
    int jw;
    if(__popcll(cand) == 1){
      int wl = __ffsll(cand) - 1;
      int e  = __shfl(le, wl);
      jw = wl + (e<<6);
    } else {
      unsigned jj = (lmax == g) ? (unsigned)(lane + (le<<6)) : 0xFFFFFFFFu;
      #pragma unroll
      for(int s=32;s>=1;s>>=1){ unsigned o = __shfl_xor(jj, s); jj = (o < jj) ? o : jj; }
      jw = (int)jj;
    }
    if(lane == k) myidx = jw;
    int WL = jw & 63, eW = jw >> 6, gW = eW >> 3;
    unsigned long long remW = __shfl(removed, WL) | (1ull << eW);
    if(lane == WL) removed = remW;
    // cooperative rescan of winner's group (8-lane octets; stride-65 layout -> banks 4e%32, no conflict)
    int e_ = (gW<<3) + (lane & 7);
    float4 pj = pts[WL + 65*e_];
    float dt = pi.x*pj.x; dt = fmaf(pi.y,pj.y,dt); dt = fmaf(pi.z,pj.z,dt);
    float d_ = fmaf(2.f,dt,-pi.w) - pj.w;
    bool ok = ((remW >> e_) & 1ull) == 0ull;
    float dd = ok ? d_ : NEGF;
    int   de = e_;
    #pragma unroll
    for(int s=1;s<8;s<<=1){
      float od = __shfl_xor(dd, s); int oe = __shfl_xor(de, s);
      if(od > dd || (od == dd && oe < de)){ dd = od; de = oe; }
    }
    if(lane == WL){
      int q = gW;
      if(q==0){ gv0=dd; gi0=de; } else if(q==1){ gv1=dd; gi1=de; }
      else if(q==2){ gv2=dd; gi2=de; } else if(q==3){ gv3=dd; gi3=de; }
      else if(q==4){ gv4=dd; gi4=de; } else if(q==5){ gv5=dd; gi5=de; }
      else if(q==6){ gv6=dd; gi6=de; } else { gv7=dd; gi7=de; }
      KLBEST
    }
  }
  if(lane < PK) idxb[((size_t)b*PN + row)*PK + lane] = myidx;
#undef KDIST
#undef KBUILDG
#undef KLBEST
}

// ---------------- dist64: symmetric tiled GEMM, K split in 2 (33 KB LDS, 4 blocks/CU) ----------------
__global__ __launch_bounds__(256) void k_dist64(const float* __restrict__ Xb, const float* __restrict__ xxb,
                                                float* __restrict__ D){
  __shared__ float Xi[128*32];
  __shared__ float Xj[128*32];
  __shared__ float xxi[128], xxj[128];
  int t = threadIdx.x;
  int p = blockIdx.x;
  int bi = (int)((65.0f - sqrtf(4225.0f - 8.0f*(float)p)) * 0.5f);
  while((bi+1)*32 - ((bi+1)*bi)/2 <= p) bi++;
  while(bi*32 - (bi*(bi-1))/2 > p) bi--;
  int bj = bi + (p - (bi*32 - (bi*(bi-1))/2));
  int i0 = bi*128, j0 = bj*128;
  int prg = t>>4, cq = t&15;
  float acc[8][8];
  #pragma unroll
  for(int pp=0;pp<8;pp++)
    #pragma unroll
    for(int oc=0;oc<8;oc++) acc[pp][oc] = 0.f;

  for(int h=0;h<2;h++){
    if(h) __syncthreads();
    #pragma unroll
    for(int k=0;k<4;k++){
      int fid = t + k*256; int row = fid>>3, c4 = fid&7;
      ((float4*)Xi)[row*8 + (c4^(row&7))] = ((const float4*)(Xb + (size_t)(i0+row)*64 + h*32))[c4];
      ((float4*)Xj)[row*8 + (c4^(row&7))] = ((const float4*)(Xb + (size_t)(j0+row)*64 + h*32))[c4];
    }
    if(h==0){
      if(t < 128) xxi[t] = xxb[i0+t];
      else        xxj[t-128] = xxb[j0+t-128];
    }
    __syncthreads();
    #pragma unroll 4
    for(int c4=0;c4<8;c4++){
      float4 a[8], bb[8];
      #pragma unroll
      for(int pp=0;pp<8;pp++){ int row = prg*8+pp; a[pp] = ((const float4*)Xi)[row*8 + (c4^(row&7))]; }
      #pragma unroll
      for(int oc=0;oc<8;oc++){ int col = cq+16*oc;  bb[oc] = ((const float4*)Xj)[col*8 + (c4^(col&7))]; }
      #pragma unroll
      for(int pp=0;pp<8;pp++)
        #pragma unroll
        for(int oc=0;oc<8;oc++) FMA4C(acc[pp][oc], a[pp], bb[oc]);
    }
  }
  #pragma unroll
  for(int pp=0;pp<8;pp++){
    int r = prg*8+pp;
    float xi2 = xxi[r];
    float* Drow = D + (size_t)(i0+r)*PN + j0;
    #pragma unroll
    for(int oc=0;oc<8;oc++){
      int c = cq + 16*oc;
      Drow[c] = fmaf(2.f, acc[pp][oc], -xi2) - xxj[c];
    }
  }
  if(bi != bj){
    #pragma unroll
    for(int oc=0;oc<8;oc++){
      int c = cq + 16*oc;
      float xj2 = xxj[c];
      float* Dcol = D + (size_t)(j0+c)*PN + i0 + prg*8;
      float4 t0, t1;
      t0.x = fmaf(2.f, acc[0][oc], -xj2) - xxi[prg*8+0];
      t0.y = fmaf(2.f, acc[1][oc], -xj2) - xxi[prg*8+1];
      t0.z = fmaf(2.f, acc[2][oc], -xj2) - xxi[prg*8+2];
      t0.w = fmaf(2.f, acc[3][oc], -xj2) - xxi[prg*8+3];
      t1.x = fmaf(2.f, acc[4][oc], -xj2) - xxi[prg*8+4];
      t1.y = fmaf(2.f, acc[5][oc], -xj2) - xxi[prg*8+5];
      t1.z = fmaf(2.f, acc[6][oc], -xj2) - xxi[prg*8+6];
      t1.w = fmaf(2.f, acc[7][oc], -xj2) - xxi[prg*8+7];
      ((float4*)Dcol)[0] = t0;
      ((float4*)Dcol)[1] = t1;
    }
  }
}

// ---------------- top-20 per row: one wave per row, poison rebuild ----------------
__global__ __launch_bounds__(256) void k_topk(const float* __restrict__ D, int* __restrict__ idxb){
  int t = threadIdx.x, lane = t & 63, w = t >> 6;
  int row = blockIdx.x*4 + w;
  const float4* rp = (const float4*)(D + (size_t)row*PN + lane*64);
  float v[64];
  #pragma unroll
  for(int c=0;c<16;c++){
    float4 q = rp[c];
    v[4*c+0]=q.x; v[4*c+1]=q.y; v[4*c+2]=q.z; v[4*c+3]=q.w;
  }
  float gv0,gv1,gv2,gv3,gv4,gv5,gv6,gv7;
  int   gi0,gi1,gi2,gi3,gi4,gi5,gi6,gi7;
#define TBUILDG(G) { float gm_=NEGF; int ge_=(G)*8; \
    _Pragma("unroll") for(int e_=(G)*8; e_<(G)*8+8; e_++){ \
      bool bt_ = v[e_] > gm_; gm_ = bt_ ? v[e_] : gm_; ge_ = bt_ ? e_ : ge_; } \
    gv##G = gm_; gi##G = ge_; }
#define TPOIS(G) { _Pragma("unroll") for(int e_=(G)*8; e_<(G)*8+8; e_++){ \
      if(e_ == rel) v[e_] = NEGF; } }
  TBUILDG(0) TBUILDG(1) TBUILDG(2) TBUILDG(3) TBUILDG(4) TBUILDG(5) TBUILDG(6) TBUILDG(7)
  float lmax; int li;
#define TLBEST { lmax = gv0; li = gi0; \
    if(gv1>lmax){lmax=gv1;li=gi1;} if(gv2>lmax){lmax=gv2;li=gi2;} \
    if(gv3>lmax){lmax=gv3;li=gi3;} if(gv4>lmax){lmax=gv4;li=gi4;} \
    if(gv5>lmax){lmax=gv5;li=gi5;} if(gv6>lmax){lmax=gv6;li=gi6;} \
    if(gv7>lmax){lmax=gv7;li=gi7;} }
  TLBEST
  int myidx = 0;
  for(int k=0;k<PK;k++){
    float g = lmax;
    #pragma unroll
    for(int s=32;s>=1;s>>=1) g = fmaxf(g, __shfl_xor(g, s));
    unsigned long long mask = __ballot(lmax == g);
    int wl = __ffsll((unsigned long long)mask) - 1;
    int rel = __shfl(li, wl);
    if(lane == k) myidx = wl*64 + rel;
    if(lane == wl){
      int q = rel >> 3;
      if(q==0){ TPOIS(0) TBUILDG(0) } else if(q==1){ TPOIS(1) TBUILDG(1) }
      else if(q==2){ TPOIS(2) TBUILDG(2) } else if(q==3){ TPOIS(3) TBUILDG(3) }
      else if(q==4){ TPOIS(4) TBUILDG(4) } else if(q==5){ TPOIS(5) TBUILDG(5) }
      else if(q==6){ TPOIS(6) TBUILDG(6) } else { TPOIS(7) TBUILDG(7) }
      TLBEST
    }
  }
  if(lane < PK) idxb[row*PK + lane] = myidx;
#undef TBUILDG
#undef TPOIS
#undef TLBEST
}

// ---------------- nodeUV: per-node partial convs ----------------
__global__ __launch_bounds__(256) void k_nodeUV3(const float* __restrict__ x, const float* __restrict__ w1,
                                                 float* __restrict__ U, float* __restrict__ V){
  __shared__ float ww[384];
  int t = threadIdx.x;
  for(int k=t;k<384;k+=256) ww[k] = w1[k];
  __syncthreads();
  int g = blockIdx.x*256 + t;
  int ng = g >> 6, o = g & 63;
  int b = ng >> 12, n = ng & 4095;
  const float* xb = x + (size_t)b*3*PN;
  float p0 = xb[n], p1 = xb[PN+n], p2 = xb[2*PN+n];
  const float* wr = ww + o*6;
  float u = p0*wr[0]; u = fmaf(p1,wr[1],u); u = fmaf(p2,wr[2],u);
  float vv = p0*(wr[3]-wr[0]); vv = fmaf(p1, wr[4]-wr[1], vv); vv = fmaf(p2, wr[5]-wr[2], vv);
  U[(size_t)ng*64+o] = u;
  V[(size_t)ng*64+o] = vv;
}

__global__ __launch_bounds__(256) void k_nodeUV64(const float* __restrict__ xf, const float* __restrict__ w,
                                                  float* __restrict__ U, float* __restrict__ V){
  __shared__ float xbuf[128*64];
  __shared__ float wbuf[128*64];
  int t = threadIdx.x;
  int r0 = blockIdx.x * 128;
  #pragma unroll
  for(int k=0;k<8;k++){
    int fid = t + k*256; int row = fid>>4, c4 = fid&15;
    ((float4*)xbuf)[row*16 + (c4^(row&15))] = ((const float4*)(xf + (size_t)(r0+row)*64))[c4];
    float4 wv;
    if(row < 64){
      wv = ((const float4*)(w + (size_t)row*128))[c4];
    } else {
      float4 w2v = ((const float4*)(w + (size_t)(row-64)*128 + 64))[c4];
      float4 w1v = ((const float4*)(w + (size_t)(row-64)*128))[c4];
      wv.x = w2v.x-w1v.x; wv.y = w2v.y-w1v.y; wv.z = w2v.z-w1v.z; wv.w = w2v.w-w1v.w;
    }
    ((float4*)wbuf)[row*16 + (c4^(row&15))] = wv;
  }
  __syncthreads();
  int rg = t>>4, cq = t&15;
  float acc[8][8];
  #pragma unroll
  for(int pp=0;pp<8;pp++)
    #pragma unroll
    for(int oc=0;oc<8;oc++) acc[pp][oc] = 0.f;
  #pragma unroll 4
  for(int c4=0;c4<16;c4++){
    float4 a[8], bb[8];
    #pragma unroll
    for(int pp=0;pp<8;pp++){ int row = rg*8+pp; a[pp] = ((const float4*)xbuf)[row*16 + (c4^(row&15))]; }
    #pragma unroll
    for(int oc=0;oc<8;oc++){ int col = cq+16*oc;  bb[oc] = ((const float4*)wbuf)[col*16 + (c4^(col&15))]; }
    #pragma unroll
    for(int pp=0;pp<8;pp++)
      #pragma unroll
      for(int oc=0;oc<8;oc++) FMA4C(acc[pp][oc], a[pp], bb[oc]);
  }
  #pragma unroll
  for(int pp=0;pp<8;pp++){
    int r = r0 + rg*8+pp;
    #pragma unroll
    for(int oc=0;oc<8;oc++){
      int col = cq + 16*oc;
      if(col < 64) U[(size_t)r*64 + col] = acc[pp][oc];
      else         V[(size_t)r*64 + col-64] = acc[pp][oc];
    }
  }
}

// ---------------- BN stats over edges, point-major (V row read once per point) ----------------
__global__ __launch_bounds__(256) void k_statUV(const float* __restrict__ U, const float* __restrict__ V,
                                                const int* __restrict__ idx, float* __restrict__ part){
  __shared__ float4 sArr[256];
  __shared__ float4 qArr[256];
  int t = threadIdx.x; int blk = blockIdx.x;
  int ch4 = t & 15, sub = t >> 4;
  int p0 = blk*32;                               // 32 points = 640 edges
  float4 s = make_float4(0,0,0,0), qq = make_float4(0,0,0,0);
  for(int pp=sub; pp<32; pp+=16){
    int p = p0 + pp;
    int b = p >> 12;
    float4 v4 = ((const float4*)(V + (size_t)p*64))[ch4];
    const int* ip = idx + (size_t)p*PK;
    #pragma unroll 4
    for(int k=0;k<PK;k++){
      int j = ip[k];
      float4 u4 = ((const float4*)(U + (size_t)(b*PN+j)*64))[ch4];
      float4 y4;
      y4.x = u4.x+v4.x; y4.y = u4.y+v4.y; y4.z = u4.z+v4.z; y4.w = u4.w+v4.w;
      s.x += y4.x; s.y += y4.y; s.z += y4.z; s.w += y4.w;
      qq.x = fmaf(y4.x,y4.x,qq.x); qq.y = fmaf(y4.y,y4.y,qq.y);
      qq.z = fmaf(y4.z,y4.z,qq.z); qq.w = fmaf(y4.w,y4.w,qq.w);
    }
  }
  sArr[t] = s; qArr[t] = qq;
  __syncthreads();
  if(t < 16){
    float4 S = make_float4(0,0,0,0), Q = make_float4(0,0,0,0);
    #pragma unroll
    for(int g=0;g<16;g++){
      float4 a = sArr[g*16 + t], b = qArr[g*16 + t];
      S.x+=a.x; S.y+=a.y; S.z+=a.z; S.w+=a.w;
      Q.x+=b.x; Q.y+=b.y; Q.z+=b.z; Q.w+=b.w;
    }
    ((float4*)(part + (size_t)blk*128))[t] = S;
    ((float4*)(part + (size_t)blk*128 + 64))[t] = Q;
  }
}

// ---------------- convA fused (MFMA split-bf16): y := W.lrelu(bn(U[j]+V[n])), + BN stats ----------------
__global__ __launch_bounds__(256) void k_convAF(const float* __restrict__ U, const float* __restrict__ V,
                                                const int* __restrict__ idx, const float* __restrict__ wg,
                                                const float* __restrict__ sb, float* __restrict__ y,
                                                float* __restrict__ part){
  __shared__ short hb[2*128*64];   // 32 KB (hi @0, lo @8192)
  __shared__ short wb[2*64*64];    // 16 KB (hi @0, lo @4096)
  int t = threadIdx.x;
  int q0 = blockIdx.x * 128;
  #pragma unroll
  for(int k=0;k<8;k++){
    int fid = t + k*256; int row = fid>>4, c4 = fid&15;
    int q = q0 + row;
    int pt = q/PK; int b = pt>>12; int j = idx[q];
    float4 uu = ((const float4*)(U + (size_t)(b*PN+j)*64))[c4];
    float4 vv = ((const float4*)(V + (size_t)pt*64))[c4];
    float4 sc = ((const float4*)sb)[c4];
    float4 bi = ((const float4*)(sb+1024))[c4];
    float4 h;
    h.x = lrelu_f(fmaf(uu.x+vv.x, sc.x, bi.x));
    h.y = lrelu_f(fmaf(uu.y+vv.y, sc.y, bi.y));
    h.z = lrelu_f(fmaf(uu.z+vv.z, sc.z, bi.z));
    h.w = lrelu_f(fmaf(uu.w+vv.w, sc.w, bi.w));
    int base = row*64 + ((((c4>>1) ^ (row&7)))<<3) + ((c4&1)<<2);
    short4 hi4, lo4;
    hi4.x = (short)f2bf(h.x); lo4.x = (short)f2bf(h.x - bf2f((unsigned short)hi4.x));
    hi4.y = (short)f2bf(h.y); lo4.y = (short)f2bf(h.y - bf2f((unsigned short)hi4.y));
    hi4.z = (short)f2bf(h.z); lo4.z = (short)f2bf(h.z - bf2f((unsigned short)hi4.z));
    hi4.w = (short)f2bf(h.w); lo4.w = (short)f2bf(h.w - bf2f((unsigned short)hi4.w));
    *(short4*)(hb + base) = hi4;
    *(short4*)(hb + 8192 + base) = lo4;
  }
  #pragma unroll
  for(int k=0;k<4;k++){
    int fid = t + k*256; int row = fid>>4, c4 = fid&15;
    float4 wv = ((const float4*)(wg + (size_t)row*64))[c4];
    int base = row*64 + ((((c4>>1) ^ (row&7)))<<3) + ((c4&1)<<2);
    short4 hi4, lo4;
    hi4.x = (short)f2bf(wv.x); lo4.x = (short)f2bf(wv.x - bf2f((unsigned short)hi4.x));
    hi4.y = (short)f2bf(wv.y); lo4.y = (short)f2bf(wv.y - bf2f((unsigned short)hi4.y));
    hi4.z = (short)f2bf(wv.z); lo4.z = (short)f2bf(wv.z - bf2f((unsigned short)hi4.z));
    hi4.w = (short)f2bf(wv.w); lo4.w = (short)f2bf(wv.w - bf2f((unsigned short)hi4.w));
    *(short4*)(wb + base) = hi4;
    *(short4*)(wb + 4096 + base) = lo4;
  }
  __syncthreads();

  int lane = t & 63, w = t >> 6;
  int r0w = w*32;
  short8v ah[2][2], al[2][2];
  #pragma unroll
  for(int rt=0;rt<2;rt++)
    #pragma unroll
    for(int kc=0;kc<2;kc++){
      int row = r0w + rt*16 + (lane&15);
      int kb  = kc*4 + (lane>>4);
      int off = row*64 + ((kb ^ (row&7))<<3);
      ah[rt][kc] = *(const short8v*)(hb + off);
      al[rt][kc] = *(const short8v*)(hb + 8192 + off);
    }
  short8v bh[4][2], bl[4][2];
  #pragma unroll
  for(int ct=0;ct<4;ct++)
    #pragma unroll
    for(int kc=0;kc<2;kc++){
      int o   = ct*16 + (lane&15);
      int kb  = kc*4 + (lane>>4);
      int off = o*64 + ((kb ^ (o&7))<<3);
      bh[ct][kc] = *(const short8v*)(wb + off);
      bl[ct][kc] = *(const short8v*)(wb + 4096 + off);
    }

  f32x4 acc[2][4];
  #pragma unroll
  for(int rt=0;rt<2;rt++)
    #pragma unroll
    for(int ct=0;ct<4;ct++)
      acc[rt][ct] = (f32x4){0.f,0.f,0.f,0.f};

  #pragma unroll
  for(int rt=0;rt<2;rt++)
    #pragma unroll
    for(int ct=0;ct<4;ct++)
      #pragma unroll
      for(int kc=0;kc<2;kc++){
        acc[rt][ct] = __builtin_amdgcn_mfma_f32_16x16x32_bf16(ah[rt][kc], bh[ct][kc], acc[rt][ct], 0,0,0);
        acc[rt][ct] = __builtin_amdgcn_mfma_f32_16x16x32_bf16(ah[rt][kc], bl[ct][kc], acc[rt][ct], 0,0,0);
        acc[rt][ct] = __builtin_amdgcn_mfma_f32_16x16x32_bf16(al[rt][kc], bh[ct][kc], acc[rt][ct], 0,0,0);
      }

  float s_[4] = {0.f,0.f,0.f,0.f}, q_[4] = {0.f,0.f,0.f,0.f};
  #pragma unroll
  for(int rt=0;rt<2;rt++)
    #pragma unroll
    for(int ct=0;ct<4;ct++){
      int colg = ct*16 + (lane&15);
      #pragma unroll
      for(int reg=0;reg<4;reg++){
        int row = r0w + rt*16 + (lane>>4)*4 + reg;
        float val = acc[rt][ct][reg];
        y[(size_t)(q0 + row)*64 + colg] = val;
        s_[ct] += val; q_[ct] = fmaf(val, val, q_[ct]);
      }
    }

  __syncthreads();                       // frag reads done; reuse wb as scratch (4096 floats)
  float* ls = (float*)wb;
  #pragma unroll
  for(int ct=0;ct<4;ct++){
    int colg = ct*16 + (lane&15);
    ls[colg*16 + (w*4 + (lane>>4))]        = s_[ct];
    ls[2048 + colg*16 + (w*4 + (lane>>4))] = q_[ct];
  }
  __syncthreads();
  if(t < 64){
    float S = 0.f, Q = 0.f;
    #pragma unroll
    for(int g=0;g<16;g++){ S += ls[t*16+g]; Q += ls[2048 + t*16+g]; }
    part[(size_t)blockIdx.x*128 + t] = S;
    part[(size_t)blockIdx.x*128 + 64 + t] = Q;
  }
}

// ---------------- finalize BN affine ----------------
__global__ __launch_bounds__(256) void k_fin(const float* __restrict__ part, int nparts, int chn, float cnt,
                                             const float* __restrict__ gamma, const float* __restrict__ beta,
                                             float* __restrict__ sb){
  __shared__ float ls[512];
  int t = threadIdx.x;
  int chl = t & 15, sub = t >> 4;
  int ch = blockIdx.x*16 + chl;
  float S = 0.f, Q = 0.f;
  for(int p=sub; p<nparts; p+=16){
    S += part[(size_t)p*2*chn + ch];
    Q += part[(size_t)p*2*chn + chn + ch];
  }
  ls[t] = S; ls[256+t] = Q;
  __syncthreads();
  if(t < 16){
    float Sa = 0.f, Qa = 0.f;
    #pragma unroll
    for(int s=0;s<16;s++){ Sa += ls[s*16+t]; Qa += ls[256+s*16+t]; }
    int c = blockIdx.x*16 + t;
    float m  = Sa/cnt;
    float vr = Qa/cnt - m*m;
    float sc = gamma[c] * rsqrtf(vr + 1e-5f);
    sb[c] = sc; sb[1024+c] = beta[c] - m*sc;
  }
}

// ---------------- finish: x = max_k lrelu(bn(y)), + fused xx for next stage ----------------
__global__ __launch_bounds__(256) void k_finish(const float* __restrict__ y, const float* __restrict__ sb,
                                                float* __restrict__ xo, float* __restrict__ xxo){
  __shared__ float ls[256];
  int t = threadIdx.x;
  int pt = blockIdx.x*16 + (t>>4), c4 = t&15;
  const float4* base = (const float4*)(y + (size_t)pt*20*64);
  float4 sc = ((const float4*)sb)[c4];
  float4 bi = ((const float4*)(sb+1024))[c4];
  float4 m = make_float4(NEGF,NEGF,NEGF,NEGF);
  #pragma unroll 4
  for(int k=0;k<20;k++){
    float4 v = base[k*16 + c4];
    v.x = lrelu_f(fmaf(v.x, sc.x, bi.x)); v.y = lrelu_f(fmaf(v.y, sc.y, bi.y));
    v.z = lrelu_f(fmaf(v.z, sc.z, bi.z)); v.w = lrelu_f(fmaf(v.w, sc.w, bi.w));
    m.x = fmaxf(m.x,v.x); m.y = fmaxf(m.y,v.y); m.z = fmaxf(m.z,v.z); m.w = fmaxf(m.w,v.w);
  }
  ((float4*)(xo + (size_t)pt*64))[c4] = m;
  float ss = m.x*m.x; ss = fmaf(m.y,m.y,ss); ss = fmaf(m.z,m.z,ss); ss = fmaf(m.w,m.w,ss);
  ls[t] = ss;
  __syncthreads();
  if(c4 == 0){
    float S = 0.f;
    #pragma unroll
    for(int c=0;c<16;c++) S += ls[(t & 0xF0) + c];
    xxo[pt] = S;
  }
}

// ---------------- finishUV: x = max_k lrelu(bn(U[j]+V[n])) ----------------
__global__ __launch_bounds__(256) void k_finishUV(const float* __restrict__ U, const float* __restrict__ V,
                                                  const int* __restrict__ idx, const float* __restrict__ sb,
                                                  float* __restrict__ xo){
  int t = threadIdx.x;
  int pt = blockIdx.x*16 + (t>>4), c4 = t&15;
  int b = pt >> 12;
  float4 sc = ((const float4*)sb)[c4];
  float4 bi = ((const float4*)(sb+1024))[c4];
  float4 vv = ((const float4*)(V + (size_t)pt*64))[c4];
  float4 m = make_float4(NEGF,NEGF,NEGF,NEGF);
  const int* ip = idx + (size_t)pt*PK;
  #pragma unroll 4
  for(int k=0;k<PK;k++){
    int j = ip[k];
    float4 uu = ((const float4*)(U + (size_t)(b*PN+j)*64))[c4];
    float4 v;
    v.x = lrelu_f(fmaf(uu.x+vv.x, sc.x, bi.x)); v.y = lrelu_f(fmaf(uu.y+vv.y, sc.y, bi.y));
    v.z = lrelu_f(fmaf(uu.z+vv.z, sc.z, bi.z)); v.w = lrelu_f(fmaf(uu.w+vv.w, sc.w, bi.w));
    m.x = fmaxf(m.x,v.x); m.y = fmaxf(m.y,v.y); m.z = fmaxf(m.z,v.z); m.w = fmaxf(m.w,v.w);
  }
  ((float4*)(xo + (size_t)pt*64))[c4] = m;
}

// ---------------- head GEMM (MFMA split-bf16): y6 = cat(x1,x2,x3) @ w6^T, + fused BN stats ----------------
__global__ __launch_bounds__(256) void k_gemm6(const float* __restrict__ x1, const float* __restrict__ x2,
                                               const float* __restrict__ x3, const float* __restrict__ w6,
                                               float* __restrict__ y6, float* __restrict__ part){
  __shared__ short cb[2*128*64];   // 32 KB hi@0 lo@8192
  __shared__ short wb[2*128*64];   // 32 KB hi@0 lo@8192
  int t = threadIdx.x;
  int rb = blockIdx.x >> 3, ob = blockIdx.x & 7;
  size_t r0 = (size_t)rb*128; int o0 = ob*128;
  int lane = t & 63, w = t >> 6;
  int r0w = w*32;
  f32x4 acc[2][8];
  #pragma unroll
  for(int rt=0;rt<2;rt++)
    #pragma unroll
    for(int ct=0;ct<8;ct++)
      acc[rt][ct] = (f32x4){0.f,0.f,0.f,0.f};
  const float* srcs[3] = {x1, x2, x3};
  for(int ph=0; ph<3; ph++){
    __syncthreads();
    const float* src = srcs[ph];
    #pragma unroll
    for(int k=0;k<8;k++){
      int fid = t + k*256; int row = fid>>4, c4 = fid&15;
      float4 av = ((const float4*)(src + (r0+row)*64))[c4];
      float4 wv = *(const float4*)(w6 + (size_t)(o0+row)*192 + ph*64 + c4*4);
      int base = row*64 + ((((c4>>1) ^ (row&7)))<<3) + ((c4&1)<<2);
      short4 hi4, lo4;
      hi4.x = (short)f2bf(av.x); lo4.x = (short)f2bf(av.x - bf2f((unsigned short)hi4.x));
      hi4.y = (short)f2bf(av.y); lo4.y = (short)f2bf(av.y - bf2f((unsigned short)hi4.y));
      hi4.z = (short)f2bf(av.z); lo4.z = (short)f2bf(av.z - bf2f((unsigned short)hi4.z));
      hi4.w = (short)f2bf(av.w); lo4.w = (short)f2bf(av.w - bf2f((unsigned short)hi4.w));
      *(short4*)(cb + base) = hi4;
      *(short4*)(cb + 8192 + base) = lo4;
      hi4.x = (short)f2bf(wv.x); lo4.x = (short)f2bf(wv.x - bf2f((unsigned short)hi4.x));
      hi4.y = (short)f2bf(wv.y); lo4.y = (short)f2bf(wv.y - bf2f((unsigned short)hi4.y));
      hi4.z = (short)f2bf(wv.z); lo4.z = (short)f2bf(wv.z - bf2f((unsigned short)hi4.z));
      hi4.w = (short)f2bf(wv.w); lo4.w = (short)f2bf(wv.w - bf2f((unsigned short)hi4.w));
      *(short4*)(wb + base) = hi4;
      *(short4*)(wb + 8192 + base) = lo4;
    }
    __syncthreads();
    short8v ah[2][2], al[2][2];
    #pragma unroll
    for(int rt=0;rt<2;rt++)
      #pragma unroll
      for(int kc=0;kc<2;kc++){
        int row = r0w + rt*16 + (lane&15);
        int kb  = kc*4 + (lane>>4);
        int off = row*64 + ((kb ^ (row&7))<<3);
        ah[rt][kc] = *(const short8v*)(cb + off);
        al[rt][kc] = *(const short8v*)(cb + 8192 + off);
      }
    #pragma unroll
    for(int ct=0;ct<8;ct++){
      short8v bh[2], bl[2];
      #pragma unroll
      for(int kc=0;kc<2;kc++){
        int o   = ct*16 + (lane&15);
        int kb  = kc*4 + (lane>>4);
        int off = o*64 + ((kb ^ (o&7))<<3);
        bh[kc] = *(const short8v*)(wb + off);
        bl[kc] = *(const short8v*)(wb + 8192 + off);
      }
      #pragma unroll
      for(int rt=0;rt<2;rt++)
        #pragma unroll
        for(int kc=0;kc<2;kc++){
          acc[rt][ct] = __builtin_amdgcn_mfma_f32_16x16x32_bf16(ah[rt][kc], bh[kc], acc[rt][ct], 0,0,0);
          acc[rt][ct] = __builtin_amdgcn_mfma_f32_16x16x32_bf16(ah[rt][kc], bl[kc], acc[rt][ct], 0,0,0);
          acc[rt][ct] = __builtin_amdgcn_mfma_f32_16x16x32_bf16(al[rt][kc], bh[kc], acc[rt][ct], 0,0,0);
        }
    }
  }
  float s_[8] = {0,0,0,0,0,0,0,0}, q_[8] = {0,0,0,0,0,0,0,0};
  #pragma unroll
  for(int rt=0;rt<2;rt++)
    #pragma unroll
    for(int ct=0;ct<8;ct++){
      int colg = ct*16 + (lane&15);
      #pragma unroll
      for(int reg=0;reg<4;reg++){
        int row = r0w + rt*16 + (lane>>4)*4 + reg;
        float val = acc[rt][ct][reg];
        y6[(r0 + row)*1024 + o0 + colg] = val;
        s_[ct] += val; q_[ct] = fmaf(val, val, q_[ct]);
      }
    }
  __syncthreads();
  float* ls = (float*)wb;                 // 4096 floats scratch
  #pragma unroll
  for(int ct=0;ct<8;ct++){
    int colg = ct*16 + (lane&15);
    ls[colg*16 + (w*4 + (lane>>4))]        = s_[ct];
    ls[2048 + colg*16 + (w*4 + (lane>>4))] = q_[ct];
  }
  __syncthreads();
  if(t < 128){
    float S = 0.f, Q = 0.f;
    #pragma unroll
    for(int g=0;g<16;g++){ S += ls[t*16+g]; Q += ls[2048 + t*16+g]; }
    part[(size_t)rb*2048 + ob*128 + t] = S;
    part[(size_t)rb*2048 + 1024 + ob*128 + t] = Q;
  }
}

// ---------------- global max over n (bn6+lrelu applied), 256 blocks x 64 rows ----------------
__global__ __launch_bounds__(256) void k_gmax(const float* __restrict__ y6, const float* __restrict__ sb,
                                              float* __restrict__ gpart){
  int t = threadIdx.x; int blk = blockIdx.x;   // 256 blocks x 64 rows
  const float4* base = (const float4*)(y6 + (size_t)blk*64*1024);
  float4 sc = ((const float4*)sb)[t];
  float4 bi = ((const float4*)(sb+1024))[t];
  float4 m = make_float4(NEGF,NEGF,NEGF,NEGF);
  for(int r=0;r<64;r++){
    float4 v = base[r*256 + t];
    v.x = lrelu_f(fmaf(v.x, sc.x, bi.x)); v.y = lrelu_f(fmaf(v.y, sc.y, bi.y));
    v.z = lrelu_f(fmaf(v.z, sc.z, bi.z)); v.w = lrelu_f(fmaf(v.w, sc.w, bi.w));
    m.x = fmaxf(m.x,v.x); m.y = fmaxf(m.y,v.y); m.z = fmaxf(m.z,v.z); m.w = fmaxf(m.w,v.w);
  }
  ((float4*)(gpart + (size_t)blk*1024))[t] = m;
}

__global__ __launch_bounds__(256) void k_gmaxfin(const float* __restrict__ gpart, float* __restrict__ g){
  int b = blockIdx.x, t = threadIdx.x;
  float4 m = make_float4(NEGF,NEGF,NEGF,NEGF);
  for(int c=0;c<64;c++){
    float4 v = ((const float4*)(gpart + ((size_t)b*64 + c)*1024))[t];
    m.x = fmaxf(m.x,v.x); m.y = fmaxf(m.y,v.y); m.z = fmaxf(m.z,v.z); m.w = fmaxf(m.w,v.w);
  }
  ((float4*)(g + (size_t)b*1024))[t] = m;
}

// ---------------- final: bn(g @ wl^T, axis 0) ----------------
__global__ __launch_bounds__(256) void k_final(const float* __restrict__ g, const float* __restrict__ wl,
                                               const float* __restrict__ g7, const float* __restrict__ b7,
                                               float* __restrict__ out){
  int gt = blockIdx.x*256 + threadIdx.x;   // 2048 = 512 o x 4 b
  int o = gt >> 2, b = gt & 3;
  const float4* gb = (const float4*)(g + (size_t)b*1024);
  const float4* wr = (const float4*)(wl + (size_t)o*1024);
  float acc = 0.f;
  #pragma unroll 4
  for(int c=0;c<256;c++){
    float4 a = gb[c], w = wr[c];
    acc = fmaf(a.x,w.x,acc); acc = fmaf(a.y,w.y,acc);
    acc = fmaf(a.z,w.z,acc); acc = fmaf(a.w,w.w,acc);
  }
  float s = acc + __shfl_xor(acc, 1);
  s = s + __shfl_xor(s, 2);
  float m = s * 0.25f;
  float d = acc - m;
  float vv = d*d;
  float v2 = vv + __shfl_xor(vv, 1);
  v2 = v2 + __shfl_xor(v2, 2);
  float var = v2 * 0.25f;
  out[b*512 + o] = d * rsqrtf(var + 1e-5f) * g7[o] + b7[o];
}

// ---------------- launch ----------------
extern "C" void kernel_launch(void* const* d_in, const int* in_sizes, int n_in,
                              void* d_out, int out_size, void* d_ws, size_t ws_size,
                              hipStream_t stream){
  const float* x  = (const float*)d_in[0];
  const float* w1 = (const float*)d_in[1];
  const float* w2 = (const float*)d_in[2];
  const float* w3 = (const float*)d_in[3];
  const float* w4 = (const float*)d_in[4];
  const float* w5 = (const float*)d_in[5];
  const float* w6 = (const float*)d_in[6];
  const float* wl = (const float*)d_in[7];
  const float* g1 = (const float*)d_in[8];  const float* b1 = (const float*)d_in[9];
  const float* g2 = (const float*)d_in[10]; const float* b2 = (const float*)d_in[11];
  const float* g3 = (const float*)d_in[12]; const float* b3 = (const float*)d_in[13];
  const float* g4 = (const float*)d_in[14]; const float* b4 = (const float*)d_in[15];
  const float* g5 = (const float*)d_in[16]; const float* b5 = (const float*)d_in[17];
  const float* g6 = (const float*)d_in[18]; const float* b6 = (const float*)d_in[19];
  const float* g7 = (const float*)d_in[20]; const float* b7 = (const float*)d_in[21];
  float* out = (float*)d_out;

  // workspace layout (floats); ~108.7 MB total
  float* ws    = (float*)d_ws;
  float* xx    = ws;                        // 16384
  int*   idx   = (int*)(ws + 16384);        // 327680
  float* y     = ws + 344064;               // 20971520 (y2/y4, y6)
  float* Dbuf  = y;                         // 16777216 (per-batch dist; y dead then)
  float* x1    = ws + 21315584;             // 1048576
  float* x2    = x1 + 1048576;
  float* x3    = x2 + 1048576;
  float* part  = x3 + 1048576;              // 327680 (max: convAF 2560 blocks x 128)
  float* sb    = part + 327680;             // 2048
  float* gpart = sb + 2048;                 // 262144 (256 blocks x 1024)
  float* g     = gpart + 262144;            // 4096
  float* U     = g + 4096;                  // 1048576
  float* V     = U + 1048576;               // 1048576

  hipFuncSetAttribute(reinterpret_cast<const void*>(&k_knn3),
                      hipFuncAttributeMaxDynamicSharedMemorySize, 66560);

  // ---- stage 1 ----
  k_knn3<<<dim3(512,4),512,66560,stream>>>(x, idx);
  k_nodeUV3<<<4096,256,0,stream>>>(x, w1, U, V);
  k_statUV<<<512,256,0,stream>>>(U, V, idx, part);
  k_fin<<<4,256,0,stream>>>(part, 512, 64, (float)PNT, g1, b1, sb);
  k_convAF<<<2560,256,0,stream>>>(U, V, idx, w2, sb, y, part);
  k_fin<<<4,256,0,stream>>>(part, 2560, 64, (float)PNT, g2, b2, sb);
  k_finish<<<1024,256,0,stream>>>(y, sb, x1, xx);

  // ---- stage 2 ----
  for(int b=0;b<PB;b++){
    k_dist64<<<528,256,0,stream>>>(x1 + (size_t)b*PN*64, xx + b*PN, Dbuf);
    k_topk<<<1024,256,0,stream>>>(Dbuf, idx + (size_t)b*PN*PK);
  }
  k_nodeUV64<<<128,256,0,stream>>>(x1, w3, U, V);
  k_statUV<<<512,256,0,stream>>>(U, V, idx, part);
  k_fin<<<4,256,0,stream>>>(part, 512, 64, (float)PNT, g3, b3, sb);
  k_convAF<<<2560,256,0,stream>>>(U, V, idx, w4, sb, y, part);
  k_fin<<<4,256,0,stream>>>(part, 2560, 64, (float)PNT, g4, b4, sb);
  k_finish<<<1024,256,0,stream>>>(y, sb, x2, xx);

  // ---- stage 3 ----
  for(int b=0;b<PB;b++){
    k_dist64<<<528,256,0,stream>>>(x2 + (size_t)b*PN*64, xx + b*PN, Dbuf);
    k_topk<<<1024,256,0,stream>>>(Dbuf, idx + (size_t)b*PN*PK);
  }
  k_nodeUV64<<<128,256,0,stream>>>(x2, w5, U, V);
  k_statUV<<<512,256,0,stream>>>(U, V, idx, part);
  k_fin<<<4,256,0,stream>>>(part, 512, 64, (float)PNT, g5, b5, sb);
  k_finishUV<<<1024,256,0,stream>>>(U, V, idx, sb, x3);

  // ---- head ----
  k_gemm6<<<1024,256,0,stream>>>(x1, x2, x3, w6, y, part);
  k_fin<<<64,256,0,stream>>>(part, 128, 1024, 16384.f, g6, b6, sb);
  k_gmax<<<256,256,0,stream>>>(y, sb, gpart);
  k_gmaxfin<<<4,256,0,stream>>>(gpart, g);
  k_final<<<8,256,0,stream>>>(g, wl, g7, b7, out);
}